// Round 1
// baseline (3935.379 us; speedup 1.0000x reference)
//
#include <hip/hip_runtime.h>
#include <math.h>

// Problem constants (fixed shapes from setup_inputs)
constexpr int Bc = 4;      // batch
constexpr int Nc = 784;    // tokens
constexpr int Cc = 512;    // enc channels
constexpr int Tc = 8;      // time
constexpr int Dc = 128;    // proj dim
constexpr int Mc = 785;    // N+1
constexpr int TM1 = 7;     // T-1
constexpr float TEMP = 0.07f;

// ---------------- reduction helpers (256-thread blocks, 4 waves) ----------------
__device__ __forceinline__ float blockReduceSum(float v, float* sbuf) {
    #pragma unroll
    for (int off = 32; off; off >>= 1) v += __shfl_down(v, off, 64);
    __syncthreads();
    if ((threadIdx.x & 63) == 0) sbuf[threadIdx.x >> 6] = v;
    __syncthreads();
    return sbuf[0] + sbuf[1] + sbuf[2] + sbuf[3];
}
__device__ __forceinline__ float blockReduceMax(float v, float* sbuf) {
    #pragma unroll
    for (int off = 32; off; off >>= 1) v = fmaxf(v, __shfl_down(v, off, 64));
    __syncthreads();
    if ((threadIdx.x & 63) == 0) sbuf[threadIdx.x >> 6] = v;
    __syncthreads();
    return fmaxf(fmaxf(sbuf[0], sbuf[1]), fmaxf(sbuf[2], sbuf[3]));
}

// ---------------- K1: projection + bias + l2norm (feats and dust) ----------------
// grid: Bc*Nc + Bc blocks, 256 threads
__global__ __launch_bounds__(256) void k_project(
    const float* __restrict__ feats, const float* __restrict__ dust,
    const float* __restrict__ Wself, const float* __restrict__ bself,
    const float* __restrict__ Wdust, const float* __restrict__ bdust,
    float* __restrict__ qT, float* __restrict__ qout)
{
    __shared__ float smem[Cc * Tc];   // 4096 floats: staging then fbuf
    __shared__ float nbuf[Tc];
    int bid = blockIdx.x;
    bool isDust = (bid >= Bc * Nc);
    int b, n;
    const float *src, *W, *bias;
    if (!isDust) {
        b = bid / Nc; n = bid % Nc;
        src = feats + (size_t)(b * Nc + n) * Cc * Tc;
        W = Wself; bias = bself;
    } else {
        b = bid - Bc * Nc; n = Nc;   // dust goes to m = 784
        src = dust + (size_t)b * Cc * Tc;
        W = Wdust; bias = bdust;
    }
    int tid = threadIdx.x;
    for (int i = tid; i < Cc * Tc; i += 256) smem[i] = src[i];
    __syncthreads();

    int d = tid & (Dc - 1);
    int tg = tid >> 7;            // 0/1 -> handles t = tg, tg+2, tg+4, tg+6
    float acc[4] = {0.f, 0.f, 0.f, 0.f};
    for (int c = 0; c < Cc; ++c) {
        float wv = W[c * Dc + d];
        #pragma unroll
        for (int k = 0; k < 4; ++k) acc[k] += smem[c * Tc + (tg + 2 * k)] * wv;
    }
    float bv = bias[d];
    #pragma unroll
    for (int k = 0; k < 4; ++k) acc[k] += bv;
    __syncthreads();
    // fbuf[t][d] reuses smem
    #pragma unroll
    for (int k = 0; k < 4; ++k) smem[(tg + 2 * k) * Dc + d] = acc[k];
    __syncthreads();
    // per-t l2 norm: group g (32 lanes) handles t = g
    int g = tid >> 5, l = tid & 31;
    float p = 0.f;
    #pragma unroll
    for (int dd0 = 0; dd0 < Dc; dd0 += 32) { float v = smem[g * Dc + dd0 + l]; p += v * v; }
    #pragma unroll
    for (int off = 16; off; off >>= 1) p += __shfl_down(p, off, 32);
    if (l == 0) nbuf[g] = fmaxf(sqrtf(p), 1e-12f);
    __syncthreads();
    #pragma unroll
    for (int k = 0; k < 4; ++k) {
        int t = tg + 2 * k;
        float v = acc[k] / nbuf[t];
        qT[(((size_t)b * Tc + t) * Mc + n) * Dc + d] = v;
        qout[(((size_t)b * Dc + d) * Tc + t) * Mc + n] = v;
    }
}

// ---------------- K2: Gram G[b,tau] = Q_tau (784xD) @ Q_{tau+1}^T, into A12 core ----------------
// grid (13,13,28), 256 threads; output row stride Mc
__global__ __launch_bounds__(256) void k_gram(const float* __restrict__ qT, float* __restrict__ A12)
{
    int bt = blockIdx.z;
    int b = bt / TM1, tau = bt % TM1;
    const float* Q1 = qT + (size_t)(b * Tc + tau) * Mc * Dc;
    const float* Q2 = qT + (size_t)(b * Tc + tau + 1) * Mc * Dc;
    float* Cm = A12 + (size_t)bt * Mc * Mc;
    __shared__ float a_s[16][65];
    __shared__ float b_s[16][65];
    int tx = threadIdx.x & 15, ty = threadIdx.x >> 4;
    int i0 = blockIdx.y * 64, j0 = blockIdx.x * 64;
    float acc[4][4] = {};
    for (int k0 = 0; k0 < Dc; k0 += 16) {
        int k = threadIdx.x & 15;
        #pragma unroll
        for (int r = 0; r < 4; ++r) {
            int i = (threadIdx.x >> 4) + r * 16;
            float va = 0.f, vb = 0.f;
            if (i0 + i < Nc) va = Q1[(size_t)(i0 + i) * Dc + k0 + k];
            if (j0 + i < Nc) vb = Q2[(size_t)(j0 + i) * Dc + k0 + k];
            a_s[k][i] = va;
            b_s[k][i] = vb;
        }
        __syncthreads();
        #pragma unroll
        for (int kk = 0; kk < 16; ++kk) {
            float ra[4], rb[4];
            #pragma unroll
            for (int ii = 0; ii < 4; ++ii) ra[ii] = a_s[kk][ty * 4 + ii];
            #pragma unroll
            for (int jj = 0; jj < 4; ++jj) rb[jj] = b_s[kk][tx * 4 + jj];
            #pragma unroll
            for (int ii = 0; ii < 4; ++ii)
                #pragma unroll
                for (int jj = 0; jj < 4; ++jj) acc[ii][jj] += ra[ii] * rb[jj];
        }
        __syncthreads();
    }
    #pragma unroll
    for (int ii = 0; ii < 4; ++ii) {
        int i = i0 + ty * 4 + ii;
        if (i >= Nc) continue;
        #pragma unroll
        for (int jj = 0; jj < 4; ++jj) {
            int j = j0 + tx * 4 + jj;
            if (j < Nc) Cm[(size_t)i * Mc + j] = acc[ii][jj];
        }
    }
}

// ---------------- K3: transpose cores: A21[b][t] = A12[b][6-t]^T ----------------
// grid (25,25,28), 256 threads (32x8)
__global__ __launch_bounds__(256) void k_transpose(const float* __restrict__ A12, float* __restrict__ A21)
{
    int bt = blockIdx.z;
    int b = bt / TM1, t = bt % TM1;
    const float* S = A12 + (size_t)(b * TM1 + (6 - t)) * Mc * Mc;
    float* Dst = A21 + (size_t)bt * Mc * Mc;
    __shared__ float tile[32][33];
    int x0 = blockIdx.x * 32, y0 = blockIdx.y * 32;
    int tx = threadIdx.x & 31, ty8 = threadIdx.x >> 5;
    for (int y = ty8; y < 32; y += 8) {
        float v = 0.f;
        if (y0 + y < Nc && x0 + tx < Nc) v = S[(size_t)(y0 + y) * Mc + x0 + tx];
        tile[y][tx] = v;
    }
    __syncthreads();
    for (int r = ty8; r < 32; r += 8) {
        if (x0 + r < Nc && y0 + tx < Nc) Dst[(size_t)(x0 + r) * Mc + y0 + tx] = tile[tx][r];
    }
}

// ---------------- K4: per-row stats (rowsum + entropy) of a core matrix ----------------
// grid 28*784, 256 threads
__global__ __launch_bounds__(256) void k_rowstats(const float* __restrict__ X,
                                                  float* __restrict__ rs, float* __restrict__ rent)
{
    int row = blockIdx.x;
    int bt = row / Nc, i = row % Nc;
    const float* r = X + ((size_t)bt * Mc + i) * Mc;
    __shared__ float sbuf[4];
    int tid = threadIdx.x;
    float v[4]; float s = 0.f;
    #pragma unroll
    for (int k = 0; k < 4; ++k) {
        int j = tid + k * 256;
        v[k] = (j < Nc) ? r[j] : 0.f;
        s += v[k];
    }
    s = blockReduceSum(s, sbuf);
    float e = 0.f;
    #pragma unroll
    for (int k = 0; k < 4; ++k) {
        int j = tid + k * 256;
        if (j < Nc) { float p = v[k] / s; e -= p * logf(fmaxf(p, 1e-20f)); }
    }
    e = blockReduceSum(e, sbuf);
    if (tid == 0) { rs[row] = s; rent[row] = e; }
}

// ---------------- K5: finalize affinity row + softmax (in place) ----------------
// grid 28*785, 256 threads. For matrix X[b][t]:
//  row i<784:  [ core_i | rent_self[i]*w ]
//  row 784:    [ -rs_other[b][6-t][j] | 0 ]
__global__ __launch_bounds__(256) void k_softmax_rows(float* __restrict__ X,
                                                      const float* __restrict__ rent_self,
                                                      const float* __restrict__ rs_other,
                                                      float wconst)
{
    int row = blockIdx.x;
    int bt = row / Mc, i = row % Mc;
    int b = bt / TM1, t = bt % TM1;
    int btf = b * TM1 + (6 - t);
    float* r = X + ((size_t)bt * Mc + i) * Mc;
    __shared__ float sbuf[4];
    int tid = threadIdx.x;
    float v[4];
    #pragma unroll
    for (int k = 0; k < 4; ++k) {
        int j = tid + k * 256;
        float val = -INFINITY;
        if (j < Mc) {
            float a;
            if (i < Nc) a = (j < Nc) ? r[j] : rent_self[bt * Nc + i] * wconst;
            else        a = (j < Nc) ? -rs_other[btf * Nc + j] : 0.f;
            val = a / TEMP;
        }
        v[k] = val;
    }
    float mx = fmaxf(fmaxf(v[0], v[1]), fmaxf(v[2], v[3]));
    mx = blockReduceMax(mx, sbuf);
    float e[4]; float s = 0.f;
    #pragma unroll
    for (int k = 0; k < 4; ++k) {
        int j = tid + k * 256;
        e[k] = (j < Mc) ? expf(v[k] - mx) : 0.f;
        s += e[k];
    }
    s = blockReduceSum(s, sbuf);
    float invs = 1.f / s;
    #pragma unroll
    for (int k = 0; k < 4; ++k) {
        int j = tid + k * 256;
        if (j < Mc) r[j] = e[k] * invs;
    }
}

// ---------------- K6: batched guarded SGEMM C = A @ B (all M x M, row-major) ----------------
// grid (13,13,4), 256 threads, 64x64 tile, 4x4 per thread
__global__ __launch_bounds__(256) void k_gemm(const float* __restrict__ Ab, const float* __restrict__ Bb,
                                              float* __restrict__ Cb,
                                              long long sA, long long sB, long long sC)
{
    int b = blockIdx.z;
    const float* A = Ab + (size_t)b * sA;
    const float* Bm = Bb + (size_t)b * sB;
    float* Cm = Cb + (size_t)b * sC;
    __shared__ float a_s[16][65];
    __shared__ float b_s[16][65];
    int tx = threadIdx.x & 15, ty = threadIdx.x >> 4;
    int i0 = blockIdx.y * 64, j0 = blockIdx.x * 64;
    float acc[4][4] = {};
    for (int k0 = 0; k0 < Mc; k0 += 16) {
        {   // A tile: a_s[k][i] = A[(i0+i)*M + k0+k]
            int k = threadIdx.x & 15;
            #pragma unroll
            for (int r = 0; r < 4; ++r) {
                int i = (threadIdx.x >> 4) + r * 16;
                float va = 0.f;
                if (i0 + i < Mc && k0 + k < Mc) va = A[(size_t)(i0 + i) * Mc + k0 + k];
                a_s[k][i] = va;
            }
        }
        {   // B tile: b_s[k][j] = B[(k0+k)*M + j0+j]
            int j = threadIdx.x & 63, kb = threadIdx.x >> 6;
            #pragma unroll
            for (int r = 0; r < 4; ++r) {
                int k = kb + r * 4;
                float vb = 0.f;
                if (k0 + k < Mc && j0 + j < Mc) vb = Bm[(size_t)(k0 + k) * Mc + j0 + j];
                b_s[k][j] = vb;
            }
        }
        __syncthreads();
        #pragma unroll
        for (int kk = 0; kk < 16; ++kk) {
            float ra[4], rb[4];
            #pragma unroll
            for (int ii = 0; ii < 4; ++ii) ra[ii] = a_s[kk][ty * 4 + ii];
            #pragma unroll
            for (int jj = 0; jj < 4; ++jj) rb[jj] = b_s[kk][tx * 4 + jj];
            #pragma unroll
            for (int ii = 0; ii < 4; ++ii)
                #pragma unroll
                for (int jj = 0; jj < 4; ++jj) acc[ii][jj] += ra[ii] * rb[jj];
        }
        __syncthreads();
    }
    #pragma unroll
    for (int ii = 0; ii < 4; ++ii) {
        int i = i0 + ty * 4 + ii;
        if (i >= Mc) continue;
        #pragma unroll
        for (int jj = 0; jj < 4; ++jj) {
            int j = j0 + tx * 4 + jj;
            if (j < Mc) Cm[(size_t)i * Mc + j] = acc[ii][jj];
        }
    }
}

// ---------------- K7: loss from AA (per-row log-softmax diagonal) ----------------
// grid Bc*Mc, 256 threads
__global__ __launch_bounds__(256) void k_loss(const float* __restrict__ AA, float* __restrict__ loss, float scale)
{
    int r = blockIdx.x;               // b*M + m
    int m = r % Mc;
    const float* row = AA + (size_t)r * Mc;
    __shared__ float sbuf[4];
    int tid = threadIdx.x;
    float x[4]; float mx = -INFINITY;
    #pragma unroll
    for (int k = 0; k < 4; ++k) {
        int j = tid + k * 256;
        x[k] = (j < Mc) ? logf(row[j] + 1e-20f) : -INFINITY;
        mx = fmaxf(mx, x[k]);
    }
    mx = blockReduceMax(mx, sbuf);
    float s = 0.f;
    #pragma unroll
    for (int k = 0; k < 4; ++k) {
        int j = tid + k * 256;
        if (j < Mc) s += expf(x[k] - mx);
    }
    s = blockReduceSum(s, sbuf);
    if (tid == 0) {
        float xt = logf(row[m] + 1e-20f);
        atomicAdd(loss, -(xt - mx - logf(s)) * scale);
    }
}

__global__ void k_zero(float* p) { *p = 0.f; }

// ---------------- host orchestration ----------------
extern "C" void kernel_launch(void* const* d_in, const int* in_sizes, int n_in,
                              void* d_out, int out_size, void* d_ws, size_t ws_size,
                              hipStream_t stream)
{
    const float* feats = (const float*)d_in[0];
    const float* dust  = (const float*)d_in[1];
    const float* Wself = (const float*)d_in[2];
    const float* bself = (const float*)d_in[3];
    const float* Wdust = (const float*)d_in[4];
    const float* bdust = (const float*)d_in[5];

    float* out  = (float*)d_out;
    float* qout = out;                               // B*D*T*M floats
    float* loss = out + (size_t)Bc * Dc * Tc * Mc;   // 1 float

    const size_t MM = (size_t)Mc * Mc;               // 616,225
    const size_t SB = (size_t)TM1 * MM;              // per-batch stride in A12/A21

    float* ws = (float*)d_ws;
    float* qT   = ws; ws += (size_t)Bc * Tc * Mc * Dc;   // 3,215,360
    float* A12  = ws; ws += (size_t)Bc * SB;             // 17,254,300
    float* A21  = ws; ws += (size_t)Bc * SB;             // 17,254,300
    float* rs12 = ws; ws += (size_t)Bc * TM1 * Nc;
    float* re12 = ws; ws += (size_t)Bc * TM1 * Nc;
    float* rs21 = ws; ws += (size_t)Bc * TM1 * Nc;
    float* re21 = ws; ws += (size_t)Bc * TM1 * Nc;
    float* l0 = ws; ws += (size_t)Bc * MM;
    float* l1 = ws; ws += (size_t)Bc * MM;
    float* r0 = ws; ws += (size_t)Bc * MM;
    float* r1 = ws; ws += (size_t)Bc * MM;
    float* AA = ws; ws += (size_t)Bc * MM;

    // 1. projection (+dust), l2norm, write qT and q output
    k_project<<<Bc * Nc + Bc, 256, 0, stream>>>(feats, dust, Wself, bself, Wdust, bdust, qT, qout);

    // 2. Grams into A12 cores
    k_gram<<<dim3(13, 13, Bc * TM1), 256, 0, stream>>>(qT, A12);

    // 3. A21 cores = transposed (time-flipped) A12 cores
    k_transpose<<<dim3(25, 25, Bc * TM1), 256, 0, stream>>>(A12, A21);

    // 4. row stats on both cores (gives rowsums+entropy; colsums come from the other buffer)
    k_rowstats<<<Bc * TM1 * Nc, 256, 0, stream>>>(A12, rs12, re12);
    k_rowstats<<<Bc * TM1 * Nc, 256, 0, stream>>>(A21, rs21, re21);

    // 5. finalize rows (entropy col, dust row, diag zero) + softmax, in place
    float wconst = (float)(1.0 / log(784.0));
    k_softmax_rows<<<Bc * TM1 * Mc, 256, 0, stream>>>(A12, re12, rs21, wconst);
    k_softmax_rows<<<Bc * TM1 * Mc, 256, 0, stream>>>(A21, re21, rs12, wconst);

    // 6. chain of batched matmuls + loss
    k_zero<<<1, 1, 0, stream>>>(loss);
    const float scale = 1.0f / (6.0f * Bc * Mc);
    dim3 gg(13, 13, Bc);

    // left_1 = A12[:,0] @ A12[:,1]; right_1 = A21[:,5] @ A21[:,6]
    k_gemm<<<gg, 256, 0, stream>>>(A12 + 0 * MM, A12 + 1 * MM, l0, SB, SB, MM);
    k_gemm<<<gg, 256, 0, stream>>>(A21 + 5 * MM, A21 + 6 * MM, r0, SB, SB, MM);

    float* lcur = l0; float* lnxt = l1;
    float* rcur = r0; float* rnxt = r1;
    for (int i = 1; i <= 6; ++i) {
        if (i > 1) {
            k_gemm<<<gg, 256, 0, stream>>>(lcur, A12 + (size_t)i * MM, lnxt, MM, SB, MM);
            { float* t = lcur; lcur = lnxt; lnxt = t; }
            k_gemm<<<gg, 256, 0, stream>>>(A21 + (size_t)(6 - i) * MM, rcur, rnxt, SB, MM, MM);
            { float* t = rcur; rcur = rnxt; rnxt = t; }
        }
        k_gemm<<<gg, 256, 0, stream>>>(lcur, rcur, AA, MM, MM, MM);
        k_loss<<<Bc * Mc, 256, 0, stream>>>(AA, loss, scale);
    }
}

// Round 2
// 946.885 us; speedup vs baseline: 4.1561x; 4.1561x over previous
//
#include <hip/hip_runtime.h>
#include <hip/hip_bf16.h>
#include <math.h>

// Problem constants
constexpr int Bc = 4;      // batch
constexpr int Nc = 784;    // tokens
constexpr int Cc = 512;    // enc channels
constexpr int Tc = 8;      // time
constexpr int Dc = 128;    // proj dim
constexpr int Mc = 785;    // N+1
constexpr int TM1 = 7;     // T-1
constexpr int Pp = 832;    // padded chain dim (13*64)
constexpr float TEMP = 0.07f;

typedef __attribute__((ext_vector_type(4))) float f32x4;
typedef __attribute__((ext_vector_type(8))) unsigned short u16x8;
typedef __attribute__((ext_vector_type(8))) __bf16 bf16x8;

__device__ __forceinline__ unsigned short f2bf(float v) {
    __hip_bfloat16 h = __float2bfloat16(v);
    return __builtin_bit_cast(unsigned short, h);
}

// ---------------- reduction helpers (256-thread blocks, 4 waves) ----------------
__device__ __forceinline__ float blockReduceSum(float v, float* sbuf) {
    #pragma unroll
    for (int off = 32; off; off >>= 1) v += __shfl_down(v, off, 64);
    __syncthreads();
    if ((threadIdx.x & 63) == 0) sbuf[threadIdx.x >> 6] = v;
    __syncthreads();
    return sbuf[0] + sbuf[1] + sbuf[2] + sbuf[3];
}
__device__ __forceinline__ float blockReduceMax(float v, float* sbuf) {
    #pragma unroll
    for (int off = 32; off; off >>= 1) v = fmaxf(v, __shfl_down(v, off, 64));
    __syncthreads();
    if ((threadIdx.x & 63) == 0) sbuf[threadIdx.x >> 6] = v;
    __syncthreads();
    return fmaxf(fmaxf(sbuf[0], sbuf[1]), fmaxf(sbuf[2], sbuf[3]));
}

// ---------------- K1: projection + bias + l2norm (feats and dust) ----------------
__global__ __launch_bounds__(256) void k_project(
    const float* __restrict__ feats, const float* __restrict__ dust,
    const float* __restrict__ Wself, const float* __restrict__ bself,
    const float* __restrict__ Wdust, const float* __restrict__ bdust,
    float* __restrict__ qT, float* __restrict__ qout)
{
    __shared__ float smem[Cc * Tc];
    __shared__ float nbuf[Tc];
    int bid = blockIdx.x;
    bool isDust = (bid >= Bc * Nc);
    int b, n;
    const float *src, *W, *bias;
    if (!isDust) {
        b = bid / Nc; n = bid % Nc;
        src = feats + (size_t)(b * Nc + n) * Cc * Tc;
        W = Wself; bias = bself;
    } else {
        b = bid - Bc * Nc; n = Nc;
        src = dust + (size_t)b * Cc * Tc;
        W = Wdust; bias = bdust;
    }
    int tid = threadIdx.x;
    for (int i = tid; i < Cc * Tc; i += 256) smem[i] = src[i];
    __syncthreads();

    int d = tid & (Dc - 1);
    int tg = tid >> 7;
    float acc[4] = {0.f, 0.f, 0.f, 0.f};
    for (int c = 0; c < Cc; ++c) {
        float wv = W[c * Dc + d];
        #pragma unroll
        for (int k = 0; k < 4; ++k) acc[k] += smem[c * Tc + (tg + 2 * k)] * wv;
    }
    float bv = bias[d];
    #pragma unroll
    for (int k = 0; k < 4; ++k) acc[k] += bv;
    __syncthreads();
    #pragma unroll
    for (int k = 0; k < 4; ++k) smem[(tg + 2 * k) * Dc + d] = acc[k];
    __syncthreads();
    int g = tid >> 5, l = tid & 31;
    float p = 0.f;
    #pragma unroll
    for (int dd0 = 0; dd0 < Dc; dd0 += 32) { float v = smem[g * Dc + dd0 + l]; p += v * v; }
    #pragma unroll
    for (int off = 16; off; off >>= 1) p += __shfl_down(p, off, 32);
    if (l == 0) nbuf[g] = fmaxf(sqrtf(p), 1e-12f);
    __syncthreads();
    #pragma unroll
    for (int k = 0; k < 4; ++k) {
        int t = tg + 2 * k;
        float v = acc[k] / nbuf[t];
        qT[(((size_t)b * Tc + t) * Mc + n) * Dc + d] = v;
        qout[(((size_t)b * Dc + d) * Tc + t) * Mc + n] = v;
    }
}

// ---------------- K2: Gram G[b,tau] = Q_tau (784xD) @ Q_{tau+1}^T (fp32) ----------------
__global__ __launch_bounds__(256) void k_gram(const float* __restrict__ qT, float* __restrict__ A12)
{
    int bt = blockIdx.z;
    int b = bt / TM1, tau = bt % TM1;
    const float* Q1 = qT + (size_t)(b * Tc + tau) * Mc * Dc;
    const float* Q2 = qT + (size_t)(b * Tc + tau + 1) * Mc * Dc;
    float* Cm = A12 + (size_t)bt * Mc * Mc;
    __shared__ float a_s[16][65];
    __shared__ float b_s[16][65];
    int tx = threadIdx.x & 15, ty = threadIdx.x >> 4;
    int i0 = blockIdx.y * 64, j0 = blockIdx.x * 64;
    float acc[4][4] = {};
    for (int k0 = 0; k0 < Dc; k0 += 16) {
        int k = threadIdx.x & 15;
        #pragma unroll
        for (int r = 0; r < 4; ++r) {
            int i = (threadIdx.x >> 4) + r * 16;
            float va = 0.f, vb = 0.f;
            if (i0 + i < Nc) va = Q1[(size_t)(i0 + i) * Dc + k0 + k];
            if (j0 + i < Nc) vb = Q2[(size_t)(j0 + i) * Dc + k0 + k];
            a_s[k][i] = va;
            b_s[k][i] = vb;
        }
        __syncthreads();
        #pragma unroll
        for (int kk = 0; kk < 16; ++kk) {
            float ra[4], rb[4];
            #pragma unroll
            for (int ii = 0; ii < 4; ++ii) ra[ii] = a_s[kk][ty * 4 + ii];
            #pragma unroll
            for (int jj = 0; jj < 4; ++jj) rb[jj] = b_s[kk][tx * 4 + jj];
            #pragma unroll
            for (int ii = 0; ii < 4; ++ii)
                #pragma unroll
                for (int jj = 0; jj < 4; ++jj) acc[ii][jj] += ra[ii] * rb[jj];
        }
        __syncthreads();
    }
    #pragma unroll
    for (int ii = 0; ii < 4; ++ii) {
        int i = i0 + ty * 4 + ii;
        if (i >= Nc) continue;
        #pragma unroll
        for (int jj = 0; jj < 4; ++jj) {
            int j = j0 + tx * 4 + jj;
            if (j < Nc) Cm[(size_t)i * Mc + j] = acc[ii][jj];
        }
    }
}

// ---------------- K3: fp32 transpose cores: A21[b][t] = A12[b][6-t]^T ----------------
__global__ __launch_bounds__(256) void k_transpose(const float* __restrict__ A12, float* __restrict__ A21)
{
    int bt = blockIdx.z;
    int b = bt / TM1, t = bt % TM1;
    const float* S = A12 + (size_t)(b * TM1 + (6 - t)) * Mc * Mc;
    float* Dst = A21 + (size_t)bt * Mc * Mc;
    __shared__ float tile[32][33];
    int x0 = blockIdx.x * 32, y0 = blockIdx.y * 32;
    int tx = threadIdx.x & 31, ty8 = threadIdx.x >> 5;
    for (int y = ty8; y < 32; y += 8) {
        float v = 0.f;
        if (y0 + y < Nc && x0 + tx < Nc) v = S[(size_t)(y0 + y) * Mc + x0 + tx];
        tile[y][tx] = v;
    }
    __syncthreads();
    for (int r = ty8; r < 32; r += 8) {
        if (x0 + r < Nc && y0 + tx < Nc) Dst[(size_t)(x0 + r) * Mc + y0 + tx] = tile[tx][r];
    }
}

// ---------------- K4: per-row stats (rowsum + entropy) ----------------
__global__ __launch_bounds__(256) void k_rowstats(const float* __restrict__ X,
                                                  float* __restrict__ rs, float* __restrict__ rent)
{
    int row = blockIdx.x;
    int bt = row / Nc, i = row % Nc;
    const float* r = X + ((size_t)bt * Mc + i) * Mc;
    __shared__ float sbuf[4];
    int tid = threadIdx.x;
    float v[4]; float s = 0.f;
    #pragma unroll
    for (int k = 0; k < 4; ++k) {
        int j = tid + k * 256;
        v[k] = (j < Nc) ? r[j] : 0.f;
        s += v[k];
    }
    s = blockReduceSum(s, sbuf);
    float e = 0.f;
    #pragma unroll
    for (int k = 0; k < 4; ++k) {
        int j = tid + k * 256;
        if (j < Nc) { float p = v[k] / s; e -= p * logf(fmaxf(p, 1e-20f)); }
    }
    e = blockReduceSum(e, sbuf);
    if (tid == 0) { rs[row] = s; rent[row] = e; }
}

// ---------------- K5: finalize affinity row + softmax -> bf16 padded out ----------------
// grid = 28 * Pp blocks. Output matrix stride Pp x Pp bf16, rows/cols >= Mc zeroed.
__global__ __launch_bounds__(256) void k_softmax_bf16(const float* __restrict__ X,
                                                      const float* __restrict__ rent_self,
                                                      const float* __restrict__ rs_other,
                                                      unsigned short* __restrict__ OUT,
                                                      float wconst)
{
    const size_t MMp = (size_t)Pp * Pp;
    int row = blockIdx.x;
    int bt = row / Pp, i = row % Pp;
    unsigned short* o = OUT + (size_t)bt * MMp + (size_t)i * Pp;
    int tid = threadIdx.x;
    if (i >= Mc) {                 // zero padding rows
        for (int j = tid; j < Pp; j += 256) o[j] = 0;
        return;
    }
    int b = bt / TM1, t = bt % TM1;
    int btf = b * TM1 + (6 - t);
    const float* r = X + ((size_t)bt * Mc + i) * Mc;
    __shared__ float sbuf[4];
    float v[4];
    #pragma unroll
    for (int k = 0; k < 4; ++k) {
        int j = tid + k * 256;
        float val = -INFINITY;
        if (j < Mc) {
            float a;
            if (i < Nc) a = (j < Nc) ? r[j] : rent_self[bt * Nc + i] * wconst;
            else        a = (j < Nc) ? -rs_other[btf * Nc + j] : 0.f;
            val = a / TEMP;
        }
        v[k] = val;
    }
    float mx = fmaxf(fmaxf(v[0], v[1]), fmaxf(v[2], v[3]));
    mx = blockReduceMax(mx, sbuf);
    float e[4]; float s = 0.f;
    #pragma unroll
    for (int k = 0; k < 4; ++k) {
        int j = tid + k * 256;
        e[k] = (j < Mc) ? expf(v[k] - mx) : 0.f;
        s += e[k];
    }
    s = blockReduceSum(s, sbuf);
    float invs = 1.f / s;
    #pragma unroll
    for (int k = 0; k < 4; ++k) {
        int j = tid + k * 256;
        if (j < Mc)       o[j] = f2bf(e[k] * invs);
        else if (j < Pp)  o[j] = 0;
    }
}

// ---------------- K6: bf16 transpose (Pp x Pp, exact tiles) ----------------
// mode 0: z in [0,24): b=z/6, t=z%6+1 : P12T[z] = P12h[b*7+t]^T
// mode 1: z in [0,4):  P21T6[z] = P21h[z*7+6]^T
__global__ __launch_bounds__(256) void k_transpose_bf16(const unsigned short* __restrict__ Sb,
                                                        unsigned short* __restrict__ Db, int mode)
{
    const size_t MMp = (size_t)Pp * Pp;
    __shared__ unsigned short tile[64][65];
    int z = blockIdx.z;
    const unsigned short* S;
    unsigned short* D;
    if (mode == 0) { int b = z / 6, tm = z % 6; S = Sb + ((size_t)b * 7 + tm + 1) * MMp; D = Db + (size_t)z * MMp; }
    else           { S = Sb + ((size_t)z * 7 + 6) * MMp; D = Db + (size_t)z * MMp; }
    int x0 = blockIdx.x * 64, y0 = blockIdx.y * 64;
    int tx = threadIdx.x & 63, ty = threadIdx.x >> 6;
    #pragma unroll
    for (int y = 0; y < 64; y += 4) tile[y + ty][tx] = S[(size_t)(y0 + y + ty) * Pp + x0 + tx];
    __syncthreads();
    #pragma unroll
    for (int y = 0; y < 64; y += 4) D[(size_t)(x0 + y + ty) * Pp + y0 + tx] = tile[tx][y + ty];
}

// ---------------- K7: fused batched MFMA GEMM, C = A @ BT^T (row-major, Pp x Pp) ----------------
// Up to 3 independent jobs per launch; gridDim.z = 4*njobs; blockIdx.z: job = z>>2, batch = z&3.
// mode 0: write bf16 C; mode 1: write fp32 C.
struct GJobs {
    const unsigned short* A[3];
    const unsigned short* BT[3];
    unsigned short* Cb[3];
    float* Cf[3];
    long long sA[3], sB[3], sC[3];
    int mode[3];
};

__global__ __launch_bounds__(256) void k_gemm_mfma(GJobs J)
{
    constexpr int LDS_STRIDE = 72;   // elems; 144B rows -> conflict-free b128 access
    __shared__ __align__(16) unsigned short As[128 * LDS_STRIDE];
    __shared__ __align__(16) unsigned short Bs[128 * LDS_STRIDE];

    int job = blockIdx.z >> 2, b = blockIdx.z & 3;
    const unsigned short* A  = J.A[job]  + (size_t)b * J.sA[job];
    const unsigned short* BT = J.BT[job] + (size_t)b * J.sB[job];
    int mode = J.mode[job];

    const int i0 = blockIdx.y * 128, j0 = blockIdx.x * 128;
    const int tid = threadIdx.x, lane = tid & 63, w = tid >> 6;
    const int wr = w >> 1, wc = w & 1;
    const int g = lane >> 4, lr = lane & 15;

    f32x4 acc[4][4] = {};

    for (int k0 = 0; k0 < Pp; k0 += 64) {
        __syncthreads();   // previous tile fully consumed
        // stage 128x64 A and BT tiles (reg-staged, fully unrolled)
        u16x8 va[4], vb[4];
        #pragma unroll
        for (int q = 0; q < 4; ++q) {
            int ci = q * 256 + tid;          // 0..1023
            int r = ci >> 3, s = ci & 7;
            va[q] = *(const u16x8*)(A  + (size_t)(i0 + r) * Pp + k0 + s * 8);
            vb[q] = *(const u16x8*)(BT + (size_t)(j0 + r) * Pp + k0 + s * 8);
        }
        #pragma unroll
        for (int q = 0; q < 4; ++q) {
            int ci = q * 256 + tid;
            int r = ci >> 3, s = ci & 7;
            *(u16x8*)(&As[r * LDS_STRIDE + s * 8]) = va[q];
            *(u16x8*)(&Bs[r * LDS_STRIDE + s * 8]) = vb[q];
        }
        __syncthreads();
        #pragma unroll
        for (int ks = 0; ks < 2; ++ks) {
            bf16x8 af[4], bf[4];
            #pragma unroll
            for (int m = 0; m < 4; ++m) {
                int r = wr * 64 + m * 16 + lr;
                af[m] = __builtin_bit_cast(bf16x8,
                        *(const u16x8*)(&As[r * LDS_STRIDE + ks * 32 + g * 8]));
            }
            #pragma unroll
            for (int n = 0; n < 4; ++n) {
                int r = wc * 64 + n * 16 + lr;
                bf[n] = __builtin_bit_cast(bf16x8,
                        *(const u16x8*)(&Bs[r * LDS_STRIDE + ks * 32 + g * 8]));
            }
            #pragma unroll
            for (int m = 0; m < 4; ++m)
                #pragma unroll
                for (int n = 0; n < 4; ++n)
                    acc[m][n] = __builtin_amdgcn_mfma_f32_16x16x32_bf16(af[m], bf[n], acc[m][n], 0, 0, 0);
        }
    }

    // epilogue: D layout col = lane&15, row = (lane>>4)*4 + reg
    if (mode == 0) {
        unsigned short* Co = J.Cb[job] + (size_t)b * J.sC[job];
        #pragma unroll
        for (int m = 0; m < 4; ++m)
            #pragma unroll
            for (int n = 0; n < 4; ++n)
                #pragma unroll
                for (int j = 0; j < 4; ++j) {
                    int row = i0 + wr * 64 + m * 16 + g * 4 + j;
                    int col = j0 + wc * 64 + n * 16 + lr;
                    if (row < Pp && col < Pp) Co[(size_t)row * Pp + col] = f2bf(acc[m][n][j]);
                }
    } else {
        float* Cf = J.Cf[job] + (size_t)b * J.sC[job];
        #pragma unroll
        for (int m = 0; m < 4; ++m)
            #pragma unroll
            for (int n = 0; n < 4; ++n)
                #pragma unroll
                for (int j = 0; j < 4; ++j) {
                    int row = i0 + wr * 64 + m * 16 + g * 4 + j;
                    int col = j0 + wc * 64 + n * 16 + lr;
                    if (row < Pp && col < Pp) Cf[(size_t)row * Pp + col] = acc[m][n][j];
                }
    }
}

// ---------------- K8: loss from fp32 AA (stride Pp) ----------------
__global__ __launch_bounds__(256) void k_loss(const float* __restrict__ AA, float* __restrict__ loss, float scale)
{
    const size_t MMp = (size_t)Pp * Pp;
    int r = blockIdx.x;               // b*Mc + m
    int b = r / Mc, m = r % Mc;
    const float* row = AA + (size_t)b * MMp + (size_t)m * Pp;
    __shared__ float sbuf[4];
    int tid = threadIdx.x;
    float x[4]; float mx = -INFINITY;
    #pragma unroll
    for (int k = 0; k < 4; ++k) {
        int j = tid + k * 256;
        x[k] = (j < Mc) ? logf(row[j] + 1e-20f) : -INFINITY;
        mx = fmaxf(mx, x[k]);
    }
    mx = blockReduceMax(mx, sbuf);
    float s = 0.f;
    #pragma unroll
    for (int k = 0; k < 4; ++k) {
        int j = tid + k * 256;
        if (j < Mc) s += expf(x[k] - mx);
    }
    s = blockReduceSum(s, sbuf);
    if (tid == 0) {
        float xt = logf(row[m] + 1e-20f);
        atomicAdd(loss, -(xt - mx - logf(s)) * scale);
    }
}

__global__ void k_zero(float* p) { *p = 0.f; }

// ---------------- host orchestration ----------------
extern "C" void kernel_launch(void* const* d_in, const int* in_sizes, int n_in,
                              void* d_out, int out_size, void* d_ws, size_t ws_size,
                              hipStream_t stream)
{
    const float* feats = (const float*)d_in[0];
    const float* dust  = (const float*)d_in[1];
    const float* Wself = (const float*)d_in[2];
    const float* bself = (const float*)d_in[3];
    const float* Wdust = (const float*)d_in[4];
    const float* bdust = (const float*)d_in[5];

    float* out  = (float*)d_out;
    float* qout = out;
    float* loss = out + (size_t)Bc * Dc * Tc * Mc;

    const size_t MMp = (size_t)Pp * Pp;       // 692,224

    // ---- workspace layout (≈191 MB; round-0 layout proved ≥200.5 MB available) ----
    float* ws = (float*)d_ws;
    float* qT   = ws; ws += (size_t)Bc * Tc * Mc * Dc;    //  3,215,360 f  (reused as AA)
    float* G    = ws; ws += (size_t)28 * Mc * Mc;         // 17,254,300 f  (reused: P21h,R0,R1)
    float* A21f = ws; ws += (size_t)28 * Mc * Mc;         // 17,254,300 f  (reused: P12T,P21T6,l0,l1)
    float* rs12 = ws; ws += 28 * Nc;
    float* re12 = ws; ws += 28 * Nc;
    float* rs21 = ws; ws += 28 * Nc;
    float* re21 = ws; ws += 28 * Nc;
    unsigned short* P12h = (unsigned short*)ws; ws += (size_t)(28 + 1) * MMp / 2;  // + slack matrix

    // overlays (stream-ordered liveness):
    float* AA = qT;                                        // qT dead after k_gram
    unsigned short* P21h  = (unsigned short*)G;            // G dead after P12 softmax
    unsigned short* R0    = P21h + (size_t)28 * MMp;
    unsigned short* R1    = R0 + (size_t)4 * MMp;
    unsigned short* P12T  = (unsigned short*)A21f;         // A21f dead after P21 softmax
    unsigned short* P21T6 = P12T + (size_t)24 * MMp;
    unsigned short* l0    = P21T6 + (size_t)4 * MMp;
    unsigned short* l1    = l0 + (size_t)4 * MMp;

    // 1. projection + l2norm
    k_project<<<Bc * Nc + Bc, 256, 0, stream>>>(feats, dust, Wself, bself, Wdust, bdust, qT, qout);
    // 2. fp32 Grams
    k_gram<<<dim3(13, 13, Bc * TM1), 256, 0, stream>>>(qT, G);
    // 3. fp32 flipped transposes
    k_transpose<<<dim3(25, 25, Bc * TM1), 256, 0, stream>>>(G, A21f);
    // 4. row stats
    k_rowstats<<<Bc * TM1 * Nc, 256, 0, stream>>>(G, rs12, re12);
    k_rowstats<<<Bc * TM1 * Nc, 256, 0, stream>>>(A21f, rs21, re21);
    // 5. softmax -> padded bf16 (P12h first: consumes G; then P21h overwrites G region)
    float wconst = (float)(1.0 / log(784.0));
    k_softmax_bf16<<<Bc * TM1 * Pp, 256, 0, stream>>>(G, re12, rs21, P12h, wconst);
    k_softmax_bf16<<<Bc * TM1 * Pp, 256, 0, stream>>>(A21f, re21, rs12, P21h, wconst);
    // 6. bf16 transposes (A21f region now dead)
    k_transpose_bf16<<<dim3(13, 13, 24), 256, 0, stream>>>(P12h, P12T, 0);
    k_transpose_bf16<<<dim3(13, 13, 4),  256, 0, stream>>>(P21h, P21T6, 1);

    // 7. chain
    k_zero<<<1, 1, 0, stream>>>(loss);
    const float scale = 1.0f / (6.0f * Bc * Mc);

    // prologue: L1 = P12[0] @ P12[1]  (BT = P12T t=1);  R1 = (P21[5]@P21[6])^T = P21T6 @ P21[5]^T
    {
        GJobs J = {};
        J.A[0] = P12h;  J.sA[0] = (long long)7 * MMp;
        J.BT[0] = P12T; J.sB[0] = (long long)6 * MMp;
        J.Cb[0] = l0;   J.sC[0] = (long long)MMp; J.mode[0] = 0;
        J.A[1] = P21T6;                 J.sA[1] = (long long)MMp;
        J.BT[1] = P21h + (size_t)5 * MMp; J.sB[1] = (long long)7 * MMp;
        J.Cb[1] = R0;   J.sC[1] = (long long)MMp; J.mode[1] = 0;
        k_gemm_mfma<<<dim3(7, 7, 8), 256, 0, stream>>>(J);
    }

    unsigned short *lcur = l0, *lnxt = l1, *rcur = R0, *rnxt = R1;
    for (int i = 1; i <= 6; ++i) {
        GJobs J = {};
        int nj = 0;
        // AA = lcur @ rcur = lcur @ (R)^T  -> fp32
        J.A[nj] = lcur; J.sA[nj] = (long long)MMp;
        J.BT[nj] = rcur; J.sB[nj] = (long long)MMp;
        J.Cf[nj] = AA;  J.sC[nj] = (long long)MMp; J.mode[nj] = 1; nj++;
        if (i < 6) {
            // L_{i+1} = lcur @ P12[i+1]  (BT = P12T t=i+1 -> offset i*MMp, stride 6*MMp)
            J.A[nj] = lcur; J.sA[nj] = (long long)MMp;
            J.BT[nj] = P12T + (size_t)i * MMp; J.sB[nj] = (long long)6 * MMp;
            J.Cb[nj] = lnxt; J.sC[nj] = (long long)MMp; J.mode[nj] = 0; nj++;
            // R_{i+1} = R_i @ P21[5-i]^T  (BT = P21h t=5-i, stride 7*MMp)
            J.A[nj] = rcur; J.sA[nj] = (long long)MMp;
            J.BT[nj] = P21h + (size_t)(5 - i) * MMp; J.sB[nj] = (long long)7 * MMp;
            J.Cb[nj] = rnxt; J.sC[nj] = (long long)MMp; J.mode[nj] = 0; nj++;
        }
        k_gemm_mfma<<<dim3(7, 7, 4 * nj), 256, 0, stream>>>(J);
        k_loss<<<Bc * Mc, 256, 0, stream>>>(AA, loss, scale);
        if (i < 6) {
            unsigned short* t;
            t = lcur; lcur = lnxt; lnxt = t;
            t = rcur; rcur = rnxt; rnxt = t;
        }
    }
}

// Round 3
// 794.451 us; speedup vs baseline: 4.9536x; 1.1919x over previous
//
#include <hip/hip_runtime.h>
#include <hip/hip_bf16.h>
#include <math.h>

// Problem constants
constexpr int Bc = 4;      // batch
constexpr int Nc = 784;    // tokens
constexpr int Cc = 512;    // enc channels
constexpr int Tc = 8;      // time
constexpr int Dc = 128;    // proj dim
constexpr int Mc = 785;    // N+1
constexpr int TM1 = 7;     // T-1
constexpr int Pp = 832;    // padded chain dim (13*64)
constexpr int Qrows = 896; // padded q rows for 128-tile gram (7*128)
constexpr float TEMP = 0.07f;

typedef __attribute__((ext_vector_type(4))) float f32x4;
typedef __attribute__((ext_vector_type(8))) unsigned short u16x8;
typedef __attribute__((ext_vector_type(8))) __bf16 bf16x8;

__device__ __forceinline__ unsigned short f2bf(float v) {
    __hip_bfloat16 h = __float2bfloat16(v);
    return __builtin_bit_cast(unsigned short, h);
}

// ---------------- reduction helpers (256-thread blocks, 4 waves) ----------------
__device__ __forceinline__ float blockReduceSum(float v, float* sbuf) {
    #pragma unroll
    for (int off = 32; off; off >>= 1) v += __shfl_down(v, off, 64);
    __syncthreads();
    if ((threadIdx.x & 63) == 0) sbuf[threadIdx.x >> 6] = v;
    __syncthreads();
    return sbuf[0] + sbuf[1] + sbuf[2] + sbuf[3];
}
__device__ __forceinline__ float blockReduceMax(float v, float* sbuf) {
    #pragma unroll
    for (int off = 32; off; off >>= 1) v = fmaxf(v, __shfl_down(v, off, 64));
    __syncthreads();
    if ((threadIdx.x & 63) == 0) sbuf[threadIdx.x >> 6] = v;
    __syncthreads();
    return fmaxf(fmaxf(sbuf[0], sbuf[1]), fmaxf(sbuf[2], sbuf[3]));
}

// ---------------- K1a: pack feats -> bf16 A[(b,t,n), c] ----------------
// one block per (b,n); LDS-transpose 512x8 -> 8 rows of 512 bf16
__global__ __launch_bounds__(256) void k_pack(const float* __restrict__ feats,
                                              unsigned int* __restrict__ Abf32)
{
    __shared__ float lds[Cc * 9];   // [c][t] padded stride 9
    int bid = blockIdx.x;
    int b = bid / Nc, n = bid % Nc;
    const float* src = feats + (size_t)(b * Nc + n) * Cc * Tc;
    int tid = threadIdx.x;
    for (int i = tid; i < Cc * Tc; i += 256) lds[(i >> 3) * 9 + (i & 7)] = src[i];
    __syncthreads();
    #pragma unroll
    for (int t = 0; t < Tc; ++t) {
        size_t row = (size_t)(b * Tc + t) * Nc + n;
        float v0 = lds[(2 * tid) * 9 + t];
        float v1 = lds[(2 * tid + 1) * 9 + t];
        unsigned int pk = (unsigned int)f2bf(v0) | ((unsigned int)f2bf(v1) << 16);
        Abf32[row * (Cc / 2) + tid] = pk;
    }
}

// ---------------- K1b: pack W -> bf16 WT[which][d][c] ----------------
// grid (2 dtiles, 8 ctiles, 2 which), 256 threads
__global__ __launch_bounds__(256) void k_packw(const float* __restrict__ Wself,
                                               const float* __restrict__ Wdust,
                                               unsigned short* __restrict__ WTb)
{
    __shared__ float tile[64][65];
    int which = blockIdx.z;
    const float* W = which ? Wdust : Wself;
    unsigned short* O = WTb + (size_t)which * Dc * Cc;
    int d0 = blockIdx.x * 64, c0 = blockIdx.y * 64;
    int tx = threadIdx.x & 63, ty = threadIdx.x >> 6;
    #pragma unroll
    for (int y = 0; y < 64; y += 4) tile[y + ty][tx] = W[(size_t)(c0 + y + ty) * Dc + d0 + tx];
    __syncthreads();
    #pragma unroll
    for (int y = 0; y < 64; y += 4) O[(size_t)(d0 + y + ty) * Cc + c0 + tx] = f2bf(tile[tx][y + ty]);
}

// ---------------- K1c: projection GEMM fbuf = Abf @ WT^T + bias (MFMA) ----------------
// M=25088 (196 tiles), N=128, K=512. grid (1,196,1), 256 threads.
__global__ __launch_bounds__(256) void k_gemm_proj(const unsigned short* __restrict__ A,
                                                   const unsigned short* __restrict__ BT,
                                                   const float* __restrict__ bias,
                                                   float* __restrict__ Cf)
{
    constexpr int LDS_STRIDE = 72;
    __shared__ __align__(16) unsigned short As[128 * LDS_STRIDE];
    __shared__ __align__(16) unsigned short Bs[128 * LDS_STRIDE];

    const int i0 = blockIdx.y * 128;
    const int tid = threadIdx.x, lane = tid & 63, w = tid >> 6;
    const int wr = w >> 1, wc = w & 1;
    const int g = lane >> 4, lr = lane & 15;

    f32x4 acc[4][4] = {};
    for (int k0 = 0; k0 < Cc; k0 += 64) {
        __syncthreads();
        u16x8 va[4], vb[4];
        #pragma unroll
        for (int q = 0; q < 4; ++q) {
            int ci = q * 256 + tid;
            int r = ci >> 3, s = ci & 7;
            va[q] = *(const u16x8*)(A  + (size_t)(i0 + r) * Cc + k0 + s * 8);
            vb[q] = *(const u16x8*)(BT + (size_t)r * Cc + k0 + s * 8);
        }
        #pragma unroll
        for (int q = 0; q < 4; ++q) {
            int ci = q * 256 + tid;
            int r = ci >> 3, s = ci & 7;
            *(u16x8*)(&As[r * LDS_STRIDE + s * 8]) = va[q];
            *(u16x8*)(&Bs[r * LDS_STRIDE + s * 8]) = vb[q];
        }
        __syncthreads();
        #pragma unroll
        for (int ks = 0; ks < 2; ++ks) {
            bf16x8 af[4], bf[4];
            #pragma unroll
            for (int m = 0; m < 4; ++m) {
                int r = wr * 64 + m * 16 + lr;
                af[m] = __builtin_bit_cast(bf16x8, *(const u16x8*)(&As[r * LDS_STRIDE + ks * 32 + g * 8]));
            }
            #pragma unroll
            for (int n = 0; n < 4; ++n) {
                int r = wc * 64 + n * 16 + lr;
                bf[n] = __builtin_bit_cast(bf16x8, *(const u16x8*)(&Bs[r * LDS_STRIDE + ks * 32 + g * 8]));
            }
            #pragma unroll
            for (int m = 0; m < 4; ++m)
                #pragma unroll
                for (int n = 0; n < 4; ++n)
                    acc[m][n] = __builtin_amdgcn_mfma_f32_16x16x32_bf16(af[m], bf[n], acc[m][n], 0, 0, 0);
        }
    }
    #pragma unroll
    for (int n = 0; n < 4; ++n) {
        int col = wc * 64 + n * 16 + lr;
        float bv = bias[col];
        #pragma unroll
        for (int m = 0; m < 4; ++m)
            #pragma unroll
            for (int j = 0; j < 4; ++j) {
                int row = i0 + wr * 64 + m * 16 + g * 4 + j;
                Cf[(size_t)row * Dc + col] = acc[m][n][j] + bv;
            }
    }
}

// ---------------- K1d: dust projection + l2norm (fp32 exact) ----------------
// grid 32 = (b,t), 128 threads (thread = d)
__global__ __launch_bounds__(128) void k_dustproj(const float* __restrict__ dust,
                                                  const float* __restrict__ Wdust,
                                                  const float* __restrict__ bdust,
                                                  unsigned short* __restrict__ qTb,
                                                  float* __restrict__ qout)
{
    __shared__ float sdust[Cc];
    __shared__ float red[2];
    int bt = blockIdx.x;
    int b = bt >> 3, t = bt & 7;
    int tid = threadIdx.x;
    for (int i = tid; i < Cc; i += 128) sdust[i] = dust[((size_t)b * Cc + i) * Tc + t];
    __syncthreads();
    float acc = 0.f;
    for (int c = 0; c < Cc; ++c) acc += sdust[c] * Wdust[(size_t)c * Dc + tid];
    acc += bdust[tid];
    // norm over 128 threads
    float s = acc * acc;
    #pragma unroll
    for (int off = 32; off; off >>= 1) s += __shfl_down(s, off, 64);
    if ((tid & 63) == 0) red[tid >> 6] = s;
    __syncthreads();
    float inv = 1.f / fmaxf(sqrtf(red[0] + red[1]), 1e-12f);
    float qv = acc * inv;
    qTb[((size_t)bt * Qrows + Nc) * Dc + tid] = f2bf(qv);
    qout[(((size_t)b * Dc + tid) * Tc + t) * Mc + Nc] = qv;
}

// ---------------- K1e: l2norm rows of fbuf -> bf16 qTb + fp32 qout (transposed) ----------------
// grid (13, 32): y=bt, x=64-row chunk. 256 threads.
__global__ __launch_bounds__(256) void k_norm(const float* __restrict__ fbuf,
                                              unsigned short* __restrict__ qTb,
                                              float* __restrict__ qout)
{
    __shared__ float lds[64][129];
    __shared__ float nrm[64][4];
    __shared__ float inv[64];
    int bt = blockIdx.y;
    int b = bt >> 3, t = bt & 7;
    int n0 = blockIdx.x * 64;
    int tid = threadIdx.x;
    // stage 64x128 fp32 (float4)
    #pragma unroll
    for (int q = 0; q < 8; ++q) {
        int i = q * 256 + tid;        // 0..2047 float4s
        int nl = i >> 5, d4 = i & 31;
        f32x4 v = {};
        if (n0 + nl < Nc) v = *(const f32x4*)(fbuf + ((size_t)bt * Nc + n0 + nl) * Dc + d4 * 4);
        *(f32x4*)(&lds[nl][d4 * 4]) = v;
    }
    __syncthreads();
    {   // norms: row = tid&63, part = tid>>6 (32 elems each)
        int r = tid & 63, p = tid >> 6;
        float s = 0.f;
        #pragma unroll
        for (int j = 0; j < 32; ++j) { float v = lds[r][p * 32 + j]; s += v * v; }
        nrm[r][p] = s;
    }
    __syncthreads();
    if (tid < 64) inv[tid] = 1.f / fmaxf(sqrtf(nrm[tid][0] + nrm[tid][1] + nrm[tid][2] + nrm[tid][3]), 1e-12f);
    __syncthreads();
    // qTb writes (packed u32), layout [bt][row][d]
    unsigned int* qT32 = (unsigned int*)(qTb + (size_t)bt * Qrows * Dc);
    #pragma unroll
    for (int q = 0; q < 16; ++q) {
        int i = q * 256 + tid;        // 0..4095 pairs
        int nl = i >> 6, dp = i & 63;
        if (n0 + nl < Nc) {
            float iv = inv[nl];
            unsigned int pk = (unsigned int)f2bf(lds[nl][2 * dp] * iv)
                            | ((unsigned int)f2bf(lds[nl][2 * dp + 1] * iv) << 16);
            qT32[((size_t)(n0 + nl) * Dc >> 1) + dp] = pk;
        }
    }
    // qout writes: [b][d][t][n]
    int nl = tid & 63;
    if (n0 + nl < Nc) {
        float iv = inv[nl];
        #pragma unroll
        for (int dd = 0; dd < Dc; dd += 4) {
            int d = dd + (tid >> 6);
            qout[(((size_t)b * Dc + d) * Tc + t) * Mc + n0 + nl] = lds[nl][d] * iv;
        }
    }
}

// ---------------- K2: Gram via MFMA: G[bt7] = Q[b,tau] @ Q[b,tau+1]^T ----------------
// grid (7,7,28); K=128; store fp32 stride Mc, guard i,j<784
__global__ __launch_bounds__(256) void k_gram_mfma(const unsigned short* __restrict__ qTb,
                                                   float* __restrict__ G)
{
    constexpr int LDS_STRIDE = 72;
    __shared__ __align__(16) unsigned short As[128 * LDS_STRIDE];
    __shared__ __align__(16) unsigned short Bs[128 * LDS_STRIDE];

    int bt7 = blockIdx.z;
    int b = bt7 / TM1, tau = bt7 % TM1;
    const unsigned short* A  = qTb + (size_t)(b * Tc + tau) * Qrows * Dc;
    const unsigned short* BT = qTb + (size_t)(b * Tc + tau + 1) * Qrows * Dc;
    float* Gm = G + (size_t)bt7 * Mc * Mc;

    const int i0 = blockIdx.y * 128, j0 = blockIdx.x * 128;
    const int tid = threadIdx.x, lane = tid & 63, w = tid >> 6;
    const int wr = w >> 1, wc = w & 1;
    const int g = lane >> 4, lr = lane & 15;

    f32x4 acc[4][4] = {};
    for (int k0 = 0; k0 < Dc; k0 += 64) {
        __syncthreads();
        u16x8 va[4], vb[4];
        #pragma unroll
        for (int q = 0; q < 4; ++q) {
            int ci = q * 256 + tid;
            int r = ci >> 3, s = ci & 7;
            va[q] = *(const u16x8*)(A  + (size_t)(i0 + r) * Dc + k0 + s * 8);
            vb[q] = *(const u16x8*)(BT + (size_t)(j0 + r) * Dc + k0 + s * 8);
        }
        #pragma unroll
        for (int q = 0; q < 4; ++q) {
            int ci = q * 256 + tid;
            int r = ci >> 3, s = ci & 7;
            *(u16x8*)(&As[r * LDS_STRIDE + s * 8]) = va[q];
            *(u16x8*)(&Bs[r * LDS_STRIDE + s * 8]) = vb[q];
        }
        __syncthreads();
        #pragma unroll
        for (int ks = 0; ks < 2; ++ks) {
            bf16x8 af[4], bf[4];
            #pragma unroll
            for (int m = 0; m < 4; ++m) {
                int r = wr * 64 + m * 16 + lr;
                af[m] = __builtin_bit_cast(bf16x8, *(const u16x8*)(&As[r * LDS_STRIDE + ks * 32 + g * 8]));
            }
            #pragma unroll
            for (int n = 0; n < 4; ++n) {
                int r = wc * 64 + n * 16 + lr;
                bf[n] = __builtin_bit_cast(bf16x8, *(const u16x8*)(&Bs[r * LDS_STRIDE + ks * 32 + g * 8]));
            }
            #pragma unroll
            for (int m = 0; m < 4; ++m)
                #pragma unroll
                for (int n = 0; n < 4; ++n)
                    acc[m][n] = __builtin_amdgcn_mfma_f32_16x16x32_bf16(af[m], bf[n], acc[m][n], 0, 0, 0);
        }
    }
    #pragma unroll
    for (int m = 0; m < 4; ++m)
        #pragma unroll
        for (int n = 0; n < 4; ++n)
            #pragma unroll
            for (int j = 0; j < 4; ++j) {
                int row = i0 + wr * 64 + m * 16 + g * 4 + j;
                int col = j0 + wc * 64 + n * 16 + lr;
                if (row < Nc && col < Nc) Gm[(size_t)row * Mc + col] = acc[m][n][j];
            }
}

// ---------------- K3: fp32 transpose cores: GT[b][t] = G[b][6-t]^T ----------------
__global__ __launch_bounds__(256) void k_transpose(const float* __restrict__ A12, float* __restrict__ A21)
{
    int bt = blockIdx.z;
    int b = bt / TM1, t = bt % TM1;
    const float* S = A12 + (size_t)(b * TM1 + (6 - t)) * Mc * Mc;
    float* Dst = A21 + (size_t)bt * Mc * Mc;
    __shared__ float tile[32][33];
    int x0 = blockIdx.x * 32, y0 = blockIdx.y * 32;
    int tx = threadIdx.x & 31, ty8 = threadIdx.x >> 5;
    for (int y = ty8; y < 32; y += 8) {
        float v = 0.f;
        if (y0 + y < Nc && x0 + tx < Nc) v = S[(size_t)(y0 + y) * Mc + x0 + tx];
        tile[y][tx] = v;
    }
    __syncthreads();
    for (int r = ty8; r < 32; r += 8) {
        if (x0 + r < Nc && y0 + tx < Nc) Dst[(size_t)(x0 + r) * Mc + y0 + tx] = tile[tx][r];
    }
}

// ---------------- K4: per-row stats (rowsum + entropy) ----------------
__global__ __launch_bounds__(256) void k_rowstats(const float* __restrict__ X,
                                                  float* __restrict__ rs, float* __restrict__ rent)
{
    int row = blockIdx.x;
    int bt = row / Nc, i = row % Nc;
    const float* r = X + ((size_t)bt * Mc + i) * Mc;
    __shared__ float sbuf[4];
    int tid = threadIdx.x;
    float v[4]; float s = 0.f;
    #pragma unroll
    for (int k = 0; k < 4; ++k) {
        int j = tid + k * 256;
        v[k] = (j < Nc) ? r[j] : 0.f;
        s += v[k];
    }
    s = blockReduceSum(s, sbuf);
    float e = 0.f;
    #pragma unroll
    for (int k = 0; k < 4; ++k) {
        int j = tid + k * 256;
        if (j < Nc) { float p = v[k] / s; e -= p * logf(fmaxf(p, 1e-20f)); }
    }
    e = blockReduceSum(e, sbuf);
    if (tid == 0) { rs[row] = s; rent[row] = e; }
}

// ---------------- K5: finalize affinity row + softmax -> bf16 padded out ----------------
__global__ __launch_bounds__(256) void k_softmax_bf16(const float* __restrict__ X,
                                                      const float* __restrict__ rent_self,
                                                      const float* __restrict__ rs_other,
                                                      unsigned short* __restrict__ OUT,
                                                      float wconst)
{
    const size_t MMp = (size_t)Pp * Pp;
    int row = blockIdx.x;
    int bt = row / Pp, i = row % Pp;
    unsigned short* o = OUT + (size_t)bt * MMp + (size_t)i * Pp;
    int tid = threadIdx.x;
    if (i >= Mc) {
        for (int j = tid; j < Pp; j += 256) o[j] = 0;
        return;
    }
    int b = bt / TM1, t = bt % TM1;
    int btf = b * TM1 + (6 - t);
    const float* r = X + ((size_t)bt * Mc + i) * Mc;
    __shared__ float sbuf[4];
    float v[4];
    #pragma unroll
    for (int k = 0; k < 4; ++k) {
        int j = tid + k * 256;
        float val = -INFINITY;
        if (j < Mc) {
            float a;
            if (i < Nc) a = (j < Nc) ? r[j] : rent_self[bt * Nc + i] * wconst;
            else        a = (j < Nc) ? -rs_other[btf * Nc + j] : 0.f;
            val = a / TEMP;
        }
        v[k] = val;
    }
    float mx = fmaxf(fmaxf(v[0], v[1]), fmaxf(v[2], v[3]));
    mx = blockReduceMax(mx, sbuf);
    float e[4]; float s = 0.f;
    #pragma unroll
    for (int k = 0; k < 4; ++k) {
        int j = tid + k * 256;
        e[k] = (j < Mc) ? expf(v[k] - mx) : 0.f;
        s += e[k];
    }
    s = blockReduceSum(s, sbuf);
    float invs = 1.f / s;
    #pragma unroll
    for (int k = 0; k < 4; ++k) {
        int j = tid + k * 256;
        if (j < Mc)       o[j] = f2bf(e[k] * invs);
        else if (j < Pp)  o[j] = 0;
    }
}

// ---------------- K6: bf16 transpose (Pp x Pp, exact tiles) ----------------
__global__ __launch_bounds__(256) void k_transpose_bf16(const unsigned short* __restrict__ Sb,
                                                        unsigned short* __restrict__ Db, int mode)
{
    const size_t MMp = (size_t)Pp * Pp;
    __shared__ unsigned short tile[64][65];
    int z = blockIdx.z;
    const unsigned short* S;
    unsigned short* D;
    if (mode == 0) { int b = z / 6, tm = z % 6; S = Sb + ((size_t)b * 7 + tm + 1) * MMp; D = Db + (size_t)z * MMp; }
    else           { S = Sb + ((size_t)z * 7 + 6) * MMp; D = Db + (size_t)z * MMp; }
    int x0 = blockIdx.x * 64, y0 = blockIdx.y * 64;
    int tx = threadIdx.x & 63, ty = threadIdx.x >> 6;
    #pragma unroll
    for (int y = 0; y < 64; y += 4) tile[y + ty][tx] = S[(size_t)(y0 + y + ty) * Pp + x0 + tx];
    __syncthreads();
    #pragma unroll
    for (int y = 0; y < 64; y += 4) D[(size_t)(x0 + y + ty) * Pp + y0 + tx] = tile[tx][y + ty];
}

// ---------------- K7: fused batched MFMA GEMM, C = A @ BT^T (row-major, Pp x Pp) ----------------
struct GJobs {
    const unsigned short* A[3];
    const unsigned short* BT[3];
    unsigned short* Cb[3];
    float* Cf[3];
    long long sA[3], sB[3], sC[3];
    int mode[3];
};

__global__ __launch_bounds__(256) void k_gemm_mfma(GJobs J)
{
    constexpr int LDS_STRIDE = 72;
    __shared__ __align__(16) unsigned short As[128 * LDS_STRIDE];
    __shared__ __align__(16) unsigned short Bs[128 * LDS_STRIDE];

    int job = blockIdx.z >> 2, b = blockIdx.z & 3;
    const unsigned short* A  = J.A[job]  + (size_t)b * J.sA[job];
    const unsigned short* BT = J.BT[job] + (size_t)b * J.sB[job];
    int mode = J.mode[job];

    const int i0 = blockIdx.y * 128, j0 = blockIdx.x * 128;
    const int tid = threadIdx.x, lane = tid & 63, w = tid >> 6;
    const int wr = w >> 1, wc = w & 1;
    const int g = lane >> 4, lr = lane & 15;

    f32x4 acc[4][4] = {};

    for (int k0 = 0; k0 < Pp; k0 += 64) {
        __syncthreads();
        u16x8 va[4], vb[4];
        #pragma unroll
        for (int q = 0; q < 4; ++q) {
            int ci = q * 256 + tid;
            int r = ci >> 3, s = ci & 7;
            va[q] = *(const u16x8*)(A  + (size_t)(i0 + r) * Pp + k0 + s * 8);
            vb[q] = *(const u16x8*)(BT + (size_t)(j0 + r) * Pp + k0 + s * 8);
        }
        #pragma unroll
        for (int q = 0; q < 4; ++q) {
            int ci = q * 256 + tid;
            int r = ci >> 3, s = ci & 7;
            *(u16x8*)(&As[r * LDS_STRIDE + s * 8]) = va[q];
            *(u16x8*)(&Bs[r * LDS_STRIDE + s * 8]) = vb[q];
        }
        __syncthreads();
        #pragma unroll
        for (int ks = 0; ks < 2; ++ks) {
            bf16x8 af[4], bf[4];
            #pragma unroll
            for (int m = 0; m < 4; ++m) {
                int r = wr * 64 + m * 16 + lr;
                af[m] = __builtin_bit_cast(bf16x8, *(const u16x8*)(&As[r * LDS_STRIDE + ks * 32 + g * 8]));
            }
            #pragma unroll
            for (int n = 0; n < 4; ++n) {
                int r = wc * 64 + n * 16 + lr;
                bf[n] = __builtin_bit_cast(bf16x8, *(const u16x8*)(&Bs[r * LDS_STRIDE + ks * 32 + g * 8]));
            }
            #pragma unroll
            for (int m = 0; m < 4; ++m)
                #pragma unroll
                for (int n = 0; n < 4; ++n)
                    acc[m][n] = __builtin_amdgcn_mfma_f32_16x16x32_bf16(af[m], bf[n], acc[m][n], 0, 0, 0);
        }
    }

    if (mode == 0) {
        unsigned short* Co = J.Cb[job] + (size_t)b * J.sC[job];
        #pragma unroll
        for (int m = 0; m < 4; ++m)
            #pragma unroll
            for (int n = 0; n < 4; ++n)
                #pragma unroll
                for (int j = 0; j < 4; ++j) {
                    int row = i0 + wr * 64 + m * 16 + g * 4 + j;
                    int col = j0 + wc * 64 + n * 16 + lr;
                    if (row < Pp && col < Pp) Co[(size_t)row * Pp + col] = f2bf(acc[m][n][j]);
                }
    } else {
        float* Cf = J.Cf[job] + (size_t)b * J.sC[job];
        #pragma unroll
        for (int m = 0; m < 4; ++m)
            #pragma unroll
            for (int n = 0; n < 4; ++n)
                #pragma unroll
                for (int j = 0; j < 4; ++j) {
                    int row = i0 + wr * 64 + m * 16 + g * 4 + j;
                    int col = j0 + wc * 64 + n * 16 + lr;
                    if (row < Pp && col < Pp) Cf[(size_t)row * Pp + col] = acc[m][n][j];
                }
    }
}

// ---------------- K8: loss from fp32 AA (stride Pp) ----------------
__global__ __launch_bounds__(256) void k_loss(const float* __restrict__ AA, float* __restrict__ loss, float scale)
{
    const size_t MMp = (size_t)Pp * Pp;
    int r = blockIdx.x;
    int b = r / Mc, m = r % Mc;
    const float* row = AA + (size_t)b * MMp + (size_t)m * Pp;
    __shared__ float sbuf[4];
    int tid = threadIdx.x;
    float x[4]; float mx = -INFINITY;
    #pragma unroll
    for (int k = 0; k < 4; ++k) {
        int j = tid + k * 256;
        x[k] = (j < Mc) ? logf(row[j] + 1e-20f) : -INFINITY;
        mx = fmaxf(mx, x[k]);
    }
    mx = blockReduceMax(mx, sbuf);
    float s = 0.f;
    #pragma unroll
    for (int k = 0; k < 4; ++k) {
        int j = tid + k * 256;
        if (j < Mc) s += expf(x[k] - mx);
    }
    s = blockReduceSum(s, sbuf);
    if (tid == 0) {
        float xt = logf(row[m] + 1e-20f);
        atomicAdd(loss, -(xt - mx - logf(s)) * scale);
    }
}

__global__ void k_zero(float* p) { *p = 0.f; }

// ---------------- host orchestration ----------------
extern "C" void kernel_launch(void* const* d_in, const int* in_sizes, int n_in,
                              void* d_out, int out_size, void* d_ws, size_t ws_size,
                              hipStream_t stream)
{
    const float* feats = (const float*)d_in[0];
    const float* dust  = (const float*)d_in[1];
    const float* Wself = (const float*)d_in[2];
    const float* bself = (const float*)d_in[3];
    const float* Wdust = (const float*)d_in[4];
    const float* bdust = (const float*)d_in[5];

    float* out  = (float*)d_out;
    float* qout = out;
    float* loss = out + (size_t)Bc * Dc * Tc * Mc;

    const size_t MM  = (size_t)Mc * Mc;       // 616,225
    const size_t MMp = (size_t)Pp * Pp;       // 692,224

    // ---- workspace arena (floats), peak 188.2 MB (≤ proven 191.4 MB) ----
    float* ws = (float*)d_ws;
    float* AA   = ws;                                   // [0 .. 4*MMp)
    float* G    = ws + 4 * MMp;                         // 28*MM fp32
    float* GT   = G + 28 * MM;                          // 28*MM fp32
    float* rs12 = GT + 28 * MM;
    float* re12 = rs12 + 28 * Nc;
    float* rs21 = re12 + 28 * Nc;
    float* re21 = rs21 + 28 * Nc;
    unsigned short* P12h = (unsigned short*)(re21 + 28 * Nc);   // 28*MMp bf16

    // phase-1 overlays (dead before their hosts are written):
    unsigned int*   Abf32 = (unsigned int*)G;                       // 12.85M bf16 (in G region)
    unsigned short* Abf   = (unsigned short*)Abf32;
    unsigned short* WTb   = Abf + (size_t)Bc * Tc * Nc * Cc;        // 131072 bf16
    float*          fbuf  = (float*)(WTb + 2 * (size_t)Dc * Cc);    // 3.21M fp32
    unsigned short* qTb   = (unsigned short*)GT;                    // 32*896*128 bf16 (in GT region)

    // chain overlays (same liveness as round 2):
    unsigned short* P21h  = (unsigned short*)G;
    unsigned short* R0    = P21h + (size_t)28 * MMp;
    unsigned short* R1    = R0 + (size_t)4 * MMp;
    unsigned short* P12T  = (unsigned short*)GT;
    unsigned short* P21T6 = P12T + (size_t)24 * MMp;
    unsigned short* l0    = P21T6 + (size_t)4 * MMp;
    unsigned short* l1    = l0 + (size_t)4 * MMp;

    // 1. pack inputs to bf16
    k_pack<<<Bc * Nc, 256, 0, stream>>>(feats, Abf32);
    k_packw<<<dim3(2, 8, 2), 256, 0, stream>>>(Wself, Wdust, WTb);
    hipMemsetAsync(qTb, 0, (size_t)Bc * Tc * Qrows * Dc * sizeof(unsigned short), stream);
    // 2. projection GEMM + bias
    k_gemm_proj<<<dim3(1, 196), 256, 0, stream>>>(Abf, WTb, bself, fbuf);
    // 3. dust projection (fp32) + norms
    k_dustproj<<<32, 128, 0, stream>>>(dust, Wdust, bdust, qTb, qout);
    k_norm<<<dim3(13, 32), 256, 0, stream>>>(fbuf, qTb, qout);
    // 4. Grams via MFMA
    k_gram_mfma<<<dim3(7, 7, 28), 256, 0, stream>>>(qTb, G);
    // 5. fp32 flipped transposes
    k_transpose<<<dim3(25, 25, 28), 256, 0, stream>>>(G, GT);
    // 6. row stats
    k_rowstats<<<28 * Nc, 256, 0, stream>>>(G, rs12, re12);
    k_rowstats<<<28 * Nc, 256, 0, stream>>>(GT, rs21, re21);
    // 7. softmax -> padded bf16
    float wconst = (float)(1.0 / log(784.0));
    k_softmax_bf16<<<28 * Pp, 256, 0, stream>>>(G, re12, rs21, P12h, wconst);
    k_softmax_bf16<<<28 * Pp, 256, 0, stream>>>(GT, re21, rs12, P21h, wconst);
    // 8. bf16 transposes
    k_transpose_bf16<<<dim3(13, 13, 24), 256, 0, stream>>>(P12h, P12T, 0);
    k_transpose_bf16<<<dim3(13, 13, 4),  256, 0, stream>>>(P21h, P21T6, 1);

    // 9. chain
    k_zero<<<1, 1, 0, stream>>>(loss);
    const float scale = 1.0f / (6.0f * Bc * Mc);

    {
        GJobs J = {};
        J.A[0] = P12h;  J.sA[0] = (long long)7 * MMp;
        J.BT[0] = P12T; J.sB[0] = (long long)6 * MMp;
        J.Cb[0] = l0;   J.sC[0] = (long long)MMp; J.mode[0] = 0;
        J.A[1] = P21T6;                   J.sA[1] = (long long)MMp;
        J.BT[1] = P21h + (size_t)5 * MMp; J.sB[1] = (long long)7 * MMp;
        J.Cb[1] = R0;   J.sC[1] = (long long)MMp; J.mode[1] = 0;
        k_gemm_mfma<<<dim3(7, 7, 8), 256, 0, stream>>>(J);
    }

    unsigned short *lcur = l0, *lnxt = l1, *rcur = R0, *rnxt = R1;
    for (int i = 1; i <= 6; ++i) {
        GJobs J = {};
        int nj = 0;
        J.A[nj] = lcur; J.sA[nj] = (long long)MMp;
        J.BT[nj] = rcur; J.sB[nj] = (long long)MMp;
        J.Cf[nj] = AA;  J.sC[nj] = (long long)MMp; J.mode[nj] = 1; nj++;
        if (i < 6) {
            J.A[nj] = lcur; J.sA[nj] = (long long)MMp;
            J.BT[nj] = P12T + (size_t)i * MMp; J.sB[nj] = (long long)6 * MMp;
            J.Cb[nj] = lnxt; J.sC[nj] = (long long)MMp; J.mode[nj] = 0; nj++;
            J.A[nj] = rcur; J.sA[nj] = (long long)MMp;
            J.BT[nj] = P21h + (size_t)(5 - i) * MMp; J.sB[nj] = (long long)7 * MMp;
            J.Cb[nj] = rnxt; J.sC[nj] = (long long)MMp; J.mode[nj] = 0; nj++;
        }
        k_gemm_mfma<<<dim3(7, 7, 4 * nj), 256, 0, stream>>>(J);
        k_loss<<<Bc * Mc, 256, 0, stream>>>(AA, loss, scale);
        if (i < 6) {
            unsigned short* t;
            t = lcur; lcur = lnxt; lnxt = t;
            t = rcur; rcur = rnxt; rnxt = t;
        }
    }
}

// Round 4
// 753.533 us; speedup vs baseline: 5.2226x; 1.0543x over previous
//
#include <hip/hip_runtime.h>
#include <hip/hip_bf16.h>
#include <math.h>

// Problem constants
constexpr int Bc = 4;      // batch
constexpr int Nc = 784;    // tokens
constexpr int Cc = 512;    // enc channels
constexpr int Tc = 8;      // time
constexpr int Dc = 128;    // proj dim
constexpr int Mc = 785;    // N+1
constexpr int TM1 = 7;     // T-1
constexpr int Pp = 832;    // padded chain dim (13*64)
constexpr int Qrows = 896; // padded q rows for 128-tile gram (7*128)
constexpr float TEMP = 0.07f;

typedef __attribute__((ext_vector_type(4))) float f32x4;
typedef __attribute__((ext_vector_type(8))) unsigned short u16x8;
typedef __attribute__((ext_vector_type(8))) __bf16 bf16x8;

__device__ __forceinline__ unsigned short f2bf(float v) {
    __hip_bfloat16 h = __float2bfloat16(v);
    return __builtin_bit_cast(unsigned short, h);
}

// ---------------- async 16B global->LDS ----------------
__device__ __forceinline__ void gload16(const void* g, void* l) {
    __builtin_amdgcn_global_load_lds(
        (const __attribute__((address_space(1))) unsigned int*)g,
        (__attribute__((address_space(3))) unsigned int*)l, 16, 0, 0);
}

// Shared MFMA K-loop: 128x128 C-tile, BK=64, 4 waves, global_load_lds staging
// with XOR-16B involution swizzle (linear LDS dest, pre-swizzled source cols,
// swizzled ds_read) -> conflict-free both sides.
template<int LD>
__device__ __forceinline__ void mfma_tile_loop(const unsigned short* __restrict__ A,
                                               const unsigned short* __restrict__ BT,
                                               unsigned short* __restrict__ As,
                                               unsigned short* __restrict__ Bs,
                                               int i0, int j0, int tid,
                                               f32x4 (&acc)[4][4])
{
    const int lane = tid & 63, w = tid >> 6;
    const int wr = w >> 1, wc = w & 1;
    const int g = lane >> 4, lr = lane & 15;

    for (int k0 = 0; k0 < LD; k0 += 64) {
        __syncthreads();   // previous tile fully consumed
        #pragma unroll
        for (int q = 0; q < 4; ++q) {
            int L16 = q * 256 + tid;                      // 16B slot 0..1023
            int r = L16 >> 3;                             // row 0..127
            int csw = ((L16 & 7) << 4) ^ ((r & 7) << 4);  // swizzled byte col
            const char* ga = (const char*)(A  + (size_t)(i0 + r) * LD + k0) + csw;
            const char* gb = (const char*)(BT + (size_t)(j0 + r) * LD + k0) + csw;
            gload16(ga, As + (size_t)L16 * 8);
            gload16(gb, Bs + (size_t)L16 * 8);
        }
        __syncthreads();   // drains vmcnt before compute
        #pragma unroll
        for (int ks = 0; ks < 2; ++ks) {
            bf16x8 af[4], bf[4];
            #pragma unroll
            for (int m = 0; m < 4; ++m) {
                int r = wr * 64 + m * 16 + lr;
                int cb = (ks * 64 + g * 16) ^ ((r & 7) << 4);
                af[m] = __builtin_bit_cast(bf16x8, *(const u16x8*)((const char*)As + r * 128 + cb));
            }
            #pragma unroll
            for (int n = 0; n < 4; ++n) {
                int r = wc * 64 + n * 16 + lr;
                int cb = (ks * 64 + g * 16) ^ ((r & 7) << 4);
                bf[n] = __builtin_bit_cast(bf16x8, *(const u16x8*)((const char*)Bs + r * 128 + cb));
            }
            #pragma unroll
            for (int m = 0; m < 4; ++m)
                #pragma unroll
                for (int n = 0; n < 4; ++n)
                    acc[m][n] = __builtin_amdgcn_mfma_f32_16x16x32_bf16(af[m], bf[n], acc[m][n], 0, 0, 0);
        }
    }
}

// ---------------- reduction helpers (256-thread blocks, 4 waves) ----------------
__device__ __forceinline__ float blockReduceSum(float v, float* sbuf) {
    #pragma unroll
    for (int off = 32; off; off >>= 1) v += __shfl_down(v, off, 64);
    __syncthreads();
    if ((threadIdx.x & 63) == 0) sbuf[threadIdx.x >> 6] = v;
    __syncthreads();
    return sbuf[0] + sbuf[1] + sbuf[2] + sbuf[3];
}
__device__ __forceinline__ float blockReduceMax(float v, float* sbuf) {
    #pragma unroll
    for (int off = 32; off; off >>= 1) v = fmaxf(v, __shfl_down(v, off, 64));
    __syncthreads();
    if ((threadIdx.x & 63) == 0) sbuf[threadIdx.x >> 6] = v;
    __syncthreads();
    return fmaxf(fmaxf(sbuf[0], sbuf[1]), fmaxf(sbuf[2], sbuf[3]));
}

// ---------------- K1a: pack feats -> bf16 A[(b,t,n), c] ----------------
__global__ __launch_bounds__(256) void k_pack(const float* __restrict__ feats,
                                              unsigned int* __restrict__ Abf32)
{
    __shared__ float lds[Cc * 9];   // [c][t] padded stride 9
    int bid = blockIdx.x;
    int b = bid / Nc, n = bid % Nc;
    const float* src = feats + (size_t)(b * Nc + n) * Cc * Tc;
    int tid = threadIdx.x;
    for (int i = tid; i < Cc * Tc; i += 256) lds[(i >> 3) * 9 + (i & 7)] = src[i];
    __syncthreads();
    #pragma unroll
    for (int t = 0; t < Tc; ++t) {
        size_t row = (size_t)(b * Tc + t) * Nc + n;
        float v0 = lds[(2 * tid) * 9 + t];
        float v1 = lds[(2 * tid + 1) * 9 + t];
        unsigned int pk = (unsigned int)f2bf(v0) | ((unsigned int)f2bf(v1) << 16);
        Abf32[row * (Cc / 2) + tid] = pk;
    }
}

// ---------------- K1b: pack W -> bf16 WT[which][d][c] ----------------
__global__ __launch_bounds__(256) void k_packw(const float* __restrict__ Wself,
                                               const float* __restrict__ Wdust,
                                               unsigned short* __restrict__ WTb)
{
    __shared__ float tile[64][65];
    int which = blockIdx.z;
    const float* W = which ? Wdust : Wself;
    unsigned short* O = WTb + (size_t)which * Dc * Cc;
    int d0 = blockIdx.x * 64, c0 = blockIdx.y * 64;
    int tx = threadIdx.x & 63, ty = threadIdx.x >> 6;
    #pragma unroll
    for (int y = 0; y < 64; y += 4) tile[y + ty][tx] = W[(size_t)(c0 + y + ty) * Dc + d0 + tx];
    __syncthreads();
    #pragma unroll
    for (int y = 0; y < 64; y += 4) O[(size_t)(d0 + y + ty) * Cc + c0 + tx] = f2bf(tile[tx][y + ty]);
}

// ---------------- K1c: projection GEMM fbuf = Abf @ WT^T + bias (MFMA) ----------------
__global__ __launch_bounds__(256, 3) void k_gemm_proj(const unsigned short* __restrict__ A,
                                                      const unsigned short* __restrict__ BT,
                                                      const float* __restrict__ bias,
                                                      float* __restrict__ Cf)
{
    __shared__ __align__(16) unsigned short As[128 * 64];
    __shared__ __align__(16) unsigned short Bs[128 * 64];
    const int i0 = blockIdx.y * 128;
    const int tid = threadIdx.x, lane = tid & 63, w = tid >> 6;
    const int wr = w >> 1, wc = w & 1;
    const int g = lane >> 4, lr = lane & 15;

    f32x4 acc[4][4] = {};
    mfma_tile_loop<Cc>(A, BT, As, Bs, i0, 0, tid, acc);

    #pragma unroll
    for (int n = 0; n < 4; ++n) {
        int col = wc * 64 + n * 16 + lr;
        float bv = bias[col];
        #pragma unroll
        for (int m = 0; m < 4; ++m)
            #pragma unroll
            for (int j = 0; j < 4; ++j) {
                int row = i0 + wr * 64 + m * 16 + g * 4 + j;
                Cf[(size_t)row * Dc + col] = acc[m][n][j] + bv;
            }
    }
}

// ---------------- K1d: dust projection + l2norm (fp32 exact) ----------------
__global__ __launch_bounds__(128) void k_dustproj(const float* __restrict__ dust,
                                                  const float* __restrict__ Wdust,
                                                  const float* __restrict__ bdust,
                                                  unsigned short* __restrict__ qTb,
                                                  float* __restrict__ qout)
{
    __shared__ float sdust[Cc];
    __shared__ float red[2];
    int bt = blockIdx.x;
    int b = bt >> 3, t = bt & 7;
    int tid = threadIdx.x;
    for (int i = tid; i < Cc; i += 128) sdust[i] = dust[((size_t)b * Cc + i) * Tc + t];
    __syncthreads();
    float acc = 0.f;
    for (int c = 0; c < Cc; ++c) acc += sdust[c] * Wdust[(size_t)c * Dc + tid];
    acc += bdust[tid];
    float s = acc * acc;
    #pragma unroll
    for (int off = 32; off; off >>= 1) s += __shfl_down(s, off, 64);
    if ((tid & 63) == 0) red[tid >> 6] = s;
    __syncthreads();
    float inv = 1.f / fmaxf(sqrtf(red[0] + red[1]), 1e-12f);
    float qv = acc * inv;
    qTb[((size_t)bt * Qrows + Nc) * Dc + tid] = f2bf(qv);
    qout[(((size_t)b * Dc + tid) * Tc + t) * Mc + Nc] = qv;
}

// ---------------- K1e: l2norm rows of fbuf -> bf16 qTb + fp32 qout (transposed) ----------------
__global__ __launch_bounds__(256) void k_norm(const float* __restrict__ fbuf,
                                              unsigned short* __restrict__ qTb,
                                              float* __restrict__ qout)
{
    __shared__ float lds[64][129];
    __shared__ float nrm[64][4];
    __shared__ float inv[64];
    int bt = blockIdx.y;
    int b = bt >> 3, t = bt & 7;
    int n0 = blockIdx.x * 64;
    int tid = threadIdx.x;
    #pragma unroll
    for (int q = 0; q < 8; ++q) {
        int i = q * 256 + tid;
        int nl = i >> 5, d4 = i & 31;
        f32x4 v = {};
        if (n0 + nl < Nc) v = *(const f32x4*)(fbuf + ((size_t)bt * Nc + n0 + nl) * Dc + d4 * 4);
        *(f32x4*)(&lds[nl][d4 * 4]) = v;
    }
    __syncthreads();
    {
        int r = tid & 63, p = tid >> 6;
        float s = 0.f;
        #pragma unroll
        for (int j = 0; j < 32; ++j) { float v = lds[r][p * 32 + j]; s += v * v; }
        nrm[r][p] = s;
    }
    __syncthreads();
    if (tid < 64) inv[tid] = 1.f / fmaxf(sqrtf(nrm[tid][0] + nrm[tid][1] + nrm[tid][2] + nrm[tid][3]), 1e-12f);
    __syncthreads();
    unsigned int* qT32 = (unsigned int*)(qTb + (size_t)bt * Qrows * Dc);
    #pragma unroll
    for (int q = 0; q < 16; ++q) {
        int i = q * 256 + tid;
        int nl = i >> 6, dp = i & 63;
        if (n0 + nl < Nc) {
            float iv = inv[nl];
            unsigned int pk = (unsigned int)f2bf(lds[nl][2 * dp] * iv)
                            | ((unsigned int)f2bf(lds[nl][2 * dp + 1] * iv) << 16);
            qT32[((size_t)(n0 + nl) * Dc >> 1) + dp] = pk;
        }
    }
    int nl = tid & 63;
    if (n0 + nl < Nc) {
        float iv = inv[nl];
        #pragma unroll
        for (int dd = 0; dd < Dc; dd += 4) {
            int d = dd + (tid >> 6);
            qout[(((size_t)b * Dc + d) * Tc + t) * Mc + n0 + nl] = lds[nl][d] * iv;
        }
    }
}

// ---------------- K2: Gram via MFMA + dual write (G and GT = flipped transpose) ----------------
// G[b,tau][i,j] = <q_tau[i], q_tau+1[j]>;  GT[b, 6-tau][j, i] = G[b,tau][i,j]
__global__ __launch_bounds__(256, 3) void k_gram_mfma(const unsigned short* __restrict__ qTb,
                                                      float* __restrict__ G,
                                                      float* __restrict__ GT)
{
    __shared__ __align__(16) float smemf[2 * 64 * 65];   // 33.3 KB: staging + transpose
    unsigned short* As = (unsigned short*)smemf;
    unsigned short* Bs = (unsigned short*)smemf + 128 * 64;

    int bt7 = blockIdx.z;
    int b = bt7 / TM1, tau = bt7 % TM1;
    const unsigned short* A  = qTb + (size_t)(b * Tc + tau) * Qrows * Dc;
    const unsigned short* BT = qTb + (size_t)(b * Tc + tau + 1) * Qrows * Dc;
    float* Gm  = G  + (size_t)bt7 * Mc * Mc;
    float* GTm = GT + (size_t)(b * TM1 + (6 - tau)) * Mc * Mc;

    const int i0 = blockIdx.y * 128, j0 = blockIdx.x * 128;
    const int tid = threadIdx.x, lane = tid & 63, w = tid >> 6;
    const int wr = w >> 1, wc = w & 1;
    const int g = lane >> 4, lr = lane & 15;

    f32x4 acc[4][4] = {};
    mfma_tile_loop<Dc>(A, BT, As, Bs, i0, j0, tid, acc);

    // direct G write
    #pragma unroll
    for (int m = 0; m < 4; ++m)
        #pragma unroll
        for (int n = 0; n < 4; ++n)
            #pragma unroll
            for (int j = 0; j < 4; ++j) {
                int row = i0 + wr * 64 + m * 16 + g * 4 + j;
                int col = j0 + wc * 64 + n * 16 + lr;
                if (row < Nc && col < Nc) Gm[(size_t)row * Mc + col] = acc[m][n][j];
            }

    // transposed write via LDS (each wave owns one 64x64 quadrant)
    float* LT = smemf;
    for (int round = 0; round < 2; ++round) {
        __syncthreads();
        if (wr == round) {
            float* Bq = LT + wc * (64 * 65);
            #pragma unroll
            for (int m = 0; m < 4; ++m)
                #pragma unroll
                for (int n = 0; n < 4; ++n)
                    #pragma unroll
                    for (int j = 0; j < 4; ++j)
                        Bq[(m * 16 + g * 4 + j) * 65 + n * 16 + lr] = acc[m][n][j];
        }
        __syncthreads();
        if (wr == round) {
            float* Bq = LT + wc * (64 * 65);
            int gtrow0 = j0 + wc * 64;          // GT row = G col
            int gtcol0 = i0 + round * 64;       // GT col = G row
            if (gtcol0 + lane < Nc) {
                #pragma unroll 4
                for (int c = 0; c < 64; ++c) {
                    int gr = gtrow0 + c;
                    if (gr < Nc) GTm[(size_t)gr * Mc + gtcol0 + lane] = Bq[lane * 65 + c];
                }
            }
        }
    }
}

// ---------------- K4: per-row stats (rowsum + entropy) ----------------
__global__ __launch_bounds__(256) void k_rowstats(const float* __restrict__ X,
                                                  float* __restrict__ rs, float* __restrict__ rent)
{
    int row = blockIdx.x;
    int bt = row / Nc, i = row % Nc;
    const float* r = X + ((size_t)bt * Mc + i) * Mc;
    __shared__ float sbuf[4];
    int tid = threadIdx.x;
    float v[4]; float s = 0.f;
    #pragma unroll
    for (int k = 0; k < 4; ++k) {
        int j = tid + k * 256;
        v[k] = (j < Nc) ? r[j] : 0.f;
        s += v[k];
    }
    s = blockReduceSum(s, sbuf);
    float e = 0.f;
    #pragma unroll
    for (int k = 0; k < 4; ++k) {
        int j = tid + k * 256;
        if (j < Nc) { float p = v[k] / s; e -= p * logf(fmaxf(p, 1e-20f)); }
    }
    e = blockReduceSum(e, sbuf);
    if (tid == 0) { rs[row] = s; rent[row] = e; }
}

// ---------------- K5: finalize affinity row + softmax -> bf16 padded out ----------------
__global__ __launch_bounds__(256) void k_softmax_bf16(const float* __restrict__ X,
                                                      const float* __restrict__ rent_self,
                                                      const float* __restrict__ rs_other,
                                                      unsigned short* __restrict__ OUT,
                                                      float wconst)
{
    const size_t MMp = (size_t)Pp * Pp;
    int row = blockIdx.x;
    int bt = row / Pp, i = row % Pp;
    unsigned short* o = OUT + (size_t)bt * MMp + (size_t)i * Pp;
    int tid = threadIdx.x;
    if (i >= Mc) {
        for (int j = tid; j < Pp; j += 256) o[j] = 0;
        return;
    }
    int b = bt / TM1, t = bt % TM1;
    int btf = b * TM1 + (6 - t);
    const float* r = X + ((size_t)bt * Mc + i) * Mc;
    __shared__ float sbuf[4];
    float v[4];
    #pragma unroll
    for (int k = 0; k < 4; ++k) {
        int j = tid + k * 256;
        float val = -INFINITY;
        if (j < Mc) {
            float a;
            if (i < Nc) a = (j < Nc) ? r[j] : rent_self[bt * Nc + i] * wconst;
            else        a = (j < Nc) ? -rs_other[btf * Nc + j] : 0.f;
            val = a / TEMP;
        }
        v[k] = val;
    }
    float mx = fmaxf(fmaxf(v[0], v[1]), fmaxf(v[2], v[3]));
    mx = blockReduceMax(mx, sbuf);
    float e[4]; float s = 0.f;
    #pragma unroll
    for (int k = 0; k < 4; ++k) {
        int j = tid + k * 256;
        e[k] = (j < Mc) ? expf(v[k] - mx) : 0.f;
        s += e[k];
    }
    s = blockReduceSum(s, sbuf);
    float invs = 1.f / s;
    #pragma unroll
    for (int k = 0; k < 4; ++k) {
        int j = tid + k * 256;
        if (j < Mc)       o[j] = f2bf(e[k] * invs);
        else if (j < Pp)  o[j] = 0;
    }
}

// ---------------- K6: bf16 transpose (Pp x Pp, exact tiles) ----------------
__global__ __launch_bounds__(256) void k_transpose_bf16(const unsigned short* __restrict__ Sb,
                                                        unsigned short* __restrict__ Db, int mode)
{
    const size_t MMp = (size_t)Pp * Pp;
    __shared__ unsigned short tile[64][65];
    int z = blockIdx.z;
    const unsigned short* S;
    unsigned short* D;
    if (mode == 0) { int b = z / 6, tm = z % 6; S = Sb + ((size_t)b * 7 + tm + 1) * MMp; D = Db + (size_t)z * MMp; }
    else           { S = Sb + ((size_t)z * 7 + 6) * MMp; D = Db + (size_t)z * MMp; }
    int x0 = blockIdx.x * 64, y0 = blockIdx.y * 64;
    int tx = threadIdx.x & 63, ty = threadIdx.x >> 6;
    #pragma unroll
    for (int y = 0; y < 64; y += 4) tile[y + ty][tx] = S[(size_t)(y0 + y + ty) * Pp + x0 + tx];
    __syncthreads();
    #pragma unroll
    for (int y = 0; y < 64; y += 4) D[(size_t)(x0 + y + ty) * Pp + y0 + tx] = tile[tx][y + ty];
}

// ---------------- K7: fused batched MFMA GEMM, C = A @ BT^T (row-major, Pp x Pp) ----------------
struct GJobs {
    const unsigned short* A[3];
    const unsigned short* BT[3];
    unsigned short* Cb[3];
    float* Cf[3];
    long long sA[3], sB[3], sC[3];
    int mode[3];
};

__global__ __launch_bounds__(256, 3) void k_gemm_mfma(GJobs J)
{
    __shared__ __align__(16) unsigned short As[128 * 64];
    __shared__ __align__(16) unsigned short Bs[128 * 64];

    int job = blockIdx.z >> 2, b = blockIdx.z & 3;
    const unsigned short* A  = J.A[job]  + (size_t)b * J.sA[job];
    const unsigned short* BT = J.BT[job] + (size_t)b * J.sB[job];
    int mode = J.mode[job];

    const int i0 = blockIdx.y * 128, j0 = blockIdx.x * 128;
    const int tid = threadIdx.x, lane = tid & 63, w = tid >> 6;
    const int wr = w >> 1, wc = w & 1;
    const int g = lane >> 4, lr = lane & 15;

    f32x4 acc[4][4] = {};
    mfma_tile_loop<Pp>(A, BT, As, Bs, i0, j0, tid, acc);

    if (mode == 0) {
        unsigned short* Co = J.Cb[job] + (size_t)b * J.sC[job];
        #pragma unroll
        for (int m = 0; m < 4; ++m)
            #pragma unroll
            for (int n = 0; n < 4; ++n)
                #pragma unroll
                for (int j = 0; j < 4; ++j) {
                    int row = i0 + wr * 64 + m * 16 + g * 4 + j;
                    int col = j0 + wc * 64 + n * 16 + lr;
                    if (row < Pp && col < Pp) Co[(size_t)row * Pp + col] = f2bf(acc[m][n][j]);
                }
    } else {
        float* Cf = J.Cf[job] + (size_t)b * J.sC[job];
        #pragma unroll
        for (int m = 0; m < 4; ++m)
            #pragma unroll
            for (int n = 0; n < 4; ++n)
                #pragma unroll
                for (int j = 0; j < 4; ++j) {
                    int row = i0 + wr * 64 + m * 16 + g * 4 + j;
                    int col = j0 + wc * 64 + n * 16 + lr;
                    if (row < Pp && col < Pp) Cf[(size_t)row * Pp + col] = acc[m][n][j];
                }
    }
}

// ---------------- K8: loss from fp32 AA (stride Pp) ----------------
__global__ __launch_bounds__(256) void k_loss(const float* __restrict__ AA, float* __restrict__ loss, float scale)
{
    const size_t MMp = (size_t)Pp * Pp;
    int r = blockIdx.x;
    int b = r / Mc, m = r % Mc;
    const float* row = AA + (size_t)b * MMp + (size_t)m * Pp;
    __shared__ float sbuf[4];
    int tid = threadIdx.x;
    float x[4]; float mx = -INFINITY;
    #pragma unroll
    for (int k = 0; k < 4; ++k) {
        int j = tid + k * 256;
        x[k] = (j < Mc) ? logf(row[j] + 1e-20f) : -INFINITY;
        mx = fmaxf(mx, x[k]);
    }
    mx = blockReduceMax(mx, sbuf);
    float s = 0.f;
    #pragma unroll
    for (int k = 0; k < 4; ++k) {
        int j = tid + k * 256;
        if (j < Mc) s += expf(x[k] - mx);
    }
    s = blockReduceSum(s, sbuf);
    if (tid == 0) {
        float xt = logf(row[m] + 1e-20f);
        atomicAdd(loss, -(xt - mx - logf(s)) * scale);
    }
}

__global__ void k_zero(float* p) { *p = 0.f; }

// ---------------- host orchestration ----------------
extern "C" void kernel_launch(void* const* d_in, const int* in_sizes, int n_in,
                              void* d_out, int out_size, void* d_ws, size_t ws_size,
                              hipStream_t stream)
{
    const float* feats = (const float*)d_in[0];
    const float* dust  = (const float*)d_in[1];
    const float* Wself = (const float*)d_in[2];
    const float* bself = (const float*)d_in[3];
    const float* Wdust = (const float*)d_in[4];
    const float* bdust = (const float*)d_in[5];

    float* out  = (float*)d_out;
    float* qout = out;
    float* loss = out + (size_t)Bc * Dc * Tc * Mc;

    const size_t MM  = (size_t)Mc * Mc;       // 616,225
    const size_t MMp = (size_t)Pp * Pp;       // 692,224

    // ---- workspace arena (floats), peak ~188.3 MB ----
    float* ws = (float*)d_ws;
    float* AA   = ws;                                   // 4*MMp fp32
    float* G    = ws + 4 * MMp;                         // 28*MM fp32
    float* GT   = G + 28 * MM;                          // 28*MM fp32
    float* rs12 = GT + 28 * MM;
    float* re12 = rs12 + 28 * Nc;
    float* rs21 = re12 + 28 * Nc;
    float* re21 = rs21 + 28 * Nc;
    unsigned short* P12h = (unsigned short*)(re21 + 28 * Nc);   // 28*MMp bf16

    // phase-1 overlays:
    unsigned int*   Abf32 = (unsigned int*)G;                       // in G region
    unsigned short* Abf   = (unsigned short*)Abf32;
    unsigned short* WTb   = Abf + (size_t)Bc * Tc * Nc * Cc;
    float*          fbuf  = (float*)(WTb + 2 * (size_t)Dc * Cc);
    unsigned short* qTb   = P12h;                                   // in P12h region (dead until softmax)

    // chain overlays:
    unsigned short* P21h  = (unsigned short*)G;
    unsigned short* R0    = P21h + (size_t)28 * MMp;
    unsigned short* R1    = R0 + (size_t)4 * MMp;
    unsigned short* P12T  = (unsigned short*)GT;
    unsigned short* P21T6 = P12T + (size_t)24 * MMp;
    unsigned short* l0    = P21T6 + (size_t)4 * MMp;
    unsigned short* l1    = l0 + (size_t)4 * MMp;

    // 1. pack inputs to bf16
    k_pack<<<Bc * Nc, 256, 0, stream>>>(feats, Abf32);
    k_packw<<<dim3(2, 8, 2), 256, 0, stream>>>(Wself, Wdust, WTb);
    hipMemsetAsync(qTb, 0, (size_t)Bc * Tc * Qrows * Dc * sizeof(unsigned short), stream);
    // 2. projection GEMM + bias
    k_gemm_proj<<<dim3(1, 196), 256, 0, stream>>>(Abf, WTb, bself, fbuf);
    // 3. dust projection (fp32) + norms
    k_dustproj<<<32, 128, 0, stream>>>(dust, Wdust, bdust, qTb, qout);
    k_norm<<<dim3(13, 32), 256, 0, stream>>>(fbuf, qTb, qout);
    // 4. Grams via MFMA (writes G and GT directly)
    k_gram_mfma<<<dim3(7, 7, 28), 256, 0, stream>>>(qTb, G, GT);
    // 5. row stats
    k_rowstats<<<28 * Nc, 256, 0, stream>>>(G, rs12, re12);
    k_rowstats<<<28 * Nc, 256, 0, stream>>>(GT, rs21, re21);
    // 6. softmax -> padded bf16
    float wconst = (float)(1.0 / log(784.0));
    k_softmax_bf16<<<28 * Pp, 256, 0, stream>>>(G, re12, rs21, P12h, wconst);
    k_softmax_bf16<<<28 * Pp, 256, 0, stream>>>(GT, re21, rs12, P21h, wconst);
    // 7. bf16 transposes
    k_transpose_bf16<<<dim3(13, 13, 24), 256, 0, stream>>>(P12h, P12T, 0);
    k_transpose_bf16<<<dim3(13, 13, 4),  256, 0, stream>>>(P21h, P21T6, 1);

    // 8. chain
    k_zero<<<1, 1, 0, stream>>>(loss);
    const float scale = 1.0f / (6.0f * Bc * Mc);

    {
        GJobs J = {};
        J.A[0] = P12h;  J.sA[0] = (long long)7 * MMp;
        J.BT[0] = P12T; J.sB[0] = (long long)6 * MMp;
        J.Cb[0] = l0;   J.sC[0] = (long long)MMp; J.mode[0] = 0;
        J.A[1] = P21T6;                   J.sA[1] = (long long)MMp;
        J.BT[1] = P21h + (size_t)5 * MMp; J.sB[1] = (long long)7 * MMp;
        J.Cb[1] = R0;   J.sC[1] = (long long)MMp; J.mode[1] = 0;
        k_gemm_mfma<<<dim3(7, 7, 8), 256, 0, stream>>>(J);
    }

    unsigned short *lcur = l0, *lnxt = l1, *rcur = R0, *rnxt = R1;
    for (int i = 1; i <= 6; ++i) {
        GJobs J = {};
        int nj = 0;
        J.A[nj] = lcur; J.sA[nj] = (long long)MMp;
        J.BT[nj] = rcur; J.sB[nj] = (long long)MMp;
        J.Cf[nj] = AA;  J.sC[nj] = (long long)MMp; J.mode[nj] = 1; nj++;
        if (i < 6) {
            J.A[nj] = lcur; J.sA[nj] = (long long)MMp;
            J.BT[nj] = P12T + (size_t)i * MMp; J.sB[nj] = (long long)6 * MMp;
            J.Cb[nj] = lnxt; J.sC[nj] = (long long)MMp; J.mode[nj] = 0; nj++;
            J.A[nj] = rcur; J.sA[nj] = (long long)MMp;
            J.BT[nj] = P21h + (size_t)(5 - i) * MMp; J.sB[nj] = (long long)7 * MMp;
            J.Cb[nj] = rnxt; J.sC[nj] = (long long)MMp; J.mode[nj] = 0; nj++;
        }
        k_gemm_mfma<<<dim3(7, 7, 4 * nj), 256, 0, stream>>>(J);
        k_loss<<<Bc * Mc, 256, 0, stream>>>(AA, loss, scale);
        if (i < 6) {
            unsigned short* t;
            t = lcur; lcur = lnxt; lnxt = t;
            t = rcur; rcur = rnxt; rnxt = t;
        }
    }
}

// Round 5
// 683.073 us; speedup vs baseline: 5.7613x; 1.1032x over previous
//
#include <hip/hip_runtime.h>
#include <hip/hip_bf16.h>
#include <math.h>

// Problem constants
constexpr int Bc = 4;      // batch
constexpr int Nc = 784;    // tokens
constexpr int Cc = 512;    // enc channels
constexpr int Tc = 8;      // time
constexpr int Dc = 128;    // proj dim
constexpr int Mc = 785;    // N+1
constexpr int TM1 = 7;     // T-1
constexpr int Pp = 832;    // padded chain dim (13*64)
constexpr int Qrows = 896; // padded q rows
constexpr float TEMP = 0.07f;

typedef __attribute__((ext_vector_type(4))) float f32x4;
typedef __attribute__((ext_vector_type(8))) unsigned short u16x8;
typedef __attribute__((ext_vector_type(8))) __bf16 bf16x8;

__device__ __forceinline__ unsigned short f2bf(float v) {
    __hip_bfloat16 h = __float2bfloat16(v);
    return __builtin_bit_cast(unsigned short, h);
}

// ---------------- async 16B global->LDS ----------------
__device__ __forceinline__ void gload16(const void* g, void* l) {
    __builtin_amdgcn_global_load_lds(
        (const __attribute__((address_space(1))) unsigned int*)g,
        (__attribute__((address_space(3))) unsigned int*)l, 16, 0, 0);
}

// Shared MFMA K-loop: 128x128 C-tile, BK=64, 4 waves, global_load_lds staging
// with XOR-16B involution swizzle.
template<int LD>
__device__ __forceinline__ void mfma_tile_loop(const unsigned short* __restrict__ A,
                                               const unsigned short* __restrict__ BT,
                                               unsigned short* __restrict__ As,
                                               unsigned short* __restrict__ Bs,
                                               int i0, int j0, int tid,
                                               f32x4 (&acc)[4][4])
{
    const int lane = tid & 63, w = tid >> 6;
    const int wr = w >> 1, wc = w & 1;
    const int g = lane >> 4, lr = lane & 15;

    for (int k0 = 0; k0 < LD; k0 += 64) {
        __syncthreads();
        #pragma unroll
        for (int q = 0; q < 4; ++q) {
            int L16 = q * 256 + tid;
            int r = L16 >> 3;
            int csw = ((L16 & 7) << 4) ^ ((r & 7) << 4);
            const char* ga = (const char*)(A  + (size_t)(i0 + r) * LD + k0) + csw;
            const char* gb = (const char*)(BT + (size_t)(j0 + r) * LD + k0) + csw;
            gload16(ga, As + (size_t)L16 * 8);
            gload16(gb, Bs + (size_t)L16 * 8);
        }
        __syncthreads();
        #pragma unroll
        for (int ks = 0; ks < 2; ++ks) {
            bf16x8 af[4], bf[4];
            #pragma unroll
            for (int m = 0; m < 4; ++m) {
                int r = wr * 64 + m * 16 + lr;
                int cb = (ks * 64 + g * 16) ^ ((r & 7) << 4);
                af[m] = __builtin_bit_cast(bf16x8, *(const u16x8*)((const char*)As + r * 128 + cb));
            }
            #pragma unroll
            for (int n = 0; n < 4; ++n) {
                int r = wc * 64 + n * 16 + lr;
                int cb = (ks * 64 + g * 16) ^ ((r & 7) << 4);
                bf[n] = __builtin_bit_cast(bf16x8, *(const u16x8*)((const char*)Bs + r * 128 + cb));
            }
            #pragma unroll
            for (int m = 0; m < 4; ++m)
                #pragma unroll
                for (int n = 0; n < 4; ++n)
                    acc[m][n] = __builtin_amdgcn_mfma_f32_16x16x32_bf16(af[m], bf[n], acc[m][n], 0, 0, 0);
        }
    }
}

// ---------------- reduction helpers (256-thread blocks, 4 waves) ----------------
__device__ __forceinline__ float blockReduceSum(float v, float* sbuf) {
    #pragma unroll
    for (int off = 32; off; off >>= 1) v += __shfl_down(v, off, 64);
    __syncthreads();
    if ((threadIdx.x & 63) == 0) sbuf[threadIdx.x >> 6] = v;
    __syncthreads();
    return sbuf[0] + sbuf[1] + sbuf[2] + sbuf[3];
}
__device__ __forceinline__ float blockReduceMax(float v, float* sbuf) {
    #pragma unroll
    for (int off = 32; off; off >>= 1) v = fmaxf(v, __shfl_down(v, off, 64));
    __syncthreads();
    if ((threadIdx.x & 63) == 0) sbuf[threadIdx.x >> 6] = v;
    __syncthreads();
    return fmaxf(fmaxf(sbuf[0], sbuf[1]), fmaxf(sbuf[2], sbuf[3]));
}

// ---------------- K1a: pack feats -> bf16 A[(b,t,n), c] ----------------
__global__ __launch_bounds__(256) void k_pack(const float* __restrict__ feats,
                                              unsigned int* __restrict__ Abf32)
{
    __shared__ float lds[Cc * 9];
    int bid = blockIdx.x;
    int b = bid / Nc, n = bid % Nc;
    const float* src = feats + (size_t)(b * Nc + n) * Cc * Tc;
    int tid = threadIdx.x;
    for (int i = tid; i < Cc * Tc; i += 256) lds[(i >> 3) * 9 + (i & 7)] = src[i];
    __syncthreads();
    #pragma unroll
    for (int t = 0; t < Tc; ++t) {
        size_t row = (size_t)(b * Tc + t) * Nc + n;
        float v0 = lds[(2 * tid) * 9 + t];
        float v1 = lds[(2 * tid + 1) * 9 + t];
        unsigned int pk = (unsigned int)f2bf(v0) | ((unsigned int)f2bf(v1) << 16);
        Abf32[row * (Cc / 2) + tid] = pk;
    }
}

// ---------------- K1b: pack W -> bf16 WT[which][d][c] ----------------
__global__ __launch_bounds__(256) void k_packw(const float* __restrict__ Wself,
                                               const float* __restrict__ Wdust,
                                               unsigned short* __restrict__ WTb)
{
    __shared__ float tile[64][65];
    int which = blockIdx.z;
    const float* W = which ? Wdust : Wself;
    unsigned short* O = WTb + (size_t)which * Dc * Cc;
    int d0 = blockIdx.x * 64, c0 = blockIdx.y * 64;
    int tx = threadIdx.x & 63, ty = threadIdx.x >> 6;
    #pragma unroll
    for (int y = 0; y < 64; y += 4) tile[y + ty][tx] = W[(size_t)(c0 + y + ty) * Dc + d0 + tx];
    __syncthreads();
    #pragma unroll
    for (int y = 0; y < 64; y += 4) O[(size_t)(d0 + y + ty) * Cc + c0 + tx] = f2bf(tile[tx][y + ty]);
}

// ---------------- K1c: projection GEMM fbuf = Abf @ WT^T + bias (MFMA) ----------------
__global__ __launch_bounds__(256, 3) void k_gemm_proj(const unsigned short* __restrict__ A,
                                                      const unsigned short* __restrict__ BT,
                                                      const float* __restrict__ bias,
                                                      float* __restrict__ Cf)
{
    __shared__ __align__(16) unsigned short As[128 * 64];
    __shared__ __align__(16) unsigned short Bs[128 * 64];
    const int i0 = blockIdx.y * 128;
    const int tid = threadIdx.x, lane = tid & 63, w = tid >> 6;
    const int wr = w >> 1, wc = w & 1;
    const int g = lane >> 4, lr = lane & 15;

    f32x4 acc[4][4] = {};
    mfma_tile_loop<Cc>(A, BT, As, Bs, i0, 0, tid, acc);

    #pragma unroll
    for (int n = 0; n < 4; ++n) {
        int col = wc * 64 + n * 16 + lr;
        float bv = bias[col];
        #pragma unroll
        for (int m = 0; m < 4; ++m)
            #pragma unroll
            for (int j = 0; j < 4; ++j) {
                int row = i0 + wr * 64 + m * 16 + g * 4 + j;
                Cf[(size_t)row * Dc + col] = acc[m][n][j] + bv;
            }
    }
}

// ---------------- K1d: dust projection + l2norm (fp32 exact) ----------------
__global__ __launch_bounds__(128) void k_dustproj(const float* __restrict__ dust,
                                                  const float* __restrict__ Wdust,
                                                  const float* __restrict__ bdust,
                                                  unsigned short* __restrict__ qTb,
                                                  float* __restrict__ qout)
{
    __shared__ float sdust[Cc];
    __shared__ float red[2];
    int bt = blockIdx.x;
    int b = bt >> 3, t = bt & 7;
    int tid = threadIdx.x;
    for (int i = tid; i < Cc; i += 128) sdust[i] = dust[((size_t)b * Cc + i) * Tc + t];
    __syncthreads();
    float acc = 0.f;
    for (int c = 0; c < Cc; ++c) acc += sdust[c] * Wdust[(size_t)c * Dc + tid];
    acc += bdust[tid];
    float s = acc * acc;
    #pragma unroll
    for (int off = 32; off; off >>= 1) s += __shfl_down(s, off, 64);
    if ((tid & 63) == 0) red[tid >> 6] = s;
    __syncthreads();
    float inv = 1.f / fmaxf(sqrtf(red[0] + red[1]), 1e-12f);
    float qv = acc * inv;
    qTb[((size_t)bt * Qrows + Nc) * Dc + tid] = f2bf(qv);
    qout[(((size_t)b * Dc + tid) * Tc + t) * Mc + Nc] = qv;
}

// ---------------- K1e: l2norm rows of fbuf -> bf16 qTb + fp32 qout ----------------
__global__ __launch_bounds__(256) void k_norm(const float* __restrict__ fbuf,
                                              unsigned short* __restrict__ qTb,
                                              float* __restrict__ qout)
{
    __shared__ float lds[64][129];
    __shared__ float nrm[64][4];
    __shared__ float inv[64];
    int bt = blockIdx.y;
    int b = bt >> 3, t = bt & 7;
    int n0 = blockIdx.x * 64;
    int tid = threadIdx.x;
    #pragma unroll
    for (int q = 0; q < 8; ++q) {
        int i = q * 256 + tid;
        int nl = i >> 5, d4 = i & 31;
        f32x4 v = {};
        if (n0 + nl < Nc) v = *(const f32x4*)(fbuf + ((size_t)bt * Nc + n0 + nl) * Dc + d4 * 4);
        *(f32x4*)(&lds[nl][d4 * 4]) = v;
    }
    __syncthreads();
    {
        int r = tid & 63, p = tid >> 6;
        float s = 0.f;
        #pragma unroll
        for (int j = 0; j < 32; ++j) { float v = lds[r][p * 32 + j]; s += v * v; }
        nrm[r][p] = s;
    }
    __syncthreads();
    if (tid < 64) inv[tid] = 1.f / fmaxf(sqrtf(nrm[tid][0] + nrm[tid][1] + nrm[tid][2] + nrm[tid][3]), 1e-12f);
    __syncthreads();
    unsigned int* qT32 = (unsigned int*)(qTb + (size_t)bt * Qrows * Dc);
    #pragma unroll
    for (int q = 0; q < 16; ++q) {
        int i = q * 256 + tid;
        int nl = i >> 6, dp = i & 63;
        if (n0 + nl < Nc) {
            float iv = inv[nl];
            unsigned int pk = (unsigned int)f2bf(lds[nl][2 * dp] * iv)
                            | ((unsigned int)f2bf(lds[nl][2 * dp + 1] * iv) << 16);
            qT32[((size_t)(n0 + nl) * Dc >> 1) + dp] = pk;
        }
    }
    int nl = tid & 63;
    if (n0 + nl < Nc) {
        float iv = inv[nl];
        #pragma unroll
        for (int dd = 0; dd < Dc; dd += 4) {
            int d = dd + (tid >> 6);
            qout[(((size_t)b * Dc + d) * Tc + t) * Mc + n0 + nl] = lds[nl][d] * iv;
        }
    }
}

// ---------------- K2: fused affinity: scores -> stats -> softmax -> bf16 P ----------------
// grid (49 strips, 28 bt, 2 sides). Block owns a 16-row strip of the 784x784 core.
// side 0: core12[b,t][i,j] = <q_t[i], q_{t+1}[j]>   -> P12h[bt], colsums -> cs12
// side 1: core21[b,t][i,j] = <q_{7-t}[i], q_{6-t}[j]> -> P21h[bt], colsums -> cs21
__global__ __launch_bounds__(256) void k_affinity(const unsigned short* __restrict__ qTb,
                                                  unsigned short* __restrict__ P12h,
                                                  unsigned short* __restrict__ P21h,
                                                  float* __restrict__ cs12,
                                                  float* __restrict__ cs21,
                                                  float wconst)
{
    constexpr float INVT = 1.0f / TEMP;
    const size_t MMp = (size_t)Pp * Pp;
    int strip = blockIdx.x, bt = blockIdx.y, side = blockIdx.z;
    int b = bt / TM1, t = bt % TM1;
    const unsigned short *Aq, *Bq;
    unsigned short* OUT;
    float* cs;
    if (side == 0) {
        Aq = qTb + (size_t)(b * Tc + t)     * Qrows * Dc;
        Bq = qTb + (size_t)(b * Tc + t + 1) * Qrows * Dc;
        OUT = P12h + (size_t)bt * MMp;
        cs  = cs12 + (size_t)bt * Pp;
    } else {
        Aq = qTb + (size_t)(b * Tc + 7 - t) * Qrows * Dc;
        Bq = qTb + (size_t)(b * Tc + 6 - t) * Qrows * Dc;
        OUT = P21h + (size_t)bt * MMp;
        cs  = cs21 + (size_t)bt * Pp;
    }
    const int r0 = strip * 16;
    const int tid = threadIdx.x, lane = tid & 63, w = tid >> 6;
    const int g = lane >> 4, lr = lane & 15;

    // MFMA: wave w owns col-tiles w*13 .. w*13+12 (tiles >= 49 are padding, skipped)
    f32x4 acc[13] = {};
    #pragma unroll
    for (int ks = 0; ks < 4; ++ks) {
        bf16x8 af = __builtin_bit_cast(bf16x8,
            *(const u16x8*)(Aq + (size_t)(r0 + lr) * Dc + ks * 32 + g * 8));
        #pragma unroll
        for (int tt = 0; tt < 13; ++tt) {
            if (w * 13 + tt < 49) {
                bf16x8 bf = __builtin_bit_cast(bf16x8,
                    *(const u16x8*)(Bq + (size_t)((w * 13 + tt) * 16 + lr) * Dc + ks * 32 + g * 8));
                acc[tt] = __builtin_amdgcn_mfma_f32_16x16x32_bf16(af, bf, acc[tt], 0, 0, 0);
            }
        }
    }
    // lane holds rows r0+g*4+j (j=0..3), cols (w*13+tt)*16+lr

    __shared__ float sred[16][4][2];
    __shared__ float rowsum[16], esumS[16], invZ[16], entP[16];

    // rowsum + exp-sum partials
    float rs[4] = {0.f, 0.f, 0.f, 0.f}, es[4] = {0.f, 0.f, 0.f, 0.f};
    #pragma unroll
    for (int tt = 0; tt < 13; ++tt) {
        if (w * 13 + tt < 49) {
            #pragma unroll
            for (int j = 0; j < 4; ++j) {
                float a = acc[tt][j];
                rs[j] += a;
                es[j] += expf(a * INVT);
            }
        }
    }
    #pragma unroll
    for (int off = 1; off <= 8; off <<= 1) {
        #pragma unroll
        for (int j = 0; j < 4; ++j) {
            rs[j] += __shfl_xor(rs[j], off, 64);
            es[j] += __shfl_xor(es[j], off, 64);
        }
    }
    if (lr == 0) {
        #pragma unroll
        for (int j = 0; j < 4; ++j) { sred[g * 4 + j][w][0] = rs[j]; sred[g * 4 + j][w][1] = es[j]; }
    }
    __syncthreads();
    if (tid < 16) {
        rowsum[tid] = sred[tid][0][0] + sred[tid][1][0] + sred[tid][2][0] + sred[tid][3][0];
        esumS[tid]  = sred[tid][0][1] + sred[tid][1][1] + sred[tid][2][1] + sred[tid][3][1];
    }
    __syncthreads();

    // entropy partials (p = A / rowsum over 784 cols)
    float rsl[4];
    #pragma unroll
    for (int j = 0; j < 4; ++j) rsl[j] = rowsum[g * 4 + j];
    float en[4] = {0.f, 0.f, 0.f, 0.f};
    #pragma unroll
    for (int tt = 0; tt < 13; ++tt) {
        if (w * 13 + tt < 49) {
            #pragma unroll
            for (int j = 0; j < 4; ++j) {
                float p = acc[tt][j] / rsl[j];
                en[j] -= p * logf(fmaxf(p, 1e-20f));
            }
        }
    }
    #pragma unroll
    for (int off = 1; off <= 8; off <<= 1) {
        #pragma unroll
        for (int j = 0; j < 4; ++j) en[j] += __shfl_xor(en[j], off, 64);
    }
    if (lr == 0) {
        #pragma unroll
        for (int j = 0; j < 4; ++j) sred[g * 4 + j][w][0] = en[j];
    }
    __syncthreads();
    if (tid < 16) {
        float ent = sred[tid][0][0] + sred[tid][1][0] + sred[tid][2][0] + sred[tid][3][0];
        float ez  = expf(ent * wconst * INVT);
        float Z   = esumS[tid] + ez;
        float iz  = 1.0f / Z;
        invZ[tid] = iz;
        entP[tid] = ez * iz;
    }
    __syncthreads();

    // column-sum partials (for dust rows) -> atomics
    #pragma unroll
    for (int tt = 0; tt < 13; ++tt) {
        int gt = w * 13 + tt;
        if (gt < 49) {
            float c = acc[tt][0] + acc[tt][1] + acc[tt][2] + acc[tt][3];
            c += __shfl_xor(c, 16, 64);
            c += __shfl_xor(c, 32, 64);
            if (g == 0) atomicAdd(&cs[gt * 16 + lr], c);
        }
    }

    // softmax writes
    float izl[4];
    #pragma unroll
    for (int j = 0; j < 4; ++j) izl[j] = invZ[g * 4 + j];
    #pragma unroll
    for (int tt = 0; tt < 13; ++tt) {
        int gt = w * 13 + tt;
        int col = gt * 16 + lr;
        #pragma unroll
        for (int j = 0; j < 4; ++j) {
            int row = r0 + g * 4 + j;
            if (gt < 49)
                OUT[(size_t)row * Pp + col] = f2bf(expf(acc[tt][j] * INVT) * izl[j]);
            else if (col != 784)
                OUT[(size_t)row * Pp + col] = 0;
        }
    }
    if (tid < 16) OUT[(size_t)(r0 + tid) * Pp + 784] = f2bf(entP[tid]);
}

// ---------------- K3: dust rows (row 784) + zero pad rows ----------------
// grid (28, 2). Row vals: [-colsum_j / TEMP | 0], max-softmax, bf16.
__global__ __launch_bounds__(256) void k_dustrow(const float* __restrict__ cs12,
                                                 const float* __restrict__ cs21,
                                                 unsigned short* __restrict__ P12h,
                                                 unsigned short* __restrict__ P21h)
{
    constexpr float INVT = 1.0f / TEMP;
    const size_t MMp = (size_t)Pp * Pp;
    int bt = blockIdx.x, side = blockIdx.y;
    const float* cs = (side ? cs21 : cs12) + (size_t)bt * Pp;
    unsigned short* OUT = (side ? P21h : P12h) + (size_t)bt * MMp;
    __shared__ float sbuf[4];
    int tid = threadIdx.x;
    float v[4];
    #pragma unroll
    for (int k = 0; k < 4; ++k) {
        int j = tid + k * 256;
        float val = -INFINITY;
        if (j < Nc)       val = -cs[j] * INVT;
        else if (j == Nc) val = 0.f;
        v[k] = val;
    }
    float mx = fmaxf(fmaxf(v[0], v[1]), fmaxf(v[2], v[3]));
    mx = blockReduceMax(mx, sbuf);
    float e[4]; float s = 0.f;
    #pragma unroll
    for (int k = 0; k < 4; ++k) {
        int j = tid + k * 256;
        e[k] = (j < Mc) ? expf(v[k] - mx) : 0.f;
        s += e[k];
    }
    s = blockReduceSum(s, sbuf);
    float invs = 1.f / s;
    #pragma unroll
    for (int k = 0; k < 4; ++k) {
        int j = tid + k * 256;
        if (j < Mc)      OUT[(size_t)Nc * Pp + j] = f2bf(e[k] * invs);
        else if (j < Pp) OUT[(size_t)Nc * Pp + j] = 0;
    }
    // zero pad rows 785..831
    u16x8 z = {};
    u16x8* dst = (u16x8*)(OUT + (size_t)785 * Pp);
    for (int i = tid; i < (Pp - 785) * Pp / 8; i += 256) dst[i] = z;
}

// ---------------- K6: bf16 transpose (Pp x Pp) ----------------
__global__ __launch_bounds__(256) void k_transpose_bf16(const unsigned short* __restrict__ Sb,
                                                        unsigned short* __restrict__ Db, int mode)
{
    const size_t MMp = (size_t)Pp * Pp;
    __shared__ unsigned short tile[64][65];
    int z = blockIdx.z;
    const unsigned short* S;
    unsigned short* D;
    if (mode == 0) { int b = z / 6, tm = z % 6; S = Sb + ((size_t)b * 7 + tm + 1) * MMp; D = Db + (size_t)z * MMp; }
    else           { S = Sb + ((size_t)z * 7 + 6) * MMp; D = Db + (size_t)z * MMp; }
    int x0 = blockIdx.x * 64, y0 = blockIdx.y * 64;
    int tx = threadIdx.x & 63, ty = threadIdx.x >> 6;
    #pragma unroll
    for (int y = 0; y < 64; y += 4) tile[y + ty][tx] = S[(size_t)(y0 + y + ty) * Pp + x0 + tx];
    __syncthreads();
    #pragma unroll
    for (int y = 0; y < 64; y += 4) D[(size_t)(x0 + y + ty) * Pp + y0 + tx] = tile[tx][y + ty];
}

// ---------------- K7: fused batched MFMA GEMM, C = A @ BT^T ----------------
struct GJobs {
    const unsigned short* A[3];
    const unsigned short* BT[3];
    unsigned short* Cb[3];
    float* Cf[3];
    long long sA[3], sB[3], sC[3];
    int mode[3];
};

__global__ __launch_bounds__(256, 3) void k_gemm_mfma(GJobs J)
{
    __shared__ __align__(16) unsigned short As[128 * 64];
    __shared__ __align__(16) unsigned short Bs[128 * 64];

    int job = blockIdx.z >> 2, b = blockIdx.z & 3;
    const unsigned short* A  = J.A[job]  + (size_t)b * J.sA[job];
    const unsigned short* BT = J.BT[job] + (size_t)b * J.sB[job];
    int mode = J.mode[job];

    const int i0 = blockIdx.y * 128, j0 = blockIdx.x * 128;
    const int tid = threadIdx.x, lane = tid & 63, w = tid >> 6;
    const int wr = w >> 1, wc = w & 1;
    const int g = lane >> 4, lr = lane & 15;

    f32x4 acc[4][4] = {};
    mfma_tile_loop<Pp>(A, BT, As, Bs, i0, j0, tid, acc);

    if (mode == 0) {
        unsigned short* Co = J.Cb[job] + (size_t)b * J.sC[job];
        #pragma unroll
        for (int m = 0; m < 4; ++m)
            #pragma unroll
            for (int n = 0; n < 4; ++n)
                #pragma unroll
                for (int j = 0; j < 4; ++j) {
                    int row = i0 + wr * 64 + m * 16 + g * 4 + j;
                    int col = j0 + wc * 64 + n * 16 + lr;
                    if (row < Pp && col < Pp) Co[(size_t)row * Pp + col] = f2bf(acc[m][n][j]);
                }
    } else {
        float* Cf = J.Cf[job] + (size_t)b * J.sC[job];
        #pragma unroll
        for (int m = 0; m < 4; ++m)
            #pragma unroll
            for (int n = 0; n < 4; ++n)
                #pragma unroll
                for (int j = 0; j < 4; ++j) {
                    int row = i0 + wr * 64 + m * 16 + g * 4 + j;
                    int col = j0 + wc * 64 + n * 16 + lr;
                    if (row < Pp && col < Pp) Cf[(size_t)row * Pp + col] = acc[m][n][j];
                }
    }
}

// ---------------- K8: loss from fp32 AA (stride Pp) ----------------
__global__ __launch_bounds__(256) void k_loss(const float* __restrict__ AA, float* __restrict__ loss, float scale)
{
    const size_t MMp = (size_t)Pp * Pp;
    int r = blockIdx.x;
    int b = r / Mc, m = r % Mc;
    const float* row = AA + (size_t)b * MMp + (size_t)m * Pp;
    __shared__ float sbuf[4];
    int tid = threadIdx.x;
    float x[4]; float mx = -INFINITY;
    #pragma unroll
    for (int k = 0; k < 4; ++k) {
        int j = tid + k * 256;
        x[k] = (j < Mc) ? logf(row[j] + 1e-20f) : -INFINITY;
        mx = fmaxf(mx, x[k]);
    }
    mx = blockReduceMax(mx, sbuf);
    float s = 0.f;
    #pragma unroll
    for (int k = 0; k < 4; ++k) {
        int j = tid + k * 256;
        if (j < Mc) s += expf(x[k] - mx);
    }
    s = blockReduceSum(s, sbuf);
    if (tid == 0) {
        float xt = logf(row[m] + 1e-20f);
        atomicAdd(loss, -(xt - mx - logf(s)) * scale);
    }
}

__global__ void k_zero(float* p) { *p = 0.f; }

// ---------------- host orchestration ----------------
extern "C" void kernel_launch(void* const* d_in, const int* in_sizes, int n_in,
                              void* d_out, int out_size, void* d_ws, size_t ws_size,
                              hipStream_t stream)
{
    const float* feats = (const float*)d_in[0];
    const float* dust  = (const float*)d_in[1];
    const float* Wself = (const float*)d_in[2];
    const float* bself = (const float*)d_in[3];
    const float* Wdust = (const float*)d_in[4];
    const float* bdust = (const float*)d_in[5];

    float* out  = (float*)d_out;
    float* qout = out;
    float* loss = out + (size_t)Bc * Dc * Tc * Mc;

    const size_t MMp = (size_t)Pp * Pp;       // 692,224

    // ---- workspace (~157 MB) ----
    float* ws = (float*)d_ws;
    float* AA = ws;                                                 // 4*MMp fp32
    unsigned short* P12h = (unsigned short*)(AA + 4 * MMp);         // 28*MMp bf16
    unsigned short* P21h = P12h + (size_t)28 * MMp;                 // 28*MMp bf16
    unsigned short* chainT = P21h + (size_t)28 * MMp;               // 44*MMp bf16 region
    unsigned short* P12T  = chainT;
    unsigned short* P21T6 = P12T + (size_t)24 * MMp;
    unsigned short* l0    = P21T6 + (size_t)4 * MMp;
    unsigned short* l1    = l0 + (size_t)4 * MMp;
    unsigned short* R0    = l1 + (size_t)4 * MMp;
    unsigned short* R1    = R0 + (size_t)4 * MMp;
    unsigned short* qTb   = R1 + (size_t)4 * MMp;                   // 32*Qrows*Dc bf16
    float* cs12 = (float*)(qTb + (size_t)32 * Qrows * Dc);          // 28*Pp fp32
    float* cs21 = cs12 + (size_t)28 * Pp;                           // 28*Pp fp32

    // phase-1 overlays in chainT region (dead before transposes write it):
    unsigned short* Abf   = chainT;
    unsigned int*   Abf32 = (unsigned int*)Abf;
    unsigned short* WTb   = Abf + (size_t)Bc * Tc * Nc * Cc;
    float*          fbuf  = (float*)(WTb + 2 * (size_t)Dc * Cc);

    // 1. pack inputs to bf16
    k_pack<<<Bc * Nc, 256, 0, stream>>>(feats, Abf32);
    k_packw<<<dim3(2, 8, 2), 256, 0, stream>>>(Wself, Wdust, WTb);
    hipMemsetAsync(cs12, 0, (size_t)2 * 28 * Pp * sizeof(float), stream);
    // 2. projection GEMM + bias
    k_gemm_proj<<<dim3(1, 196), 256, 0, stream>>>(Abf, WTb, bself, fbuf);
    // 3. dust projection (fp32) + norms
    k_dustproj<<<32, 128, 0, stream>>>(dust, Wdust, bdust, qTb, qout);
    k_norm<<<dim3(13, 32), 256, 0, stream>>>(fbuf, qTb, qout);
    // 4. fused affinity (scores+entropy+softmax+colsums), then dust rows
    float wconst = (float)(1.0 / log(784.0));
    k_affinity<<<dim3(49, 28, 2), 256, 0, stream>>>(qTb, P12h, P21h, cs12, cs21, wconst);
    k_dustrow<<<dim3(28, 2), 256, 0, stream>>>(cs12, cs21, P12h, P21h);
    // 5. bf16 transposes
    k_transpose_bf16<<<dim3(13, 13, 24), 256, 0, stream>>>(P12h, P12T, 0);
    k_transpose_bf16<<<dim3(13, 13, 4),  256, 0, stream>>>(P21h, P21T6, 1);

    // 6. chain
    k_zero<<<1, 1, 0, stream>>>(loss);
    const float scale = 1.0f / (6.0f * Bc * Mc);

    {
        GJobs J = {};
        J.A[0] = P12h;  J.sA[0] = (long long)7 * MMp;
        J.BT[0] = P12T; J.sB[0] = (long long)6 * MMp;
        J.Cb[0] = l0;   J.sC[0] = (long long)MMp; J.mode[0] = 0;
        J.A[1] = P21T6;                   J.sA[1] = (long long)MMp;
        J.BT[1] = P21h + (size_t)5 * MMp; J.sB[1] = (long long)7 * MMp;
        J.Cb[1] = R0;   J.sC[1] = (long long)MMp; J.mode[1] = 0;
        k_gemm_mfma<<<dim3(7, 7, 8), 256, 0, stream>>>(J);
    }

    unsigned short *lcur = l0, *lnxt = l1, *rcur = R0, *rnxt = R1;
    for (int i = 1; i <= 6; ++i) {
        GJobs J = {};
        int nj = 0;
        J.A[nj] = lcur; J.sA[nj] = (long long)MMp;
        J.BT[nj] = rcur; J.sB[nj] = (long long)MMp;
        J.Cf[nj] = AA;  J.sC[nj] = (long long)MMp; J.mode[nj] = 1; nj++;
        if (i < 6) {
            J.A[nj] = lcur; J.sA[nj] = (long long)MMp;
            J.BT[nj] = P12T + (size_t)i * MMp; J.sB[nj] = (long long)6 * MMp;
            J.Cb[nj] = lnxt; J.sC[nj] = (long long)MMp; J.mode[nj] = 0; nj++;
            J.A[nj] = rcur; J.sA[nj] = (long long)MMp;
            J.BT[nj] = P21h + (size_t)(5 - i) * MMp; J.sB[nj] = (long long)7 * MMp;
            J.Cb[nj] = rnxt; J.sC[nj] = (long long)MMp; J.mode[nj] = 0; nj++;
        }
        k_gemm_mfma<<<dim3(7, 7, 4 * nj), 256, 0, stream>>>(J);
        k_loss<<<Bc * Mc, 256, 0, stream>>>(AA, loss, scale);
        if (i < 6) {
            unsigned short* t;
            t = lcur; lcur = lnxt; lnxt = t;
            t = rcur; rcur = rnxt; rnxt = t;
        }
    }
}

// Round 6
// 661.473 us; speedup vs baseline: 5.9494x; 1.0327x over previous
//
#include <hip/hip_runtime.h>
#include <hip/hip_bf16.h>
#include <math.h>

// Problem constants
constexpr int Bc = 4;      // batch
constexpr int Nc = 784;    // tokens
constexpr int Cc = 512;    // enc channels
constexpr int Tc = 8;      // time
constexpr int Dc = 128;    // proj dim
constexpr int Mc = 785;    // N+1
constexpr int TM1 = 7;     // T-1
constexpr int Pp = 832;    // padded chain dim (13*64)
constexpr int Qrows = 896; // padded q rows
constexpr float TEMP = 0.07f;

typedef __attribute__((ext_vector_type(4))) float f32x4;
typedef __attribute__((ext_vector_type(8))) unsigned short u16x8;
typedef __attribute__((ext_vector_type(8))) __bf16 bf16x8;

__device__ __forceinline__ unsigned short f2bf(float v) {
    __hip_bfloat16 h = __float2bfloat16(v);
    return __builtin_bit_cast(unsigned short, h);
}

// ---------------- async 16B global->LDS ----------------
__device__ __forceinline__ void gload16(const void* g, void* l) {
    __builtin_amdgcn_global_load_lds(
        (const __attribute__((address_space(1))) unsigned int*)g,
        (__attribute__((address_space(3))) unsigned int*)l, 16, 0, 0);
}

// Shared MFMA K-loop: 128x128 C-tile, BK=64, 4 waves, global_load_lds staging
// with XOR-16B involution swizzle.
template<int LD>
__device__ __forceinline__ void mfma_tile_loop(const unsigned short* __restrict__ A,
                                               const unsigned short* __restrict__ BT,
                                               unsigned short* __restrict__ As,
                                               unsigned short* __restrict__ Bs,
                                               int i0, int j0, int tid,
                                               f32x4 (&acc)[4][4])
{
    const int lane = tid & 63, w = tid >> 6;
    const int wr = w >> 1, wc = w & 1;
    const int g = lane >> 4, lr = lane & 15;

    for (int k0 = 0; k0 < LD; k0 += 64) {
        __syncthreads();
        #pragma unroll
        for (int q = 0; q < 4; ++q) {
            int L16 = q * 256 + tid;
            int r = L16 >> 3;
            int csw = ((L16 & 7) << 4) ^ ((r & 7) << 4);
            const char* ga = (const char*)(A  + (size_t)(i0 + r) * LD + k0) + csw;
            const char* gb = (const char*)(BT + (size_t)(j0 + r) * LD + k0) + csw;
            gload16(ga, As + (size_t)L16 * 8);
            gload16(gb, Bs + (size_t)L16 * 8);
        }
        __syncthreads();
        #pragma unroll
        for (int ks = 0; ks < 2; ++ks) {
            bf16x8 af[4], bf[4];
            #pragma unroll
            for (int m = 0; m < 4; ++m) {
                int r = wr * 64 + m * 16 + lr;
                int cb = (ks * 64 + g * 16) ^ ((r & 7) << 4);
                af[m] = __builtin_bit_cast(bf16x8, *(const u16x8*)((const char*)As + r * 128 + cb));
            }
            #pragma unroll
            for (int n = 0; n < 4; ++n) {
                int r = wc * 64 + n * 16 + lr;
                int cb = (ks * 64 + g * 16) ^ ((r & 7) << 4);
                bf[n] = __builtin_bit_cast(bf16x8, *(const u16x8*)((const char*)Bs + r * 128 + cb));
            }
            #pragma unroll
            for (int m = 0; m < 4; ++m)
                #pragma unroll
                for (int n = 0; n < 4; ++n)
                    acc[m][n] = __builtin_amdgcn_mfma_f32_16x16x32_bf16(af[m], bf[n], acc[m][n], 0, 0, 0);
        }
    }
}

// ---------------- reduction helpers (256-thread blocks, 4 waves) ----------------
__device__ __forceinline__ float blockReduceSum(float v, float* sbuf) {
    #pragma unroll
    for (int off = 32; off; off >>= 1) v += __shfl_down(v, off, 64);
    __syncthreads();
    if ((threadIdx.x & 63) == 0) sbuf[threadIdx.x >> 6] = v;
    __syncthreads();
    return sbuf[0] + sbuf[1] + sbuf[2] + sbuf[3];
}
__device__ __forceinline__ float blockReduceMax(float v, float* sbuf) {
    #pragma unroll
    for (int off = 32; off; off >>= 1) v = fmaxf(v, __shfl_down(v, off, 64));
    __syncthreads();
    if ((threadIdx.x & 63) == 0) sbuf[threadIdx.x >> 6] = v;
    __syncthreads();
    return fmaxf(fmaxf(sbuf[0], sbuf[1]), fmaxf(sbuf[2], sbuf[3]));
}

// ---------------- K1a: pack feats -> bf16 A[(b,t,n), c] ----------------
__global__ __launch_bounds__(256) void k_pack(const float* __restrict__ feats,
                                              unsigned int* __restrict__ Abf32)
{
    __shared__ float lds[Cc * 9];
    int bid = blockIdx.x;
    int b = bid / Nc, n = bid % Nc;
    const float* src = feats + (size_t)(b * Nc + n) * Cc * Tc;
    int tid = threadIdx.x;
    for (int i = tid; i < Cc * Tc; i += 256) lds[(i >> 3) * 9 + (i & 7)] = src[i];
    __syncthreads();
    #pragma unroll
    for (int t = 0; t < Tc; ++t) {
        size_t row = (size_t)(b * Tc + t) * Nc + n;
        float v0 = lds[(2 * tid) * 9 + t];
        float v1 = lds[(2 * tid + 1) * 9 + t];
        unsigned int pk = (unsigned int)f2bf(v0) | ((unsigned int)f2bf(v1) << 16);
        Abf32[row * (Cc / 2) + tid] = pk;
    }
}

// ---------------- K1b: pack W -> bf16 WT[which][d][c] ----------------
__global__ __launch_bounds__(256) void k_packw(const float* __restrict__ Wself,
                                               const float* __restrict__ Wdust,
                                               unsigned short* __restrict__ WTb)
{
    __shared__ float tile[64][65];
    int which = blockIdx.z;
    const float* W = which ? Wdust : Wself;
    unsigned short* O = WTb + (size_t)which * Dc * Cc;
    int d0 = blockIdx.x * 64, c0 = blockIdx.y * 64;
    int tx = threadIdx.x & 63, ty = threadIdx.x >> 6;
    #pragma unroll
    for (int y = 0; y < 64; y += 4) tile[y + ty][tx] = W[(size_t)(c0 + y + ty) * Dc + d0 + tx];
    __syncthreads();
    #pragma unroll
    for (int y = 0; y < 64; y += 4) O[(size_t)(d0 + y + ty) * Cc + c0 + tx] = f2bf(tile[tx][y + ty]);
}

// ---------------- K1c: projection GEMM fbuf = Abf @ WT^T + bias (MFMA) ----------------
__global__ __launch_bounds__(256, 3) void k_gemm_proj(const unsigned short* __restrict__ A,
                                                      const unsigned short* __restrict__ BT,
                                                      const float* __restrict__ bias,
                                                      float* __restrict__ Cf)
{
    __shared__ __align__(16) unsigned short As[128 * 64];
    __shared__ __align__(16) unsigned short Bs[128 * 64];
    const int i0 = blockIdx.y * 128;
    const int tid = threadIdx.x, lane = tid & 63, w = tid >> 6;
    const int wr = w >> 1, wc = w & 1;
    const int g = lane >> 4, lr = lane & 15;

    f32x4 acc[4][4] = {};
    mfma_tile_loop<Cc>(A, BT, As, Bs, i0, 0, tid, acc);

    #pragma unroll
    for (int n = 0; n < 4; ++n) {
        int col = wc * 64 + n * 16 + lr;
        float bv = bias[col];
        #pragma unroll
        for (int m = 0; m < 4; ++m)
            #pragma unroll
            for (int j = 0; j < 4; ++j) {
                int row = i0 + wr * 64 + m * 16 + g * 4 + j;
                Cf[(size_t)row * Dc + col] = acc[m][n][j] + bv;
            }
    }
}

// ---------------- K1d: dust projection + l2norm (fp32 exact) ----------------
__global__ __launch_bounds__(128) void k_dustproj(const float* __restrict__ dust,
                                                  const float* __restrict__ Wdust,
                                                  const float* __restrict__ bdust,
                                                  unsigned short* __restrict__ qTb,
                                                  float* __restrict__ qout)
{
    __shared__ float sdust[Cc];
    __shared__ float red[2];
    int bt = blockIdx.x;
    int b = bt >> 3, t = bt & 7;
    int tid = threadIdx.x;
    for (int i = tid; i < Cc; i += 128) sdust[i] = dust[((size_t)b * Cc + i) * Tc + t];
    __syncthreads();
    float acc = 0.f;
    for (int c = 0; c < Cc; ++c) acc += sdust[c] * Wdust[(size_t)c * Dc + tid];
    acc += bdust[tid];
    float s = acc * acc;
    #pragma unroll
    for (int off = 32; off; off >>= 1) s += __shfl_down(s, off, 64);
    if ((tid & 63) == 0) red[tid >> 6] = s;
    __syncthreads();
    float inv = 1.f / fmaxf(sqrtf(red[0] + red[1]), 1e-12f);
    float qv = acc * inv;
    qTb[((size_t)bt * Qrows + Nc) * Dc + tid] = f2bf(qv);
    qout[(((size_t)b * Dc + tid) * Tc + t) * Mc + Nc] = qv;
}

// ---------------- K1e: l2norm rows of fbuf -> bf16 qTb + fp32 qout ----------------
__global__ __launch_bounds__(256) void k_norm(const float* __restrict__ fbuf,
                                              unsigned short* __restrict__ qTb,
                                              float* __restrict__ qout)
{
    __shared__ float lds[64][129];
    __shared__ float nrm[64][4];
    __shared__ float inv[64];
    int bt = blockIdx.y;
    int b = bt >> 3, t = bt & 7;
    int n0 = blockIdx.x * 64;
    int tid = threadIdx.x;
    #pragma unroll
    for (int q = 0; q < 8; ++q) {
        int i = q * 256 + tid;
        int nl = i >> 5, d4 = i & 31;
        f32x4 v = {};
        if (n0 + nl < Nc) v = *(const f32x4*)(fbuf + ((size_t)bt * Nc + n0 + nl) * Dc + d4 * 4);
        *(f32x4*)(&lds[nl][d4 * 4]) = v;
    }
    __syncthreads();
    {
        int r = tid & 63, p = tid >> 6;
        float s = 0.f;
        #pragma unroll
        for (int j = 0; j < 32; ++j) { float v = lds[r][p * 32 + j]; s += v * v; }
        nrm[r][p] = s;
    }
    __syncthreads();
    if (tid < 64) inv[tid] = 1.f / fmaxf(sqrtf(nrm[tid][0] + nrm[tid][1] + nrm[tid][2] + nrm[tid][3]), 1e-12f);
    __syncthreads();
    unsigned int* qT32 = (unsigned int*)(qTb + (size_t)bt * Qrows * Dc);
    #pragma unroll
    for (int q = 0; q < 16; ++q) {
        int i = q * 256 + tid;
        int nl = i >> 6, dp = i & 63;
        if (n0 + nl < Nc) {
            float iv = inv[nl];
            unsigned int pk = (unsigned int)f2bf(lds[nl][2 * dp] * iv)
                            | ((unsigned int)f2bf(lds[nl][2 * dp + 1] * iv) << 16);
            qT32[((size_t)(n0 + nl) * Dc >> 1) + dp] = pk;
        }
    }
    int nl = tid & 63;
    if (n0 + nl < Nc) {
        float iv = inv[nl];
        #pragma unroll
        for (int dd = 0; dd < Dc; dd += 4) {
            int d = dd + (tid >> 6);
            qout[(((size_t)b * Dc + d) * Tc + t) * Mc + n0 + nl] = lds[nl][d] * iv;
        }
    }
}

// ---------------- K2: fused affinity: scores -> stats -> softmax -> bf16 P ----------------
// grid (49 strips, 28 bt, 2 sides). Block owns a 16-row strip of the 784x784 core.
__global__ __launch_bounds__(256) void k_affinity(const unsigned short* __restrict__ qTb,
                                                  unsigned short* __restrict__ P12h,
                                                  unsigned short* __restrict__ P21h,
                                                  float* __restrict__ cs12,
                                                  float* __restrict__ cs21,
                                                  float wconst)
{
    constexpr float INVT = 1.0f / TEMP;
    const size_t MMp = (size_t)Pp * Pp;
    int strip = blockIdx.x, bt = blockIdx.y, side = blockIdx.z;
    int b = bt / TM1, t = bt % TM1;
    const unsigned short *Aq, *Bq;
    unsigned short* OUT;
    float* cs;
    if (side == 0) {
        Aq = qTb + (size_t)(b * Tc + t)     * Qrows * Dc;
        Bq = qTb + (size_t)(b * Tc + t + 1) * Qrows * Dc;
        OUT = P12h + (size_t)bt * MMp;
        cs  = cs12 + (size_t)bt * Pp;
    } else {
        Aq = qTb + (size_t)(b * Tc + 7 - t) * Qrows * Dc;
        Bq = qTb + (size_t)(b * Tc + 6 - t) * Qrows * Dc;
        OUT = P21h + (size_t)bt * MMp;
        cs  = cs21 + (size_t)bt * Pp;
    }
    const int r0 = strip * 16;
    const int tid = threadIdx.x, lane = tid & 63, w = tid >> 6;
    const int g = lane >> 4, lr = lane & 15;

    // MFMA: wave w owns col-tiles w*13 .. w*13+12 (tiles >= 49 are padding, skipped)
    f32x4 acc[13] = {};
    #pragma unroll
    for (int ks = 0; ks < 4; ++ks) {
        bf16x8 af = __builtin_bit_cast(bf16x8,
            *(const u16x8*)(Aq + (size_t)(r0 + lr) * Dc + ks * 32 + g * 8));
        #pragma unroll
        for (int tt = 0; tt < 13; ++tt) {
            if (w * 13 + tt < 49) {
                bf16x8 bf = __builtin_bit_cast(bf16x8,
                    *(const u16x8*)(Bq + (size_t)((w * 13 + tt) * 16 + lr) * Dc + ks * 32 + g * 8));
                acc[tt] = __builtin_amdgcn_mfma_f32_16x16x32_bf16(af, bf, acc[tt], 0, 0, 0);
            }
        }
    }
    // lane holds rows r0+g*4+j (j=0..3), cols (w*13+tt)*16+lr

    __shared__ float sred[16][4][2];
    __shared__ float rowsum[16], esumS[16], invZ[16], entP[16];

    // rowsum + exp-sum partials (native exp)
    float rs[4] = {0.f, 0.f, 0.f, 0.f}, es[4] = {0.f, 0.f, 0.f, 0.f};
    #pragma unroll
    for (int tt = 0; tt < 13; ++tt) {
        if (w * 13 + tt < 49) {
            #pragma unroll
            for (int j = 0; j < 4; ++j) {
                float a = acc[tt][j];
                rs[j] += a;
                es[j] += __expf(a * INVT);
            }
        }
    }
    #pragma unroll
    for (int off = 1; off <= 8; off <<= 1) {
        #pragma unroll
        for (int j = 0; j < 4; ++j) {
            rs[j] += __shfl_xor(rs[j], off, 64);
            es[j] += __shfl_xor(es[j], off, 64);
        }
    }
    if (lr == 0) {
        #pragma unroll
        for (int j = 0; j < 4; ++j) { sred[g * 4 + j][w][0] = rs[j]; sred[g * 4 + j][w][1] = es[j]; }
    }
    __syncthreads();
    if (tid < 16) {
        rowsum[tid] = sred[tid][0][0] + sred[tid][1][0] + sred[tid][2][0] + sred[tid][3][0];
        esumS[tid]  = sred[tid][0][1] + sred[tid][1][1] + sred[tid][2][1] + sred[tid][3][1];
    }
    __syncthreads();

    // entropy partials (p = A * (1/rowsum), native log)
    float invr[4];
    #pragma unroll
    for (int j = 0; j < 4; ++j) invr[j] = 1.0f / rowsum[g * 4 + j];
    float en[4] = {0.f, 0.f, 0.f, 0.f};
    #pragma unroll
    for (int tt = 0; tt < 13; ++tt) {
        if (w * 13 + tt < 49) {
            #pragma unroll
            for (int j = 0; j < 4; ++j) {
                float p = acc[tt][j] * invr[j];
                en[j] -= p * __logf(fmaxf(p, 1e-20f));
            }
        }
    }
    #pragma unroll
    for (int off = 1; off <= 8; off <<= 1) {
        #pragma unroll
        for (int j = 0; j < 4; ++j) en[j] += __shfl_xor(en[j], off, 64);
    }
    if (lr == 0) {
        #pragma unroll
        for (int j = 0; j < 4; ++j) sred[g * 4 + j][w][0] = en[j];
    }
    __syncthreads();
    if (tid < 16) {
        float ent = sred[tid][0][0] + sred[tid][1][0] + sred[tid][2][0] + sred[tid][3][0];
        float ez  = __expf(ent * wconst * INVT);
        float Z   = esumS[tid] + ez;
        float iz  = 1.0f / Z;
        invZ[tid] = iz;
        entP[tid] = ez * iz;
    }
    __syncthreads();

    // column-sum partials (for dust rows) -> atomics
    #pragma unroll
    for (int tt = 0; tt < 13; ++tt) {
        int gt = w * 13 + tt;
        if (gt < 49) {
            float c = acc[tt][0] + acc[tt][1] + acc[tt][2] + acc[tt][3];
            c += __shfl_xor(c, 16, 64);
            c += __shfl_xor(c, 32, 64);
            if (g == 0) atomicAdd(&cs[gt * 16 + lr], c);
        }
    }

    // softmax writes (native exp)
    float izl[4];
    #pragma unroll
    for (int j = 0; j < 4; ++j) izl[j] = invZ[g * 4 + j];
    #pragma unroll
    for (int tt = 0; tt < 13; ++tt) {
        int gt = w * 13 + tt;
        int col = gt * 16 + lr;
        #pragma unroll
        for (int j = 0; j < 4; ++j) {
            int row = r0 + g * 4 + j;
            if (gt < 49)
                OUT[(size_t)row * Pp + col] = f2bf(__expf(acc[tt][j] * INVT) * izl[j]);
            else if (col != 784)
                OUT[(size_t)row * Pp + col] = 0;
        }
    }
    if (tid < 16) OUT[(size_t)(r0 + tid) * Pp + 784] = f2bf(entP[tid]);
}

// ---------------- K3: dust rows (row 784) + zero pad rows ----------------
__global__ __launch_bounds__(256) void k_dustrow(const float* __restrict__ cs12,
                                                 const float* __restrict__ cs21,
                                                 unsigned short* __restrict__ P12h,
                                                 unsigned short* __restrict__ P21h)
{
    constexpr float INVT = 1.0f / TEMP;
    const size_t MMp = (size_t)Pp * Pp;
    int bt = blockIdx.x, side = blockIdx.y;
    const float* cs = (side ? cs21 : cs12) + (size_t)bt * Pp;
    unsigned short* OUT = (side ? P21h : P12h) + (size_t)bt * MMp;
    __shared__ float sbuf[4];
    int tid = threadIdx.x;
    float v[4];
    #pragma unroll
    for (int k = 0; k < 4; ++k) {
        int j = tid + k * 256;
        float val = -INFINITY;
        if (j < Nc)       val = -cs[j] * INVT;
        else if (j == Nc) val = 0.f;
        v[k] = val;
    }
    float mx = fmaxf(fmaxf(v[0], v[1]), fmaxf(v[2], v[3]));
    mx = blockReduceMax(mx, sbuf);
    float e[4]; float s = 0.f;
    #pragma unroll
    for (int k = 0; k < 4; ++k) {
        int j = tid + k * 256;
        e[k] = (j < Mc) ? __expf(v[k] - mx) : 0.f;
        s += e[k];
    }
    s = blockReduceSum(s, sbuf);
    float invs = 1.f / s;
    #pragma unroll
    for (int k = 0; k < 4; ++k) {
        int j = tid + k * 256;
        if (j < Mc)      OUT[(size_t)Nc * Pp + j] = f2bf(e[k] * invs);
        else if (j < Pp) OUT[(size_t)Nc * Pp + j] = 0;
    }
    // zero pad rows 785..831
    u16x8 z = {};
    u16x8* dst = (u16x8*)(OUT + (size_t)785 * Pp);
    for (int i = tid; i < (Pp - 785) * Pp / 8; i += 256) dst[i] = z;
}

// ---------------- K6: bf16 transpose (Pp x Pp) ----------------
__global__ __launch_bounds__(256) void k_transpose_bf16(const unsigned short* __restrict__ Sb,
                                                        unsigned short* __restrict__ Db, int mode)
{
    const size_t MMp = (size_t)Pp * Pp;
    __shared__ unsigned short tile[64][65];
    int z = blockIdx.z;
    const unsigned short* S;
    unsigned short* D;
    if (mode == 0) { int b = z / 6, tm = z % 6; S = Sb + ((size_t)b * 7 + tm + 1) * MMp; D = Db + (size_t)z * MMp; }
    else           { S = Sb + ((size_t)z * 7 + 6) * MMp; D = Db + (size_t)z * MMp; }
    int x0 = blockIdx.x * 64, y0 = blockIdx.y * 64;
    int tx = threadIdx.x & 63, ty = threadIdx.x >> 6;
    #pragma unroll
    for (int y = 0; y < 64; y += 4) tile[y + ty][tx] = S[(size_t)(y0 + y + ty) * Pp + x0 + tx];
    __syncthreads();
    #pragma unroll
    for (int y = 0; y < 64; y += 4) D[(size_t)(x0 + y + ty) * Pp + y0 + tx] = tile[tx][y + ty];
}

// ---------------- K7: fused batched MFMA GEMM, C = A @ BT^T ----------------
struct GJobs {
    const unsigned short* A[3];
    const unsigned short* BT[3];
    unsigned short* Cb[3];
    float* Cf[3];
    long long sA[3], sB[3], sC[3];
    int mode[3];
};

__global__ __launch_bounds__(256, 3) void k_gemm_mfma(GJobs J)
{
    __shared__ __align__(16) unsigned short As[128 * 64];
    __shared__ __align__(16) unsigned short Bs[128 * 64];

    int job = blockIdx.z >> 2, b = blockIdx.z & 3;
    const unsigned short* A  = J.A[job]  + (size_t)b * J.sA[job];
    const unsigned short* BT = J.BT[job] + (size_t)b * J.sB[job];
    int mode = J.mode[job];

    const int i0 = blockIdx.y * 128, j0 = blockIdx.x * 128;
    const int tid = threadIdx.x, lane = tid & 63, w = tid >> 6;
    const int wr = w >> 1, wc = w & 1;
    const int g = lane >> 4, lr = lane & 15;

    f32x4 acc[4][4] = {};
    mfma_tile_loop<Pp>(A, BT, As, Bs, i0, j0, tid, acc);

    if (mode == 0) {
        unsigned short* Co = J.Cb[job] + (size_t)b * J.sC[job];
        #pragma unroll
        for (int m = 0; m < 4; ++m)
            #pragma unroll
            for (int n = 0; n < 4; ++n)
                #pragma unroll
                for (int j = 0; j < 4; ++j) {
                    int row = i0 + wr * 64 + m * 16 + g * 4 + j;
                    int col = j0 + wc * 64 + n * 16 + lr;
                    if (row < Pp && col < Pp) Co[(size_t)row * Pp + col] = f2bf(acc[m][n][j]);
                }
    } else {
        float* Cf = J.Cf[job] + (size_t)b * J.sC[job];
        #pragma unroll
        for (int m = 0; m < 4; ++m)
            #pragma unroll
            for (int n = 0; n < 4; ++n)
                #pragma unroll
                for (int j = 0; j < 4; ++j) {
                    int row = i0 + wr * 64 + m * 16 + g * 4 + j;
                    int col = j0 + wc * 64 + n * 16 + lr;
                    if (row < Pp && col < Pp) Cf[(size_t)row * Pp + col] = acc[m][n][j];
                }
    }
}

// ---------------- K8: loss from fp32 AA (stride Pp) ----------------
// -log_softmax[m] = log(sum_j (AA[j]+eps)) - log(AA[m]+eps)   (exact algebra)
__global__ __launch_bounds__(256) void k_loss(const float* __restrict__ AA, float* __restrict__ loss, float scale)
{
    const size_t MMp = (size_t)Pp * Pp;
    int r = blockIdx.x;
    int b = r / Mc, m = r % Mc;
    const float* row = AA + (size_t)b * MMp + (size_t)m * Pp;
    __shared__ float sbuf[4];
    int tid = threadIdx.x;
    float s = 0.f;
    #pragma unroll
    for (int k = 0; k < 4; ++k) {
        int j = tid + k * 256;
        if (j < Mc) s += row[j] + 1e-20f;
    }
    s = blockReduceSum(s, sbuf);
    if (tid == 0) {
        float xt = logf(row[m] + 1e-20f);
        atomicAdd(loss, (logf(s) - xt) * scale);
    }
}

__global__ void k_zero(float* p) { *p = 0.f; }

// ---------------- host orchestration ----------------
extern "C" void kernel_launch(void* const* d_in, const int* in_sizes, int n_in,
                              void* d_out, int out_size, void* d_ws, size_t ws_size,
                              hipStream_t stream)
{
    const float* feats = (const float*)d_in[0];
    const float* dust  = (const float*)d_in[1];
    const float* Wself = (const float*)d_in[2];
    const float* bself = (const float*)d_in[3];
    const float* Wdust = (const float*)d_in[4];
    const float* bdust = (const float*)d_in[5];

    float* out  = (float*)d_out;
    float* qout = out;
    float* loss = out + (size_t)Bc * Dc * Tc * Mc;

    const size_t MMp = (size_t)Pp * Pp;       // 692,224

    // ---- workspace (~157 MB) ----
    float* ws = (float*)d_ws;
    float* AA = ws;                                                 // 4*MMp fp32
    unsigned short* P12h = (unsigned short*)(AA + 4 * MMp);         // 28*MMp bf16
    unsigned short* P21h = P12h + (size_t)28 * MMp;                 // 28*MMp bf16
    unsigned short* chainT = P21h + (size_t)28 * MMp;               // 44*MMp bf16 region
    unsigned short* P12T  = chainT;
    unsigned short* P21T6 = P12T + (size_t)24 * MMp;
    unsigned short* l0    = P21T6 + (size_t)4 * MMp;
    unsigned short* l1    = l0 + (size_t)4 * MMp;
    unsigned short* R0    = l1 + (size_t)4 * MMp;
    unsigned short* R1    = R0 + (size_t)4 * MMp;
    unsigned short* qTb   = R1 + (size_t)4 * MMp;                   // 32*Qrows*Dc bf16
    float* cs12 = (float*)(qTb + (size_t)32 * Qrows * Dc);          // 28*Pp fp32
    float* cs21 = cs12 + (size_t)28 * Pp;                           // 28*Pp fp32

    // phase-1 overlays in chainT region (dead before transposes write it):
    unsigned short* Abf   = chainT;
    unsigned int*   Abf32 = (unsigned int*)Abf;
    unsigned short* WTb   = Abf + (size_t)Bc * Tc * Nc * Cc;
    float*          fbuf  = (float*)(WTb + 2 * (size_t)Dc * Cc);

    // 1. pack inputs to bf16
    k_pack<<<Bc * Nc, 256, 0, stream>>>(feats, Abf32);
    k_packw<<<dim3(2, 8, 2), 256, 0, stream>>>(Wself, Wdust, WTb);
    hipMemsetAsync(cs12, 0, (size_t)2 * 28 * Pp * sizeof(float), stream);
    // 2. projection GEMM + bias
    k_gemm_proj<<<dim3(1, 196), 256, 0, stream>>>(Abf, WTb, bself, fbuf);
    // 3. dust projection (fp32) + norms
    k_dustproj<<<32, 128, 0, stream>>>(dust, Wdust, bdust, qTb, qout);
    k_norm<<<dim3(13, 32), 256, 0, stream>>>(fbuf, qTb, qout);
    // 4. fused affinity (scores+entropy+softmax+colsums), then dust rows
    float wconst = (float)(1.0 / log(784.0));
    k_affinity<<<dim3(49, 28, 2), 256, 0, stream>>>(qTb, P12h, P21h, cs12, cs21, wconst);
    k_dustrow<<<dim3(28, 2), 256, 0, stream>>>(cs12, cs21, P12h, P21h);
    // 5. bf16 transposes
    k_transpose_bf16<<<dim3(13, 13, 24), 256, 0, stream>>>(P12h, P12T, 0);
    k_transpose_bf16<<<dim3(13, 13, 4),  256, 0, stream>>>(P21h, P21T6, 1);

    // 6. chain
    k_zero<<<1, 1, 0, stream>>>(loss);
    const float scale = 1.0f / (6.0f * Bc * Mc);

    {
        GJobs J = {};
        J.A[0] = P12h;  J.sA[0] = (long long)7 * MMp;
        J.BT[0] = P12T; J.sB[0] = (long long)6 * MMp;
        J.Cb[0] = l0;   J.sC[0] = (long long)MMp; J.mode[0] = 0;
        J.A[1] = P21T6;                   J.sA[1] = (long long)MMp;
        J.BT[1] = P21h + (size_t)5 * MMp; J.sB[1] = (long long)7 * MMp;
        J.Cb[1] = R0;   J.sC[1] = (long long)MMp; J.mode[1] = 0;
        k_gemm_mfma<<<dim3(7, 7, 8), 256, 0, stream>>>(J);
    }

    unsigned short *lcur = l0, *lnxt = l1, *rcur = R0, *rnxt = R1;
    for (int i = 1; i <= 6; ++i) {
        GJobs J = {};
        int nj = 0;
        J.A[nj] = lcur; J.sA[nj] = (long long)MMp;
        J.BT[nj] = rcur; J.sB[nj] = (long long)MMp;
        J.Cf[nj] = AA;  J.sC[nj] = (long long)MMp; J.mode[nj] = 1; nj++;
        if (i < 6) {
            J.A[nj] = lcur; J.sA[nj] = (long long)MMp;
            J.BT[nj] = P12T + (size_t)i * MMp; J.sB[nj] = (long long)6 * MMp;
            J.Cb[nj] = lnxt; J.sC[nj] = (long long)MMp; J.mode[nj] = 0; nj++;
            J.A[nj] = rcur; J.sA[nj] = (long long)MMp;
            J.BT[nj] = P21h + (size_t)(5 - i) * MMp; J.sB[nj] = (long long)7 * MMp;
            J.Cb[nj] = rnxt; J.sC[nj] = (long long)MMp; J.mode[nj] = 0; nj++;
        }
        k_gemm_mfma<<<dim3(7, 7, 4 * nj), 256, 0, stream>>>(J);
        k_loss<<<Bc * Mc, 256, 0, stream>>>(AA, loss, scale);
        if (i < 6) {
            unsigned short* t;
            t = lcur; lcur = lnxt; lnxt = t;
            t = rcur; rcur = rnxt; rnxt = t;
        }
    }
}

// Round 7
// 608.325 us; speedup vs baseline: 6.4692x; 1.0874x over previous
//
#include <hip/hip_runtime.h>
#include <hip/hip_bf16.h>
#include <math.h>

// Problem constants
constexpr int Bc = 4;      // batch
constexpr int Nc = 784;    // tokens
constexpr int Cc = 512;    // enc channels
constexpr int Tc = 8;      // time
constexpr int Dc = 128;    // proj dim
constexpr int Mc = 785;    // N+1
constexpr int TM1 = 7;     // T-1
constexpr int Pp = 832;    // padded chain dim (13*64)
constexpr int Qrows = 896; // padded q rows
constexpr float TEMP = 0.07f;

typedef __attribute__((ext_vector_type(4))) float f32x4;
typedef __attribute__((ext_vector_type(8))) unsigned short u16x8;
typedef __attribute__((ext_vector_type(8))) __bf16 bf16x8;

__device__ __forceinline__ unsigned short f2bf(float v) {
    __hip_bfloat16 h = __float2bfloat16(v);
    return __builtin_bit_cast(unsigned short, h);
}
__device__ __forceinline__ float bf2f(unsigned short u) {
    return __builtin_bit_cast(float, (unsigned int)u << 16);
}

// ---------------- async 16B global->LDS ----------------
__device__ __forceinline__ void gload16(const void* g, void* l) {
    __builtin_amdgcn_global_load_lds(
        (const __attribute__((address_space(1))) unsigned int*)g,
        (__attribute__((address_space(3))) unsigned int*)l, 16, 0, 0);
}

// Shared MFMA K-loop: 128x128 C-tile, BK=64, 4 waves, global_load_lds staging
// with XOR-16B involution swizzle.
template<int LD>
__device__ __forceinline__ void mfma_tile_loop(const unsigned short* __restrict__ A,
                                               const unsigned short* __restrict__ BT,
                                               unsigned short* __restrict__ As,
                                               unsigned short* __restrict__ Bs,
                                               int i0, int j0, int tid,
                                               f32x4 (&acc)[4][4])
{
    const int lane = tid & 63, w = tid >> 6;
    const int wr = w >> 1, wc = w & 1;
    const int g = lane >> 4, lr = lane & 15;

    for (int k0 = 0; k0 < LD; k0 += 64) {
        __syncthreads();
        #pragma unroll
        for (int q = 0; q < 4; ++q) {
            int L16 = q * 256 + tid;
            int r = L16 >> 3;
            int csw = ((L16 & 7) << 4) ^ ((r & 7) << 4);
            const char* ga = (const char*)(A  + (size_t)(i0 + r) * LD + k0) + csw;
            const char* gb = (const char*)(BT + (size_t)(j0 + r) * LD + k0) + csw;
            gload16(ga, As + (size_t)L16 * 8);
            gload16(gb, Bs + (size_t)L16 * 8);
        }
        __syncthreads();
        #pragma unroll
        for (int ks = 0; ks < 2; ++ks) {
            bf16x8 af[4], bf[4];
            #pragma unroll
            for (int m = 0; m < 4; ++m) {
                int r = wr * 64 + m * 16 + lr;
                int cb = (ks * 64 + g * 16) ^ ((r & 7) << 4);
                af[m] = __builtin_bit_cast(bf16x8, *(const u16x8*)((const char*)As + r * 128 + cb));
            }
            #pragma unroll
            for (int n = 0; n < 4; ++n) {
                int r = wc * 64 + n * 16 + lr;
                int cb = (ks * 64 + g * 16) ^ ((r & 7) << 4);
                bf[n] = __builtin_bit_cast(bf16x8, *(const u16x8*)((const char*)Bs + r * 128 + cb));
            }
            #pragma unroll
            for (int m = 0; m < 4; ++m)
                #pragma unroll
                for (int n = 0; n < 4; ++n)
                    acc[m][n] = __builtin_amdgcn_mfma_f32_16x16x32_bf16(af[m], bf[n], acc[m][n], 0, 0, 0);
        }
    }
}

// ---------------- reduction helpers (256-thread blocks, 4 waves) ----------------
__device__ __forceinline__ float blockReduceSum(float v, float* sbuf) {
    #pragma unroll
    for (int off = 32; off; off >>= 1) v += __shfl_down(v, off, 64);
    __syncthreads();
    if ((threadIdx.x & 63) == 0) sbuf[threadIdx.x >> 6] = v;
    __syncthreads();
    return sbuf[0] + sbuf[1] + sbuf[2] + sbuf[3];
}
__device__ __forceinline__ float blockReduceMax(float v, float* sbuf) {
    #pragma unroll
    for (int off = 32; off; off >>= 1) v = fmaxf(v, __shfl_down(v, off, 64));
    __syncthreads();
    if ((threadIdx.x & 63) == 0) sbuf[threadIdx.x >> 6] = v;
    __syncthreads();
    return fmaxf(fmaxf(sbuf[0], sbuf[1]), fmaxf(sbuf[2], sbuf[3]));
}

// ---------------- K1a: pack feats -> bf16 A[(b,t,n), c] ----------------
__global__ __launch_bounds__(256) void k_pack(const float* __restrict__ feats,
                                              unsigned int* __restrict__ Abf32)
{
    __shared__ float lds[Cc * 9];
    int bid = blockIdx.x;
    int b = bid / Nc, n = bid % Nc;
    const float* src = feats + (size_t)(b * Nc + n) * Cc * Tc;
    int tid = threadIdx.x;
    for (int i = tid; i < Cc * Tc; i += 256) lds[(i >> 3) * 9 + (i & 7)] = src[i];
    __syncthreads();
    #pragma unroll
    for (int t = 0; t < Tc; ++t) {
        size_t row = (size_t)(b * Tc + t) * Nc + n;
        float v0 = lds[(2 * tid) * 9 + t];
        float v1 = lds[(2 * tid + 1) * 9 + t];
        unsigned int pk = (unsigned int)f2bf(v0) | ((unsigned int)f2bf(v1) << 16);
        Abf32[row * (Cc / 2) + tid] = pk;
    }
}

// ---------------- K1b: pack W -> bf16 WT[which][d][c] ----------------
__global__ __launch_bounds__(256) void k_packw(const float* __restrict__ Wself,
                                               const float* __restrict__ Wdust,
                                               unsigned short* __restrict__ WTb)
{
    __shared__ float tile[64][65];
    int which = blockIdx.z;
    const float* W = which ? Wdust : Wself;
    unsigned short* O = WTb + (size_t)which * Dc * Cc;
    int d0 = blockIdx.x * 64, c0 = blockIdx.y * 64;
    int tx = threadIdx.x & 63, ty = threadIdx.x >> 6;
    #pragma unroll
    for (int y = 0; y < 64; y += 4) tile[y + ty][tx] = W[(size_t)(c0 + y + ty) * Dc + d0 + tx];
    __syncthreads();
    #pragma unroll
    for (int y = 0; y < 64; y += 4) O[(size_t)(d0 + y + ty) * Cc + c0 + tx] = f2bf(tile[tx][y + ty]);
}

// ---------------- K1c: projection GEMM fbuf = Abf @ WT^T + bias (MFMA) ----------------
__global__ __launch_bounds__(256, 3) void k_gemm_proj(const unsigned short* __restrict__ A,
                                                      const unsigned short* __restrict__ BT,
                                                      const float* __restrict__ bias,
                                                      float* __restrict__ Cf)
{
    __shared__ __align__(16) unsigned short As[128 * 64];
    __shared__ __align__(16) unsigned short Bs[128 * 64];
    const int i0 = blockIdx.y * 128;
    const int tid = threadIdx.x, lane = tid & 63, w = tid >> 6;
    const int wr = w >> 1, wc = w & 1;
    const int g = lane >> 4, lr = lane & 15;

    f32x4 acc[4][4] = {};
    mfma_tile_loop<Cc>(A, BT, As, Bs, i0, 0, tid, acc);

    #pragma unroll
    for (int n = 0; n < 4; ++n) {
        int col = wc * 64 + n * 16 + lr;
        float bv = bias[col];
        #pragma unroll
        for (int m = 0; m < 4; ++m)
            #pragma unroll
            for (int j = 0; j < 4; ++j) {
                int row = i0 + wr * 64 + m * 16 + g * 4 + j;
                Cf[(size_t)row * Dc + col] = acc[m][n][j] + bv;
            }
    }
}

// ---------------- K1d: dust projection + l2norm (fp32 exact) ----------------
__global__ __launch_bounds__(128) void k_dustproj(const float* __restrict__ dust,
                                                  const float* __restrict__ Wdust,
                                                  const float* __restrict__ bdust,
                                                  unsigned short* __restrict__ qTb,
                                                  float* __restrict__ qout)
{
    __shared__ float sdust[Cc];
    __shared__ float red[2];
    int bt = blockIdx.x;
    int b = bt >> 3, t = bt & 7;
    int tid = threadIdx.x;
    for (int i = tid; i < Cc; i += 128) sdust[i] = dust[((size_t)b * Cc + i) * Tc + t];
    __syncthreads();
    float acc = 0.f;
    for (int c = 0; c < Cc; ++c) acc += sdust[c] * Wdust[(size_t)c * Dc + tid];
    acc += bdust[tid];
    float s = acc * acc;
    #pragma unroll
    for (int off = 32; off; off >>= 1) s += __shfl_down(s, off, 64);
    if ((tid & 63) == 0) red[tid >> 6] = s;
    __syncthreads();
    float inv = 1.f / fmaxf(sqrtf(red[0] + red[1]), 1e-12f);
    float qv = acc * inv;
    qTb[((size_t)bt * Qrows + Nc) * Dc + tid] = f2bf(qv);
    qout[(((size_t)b * Dc + tid) * Tc + t) * Mc + Nc] = qv;
}

// ---------------- K1e: l2norm rows of fbuf -> bf16 qTb + fp32 qout ----------------
__global__ __launch_bounds__(256) void k_norm(const float* __restrict__ fbuf,
                                              unsigned short* __restrict__ qTb,
                                              float* __restrict__ qout)
{
    __shared__ float lds[64][129];
    __shared__ float nrm[64][4];
    __shared__ float inv[64];
    int bt = blockIdx.y;
    int b = bt >> 3, t = bt & 7;
    int n0 = blockIdx.x * 64;
    int tid = threadIdx.x;
    #pragma unroll
    for (int q = 0; q < 8; ++q) {
        int i = q * 256 + tid;
        int nl = i >> 5, d4 = i & 31;
        f32x4 v = {};
        if (n0 + nl < Nc) v = *(const f32x4*)(fbuf + ((size_t)bt * Nc + n0 + nl) * Dc + d4 * 4);
        *(f32x4*)(&lds[nl][d4 * 4]) = v;
    }
    __syncthreads();
    {
        int r = tid & 63, p = tid >> 6;
        float s = 0.f;
        #pragma unroll
        for (int j = 0; j < 32; ++j) { float v = lds[r][p * 32 + j]; s += v * v; }
        nrm[r][p] = s;
    }
    __syncthreads();
    if (tid < 64) inv[tid] = 1.f / fmaxf(sqrtf(nrm[tid][0] + nrm[tid][1] + nrm[tid][2] + nrm[tid][3]), 1e-12f);
    __syncthreads();
    unsigned int* qT32 = (unsigned int*)(qTb + (size_t)bt * Qrows * Dc);
    #pragma unroll
    for (int q = 0; q < 16; ++q) {
        int i = q * 256 + tid;
        int nl = i >> 6, dp = i & 63;
        if (n0 + nl < Nc) {
            float iv = inv[nl];
            unsigned int pk = (unsigned int)f2bf(lds[nl][2 * dp] * iv)
                            | ((unsigned int)f2bf(lds[nl][2 * dp + 1] * iv) << 16);
            qT32[((size_t)(n0 + nl) * Dc >> 1) + dp] = pk;
        }
    }
    int nl = tid & 63;
    if (n0 + nl < Nc) {
        float iv = inv[nl];
        #pragma unroll
        for (int dd = 0; dd < Dc; dd += 4) {
            int d = dd + (tid >> 6);
            qout[(((size_t)b * Dc + d) * Tc + t) * Mc + n0 + nl] = lds[nl][d] * iv;
        }
    }
}

// ---------------- K2: fused affinity: scores -> stats -> softmax -> bf16 P ----------------
__global__ __launch_bounds__(256) void k_affinity(const unsigned short* __restrict__ qTb,
                                                  unsigned short* __restrict__ P12h,
                                                  unsigned short* __restrict__ P21h,
                                                  float* __restrict__ cs12,
                                                  float* __restrict__ cs21,
                                                  float wconst)
{
    constexpr float INVT = 1.0f / TEMP;
    const size_t MMp = (size_t)Pp * Pp;
    int strip = blockIdx.x, bt = blockIdx.y, side = blockIdx.z;
    int b = bt / TM1, t = bt % TM1;
    const unsigned short *Aq, *Bq;
    unsigned short* OUT;
    float* cs;
    if (side == 0) {
        Aq = qTb + (size_t)(b * Tc + t)     * Qrows * Dc;
        Bq = qTb + (size_t)(b * Tc + t + 1) * Qrows * Dc;
        OUT = P12h + (size_t)bt * MMp;
        cs  = cs12 + (size_t)bt * Pp;
    } else {
        Aq = qTb + (size_t)(b * Tc + 7 - t) * Qrows * Dc;
        Bq = qTb + (size_t)(b * Tc + 6 - t) * Qrows * Dc;
        OUT = P21h + (size_t)bt * MMp;
        cs  = cs21 + (size_t)bt * Pp;
    }
    const int r0 = strip * 16;
    const int tid = threadIdx.x, lane = tid & 63, w = tid >> 6;
    const int g = lane >> 4, lr = lane & 15;

    // MFMA: wave w owns col-tiles w*13 .. w*13+12 (tiles >= 49 are padding, skipped)
    f32x4 acc[13] = {};
    #pragma unroll
    for (int ks = 0; ks < 4; ++ks) {
        bf16x8 af = __builtin_bit_cast(bf16x8,
            *(const u16x8*)(Aq + (size_t)(r0 + lr) * Dc + ks * 32 + g * 8));
        #pragma unroll
        for (int tt = 0; tt < 13; ++tt) {
            if (w * 13 + tt < 49) {
                bf16x8 bf = __builtin_bit_cast(bf16x8,
                    *(const u16x8*)(Bq + (size_t)((w * 13 + tt) * 16 + lr) * Dc + ks * 32 + g * 8));
                acc[tt] = __builtin_amdgcn_mfma_f32_16x16x32_bf16(af, bf, acc[tt], 0, 0, 0);
            }
        }
    }
    // lane holds rows r0+g*4+j (j=0..3), cols (w*13+tt)*16+lr

    __shared__ float sred[16][4][2];
    __shared__ float rowsum[16], esumS[16], invZ[16], entP[16];

    // sweep 1: rowsum + exp-sum + colsum partials
    float rs[4] = {0.f, 0.f, 0.f, 0.f}, es[4] = {0.f, 0.f, 0.f, 0.f};
    #pragma unroll
    for (int tt = 0; tt < 13; ++tt) {
        int gt = w * 13 + tt;
        if (gt < 49) {
            float c = 0.f;
            #pragma unroll
            for (int j = 0; j < 4; ++j) {
                float a = acc[tt][j];
                rs[j] += a;
                es[j] += __expf(a * INVT);
                c += a;
            }
            c += __shfl_xor(c, 16, 64);
            c += __shfl_xor(c, 32, 64);
            if (g == 0) atomicAdd(&cs[gt * 16 + lr], c);
        }
    }
    #pragma unroll
    for (int off = 1; off <= 8; off <<= 1) {
        #pragma unroll
        for (int j = 0; j < 4; ++j) {
            rs[j] += __shfl_xor(rs[j], off, 64);
            es[j] += __shfl_xor(es[j], off, 64);
        }
    }
    if (lr == 0) {
        #pragma unroll
        for (int j = 0; j < 4; ++j) { sred[g * 4 + j][w][0] = rs[j]; sred[g * 4 + j][w][1] = es[j]; }
    }
    __syncthreads();
    if (tid < 16) {
        rowsum[tid] = sred[tid][0][0] + sred[tid][1][0] + sred[tid][2][0] + sred[tid][3][0];
        esumS[tid]  = sred[tid][0][1] + sred[tid][1][1] + sred[tid][2][1] + sred[tid][3][1];
    }
    __syncthreads();

    // sweep 2: entropy partials (p = A * (1/rowsum), native log)
    float invr[4];
    #pragma unroll
    for (int j = 0; j < 4; ++j) invr[j] = 1.0f / rowsum[g * 4 + j];
    float en[4] = {0.f, 0.f, 0.f, 0.f};
    #pragma unroll
    for (int tt = 0; tt < 13; ++tt) {
        if (w * 13 + tt < 49) {
            #pragma unroll
            for (int j = 0; j < 4; ++j) {
                float p = acc[tt][j] * invr[j];
                en[j] -= p * __logf(fmaxf(p, 1e-20f));
            }
        }
    }
    #pragma unroll
    for (int off = 1; off <= 8; off <<= 1) {
        #pragma unroll
        for (int j = 0; j < 4; ++j) en[j] += __shfl_xor(en[j], off, 64);
    }
    if (lr == 0) {
        #pragma unroll
        for (int j = 0; j < 4; ++j) sred[g * 4 + j][w][0] = en[j];
    }
    __syncthreads();
    if (tid < 16) {
        float ent = sred[tid][0][0] + sred[tid][1][0] + sred[tid][2][0] + sred[tid][3][0];
        float ez  = __expf(ent * wconst * INVT);
        float Z   = esumS[tid] + ez;
        float iz  = 1.0f / Z;
        invZ[tid] = iz;
        entP[tid] = ez * iz;
    }
    __syncthreads();

    // sweep 3: softmax writes (native exp)
    float izl[4];
    #pragma unroll
    for (int j = 0; j < 4; ++j) izl[j] = invZ[g * 4 + j];
    #pragma unroll
    for (int tt = 0; tt < 13; ++tt) {
        int gt = w * 13 + tt;
        int col = gt * 16 + lr;
        #pragma unroll
        for (int j = 0; j < 4; ++j) {
            int row = r0 + g * 4 + j;
            if (gt < 49)
                OUT[(size_t)row * Pp + col] = f2bf(__expf(acc[tt][j] * INVT) * izl[j]);
            else if (col != 784)
                OUT[(size_t)row * Pp + col] = 0;
        }
    }
    if (tid < 16) OUT[(size_t)(r0 + tid) * Pp + 784] = f2bf(entP[tid]);
}

// ---------------- K3: dust rows (row 784) + zero pad rows ----------------
__global__ __launch_bounds__(256) void k_dustrow(const float* __restrict__ cs12,
                                                 const float* __restrict__ cs21,
                                                 unsigned short* __restrict__ P12h,
                                                 unsigned short* __restrict__ P21h)
{
    constexpr float INVT = 1.0f / TEMP;
    const size_t MMp = (size_t)Pp * Pp;
    int bt = blockIdx.x, side = blockIdx.y;
    const float* cs = (side ? cs21 : cs12) + (size_t)bt * Pp;
    unsigned short* OUT = (side ? P21h : P12h) + (size_t)bt * MMp;
    __shared__ float sbuf[4];
    int tid = threadIdx.x;
    float v[4];
    #pragma unroll
    for (int k = 0; k < 4; ++k) {
        int j = tid + k * 256;
        float val = -INFINITY;
        if (j < Nc)       val = -cs[j] * INVT;
        else if (j == Nc) val = 0.f;
        v[k] = val;
    }
    float mx = fmaxf(fmaxf(v[0], v[1]), fmaxf(v[2], v[3]));
    mx = blockReduceMax(mx, sbuf);
    float e[4]; float s = 0.f;
    #pragma unroll
    for (int k = 0; k < 4; ++k) {
        int j = tid + k * 256;
        e[k] = (j < Mc) ? __expf(v[k] - mx) : 0.f;
        s += e[k];
    }
    s = blockReduceSum(s, sbuf);
    float invs = 1.f / s;
    #pragma unroll
    for (int k = 0; k < 4; ++k) {
        int j = tid + k * 256;
        if (j < Mc)      OUT[(size_t)Nc * Pp + j] = f2bf(e[k] * invs);
        else if (j < Pp) OUT[(size_t)Nc * Pp + j] = 0;
    }
    // zero pad rows 785..831
    u16x8 z = {};
    u16x8* dst = (u16x8*)(OUT + (size_t)785 * Pp);
    for (int i = tid; i < (Pp - 785) * Pp / 8; i += 256) dst[i] = z;
}

// ---------------- K6: bf16 transpose (Pp x Pp) ----------------
__global__ __launch_bounds__(256) void k_transpose_bf16(const unsigned short* __restrict__ Sb,
                                                        unsigned short* __restrict__ Db, int mode)
{
    const size_t MMp = (size_t)Pp * Pp;
    __shared__ unsigned short tile[64][65];
    int z = blockIdx.z;
    const unsigned short* S;
    unsigned short* D;
    if (mode == 0) { int b = z / 6, tm = z % 6; S = Sb + ((size_t)b * 7 + tm + 1) * MMp; D = Db + (size_t)z * MMp; }
    else           { S = Sb + ((size_t)z * 7 + 6) * MMp; D = Db + (size_t)z * MMp; }
    int x0 = blockIdx.x * 64, y0 = blockIdx.y * 64;
    int tx = threadIdx.x & 63, ty = threadIdx.x >> 6;
    #pragma unroll
    for (int y = 0; y < 64; y += 4) tile[y + ty][tx] = S[(size_t)(y0 + y + ty) * Pp + x0 + tx];
    __syncthreads();
    #pragma unroll
    for (int y = 0; y < 64; y += 4) D[(size_t)(x0 + y + ty) * Pp + y0 + tx] = tile[tx][y + ty];
}

// ---------------- K7: fused batched MFMA GEMM, C = A @ BT^T (bf16 out, optional colsum) ----------------
struct GJobs {
    const unsigned short* A[2];
    const unsigned short* BT[2];
    unsigned short* Cb[2];
    float* cs[2];                 // per-job colsum base (nullptr = skip); +b*Pp per batch
    long long sA[2], sB[2], sC[2];
};

__global__ __launch_bounds__(256, 3) void k_gemm_mfma(GJobs J)
{
    __shared__ __align__(16) unsigned short As[128 * 64];
    __shared__ __align__(16) unsigned short Bs[128 * 64];

    int job = blockIdx.z >> 2, b = blockIdx.z & 3;
    const unsigned short* A  = J.A[job]  + (size_t)b * J.sA[job];
    const unsigned short* BT = J.BT[job] + (size_t)b * J.sB[job];

    const int i0 = blockIdx.y * 128, j0 = blockIdx.x * 128;
    const int tid = threadIdx.x, lane = tid & 63, w = tid >> 6;
    const int wr = w >> 1, wc = w & 1;
    const int g = lane >> 4, lr = lane & 15;

    f32x4 acc[4][4] = {};
    mfma_tile_loop<Pp>(A, BT, As, Bs, i0, j0, tid, acc);

    unsigned short* Co = J.Cb[job] + (size_t)b * J.sC[job];
    float* csp = J.cs[job];
    float csacc[4] = {0.f, 0.f, 0.f, 0.f};
    #pragma unroll
    for (int m = 0; m < 4; ++m)
        #pragma unroll
        for (int n = 0; n < 4; ++n)
            #pragma unroll
            for (int j = 0; j < 4; ++j) {
                int row = i0 + wr * 64 + m * 16 + g * 4 + j;
                int col = j0 + wc * 64 + n * 16 + lr;
                if (row < Pp && col < Pp) {
                    unsigned short h = f2bf(acc[m][n][j]);
                    Co[(size_t)row * Pp + col] = h;
                    csacc[n] += bf2f(h);
                }
            }
    if (csp) {
        csp += (size_t)b * Pp;
        #pragma unroll
        for (int n = 0; n < 4; ++n) {
            float p = csacc[n];
            p += __shfl_xor(p, 16, 64);
            p += __shfl_xor(p, 32, 64);
            int col = j0 + wc * 64 + n * 16 + lr;
            if (g == 0 && col < Pp) atomicAdd(&csp[col], p);
        }
    }
}

// ---------------- K8: loss rows via dot products (no AA GEMM) ----------------
// loss_i += log(rowsum_i + Mc*eps) - log(diag_i + eps)
// rowsum_i = L[i,:] . colsum(R);  diag_i = L[i,:] . R[i,:]
__global__ __launch_bounds__(64) void k_lossrow(const unsigned short* __restrict__ L,
                                                const unsigned short* __restrict__ R,
                                                const float* __restrict__ csR,
                                                float* __restrict__ loss, float scale)
{
    const size_t MMp = (size_t)Pp * Pp;
    int r = blockIdx.x;
    int b = r / Mc, i = r % Mc;
    const u16x8* lrow = (const u16x8*)(L + (size_t)b * MMp + (size_t)i * Pp);
    const u16x8* rrow = (const u16x8*)(R + (size_t)b * MMp + (size_t)i * Pp);
    const f32x4* cs4  = (const f32x4*)(csR + (size_t)b * Pp);
    int lane = threadIdx.x;
    float sR = 0.f, sD = 0.f;
    for (int c = lane; c < Pp / 8; c += 64) {
        u16x8 lv = lrow[c];
        u16x8 rv = rrow[c];
        f32x4 c0 = cs4[2 * c], c1 = cs4[2 * c + 1];
        #pragma unroll
        for (int k = 0; k < 4; ++k) {
            float fl = bf2f(lv[k]);
            sR += fl * c0[k];
            sD += fl * bf2f(rv[k]);
        }
        #pragma unroll
        for (int k = 0; k < 4; ++k) {
            float fl = bf2f(lv[4 + k]);
            sR += fl * c1[k];
            sD += fl * bf2f(rv[4 + k]);
        }
    }
    #pragma unroll
    for (int off = 1; off <= 32; off <<= 1) {
        sR += __shfl_xor(sR, off, 64);
        sD += __shfl_xor(sD, off, 64);
    }
    if (lane == 0)
        atomicAdd(loss, (logf(sR + Mc * 1e-20f) - logf(sD + 1e-20f)) * scale);
}

__global__ void k_zero(float* p) { *p = 0.f; }

// ---------------- host orchestration ----------------
extern "C" void kernel_launch(void* const* d_in, const int* in_sizes, int n_in,
                              void* d_out, int out_size, void* d_ws, size_t ws_size,
                              hipStream_t stream)
{
    const float* feats = (const float*)d_in[0];
    const float* dust  = (const float*)d_in[1];
    const float* Wself = (const float*)d_in[2];
    const float* bself = (const float*)d_in[3];
    const float* Wdust = (const float*)d_in[4];
    const float* bdust = (const float*)d_in[5];

    float* out  = (float*)d_out;
    float* qout = out;
    float* loss = out + (size_t)Bc * Dc * Tc * Mc;

    const size_t MMp = (size_t)Pp * Pp;       // 692,224

    // ---- workspace ----
    float* ws = (float*)d_ws;
    float* csR = ws;                                                // 6 slots * Bc * Pp fp32 (in old AA region)
    unsigned short* P12h = (unsigned short*)(ws + 4 * MMp);         // 28*MMp bf16
    unsigned short* P21h = P12h + (size_t)28 * MMp;                 // 28*MMp bf16
    unsigned short* chainT = P21h + (size_t)28 * MMp;               // 44*MMp bf16 region
    unsigned short* P12T  = chainT;
    unsigned short* P21T6 = P12T + (size_t)24 * MMp;
    unsigned short* l0    = P21T6 + (size_t)4 * MMp;
    unsigned short* l1    = l0 + (size_t)4 * MMp;
    unsigned short* R0    = l1 + (size_t)4 * MMp;
    unsigned short* R1    = R0 + (size_t)4 * MMp;
    unsigned short* qTb   = R1 + (size_t)4 * MMp;                   // 32*Qrows*Dc bf16
    float* cs12 = (float*)(qTb + (size_t)32 * Qrows * Dc);          // 28*Pp fp32
    float* cs21 = cs12 + (size_t)28 * Pp;                           // 28*Pp fp32

    // phase-1 overlays in chainT region (dead before transposes write it):
    unsigned short* Abf   = chainT;
    unsigned int*   Abf32 = (unsigned int*)Abf;
    unsigned short* WTb   = Abf + (size_t)Bc * Tc * Nc * Cc;
    float*          fbuf  = (float*)(WTb + 2 * (size_t)Dc * Cc);

    // 1. pack inputs to bf16
    k_pack<<<Bc * Nc, 256, 0, stream>>>(feats, Abf32);
    k_packw<<<dim3(2, 8, 2), 256, 0, stream>>>(Wself, Wdust, WTb);
    hipMemsetAsync(cs12, 0, (size_t)2 * 28 * Pp * sizeof(float), stream);
    hipMemsetAsync(csR, 0, (size_t)6 * Bc * Pp * sizeof(float), stream);
    // 2. projection GEMM + bias
    k_gemm_proj<<<dim3(1, 196), 256, 0, stream>>>(Abf, WTb, bself, fbuf);
    // 3. dust projection (fp32) + norms
    k_dustproj<<<32, 128, 0, stream>>>(dust, Wdust, bdust, qTb, qout);
    k_norm<<<dim3(13, 32), 256, 0, stream>>>(fbuf, qTb, qout);
    // 4. fused affinity (scores+entropy+softmax+colsums), then dust rows
    float wconst = (float)(1.0 / log(784.0));
    k_affinity<<<dim3(49, 28, 2), 256, 0, stream>>>(qTb, P12h, P21h, cs12, cs21, wconst);
    k_dustrow<<<dim3(28, 2), 256, 0, stream>>>(cs12, cs21, P12h, P21h);
    // 5. bf16 transposes
    k_transpose_bf16<<<dim3(13, 13, 24), 256, 0, stream>>>(P12h, P12T, 0);
    k_transpose_bf16<<<dim3(13, 13, 4),  256, 0, stream>>>(P21h, P21T6, 1);

    // 6. chain
    k_zero<<<1, 1, 0, stream>>>(loss);
    const float scale = 1.0f / (6.0f * Bc * Mc);

    // prologue: L1 = P12[0] @ P12[1]^T-form;  R1 = P21T6 @ P21[5]^T (with colsum slot 0)
    {
        GJobs J = {};
        J.A[0] = P12h;  J.sA[0] = (long long)7 * MMp;
        J.BT[0] = P12T; J.sB[0] = (long long)6 * MMp;
        J.Cb[0] = l0;   J.sC[0] = (long long)MMp; J.cs[0] = nullptr;
        J.A[1] = P21T6;                   J.sA[1] = (long long)MMp;
        J.BT[1] = P21h + (size_t)5 * MMp; J.sB[1] = (long long)7 * MMp;
        J.Cb[1] = R0;   J.sC[1] = (long long)MMp; J.cs[1] = csR;   // slot 0
        k_gemm_mfma<<<dim3(7, 7, 8), 256, 0, stream>>>(J);
    }

    unsigned short *lcur = l0, *lnxt = l1, *rcur = R0, *rnxt = R1;
    for (int i = 1; i <= 6; ++i) {
        // loss from current states (no AA materialization)
        k_lossrow<<<Bc * Mc, 64, 0, stream>>>(lcur, rcur, csR + (size_t)(i - 1) * Bc * Pp, loss, scale);
        if (i < 6) {
            GJobs J = {};
            J.A[0] = lcur; J.sA[0] = (long long)MMp;
            J.BT[0] = P12T + (size_t)i * MMp; J.sB[0] = (long long)6 * MMp;
            J.Cb[0] = lnxt; J.sC[0] = (long long)MMp; J.cs[0] = nullptr;
            J.A[1] = rcur; J.sA[1] = (long long)MMp;
            J.BT[1] = P21h + (size_t)(5 - i) * MMp; J.sB[1] = (long long)7 * MMp;
            J.Cb[1] = rnxt; J.sC[1] = (long long)MMp; J.cs[1] = csR + (size_t)i * Bc * Pp;
            k_gemm_mfma<<<dim3(7, 7, 8), 256, 0, stream>>>(J);
            unsigned short* t;
            t = lcur; lcur = lnxt; lnxt = t;
            t = rcur; rcur = rnxt; rnxt = t;
        }
    }
}

// Round 8
// 550.316 us; speedup vs baseline: 7.1511x; 1.1054x over previous
//
#include <hip/hip_runtime.h>
#include <hip/hip_bf16.h>
#include <math.h>

// Problem constants
constexpr int Bc = 4;      // batch
constexpr int Nc = 784;    // tokens
constexpr int Cc = 512;    // enc channels
constexpr int Tc = 8;      // time
constexpr int Dc = 128;    // proj dim
constexpr int Mc = 785;    // N+1
constexpr int TM1 = 7;     // T-1
constexpr int Pp = 832;    // padded chain dim (13*64)
constexpr int Qrows = 896; // padded q rows
constexpr float TEMP = 0.07f;

typedef __attribute__((ext_vector_type(4))) float f32x4;
typedef __attribute__((ext_vector_type(8))) unsigned short u16x8;
typedef __attribute__((ext_vector_type(8))) __bf16 bf16x8;

__device__ __forceinline__ unsigned short f2bf(float v) {
    __hip_bfloat16 h = __float2bfloat16(v);
    return __builtin_bit_cast(unsigned short, h);
}
__device__ __forceinline__ float bf2f(unsigned short u) {
    return __builtin_bit_cast(float, (unsigned int)u << 16);
}

// ---------------- async 16B global->LDS ----------------
__device__ __forceinline__ void gload16(const void* g, void* l) {
    __builtin_amdgcn_global_load_lds(
        (const __attribute__((address_space(1))) unsigned int*)g,
        (__attribute__((address_space(3))) unsigned int*)l, 16, 0, 0);
}

// Shared MFMA K-loop: 128x128 C-tile, BK=64, 4 waves, global_load_lds staging
// with XOR-16B involution swizzle.
template<int LD>
__device__ __forceinline__ void mfma_tile_loop(const unsigned short* __restrict__ A,
                                               const unsigned short* __restrict__ BT,
                                               unsigned short* __restrict__ As,
                                               unsigned short* __restrict__ Bs,
                                               int i0, int j0, int tid,
                                               f32x4 (&acc)[4][4])
{
    const int lane = tid & 63, w = tid >> 6;
    const int wr = w >> 1, wc = w & 1;
    const int g = lane >> 4, lr = lane & 15;

    for (int k0 = 0; k0 < LD; k0 += 64) {
        __syncthreads();
        #pragma unroll
        for (int q = 0; q < 4; ++q) {
            int L16 = q * 256 + tid;
            int r = L16 >> 3;
            int csw = ((L16 & 7) << 4) ^ ((r & 7) << 4);
            const char* ga = (const char*)(A  + (size_t)(i0 + r) * LD + k0) + csw;
            const char* gb = (const char*)(BT + (size_t)(j0 + r) * LD + k0) + csw;
            gload16(ga, As + (size_t)L16 * 8);
            gload16(gb, Bs + (size_t)L16 * 8);
        }
        __syncthreads();
        #pragma unroll
        for (int ks = 0; ks < 2; ++ks) {
            bf16x8 af[4], bf[4];
            #pragma unroll
            for (int m = 0; m < 4; ++m) {
                int r = wr * 64 + m * 16 + lr;
                int cb = (ks * 64 + g * 16) ^ ((r & 7) << 4);
                af[m] = __builtin_bit_cast(bf16x8, *(const u16x8*)((const char*)As + r * 128 + cb));
            }
            #pragma unroll
            for (int n = 0; n < 4; ++n) {
                int r = wc * 64 + n * 16 + lr;
                int cb = (ks * 64 + g * 16) ^ ((r & 7) << 4);
                bf[n] = __builtin_bit_cast(bf16x8, *(const u16x8*)((const char*)Bs + r * 128 + cb));
            }
            #pragma unroll
            for (int m = 0; m < 4; ++m)
                #pragma unroll
                for (int n = 0; n < 4; ++n)
                    acc[m][n] = __builtin_amdgcn_mfma_f32_16x16x32_bf16(af[m], bf[n], acc[m][n], 0, 0, 0);
        }
    }
}

// ---------------- reduction helpers (256-thread blocks, 4 waves) ----------------
__device__ __forceinline__ float blockReduceSum(float v, float* sbuf) {
    #pragma unroll
    for (int off = 32; off; off >>= 1) v += __shfl_down(v, off, 64);
    __syncthreads();
    if ((threadIdx.x & 63) == 0) sbuf[threadIdx.x >> 6] = v;
    __syncthreads();
    return sbuf[0] + sbuf[1] + sbuf[2] + sbuf[3];
}
__device__ __forceinline__ float blockReduceMax(float v, float* sbuf) {
    #pragma unroll
    for (int off = 32; off; off >>= 1) v = fmaxf(v, __shfl_down(v, off, 64));
    __syncthreads();
    if ((threadIdx.x & 63) == 0) sbuf[threadIdx.x >> 6] = v;
    __syncthreads();
    return fmaxf(fmaxf(sbuf[0], sbuf[1]), fmaxf(sbuf[2], sbuf[3]));
}

// ---------------- K1a: pack feats -> bf16 A[(b,t,n), c] ----------------
__global__ __launch_bounds__(256) void k_pack(const float* __restrict__ feats,
                                              unsigned int* __restrict__ Abf32)
{
    __shared__ float lds[Cc * 9];
    int bid = blockIdx.x;
    int b = bid / Nc, n = bid % Nc;
    const float* src = feats + (size_t)(b * Nc + n) * Cc * Tc;
    int tid = threadIdx.x;
    for (int i = tid; i < Cc * Tc; i += 256) lds[(i >> 3) * 9 + (i & 7)] = src[i];
    __syncthreads();
    #pragma unroll
    for (int t = 0; t < Tc; ++t) {
        size_t row = (size_t)(b * Tc + t) * Nc + n;
        float v0 = lds[(2 * tid) * 9 + t];
        float v1 = lds[(2 * tid + 1) * 9 + t];
        unsigned int pk = (unsigned int)f2bf(v0) | ((unsigned int)f2bf(v1) << 16);
        Abf32[row * (Cc / 2) + tid] = pk;
    }
}

// ---------------- K1b: pack W -> bf16 WT[which][d][c] ----------------
__global__ __launch_bounds__(256) void k_packw(const float* __restrict__ Wself,
                                               const float* __restrict__ Wdust,
                                               unsigned short* __restrict__ WTb)
{
    __shared__ float tile[64][65];
    int which = blockIdx.z;
    const float* W = which ? Wdust : Wself;
    unsigned short* O = WTb + (size_t)which * Dc * Cc;
    int d0 = blockIdx.x * 64, c0 = blockIdx.y * 64;
    int tx = threadIdx.x & 63, ty = threadIdx.x >> 6;
    #pragma unroll
    for (int y = 0; y < 64; y += 4) tile[y + ty][tx] = W[(size_t)(c0 + y + ty) * Dc + d0 + tx];
    __syncthreads();
    #pragma unroll
    for (int y = 0; y < 64; y += 4) O[(size_t)(d0 + y + ty) * Cc + c0 + tx] = f2bf(tile[tx][y + ty]);
}

// ---------------- K1c: projection GEMM fbuf = Abf @ WT^T + bias (MFMA) ----------------
__global__ __launch_bounds__(256, 3) void k_gemm_proj(const unsigned short* __restrict__ A,
                                                      const unsigned short* __restrict__ BT,
                                                      const float* __restrict__ bias,
                                                      float* __restrict__ Cf)
{
    __shared__ __align__(16) unsigned short As[128 * 64];
    __shared__ __align__(16) unsigned short Bs[128 * 64];
    const int i0 = blockIdx.y * 128;
    const int tid = threadIdx.x, lane = tid & 63, w = tid >> 6;
    const int wr = w >> 1, wc = w & 1;
    const int g = lane >> 4, lr = lane & 15;

    f32x4 acc[4][4] = {};
    mfma_tile_loop<Cc>(A, BT, As, Bs, i0, 0, tid, acc);

    #pragma unroll
    for (int n = 0; n < 4; ++n) {
        int col = wc * 64 + n * 16 + lr;
        float bv = bias[col];
        #pragma unroll
        for (int m = 0; m < 4; ++m)
            #pragma unroll
            for (int j = 0; j < 4; ++j) {
                int row = i0 + wr * 64 + m * 16 + g * 4 + j;
                Cf[(size_t)row * Dc + col] = acc[m][n][j] + bv;
            }
    }
}

// ---------------- K1d: dust projection + l2norm (fp32 exact) ----------------
__global__ __launch_bounds__(128) void k_dustproj(const float* __restrict__ dust,
                                                  const float* __restrict__ Wdust,
                                                  const float* __restrict__ bdust,
                                                  unsigned short* __restrict__ qTb,
                                                  float* __restrict__ qout)
{
    __shared__ float sdust[Cc];
    __shared__ float red[2];
    int bt = blockIdx.x;
    int b = bt >> 3, t = bt & 7;
    int tid = threadIdx.x;
    for (int i = tid; i < Cc; i += 128) sdust[i] = dust[((size_t)b * Cc + i) * Tc + t];
    __syncthreads();
    float acc = 0.f;
    for (int c = 0; c < Cc; ++c) acc += sdust[c] * Wdust[(size_t)c * Dc + tid];
    acc += bdust[tid];
    float s = acc * acc;
    #pragma unroll
    for (int off = 32; off; off >>= 1) s += __shfl_down(s, off, 64);
    if ((tid & 63) == 0) red[tid >> 6] = s;
    __syncthreads();
    float inv = 1.f / fmaxf(sqrtf(red[0] + red[1]), 1e-12f);
    float qv = acc * inv;
    qTb[((size_t)bt * Qrows + Nc) * Dc + tid] = f2bf(qv);
    qout[(((size_t)b * Dc + tid) * Tc + t) * Mc + Nc] = qv;
}

// ---------------- K1e: l2norm rows of fbuf -> bf16 qTb + fp32 qout ----------------
__global__ __launch_bounds__(256) void k_norm(const float* __restrict__ fbuf,
                                              unsigned short* __restrict__ qTb,
                                              float* __restrict__ qout)
{
    __shared__ float lds[64][129];
    __shared__ float nrm[64][4];
    __shared__ float inv[64];
    int bt = blockIdx.y;
    int b = bt >> 3, t = bt & 7;
    int n0 = blockIdx.x * 64;
    int tid = threadIdx.x;
    #pragma unroll
    for (int q = 0; q < 8; ++q) {
        int i = q * 256 + tid;
        int nl = i >> 5, d4 = i & 31;
        f32x4 v = {};
        if (n0 + nl < Nc) v = *(const f32x4*)(fbuf + ((size_t)bt * Nc + n0 + nl) * Dc + d4 * 4);
        *(f32x4*)(&lds[nl][d4 * 4]) = v;
    }
    __syncthreads();
    {
        int r = tid & 63, p = tid >> 6;
        float s = 0.f;
        #pragma unroll
        for (int j = 0; j < 32; ++j) { float v = lds[r][p * 32 + j]; s += v * v; }
        nrm[r][p] = s;
    }
    __syncthreads();
    if (tid < 64) inv[tid] = 1.f / fmaxf(sqrtf(nrm[tid][0] + nrm[tid][1] + nrm[tid][2] + nrm[tid][3]), 1e-12f);
    __syncthreads();
    unsigned int* qT32 = (unsigned int*)(qTb + (size_t)bt * Qrows * Dc);
    #pragma unroll
    for (int q = 0; q < 16; ++q) {
        int i = q * 256 + tid;
        int nl = i >> 6, dp = i & 63;
        if (n0 + nl < Nc) {
            float iv = inv[nl];
            unsigned int pk = (unsigned int)f2bf(lds[nl][2 * dp] * iv)
                            | ((unsigned int)f2bf(lds[nl][2 * dp + 1] * iv) << 16);
            qT32[((size_t)(n0 + nl) * Dc >> 1) + dp] = pk;
        }
    }
    int nl = tid & 63;
    if (n0 + nl < Nc) {
        float iv = inv[nl];
        #pragma unroll
        for (int dd = 0; dd < Dc; dd += 4) {
            int d = dd + (tid >> 6);
            qout[(((size_t)b * Dc + d) * Tc + t) * Mc + n0 + nl] = lds[nl][d] * iv;
        }
    }
}

// ---------------- K2: fused affinity with XCD-pinned groups ----------------
// 1-D grid 2744 = 8 XCDs * 343. xcd = f&7, slot = f>>3; grp = xcd + 8*(slot/49)
// (bt,side); strip = slot%49 -> all 49 strips of one (bt,side) on one XCD, so
// the 400 KB working set is L2-resident.
__global__ __launch_bounds__(256) void k_affinity(const unsigned short* __restrict__ qTb,
                                                  unsigned short* __restrict__ P12h,
                                                  unsigned short* __restrict__ P21h,
                                                  float* __restrict__ cs12,
                                                  float* __restrict__ cs21,
                                                  float wconst)
{
    constexpr float INVT = 1.0f / TEMP;
    const size_t MMp = (size_t)Pp * Pp;
    int f = blockIdx.x;
    int xcd = f & 7, slot = f >> 3;
    int grp = xcd + 8 * (slot / 49);
    int strip = slot % 49;
    int side = grp >= 28 ? 1 : 0;
    int bt = grp - side * 28;
    int b = bt / TM1, t = bt % TM1;
    const unsigned short *Aq, *Bq;
    unsigned short* OUT;
    float* cs;
    if (side == 0) {
        Aq = qTb + (size_t)(b * Tc + t)     * Qrows * Dc;
        Bq = qTb + (size_t)(b * Tc + t + 1) * Qrows * Dc;
        OUT = P12h + (size_t)bt * MMp;
        cs  = cs12 + (size_t)bt * Pp;
    } else {
        Aq = qTb + (size_t)(b * Tc + 7 - t) * Qrows * Dc;
        Bq = qTb + (size_t)(b * Tc + 6 - t) * Qrows * Dc;
        OUT = P21h + (size_t)bt * MMp;
        cs  = cs21 + (size_t)bt * Pp;
    }
    const int r0 = strip * 16;
    const int tid = threadIdx.x, lane = tid & 63, w = tid >> 6;
    const int g = lane >> 4, lr = lane & 15;

    // MFMA: wave w owns col-tiles w*13 .. w*13+12 (tiles >= 49 are padding, skipped)
    f32x4 acc[13] = {};
    #pragma unroll
    for (int ks = 0; ks < 4; ++ks) {
        bf16x8 af = __builtin_bit_cast(bf16x8,
            *(const u16x8*)(Aq + (size_t)(r0 + lr) * Dc + ks * 32 + g * 8));
        #pragma unroll
        for (int tt = 0; tt < 13; ++tt) {
            if (w * 13 + tt < 49) {
                bf16x8 bf = __builtin_bit_cast(bf16x8,
                    *(const u16x8*)(Bq + (size_t)((w * 13 + tt) * 16 + lr) * Dc + ks * 32 + g * 8));
                acc[tt] = __builtin_amdgcn_mfma_f32_16x16x32_bf16(af, bf, acc[tt], 0, 0, 0);
            }
        }
    }
    // lane holds rows r0+g*4+j (j=0..3), cols (w*13+tt)*16+lr

    __shared__ float sred[16][4][2];
    __shared__ float rowsum[16], esumS[16], invZ[16], entP[16];

    // sweep 1: rowsum + exp-sum + colsum partials
    float rs[4] = {0.f, 0.f, 0.f, 0.f}, es[4] = {0.f, 0.f, 0.f, 0.f};
    #pragma unroll
    for (int tt = 0; tt < 13; ++tt) {
        int gt = w * 13 + tt;
        if (gt < 49) {
            float c = 0.f;
            #pragma unroll
            for (int j = 0; j < 4; ++j) {
                float a = acc[tt][j];
                rs[j] += a;
                es[j] += __expf(a * INVT);
                c += a;
            }
            c += __shfl_xor(c, 16, 64);
            c += __shfl_xor(c, 32, 64);
            if (g == 0) atomicAdd(&cs[gt * 16 + lr], c);
        }
    }
    #pragma unroll
    for (int off = 1; off <= 8; off <<= 1) {
        #pragma unroll
        for (int j = 0; j < 4; ++j) {
            rs[j] += __shfl_xor(rs[j], off, 64);
            es[j] += __shfl_xor(es[j], off, 64);
        }
    }
    if (lr == 0) {
        #pragma unroll
        for (int j = 0; j < 4; ++j) { sred[g * 4 + j][w][0] = rs[j]; sred[g * 4 + j][w][1] = es[j]; }
    }
    __syncthreads();
    if (tid < 16) {
        rowsum[tid] = sred[tid][0][0] + sred[tid][1][0] + sred[tid][2][0] + sred[tid][3][0];
        esumS[tid]  = sred[tid][0][1] + sred[tid][1][1] + sred[tid][2][1] + sred[tid][3][1];
    }
    __syncthreads();

    // sweep 2: entropy partials (p = A * (1/rowsum), native log)
    float invr[4];
    #pragma unroll
    for (int j = 0; j < 4; ++j) invr[j] = 1.0f / rowsum[g * 4 + j];
    float en[4] = {0.f, 0.f, 0.f, 0.f};
    #pragma unroll
    for (int tt = 0; tt < 13; ++tt) {
        if (w * 13 + tt < 49) {
            #pragma unroll
            for (int j = 0; j < 4; ++j) {
                float p = acc[tt][j] * invr[j];
                en[j] -= p * __logf(fmaxf(p, 1e-20f));
            }
        }
    }
    #pragma unroll
    for (int off = 1; off <= 8; off <<= 1) {
        #pragma unroll
        for (int j = 0; j < 4; ++j) en[j] += __shfl_xor(en[j], off, 64);
    }
    if (lr == 0) {
        #pragma unroll
        for (int j = 0; j < 4; ++j) sred[g * 4 + j][w][0] = en[j];
    }
    __syncthreads();
    if (tid < 16) {
        float ent = sred[tid][0][0] + sred[tid][1][0] + sred[tid][2][0] + sred[tid][3][0];
        float ez  = __expf(ent * wconst * INVT);
        float Z   = esumS[tid] + ez;
        float iz  = 1.0f / Z;
        invZ[tid] = iz;
        entP[tid] = ez * iz;
    }
    __syncthreads();

    // sweep 3: softmax writes (native exp)
    float izl[4];
    #pragma unroll
    for (int j = 0; j < 4; ++j) izl[j] = invZ[g * 4 + j];
    #pragma unroll
    for (int tt = 0; tt < 13; ++tt) {
        int gt = w * 13 + tt;
        int col = gt * 16 + lr;
        #pragma unroll
        for (int j = 0; j < 4; ++j) {
            int row = r0 + g * 4 + j;
            if (gt < 49)
                OUT[(size_t)row * Pp + col] = f2bf(__expf(acc[tt][j] * INVT) * izl[j]);
            else if (col != 784)
                OUT[(size_t)row * Pp + col] = 0;
        }
    }
    if (tid < 16) OUT[(size_t)(r0 + tid) * Pp + 784] = f2bf(entP[tid]);
}

// ---------------- K3: dust rows (row 784) + zero pad rows ----------------
__global__ __launch_bounds__(256) void k_dustrow(const float* __restrict__ cs12,
                                                 const float* __restrict__ cs21,
                                                 unsigned short* __restrict__ P12h,
                                                 unsigned short* __restrict__ P21h)
{
    constexpr float INVT = 1.0f / TEMP;
    const size_t MMp = (size_t)Pp * Pp;
    int bt = blockIdx.x, side = blockIdx.y;
    const float* cs = (side ? cs21 : cs12) + (size_t)bt * Pp;
    unsigned short* OUT = (side ? P21h : P12h) + (size_t)bt * MMp;
    __shared__ float sbuf[4];
    int tid = threadIdx.x;
    float v[4];
    #pragma unroll
    for (int k = 0; k < 4; ++k) {
        int j = tid + k * 256;
        float val = -INFINITY;
        if (j < Nc)       val = -cs[j] * INVT;
        else if (j == Nc) val = 0.f;
        v[k] = val;
    }
    float mx = fmaxf(fmaxf(v[0], v[1]), fmaxf(v[2], v[3]));
    mx = blockReduceMax(mx, sbuf);
    float e[4]; float s = 0.f;
    #pragma unroll
    for (int k = 0; k < 4; ++k) {
        int j = tid + k * 256;
        e[k] = (j < Mc) ? __expf(v[k] - mx) : 0.f;
        s += e[k];
    }
    s = blockReduceSum(s, sbuf);
    float invs = 1.f / s;
    #pragma unroll
    for (int k = 0; k < 4; ++k) {
        int j = tid + k * 256;
        if (j < Mc)      OUT[(size_t)Nc * Pp + j] = f2bf(e[k] * invs);
        else if (j < Pp) OUT[(size_t)Nc * Pp + j] = 0;
    }
    // zero pad rows 785..831
    u16x8 z = {};
    u16x8* dst = (u16x8*)(OUT + (size_t)785 * Pp);
    for (int i = tid; i < (Pp - 785) * Pp / 8; i += 256) dst[i] = z;
}

// ---------------- K6: bf16 transpose (Pp x Pp) ----------------
__global__ __launch_bounds__(256) void k_transpose_bf16(const unsigned short* __restrict__ Sb,
                                                        unsigned short* __restrict__ Db, int mode)
{
    const size_t MMp = (size_t)Pp * Pp;
    __shared__ unsigned short tile[64][65];
    int z = blockIdx.z;
    const unsigned short* S;
    unsigned short* D;
    if (mode == 0) { int b = z / 6, tm = z % 6; S = Sb + ((size_t)b * 7 + tm + 1) * MMp; D = Db + (size_t)z * MMp; }
    else           { S = Sb + ((size_t)z * 7 + 6) * MMp; D = Db + (size_t)z * MMp; }
    int x0 = blockIdx.x * 64, y0 = blockIdx.y * 64;
    int tx = threadIdx.x & 63, ty = threadIdx.x >> 6;
    #pragma unroll
    for (int y = 0; y < 64; y += 4) tile[y + ty][tx] = S[(size_t)(y0 + y + ty) * Pp + x0 + tx];
    __syncthreads();
    #pragma unroll
    for (int y = 0; y < 64; y += 4) D[(size_t)(x0 + y + ty) * Pp + y0 + tx] = tile[tx][y + ty];
}

// ---------------- K7: fused batched MFMA GEMM, C = A @ BT^T, XCD-pinned ----------------
// 1-D grid 392 = 8 * 49. zz = f&7 (job*4+batch pinned per XCD); slot = f>>3:
// x = slot%7, y = slot/7.
struct GJobs {
    const unsigned short* A[2];
    const unsigned short* BT[2];
    unsigned short* Cb[2];
    float* cs[2];                 // per-job colsum base (nullptr = skip); +b*Pp per batch
    long long sA[2], sB[2], sC[2];
};

__global__ __launch_bounds__(256, 3) void k_gemm_mfma(GJobs J)
{
    __shared__ __align__(16) unsigned short As[128 * 64];
    __shared__ __align__(16) unsigned short Bs[128 * 64];

    int f = blockIdx.x;
    int zz = f & 7, slot = f >> 3;
    int job = zz >> 2, b = zz & 3;
    const unsigned short* A  = J.A[job]  + (size_t)b * J.sA[job];
    const unsigned short* BT = J.BT[job] + (size_t)b * J.sB[job];

    const int i0 = (slot / 7) * 128, j0 = (slot % 7) * 128;
    const int tid = threadIdx.x, lane = tid & 63, w = tid >> 6;
    const int wr = w >> 1, wc = w & 1;
    const int g = lane >> 4, lr = lane & 15;

    f32x4 acc[4][4] = {};
    mfma_tile_loop<Pp>(A, BT, As, Bs, i0, j0, tid, acc);

    unsigned short* Co = J.Cb[job] + (size_t)b * J.sC[job];
    float* csp = J.cs[job];
    float csacc[4] = {0.f, 0.f, 0.f, 0.f};
    #pragma unroll
    for (int m = 0; m < 4; ++m)
        #pragma unroll
        for (int n = 0; n < 4; ++n)
            #pragma unroll
            for (int j = 0; j < 4; ++j) {
                int row = i0 + wr * 64 + m * 16 + g * 4 + j;
                int col = j0 + wc * 64 + n * 16 + lr;
                if (row < Pp && col < Pp) {
                    unsigned short h = f2bf(acc[m][n][j]);
                    Co[(size_t)row * Pp + col] = h;
                    csacc[n] += bf2f(h);
                }
            }
    if (csp) {
        csp += (size_t)b * Pp;
        #pragma unroll
        for (int n = 0; n < 4; ++n) {
            float p = csacc[n];
            p += __shfl_xor(p, 16, 64);
            p += __shfl_xor(p, 32, 64);
            int col = j0 + wc * 64 + n * 16 + lr;
            if (g == 0 && col < Pp) atomicAdd(&csp[col], p);
        }
    }
}

// ---------------- K8: loss rows via dot products (no AA GEMM) ----------------
// loss_i += log(rowsum_i + Mc*eps) - log(diag_i + eps)
// rowsum_i = L[i,:] . colsum(R);  diag_i = L[i,:] . R[i,:]
__global__ __launch_bounds__(64) void k_lossrow(const unsigned short* __restrict__ L,
                                                const unsigned short* __restrict__ R,
                                                const float* __restrict__ csR,
                                                float* __restrict__ loss, float scale)
{
    const size_t MMp = (size_t)Pp * Pp;
    int r = blockIdx.x;
    int b = r / Mc, i = r % Mc;
    const u16x8* lrow = (const u16x8*)(L + (size_t)b * MMp + (size_t)i * Pp);
    const u16x8* rrow = (const u16x8*)(R + (size_t)b * MMp + (size_t)i * Pp);
    const f32x4* cs4  = (const f32x4*)(csR + (size_t)b * Pp);
    int lane = threadIdx.x;
    float sR = 0.f, sD = 0.f;
    for (int c = lane; c < Pp / 8; c += 64) {
        u16x8 lv = lrow[c];
        u16x8 rv = rrow[c];
        f32x4 c0 = cs4[2 * c], c1 = cs4[2 * c + 1];
        #pragma unroll
        for (int k = 0; k < 4; ++k) {
            float fl = bf2f(lv[k]);
            sR += fl * c0[k];
            sD += fl * bf2f(rv[k]);
        }
        #pragma unroll
        for (int k = 0; k < 4; ++k) {
            float fl = bf2f(lv[4 + k]);
            sR += fl * c1[k];
            sD += fl * bf2f(rv[4 + k]);
        }
    }
    #pragma unroll
    for (int off = 1; off <= 32; off <<= 1) {
        sR += __shfl_xor(sR, off, 64);
        sD += __shfl_xor(sD, off, 64);
    }
    if (lane == 0)
        atomicAdd(loss, (logf(sR + Mc * 1e-20f) - logf(sD + 1e-20f)) * scale);
}

__global__ void k_zero(float* p) { *p = 0.f; }

// ---------------- host orchestration ----------------
extern "C" void kernel_launch(void* const* d_in, const int* in_sizes, int n_in,
                              void* d_out, int out_size, void* d_ws, size_t ws_size,
                              hipStream_t stream)
{
    const float* feats = (const float*)d_in[0];
    const float* dust  = (const float*)d_in[1];
    const float* Wself = (const float*)d_in[2];
    const float* bself = (const float*)d_in[3];
    const float* Wdust = (const float*)d_in[4];
    const float* bdust = (const float*)d_in[5];

    float* out  = (float*)d_out;
    float* qout = out;
    float* loss = out + (size_t)Bc * Dc * Tc * Mc;

    const size_t MMp = (size_t)Pp * Pp;       // 692,224

    // ---- workspace ----
    float* ws = (float*)d_ws;
    float* csR = ws;                                                // 6 slots * Bc * Pp fp32
    unsigned short* P12h = (unsigned short*)(ws + 4 * MMp);         // 28*MMp bf16
    unsigned short* P21h = P12h + (size_t)28 * MMp;                 // 28*MMp bf16
    unsigned short* chainT = P21h + (size_t)28 * MMp;               // 44*MMp bf16 region
    unsigned short* P12T  = chainT;
    unsigned short* P21T6 = P12T + (size_t)24 * MMp;
    unsigned short* l0    = P21T6 + (size_t)4 * MMp;
    unsigned short* l1    = l0 + (size_t)4 * MMp;
    unsigned short* R0    = l1 + (size_t)4 * MMp;
    unsigned short* R1    = R0 + (size_t)4 * MMp;
    unsigned short* qTb   = R1 + (size_t)4 * MMp;                   // 32*Qrows*Dc bf16
    float* cs12 = (float*)(qTb + (size_t)32 * Qrows * Dc);          // 28*Pp fp32
    float* cs21 = cs12 + (size_t)28 * Pp;                           // 28*Pp fp32

    // phase-1 overlays in chainT region (dead before transposes write it):
    unsigned short* Abf   = chainT;
    unsigned int*   Abf32 = (unsigned int*)Abf;
    unsigned short* WTb   = Abf + (size_t)Bc * Tc * Nc * Cc;
    float*          fbuf  = (float*)(WTb + 2 * (size_t)Dc * Cc);

    // 1. pack inputs to bf16
    k_pack<<<Bc * Nc, 256, 0, stream>>>(feats, Abf32);
    k_packw<<<dim3(2, 8, 2), 256, 0, stream>>>(Wself, Wdust, WTb);
    hipMemsetAsync(cs12, 0, (size_t)2 * 28 * Pp * sizeof(float), stream);
    hipMemsetAsync(csR, 0, (size_t)6 * Bc * Pp * sizeof(float), stream);
    // 2. projection GEMM + bias
    k_gemm_proj<<<dim3(1, 196), 256, 0, stream>>>(Abf, WTb, bself, fbuf);
    // 3. dust projection (fp32) + norms
    k_dustproj<<<32, 128, 0, stream>>>(dust, Wdust, bdust, qTb, qout);
    k_norm<<<dim3(13, 32), 256, 0, stream>>>(fbuf, qTb, qout);
    // 4. fused affinity (XCD-pinned), then dust rows
    float wconst = (float)(1.0 / log(784.0));
    k_affinity<<<2744, 256, 0, stream>>>(qTb, P12h, P21h, cs12, cs21, wconst);
    k_dustrow<<<dim3(28, 2), 256, 0, stream>>>(cs12, cs21, P12h, P21h);
    // 5. bf16 transposes
    k_transpose_bf16<<<dim3(13, 13, 24), 256, 0, stream>>>(P12h, P12T, 0);
    k_transpose_bf16<<<dim3(13, 13, 4),  256, 0, stream>>>(P21h, P21T6, 1);

    // 6. chain
    k_zero<<<1, 1, 0, stream>>>(loss);
    const float scale = 1.0f / (6.0f * Bc * Mc);

    // prologue: L1 = P12[0] @ P12[1]^T-form;  R1 = P21T6 @ P21[5]^T (colsum slot 0)
    {
        GJobs J = {};
        J.A[0] = P12h;  J.sA[0] = (long long)7 * MMp;
        J.BT[0] = P12T; J.sB[0] = (long long)6 * MMp;
        J.Cb[0] = l0;   J.sC[0] = (long long)MMp; J.cs[0] = nullptr;
        J.A[1] = P21T6;                   J.sA[1] = (long long)MMp;
        J.BT[1] = P21h + (size_t)5 * MMp; J.sB[1] = (long long)7 * MMp;
        J.Cb[1] = R0;   J.sC[1] = (long long)MMp; J.cs[1] = csR;   // slot 0
        k_gemm_mfma<<<392, 256, 0, stream>>>(J);
    }

    unsigned short *lcur = l0, *lnxt = l1, *rcur = R0, *rnxt = R1;
    for (int i = 1; i <= 6; ++i) {
        // loss from current states (no AA materialization)
        k_lossrow<<<Bc * Mc, 64, 0, stream>>>(lcur, rcur, csR + (size_t)(i - 1) * Bc * Pp, loss, scale);
        if (i < 6) {
            GJobs J = {};
            J.A[0] = lcur; J.sA[0] = (long long)MMp;
            J.BT[0] = P12T + (size_t)i * MMp; J.sB[0] = (long long)6 * MMp;
            J.Cb[0] = lnxt; J.sC[0] = (long long)MMp; J.cs[0] = nullptr;
            J.A[1] = rcur; J.sA[1] = (long long)MMp;
            J.BT[1] = P21h + (size_t)(5 - i) * MMp; J.sB[1] = (long long)7 * MMp;
            J.Cb[1] = rnxt; J.sC[1] = (long long)MMp; J.cs[1] = csR + (size_t)i * Bc * Pp;
            k_gemm_mfma<<<392, 256, 0, stream>>>(J);
            unsigned short* t;
            t = lcur; lcur = lnxt; lnxt = t;
            t = rcur; rcur = rnxt; rnxt = t;
        }
    }
}

// Round 9
// 507.537 us; speedup vs baseline: 7.7539x; 1.0843x over previous
//
#include <hip/hip_runtime.h>
#include <hip/hip_bf16.h>
#include <math.h>

// Problem constants
constexpr int Bc = 4;      // batch
constexpr int Nc = 784;    // tokens
constexpr int Cc = 512;    // enc channels
constexpr int Tc = 8;      // time
constexpr int Dc = 128;    // proj dim
constexpr int Mc = 785;    // N+1
constexpr int TM1 = 7;     // T-1
constexpr int Pp = 832;    // padded chain dim (13*64)
constexpr int Qrows = 896; // padded q rows
constexpr float TEMP = 0.07f;

typedef __attribute__((ext_vector_type(4))) float f32x4;
typedef __attribute__((ext_vector_type(8))) unsigned short u16x8;
typedef __attribute__((ext_vector_type(8))) __bf16 bf16x8;

__device__ __forceinline__ unsigned short f2bf(float v) {
    __hip_bfloat16 h = __float2bfloat16(v);
    return __builtin_bit_cast(unsigned short, h);
}
__device__ __forceinline__ float bf2f(unsigned short u) {
    return __builtin_bit_cast(float, (unsigned int)u << 16);
}

// ---------------- async 16B global->LDS ----------------
__device__ __forceinline__ void gload16(const void* g, void* l) {
    __builtin_amdgcn_global_load_lds(
        (const __attribute__((address_space(1))) unsigned int*)g,
        (__attribute__((address_space(3))) unsigned int*)l, 16, 0, 0);
}

// Shared MFMA K-loop: 128x128 C-tile, BK=64, 4 waves, global_load_lds staging
// with XOR-16B involution swizzle.
template<int LD>
__device__ __forceinline__ void mfma_tile_loop(const unsigned short* __restrict__ A,
                                               const unsigned short* __restrict__ BT,
                                               unsigned short* __restrict__ As,
                                               unsigned short* __restrict__ Bs,
                                               int i0, int j0, int tid,
                                               f32x4 (&acc)[4][4])
{
    const int lane = tid & 63, w = tid >> 6;
    const int wr = w >> 1, wc = w & 1;
    const int g = lane >> 4, lr = lane & 15;

    for (int k0 = 0; k0 < LD; k0 += 64) {
        __syncthreads();
        #pragma unroll
        for (int q = 0; q < 4; ++q) {
            int L16 = q * 256 + tid;
            int r = L16 >> 3;
            int csw = ((L16 & 7) << 4) ^ ((r & 7) << 4);
            const char* ga = (const char*)(A  + (size_t)(i0 + r) * LD + k0) + csw;
            const char* gb = (const char*)(BT + (size_t)(j0 + r) * LD + k0) + csw;
            gload16(ga, As + (size_t)L16 * 8);
            gload16(gb, Bs + (size_t)L16 * 8);
        }
        __syncthreads();
        #pragma unroll
        for (int ks = 0; ks < 2; ++ks) {
            bf16x8 af[4], bf[4];
            #pragma unroll
            for (int m = 0; m < 4; ++m) {
                int r = wr * 64 + m * 16 + lr;
                int cb = (ks * 64 + g * 16) ^ ((r & 7) << 4);
                af[m] = __builtin_bit_cast(bf16x8, *(const u16x8*)((const char*)As + r * 128 + cb));
            }
            #pragma unroll
            for (int n = 0; n < 4; ++n) {
                int r = wc * 64 + n * 16 + lr;
                int cb = (ks * 64 + g * 16) ^ ((r & 7) << 4);
                bf[n] = __builtin_bit_cast(bf16x8, *(const u16x8*)((const char*)Bs + r * 128 + cb));
            }
            #pragma unroll
            for (int m = 0; m < 4; ++m)
                #pragma unroll
                for (int n = 0; n < 4; ++n)
                    acc[m][n] = __builtin_amdgcn_mfma_f32_16x16x32_bf16(af[m], bf[n], acc[m][n], 0, 0, 0);
        }
    }
}

// ---------------- reduction helpers ----------------
__device__ __forceinline__ float blockReduceSum(float v, float* sbuf) {
    #pragma unroll
    for (int off = 32; off; off >>= 1) v += __shfl_down(v, off, 64);
    __syncthreads();
    if ((threadIdx.x & 63) == 0) sbuf[threadIdx.x >> 6] = v;
    __syncthreads();
    return sbuf[0] + sbuf[1] + sbuf[2] + sbuf[3];
}
__device__ __forceinline__ float blockReduceMax(float v, float* sbuf) {
    #pragma unroll
    for (int off = 32; off; off >>= 1) v = fmaxf(v, __shfl_down(v, off, 64));
    __syncthreads();
    if ((threadIdx.x & 63) == 0) sbuf[threadIdx.x >> 6] = v;
    __syncthreads();
    return fmaxf(fmaxf(sbuf[0], sbuf[1]), fmaxf(sbuf[2], sbuf[3]));
}

// ---------------- K1a: pack feats -> bf16 A[(b,t,n), c] ----------------
__global__ __launch_bounds__(256) void k_pack(const float* __restrict__ feats,
                                              unsigned int* __restrict__ Abf32)
{
    __shared__ float lds[Cc * 9];
    int bid = blockIdx.x;
    int b = bid / Nc, n = bid % Nc;
    const float* src = feats + (size_t)(b * Nc + n) * Cc * Tc;
    int tid = threadIdx.x;
    for (int i = tid; i < Cc * Tc; i += 256) lds[(i >> 3) * 9 + (i & 7)] = src[i];
    __syncthreads();
    #pragma unroll
    for (int t = 0; t < Tc; ++t) {
        size_t row = (size_t)(b * Tc + t) * Nc + n;
        float v0 = lds[(2 * tid) * 9 + t];
        float v1 = lds[(2 * tid + 1) * 9 + t];
        unsigned int pk = (unsigned int)f2bf(v0) | ((unsigned int)f2bf(v1) << 16);
        Abf32[row * (Cc / 2) + tid] = pk;
    }
}

// ---------------- K1b: pack W -> bf16 WT[which][d][c] ----------------
__global__ __launch_bounds__(256) void k_packw(const float* __restrict__ Wself,
                                               const float* __restrict__ Wdust,
                                               unsigned short* __restrict__ WTb)
{
    __shared__ float tile[64][65];
    int which = blockIdx.z;
    const float* W = which ? Wdust : Wself;
    unsigned short* O = WTb + (size_t)which * Dc * Cc;
    int d0 = blockIdx.x * 64, c0 = blockIdx.y * 64;
    int tx = threadIdx.x & 63, ty = threadIdx.x >> 6;
    #pragma unroll
    for (int y = 0; y < 64; y += 4) tile[y + ty][tx] = W[(size_t)(c0 + y + ty) * Dc + d0 + tx];
    __syncthreads();
    #pragma unroll
    for (int y = 0; y < 64; y += 4) O[(size_t)(d0 + y + ty) * Cc + c0 + tx] = f2bf(tile[tx][y + ty]);
}

// ---------------- K1c: projection GEMM fbuf = Abf @ WT^T + bias (MFMA) ----------------
__global__ __launch_bounds__(256, 3) void k_gemm_proj(const unsigned short* __restrict__ A,
                                                      const unsigned short* __restrict__ BT,
                                                      const float* __restrict__ bias,
                                                      float* __restrict__ Cf)
{
    __shared__ __align__(16) unsigned short As[128 * 64];
    __shared__ __align__(16) unsigned short Bs[128 * 64];
    const int i0 = blockIdx.y * 128;
    const int tid = threadIdx.x, lane = tid & 63, w = tid >> 6;
    const int wr = w >> 1, wc = w & 1;
    const int g = lane >> 4, lr = lane & 15;

    f32x4 acc[4][4] = {};
    mfma_tile_loop<Cc>(A, BT, As, Bs, i0, 0, tid, acc);

    #pragma unroll
    for (int n = 0; n < 4; ++n) {
        int col = wc * 64 + n * 16 + lr;
        float bv = bias[col];
        #pragma unroll
        for (int m = 0; m < 4; ++m)
            #pragma unroll
            for (int j = 0; j < 4; ++j) {
                int row = i0 + wr * 64 + m * 16 + g * 4 + j;
                Cf[(size_t)row * Dc + col] = acc[m][n][j] + bv;
            }
    }
}

// ---------------- K1d: dust projection + l2norm (fp32 exact) ----------------
__global__ __launch_bounds__(128) void k_dustproj(const float* __restrict__ dust,
                                                  const float* __restrict__ Wdust,
                                                  const float* __restrict__ bdust,
                                                  unsigned short* __restrict__ qTb,
                                                  float* __restrict__ qout)
{
    __shared__ float sdust[Cc];
    __shared__ float red[2];
    int bt = blockIdx.x;
    int b = bt >> 3, t = bt & 7;
    int tid = threadIdx.x;
    for (int i = tid; i < Cc; i += 128) sdust[i] = dust[((size_t)b * Cc + i) * Tc + t];
    __syncthreads();
    float acc = 0.f;
    for (int c = 0; c < Cc; ++c) acc += sdust[c] * Wdust[(size_t)c * Dc + tid];
    acc += bdust[tid];
    float s = acc * acc;
    #pragma unroll
    for (int off = 32; off; off >>= 1) s += __shfl_down(s, off, 64);
    if ((tid & 63) == 0) red[tid >> 6] = s;
    __syncthreads();
    float inv = 1.f / fmaxf(sqrtf(red[0] + red[1]), 1e-12f);
    float qv = acc * inv;
    qTb[((size_t)bt * Qrows + Nc) * Dc + tid] = f2bf(qv);
    qout[(((size_t)b * Dc + tid) * Tc + t) * Mc + Nc] = qv;
}

// ---------------- K1e: l2norm rows of fbuf -> bf16 qTb + fp32 qout ----------------
__global__ __launch_bounds__(256) void k_norm(const float* __restrict__ fbuf,
                                              unsigned short* __restrict__ qTb,
                                              float* __restrict__ qout)
{
    __shared__ float lds[64][129];
    __shared__ float nrm[64][4];
    __shared__ float inv[64];
    int bt = blockIdx.y;
    int b = bt >> 3, t = bt & 7;
    int n0 = blockIdx.x * 64;
    int tid = threadIdx.x;
    #pragma unroll
    for (int q = 0; q < 8; ++q) {
        int i = q * 256 + tid;
        int nl = i >> 5, d4 = i & 31;
        f32x4 v = {};
        if (n0 + nl < Nc) v = *(const f32x4*)(fbuf + ((size_t)bt * Nc + n0 + nl) * Dc + d4 * 4);
        *(f32x4*)(&lds[nl][d4 * 4]) = v;
    }
    __syncthreads();
    {
        int r = tid & 63, p = tid >> 6;
        float s = 0.f;
        #pragma unroll
        for (int j = 0; j < 32; ++j) { float v = lds[r][p * 32 + j]; s += v * v; }
        nrm[r][p] = s;
    }
    __syncthreads();
    if (tid < 64) inv[tid] = 1.f / fmaxf(sqrtf(nrm[tid][0] + nrm[tid][1] + nrm[tid][2] + nrm[tid][3]), 1e-12f);
    __syncthreads();
    unsigned int* qT32 = (unsigned int*)(qTb + (size_t)bt * Qrows * Dc);
    #pragma unroll
    for (int q = 0; q < 16; ++q) {
        int i = q * 256 + tid;
        int nl = i >> 6, dp = i & 63;
        if (n0 + nl < Nc) {
            float iv = inv[nl];
            unsigned int pk = (unsigned int)f2bf(lds[nl][2 * dp] * iv)
                            | ((unsigned int)f2bf(lds[nl][2 * dp + 1] * iv) << 16);
            qT32[((size_t)(n0 + nl) * Dc >> 1) + dp] = pk;
        }
    }
    int nl = tid & 63;
    if (n0 + nl < Nc) {
        float iv = inv[nl];
        #pragma unroll
        for (int dd = 0; dd < Dc; dd += 4) {
            int d = dd + (tid >> 6);
            qout[(((size_t)b * Dc + d) * Tc + t) * Mc + n0 + nl] = lds[nl][d] * iv;
        }
    }
}

// ---------------- K2: fused affinity, XCD-pinned, batched loads, cached exp ----------------
// 1-D grid 2744 = 8 XCDs * 343. xcd = f&7, slot = f>>3; grp = xcd + 8*(slot/49).
__global__ __launch_bounds__(256) void k_affinity(const unsigned short* __restrict__ qTb,
                                                  unsigned short* __restrict__ P12h,
                                                  unsigned short* __restrict__ P21h,
                                                  float* __restrict__ cs12,
                                                  float* __restrict__ cs21,
                                                  float wconst)
{
    constexpr float INVT = 1.0f / TEMP;
    const size_t MMp = (size_t)Pp * Pp;
    int f = blockIdx.x;
    int xcd = f & 7, slot = f >> 3;
    int grp = xcd + 8 * (slot / 49);
    int strip = slot % 49;
    int side = grp >= 28 ? 1 : 0;
    int bt = grp - side * 28;
    int b = bt / TM1, t = bt % TM1;
    const unsigned short *Aq, *Bq;
    unsigned short* OUT;
    float* cs;
    if (side == 0) {
        Aq = qTb + (size_t)(b * Tc + t)     * Qrows * Dc;
        Bq = qTb + (size_t)(b * Tc + t + 1) * Qrows * Dc;
        OUT = P12h + (size_t)bt * MMp;
        cs  = cs12 + (size_t)bt * Pp;
    } else {
        Aq = qTb + (size_t)(b * Tc + 7 - t) * Qrows * Dc;
        Bq = qTb + (size_t)(b * Tc + 6 - t) * Qrows * Dc;
        OUT = P21h + (size_t)bt * MMp;
        cs  = cs21 + (size_t)bt * Pp;
    }
    const int r0 = strip * 16;
    const int tid = threadIdx.x, lane = tid & 63, w = tid >> 6;
    const int g = lane >> 4, lr = lane & 15;

    // MFMA: wave w owns col-tiles w*13 .. w*13+12; B loads batched in chunks of 7
    f32x4 acc[13] = {};
    #pragma unroll
    for (int ks = 0; ks < 4; ++ks) {
        bf16x8 af = __builtin_bit_cast(bf16x8,
            *(const u16x8*)(Aq + (size_t)(r0 + lr) * Dc + ks * 32 + g * 8));
        bf16x8 bfr[7];
        #pragma unroll
        for (int tt = 0; tt < 7; ++tt)
            if (w * 13 + tt < 49)
                bfr[tt] = __builtin_bit_cast(bf16x8,
                    *(const u16x8*)(Bq + (size_t)((w * 13 + tt) * 16 + lr) * Dc + ks * 32 + g * 8));
        #pragma unroll
        for (int tt = 0; tt < 7; ++tt)
            if (w * 13 + tt < 49)
                acc[tt] = __builtin_amdgcn_mfma_f32_16x16x32_bf16(af, bfr[tt], acc[tt], 0, 0, 0);
        #pragma unroll
        for (int tt = 7; tt < 13; ++tt)
            if (w * 13 + tt < 49)
                bfr[tt - 7] = __builtin_bit_cast(bf16x8,
                    *(const u16x8*)(Bq + (size_t)((w * 13 + tt) * 16 + lr) * Dc + ks * 32 + g * 8));
        #pragma unroll
        for (int tt = 7; tt < 13; ++tt)
            if (w * 13 + tt < 49)
                acc[tt] = __builtin_amdgcn_mfma_f32_16x16x32_bf16(af, bfr[tt - 7], acc[tt], 0, 0, 0);
    }
    // lane holds rows r0+g*4+j (j=0..3), cols (w*13+tt)*16+lr

    __shared__ float sred[16][4][2];
    __shared__ float rowsum[16], invZ[16], entP[16];

    // sweep 1: rowsum + colsum partials (raw scores)
    float rs[4] = {0.f, 0.f, 0.f, 0.f};
    #pragma unroll
    for (int tt = 0; tt < 13; ++tt) {
        int gt = w * 13 + tt;
        if (gt < 49) {
            float c = 0.f;
            #pragma unroll
            for (int j = 0; j < 4; ++j) {
                float a = acc[tt][j];
                rs[j] += a;
                c += a;
            }
            c += __shfl_xor(c, 16, 64);
            c += __shfl_xor(c, 32, 64);
            if (g == 0) atomicAdd(&cs[gt * 16 + lr], c);
        }
    }
    #pragma unroll
    for (int off = 1; off <= 8; off <<= 1) {
        #pragma unroll
        for (int j = 0; j < 4; ++j) rs[j] += __shfl_xor(rs[j], off, 64);
    }
    if (lr == 0) {
        #pragma unroll
        for (int j = 0; j < 4; ++j) sred[g * 4 + j][w][0] = rs[j];
    }
    __syncthreads();
    if (tid < 16)
        rowsum[tid] = sred[tid][0][0] + sred[tid][1][0] + sred[tid][2][0] + sred[tid][3][0];
    __syncthreads();

    // sweep 2: exp-sum + entropy; cache exp into acc
    float invr[4];
    #pragma unroll
    for (int j = 0; j < 4; ++j) invr[j] = 1.0f / rowsum[g * 4 + j];
    float en[4] = {0.f, 0.f, 0.f, 0.f}, es[4] = {0.f, 0.f, 0.f, 0.f};
    #pragma unroll
    for (int tt = 0; tt < 13; ++tt) {
        if (w * 13 + tt < 49) {
            #pragma unroll
            for (int j = 0; j < 4; ++j) {
                float a = acc[tt][j];
                float e = __expf(a * INVT);
                es[j] += e;
                float p = a * invr[j];
                en[j] -= p * __logf(fmaxf(p, 1e-20f));
                acc[tt][j] = e;
            }
        }
    }
    #pragma unroll
    for (int off = 1; off <= 8; off <<= 1) {
        #pragma unroll
        for (int j = 0; j < 4; ++j) {
            es[j] += __shfl_xor(es[j], off, 64);
            en[j] += __shfl_xor(en[j], off, 64);
        }
    }
    if (lr == 0) {
        #pragma unroll
        for (int j = 0; j < 4; ++j) { sred[g * 4 + j][w][0] = es[j]; sred[g * 4 + j][w][1] = en[j]; }
    }
    __syncthreads();
    if (tid < 16) {
        float esum = sred[tid][0][0] + sred[tid][1][0] + sred[tid][2][0] + sred[tid][3][0];
        float ent  = sred[tid][0][1] + sred[tid][1][1] + sred[tid][2][1] + sred[tid][3][1];
        float ez  = __expf(ent * wconst * INVT);
        float Z   = esum + ez;
        float iz  = 1.0f / Z;
        invZ[tid] = iz;
        entP[tid] = ez * iz;
    }
    __syncthreads();

    // sweep 3: writes from cached exp
    float izl[4];
    #pragma unroll
    for (int j = 0; j < 4; ++j) izl[j] = invZ[g * 4 + j];
    #pragma unroll
    for (int tt = 0; tt < 13; ++tt) {
        int gt = w * 13 + tt;
        int col = gt * 16 + lr;
        #pragma unroll
        for (int j = 0; j < 4; ++j) {
            int row = r0 + g * 4 + j;
            if (gt < 49)
                OUT[(size_t)row * Pp + col] = f2bf(acc[tt][j] * izl[j]);
            else if (col != 784)
                OUT[(size_t)row * Pp + col] = 0;
        }
    }
    if (tid < 16) OUT[(size_t)(r0 + tid) * Pp + 784] = f2bf(entP[tid]);
}

// ---------------- K3: dust rows (row 784) + zero pad rows ----------------
__global__ __launch_bounds__(256) void k_dustrow(const float* __restrict__ cs12,
                                                 const float* __restrict__ cs21,
                                                 unsigned short* __restrict__ P12h,
                                                 unsigned short* __restrict__ P21h)
{
    constexpr float INVT = 1.0f / TEMP;
    const size_t MMp = (size_t)Pp * Pp;
    int bt = blockIdx.x, side = blockIdx.y;
    const float* cs = (side ? cs21 : cs12) + (size_t)bt * Pp;
    unsigned short* OUT = (side ? P21h : P12h) + (size_t)bt * MMp;
    __shared__ float sbuf[4];
    int tid = threadIdx.x;
    float v[4];
    #pragma unroll
    for (int k = 0; k < 4; ++k) {
        int j = tid + k * 256;
        float val = -INFINITY;
        if (j < Nc)       val = -cs[j] * INVT;
        else if (j == Nc) val = 0.f;
        v[k] = val;
    }
    float mx = fmaxf(fmaxf(v[0], v[1]), fmaxf(v[2], v[3]));
    mx = blockReduceMax(mx, sbuf);
    float e[4]; float s = 0.f;
    #pragma unroll
    for (int k = 0; k < 4; ++k) {
        int j = tid + k * 256;
        e[k] = (j < Mc) ? __expf(v[k] - mx) : 0.f;
        s += e[k];
    }
    s = blockReduceSum(s, sbuf);
    float invs = 1.f / s;
    #pragma unroll
    for (int k = 0; k < 4; ++k) {
        int j = tid + k * 256;
        if (j < Mc)      OUT[(size_t)Nc * Pp + j] = f2bf(e[k] * invs);
        else if (j < Pp) OUT[(size_t)Nc * Pp + j] = 0;
    }
    u16x8 z = {};
    u16x8* dst = (u16x8*)(OUT + (size_t)785 * Pp);
    for (int i = tid; i < (Pp - 785) * Pp / 8; i += 256) dst[i] = z;
}

// ---------------- K6: merged bf16 transposes (grid z = 0..27) ----------------
// z<24: D = P12T+z = (P12h[b*7 + z%6 + 1])^T ; z>=24: D = P12T+z = (P21h[(z-24)*7+6])^T
__global__ __launch_bounds__(256) void k_transpose_bf16(const unsigned short* __restrict__ P12h,
                                                        const unsigned short* __restrict__ P21h,
                                                        unsigned short* __restrict__ Db)
{
    const size_t MMp = (size_t)Pp * Pp;
    __shared__ unsigned short tile[64][65];
    int z = blockIdx.z;
    const unsigned short* S;
    if (z < 24) { int b = z / 6, tm = z % 6; S = P12h + ((size_t)b * 7 + tm + 1) * MMp; }
    else        { S = P21h + ((size_t)(z - 24) * 7 + 6) * MMp; }
    unsigned short* D = Db + (size_t)z * MMp;
    int x0 = blockIdx.x * 64, y0 = blockIdx.y * 64;
    int tx = threadIdx.x & 63, ty = threadIdx.x >> 6;
    #pragma unroll
    for (int y = 0; y < 64; y += 4) tile[y + ty][tx] = S[(size_t)(y0 + y + ty) * Pp + x0 + tx];
    __syncthreads();
    #pragma unroll
    for (int y = 0; y < 64; y += 4) D[(size_t)(x0 + y + ty) * Pp + y0 + tx] = tile[tx][y + ty];
}

// ---------------- K7: fused chain GEMM + loss ----------------
// Blocks [0,392): XCD-pinned GEMM (zz = f&7 -> job*4+batch; slot = f>>3 -> tile).
// Blocks [392, 392+785): loss role — wave per row: loss += log(L.csR) - log(L.R).
struct GJobs {
    const unsigned short* A[2];
    const unsigned short* BT[2];
    unsigned short* Cb[2];
    float* cs[2];
    long long sA[2], sB[2], sC[2];
    const unsigned short* Lr;     // loss inputs (may be null for prologue)
    const unsigned short* Rr;
    const float* csL;
    float* loss;
    float scale;
};

__global__ __launch_bounds__(256, 3) void k_gemm_loss(GJobs J)
{
    const size_t MMp = (size_t)Pp * Pp;
    if (blockIdx.x >= 392) {
        // ---- loss role ----
        int q = blockIdx.x - 392;
        int w = threadIdx.x >> 6, lane = threadIdx.x & 63;
        int r = q * 4 + w;                 // 0..3139
        int b = r / Mc, i = r % Mc;
        const u16x8* lrow = (const u16x8*)(J.Lr + (size_t)b * MMp + (size_t)i * Pp);
        const u16x8* rrow = (const u16x8*)(J.Rr + (size_t)b * MMp + (size_t)i * Pp);
        const f32x4* cs4  = (const f32x4*)(J.csL + (size_t)b * Pp);
        float sR = 0.f, sD = 0.f;
        for (int c = lane; c < Pp / 8; c += 64) {
            u16x8 lv = lrow[c];
            u16x8 rv = rrow[c];
            f32x4 c0 = cs4[2 * c], c1 = cs4[2 * c + 1];
            #pragma unroll
            for (int k = 0; k < 4; ++k) {
                float fl = bf2f(lv[k]);
                sR += fl * c0[k];
                sD += fl * bf2f(rv[k]);
            }
            #pragma unroll
            for (int k = 0; k < 4; ++k) {
                float fl = bf2f(lv[4 + k]);
                sR += fl * c1[k];
                sD += fl * bf2f(rv[4 + k]);
            }
        }
        #pragma unroll
        for (int off = 1; off <= 32; off <<= 1) {
            sR += __shfl_xor(sR, off, 64);
            sD += __shfl_xor(sD, off, 64);
        }
        if (lane == 0)
            atomicAdd(J.loss, (logf(sR + Mc * 1e-20f) - logf(sD + 1e-20f)) * J.scale);
        return;
    }

    // ---- GEMM role ----
    __shared__ __align__(16) unsigned short As[128 * 64];
    __shared__ __align__(16) unsigned short Bs[128 * 64];

    int f = blockIdx.x;
    int zz = f & 7, slot = f >> 3;
    int job = zz >> 2, b = zz & 3;
    const unsigned short* A  = J.A[job]  + (size_t)b * J.sA[job];
    const unsigned short* BT = J.BT[job] + (size_t)b * J.sB[job];

    const int i0 = (slot / 7) * 128, j0 = (slot % 7) * 128;
    const int tid = threadIdx.x, lane = tid & 63, w = tid >> 6;
    const int wr = w >> 1, wc = w & 1;
    const int g = lane >> 4, lr = lane & 15;

    f32x4 acc[4][4] = {};
    mfma_tile_loop<Pp>(A, BT, As, Bs, i0, j0, tid, acc);

    unsigned short* Co = J.Cb[job] + (size_t)b * J.sC[job];
    float* csp = J.cs[job];
    float csacc[4] = {0.f, 0.f, 0.f, 0.f};
    #pragma unroll
    for (int m = 0; m < 4; ++m)
        #pragma unroll
        for (int n = 0; n < 4; ++n)
            #pragma unroll
            for (int j = 0; j < 4; ++j) {
                int row = i0 + wr * 64 + m * 16 + g * 4 + j;
                int col = j0 + wc * 64 + n * 16 + lr;
                if (row < Pp && col < Pp) {
                    unsigned short h = f2bf(acc[m][n][j]);
                    Co[(size_t)row * Pp + col] = h;
                    csacc[n] += bf2f(h);
                }
            }
    if (csp) {
        csp += (size_t)b * Pp;
        #pragma unroll
        for (int n = 0; n < 4; ++n) {
            float p = csacc[n];
            p += __shfl_xor(p, 16, 64);
            p += __shfl_xor(p, 32, 64);
            int col = j0 + wc * 64 + n * 16 + lr;
            if (g == 0 && col < Pp) atomicAdd(&csp[col], p);
        }
    }
}

// ---------------- K8: standalone loss rows (final step) ----------------
__global__ __launch_bounds__(64) void k_lossrow(const unsigned short* __restrict__ L,
                                                const unsigned short* __restrict__ R,
                                                const float* __restrict__ csR,
                                                float* __restrict__ loss, float scale)
{
    const size_t MMp = (size_t)Pp * Pp;
    int r = blockIdx.x;
    int b = r / Mc, i = r % Mc;
    const u16x8* lrow = (const u16x8*)(L + (size_t)b * MMp + (size_t)i * Pp);
    const u16x8* rrow = (const u16x8*)(R + (size_t)b * MMp + (size_t)i * Pp);
    const f32x4* cs4  = (const f32x4*)(csR + (size_t)b * Pp);
    int lane = threadIdx.x;
    float sR = 0.f, sD = 0.f;
    for (int c = lane; c < Pp / 8; c += 64) {
        u16x8 lv = lrow[c];
        u16x8 rv = rrow[c];
        f32x4 c0 = cs4[2 * c], c1 = cs4[2 * c + 1];
        #pragma unroll
        for (int k = 0; k < 4; ++k) {
            float fl = bf2f(lv[k]);
            sR += fl * c0[k];
            sD += fl * bf2f(rv[k]);
        }
        #pragma unroll
        for (int k = 0; k < 4; ++k) {
            float fl = bf2f(lv[4 + k]);
            sR += fl * c1[k];
            sD += fl * bf2f(rv[4 + k]);
        }
    }
    #pragma unroll
    for (int off = 1; off <= 32; off <<= 1) {
        sR += __shfl_xor(sR, off, 64);
        sD += __shfl_xor(sD, off, 64);
    }
    if (lane == 0)
        atomicAdd(loss, (logf(sR + Mc * 1e-20f) - logf(sD + 1e-20f)) * scale);
}

__global__ void k_zero(float* p) { *p = 0.f; }

// ---------------- host orchestration ----------------
extern "C" void kernel_launch(void* const* d_in, const int* in_sizes, int n_in,
                              void* d_out, int out_size, void* d_ws, size_t ws_size,
                              hipStream_t stream)
{
    const float* feats = (const float*)d_in[0];
    const float* dust  = (const float*)d_in[1];
    const float* Wself = (const float*)d_in[2];
    const float* bself = (const float*)d_in[3];
    const float* Wdust = (const float*)d_in[4];
    const float* bdust = (const float*)d_in[5];

    float* out  = (float*)d_out;
    float* qout = out;
    float* loss = out + (size_t)Bc * Dc * Tc * Mc;

    const size_t MMp = (size_t)Pp * Pp;       // 692,224

    // ---- workspace ----
    float* ws = (float*)d_ws;
    float* csR = ws;                                                // 6 slots * Bc * Pp fp32
    unsigned short* P12h = (unsigned short*)(ws + 4 * MMp);         // 28*MMp bf16
    unsigned short* P21h = P12h + (size_t)28 * MMp;                 // 28*MMp bf16
    unsigned short* chainT = P21h + (size_t)28 * MMp;               // 44*MMp bf16 region
    unsigned short* P12T  = chainT;                                 // 24+4 transposed mats
    unsigned short* P21T6 = P12T + (size_t)24 * MMp;
    unsigned short* l0    = P21T6 + (size_t)4 * MMp;
    unsigned short* l1    = l0 + (size_t)4 * MMp;
    unsigned short* R0    = l1 + (size_t)4 * MMp;
    unsigned short* R1    = R0 + (size_t)4 * MMp;
    unsigned short* qTb   = R1 + (size_t)4 * MMp;                   // 32*Qrows*Dc bf16
    float* cs12 = (float*)(qTb + (size_t)32 * Qrows * Dc);          // 28*Pp fp32
    float* cs21 = cs12 + (size_t)28 * Pp;                           // 28*Pp fp32

    // phase-1 overlays in chainT region:
    unsigned short* Abf   = chainT;
    unsigned int*   Abf32 = (unsigned int*)Abf;
    unsigned short* WTb   = Abf + (size_t)Bc * Tc * Nc * Cc;
    float*          fbuf  = (float*)(WTb + 2 * (size_t)Dc * Cc);

    // 1. pack inputs to bf16
    k_pack<<<Bc * Nc, 256, 0, stream>>>(feats, Abf32);
    k_packw<<<dim3(2, 8, 2), 256, 0, stream>>>(Wself, Wdust, WTb);
    hipMemsetAsync(cs12, 0, (size_t)2 * 28 * Pp * sizeof(float), stream);
    hipMemsetAsync(csR, 0, (size_t)6 * Bc * Pp * sizeof(float), stream);
    // 2. projection GEMM + bias
    k_gemm_proj<<<dim3(1, 196), 256, 0, stream>>>(Abf, WTb, bself, fbuf);
    // 3. dust projection (fp32) + norms
    k_dustproj<<<32, 128, 0, stream>>>(dust, Wdust, bdust, qTb, qout);
    k_norm<<<dim3(13, 32), 256, 0, stream>>>(fbuf, qTb, qout);
    // 4. fused affinity (XCD-pinned), then dust rows
    float wconst = (float)(1.0 / log(784.0));
    k_affinity<<<2744, 256, 0, stream>>>(qTb, P12h, P21h, cs12, cs21, wconst);
    k_dustrow<<<dim3(28, 2), 256, 0, stream>>>(cs12, cs21, P12h, P21h);
    // 5. merged bf16 transposes
    k_transpose_bf16<<<dim3(13, 13, 28), 256, 0, stream>>>(P12h, P21h, P12T);

    // 6. chain
    k_zero<<<1, 1, 0, stream>>>(loss);
    const float scale = 1.0f / (6.0f * Bc * Mc);

    // prologue: L1 = P12[0] @ P12[1]^T-form;  R1 = P21T6 @ P21[5]^T (colsum slot 0)
    {
        GJobs J = {};
        J.A[0] = P12h;  J.sA[0] = (long long)7 * MMp;
        J.BT[0] = P12T; J.sB[0] = (long long)6 * MMp;
        J.Cb[0] = l0;   J.sC[0] = (long long)MMp; J.cs[0] = nullptr;
        J.A[1] = P21T6;                   J.sA[1] = (long long)MMp;
        J.BT[1] = P21h + (size_t)5 * MMp; J.sB[1] = (long long)7 * MMp;
        J.Cb[1] = R0;   J.sC[1] = (long long)MMp; J.cs[1] = csR;   // slot 0
        k_gemm_loss<<<392, 256, 0, stream>>>(J);
    }

    unsigned short *lcur = l0, *lnxt = l1, *rcur = R0, *rnxt = R1;
    for (int i = 1; i <= 5; ++i) {
        GJobs J = {};
        J.A[0] = lcur; J.sA[0] = (long long)MMp;
        J.BT[0] = P12T + (size_t)i * MMp; J.sB[0] = (long long)6 * MMp;
        J.Cb[0] = lnxt; J.sC[0] = (long long)MMp; J.cs[0] = nullptr;
        J.A[1] = rcur; J.sA[1] = (long long)MMp;
        J.BT[1] = P21h + (size_t)(5 - i) * MMp; J.sB[1] = (long long)7 * MMp;
        J.Cb[1] = rnxt; J.sC[1] = (long long)MMp; J.cs[1] = csR + (size_t)i * Bc * Pp;
        J.Lr = lcur; J.Rr = rcur; J.csL = csR + (size_t)(i - 1) * Bc * Pp;
        J.loss = loss; J.scale = scale;
        k_gemm_loss<<<392 + 785, 256, 0, stream>>>(J);
        unsigned short* t;
        t = lcur; lcur = lnxt; lnxt = t;
        t = rcur; rcur = rnxt; rnxt = t;
    }
    // final loss (state 6)
    k_lossrow<<<Bc * Mc, 64, 0, stream>>>(lcur, rcur, csR + (size_t)5 * Bc * Pp, loss, scale);
}

// Round 10
// 497.460 us; speedup vs baseline: 7.9110x; 1.0203x over previous
//
#include <hip/hip_runtime.h>
#include <hip/hip_bf16.h>
#include <math.h>

// Problem constants
constexpr int Bc = 4;      // batch
constexpr int Nc = 784;    // tokens
constexpr int Cc = 512;    // enc channels
constexpr int Tc = 8;      // time
constexpr int Dc = 128;    // proj dim
constexpr int Mc = 785;    // N+1
constexpr int TM1 = 7;     // T-1
constexpr int Pp = 832;    // padded chain dim (13*64)
constexpr int Qrows = 896; // padded q rows
constexpr float TEMP = 0.07f;

typedef __attribute__((ext_vector_type(4))) float f32x4;
typedef __attribute__((ext_vector_type(8))) unsigned short u16x8;
typedef __attribute__((ext_vector_type(8))) __bf16 bf16x8;

__device__ __forceinline__ unsigned short f2bf(float v) {
    __hip_bfloat16 h = __float2bfloat16(v);
    return __builtin_bit_cast(unsigned short, h);
}
__device__ __forceinline__ float bf2f(unsigned short u) {
    return __builtin_bit_cast(float, (unsigned int)u << 16);
}

// ---------------- async 16B global->LDS ----------------
__device__ __forceinline__ void gload16(const void* g, void* l) {
    __builtin_amdgcn_global_load_lds(
        (const __attribute__((address_space(1))) unsigned int*)g,
        (__attribute__((address_space(3))) unsigned int*)l, 16, 0, 0);
}

// Shared MFMA K-loop: 128x128 C-tile, BK=64, 4 waves, global_load_lds staging
// with XOR-16B involution swizzle.
template<int LD>
__device__ __forceinline__ void mfma_tile_loop(const unsigned short* __restrict__ A,
                                               const unsigned short* __restrict__ BT,
                                               unsigned short* __restrict__ As,
                                               unsigned short* __restrict__ Bs,
                                               int i0, int j0, int tid,
                                               f32x4 (&acc)[4][4])
{
    const int lane = tid & 63, w = tid >> 6;
    const int wr = w >> 1, wc = w & 1;
    const int g = lane >> 4, lr = lane & 15;

    for (int k0 = 0; k0 < LD; k0 += 64) {
        __syncthreads();
        #pragma unroll
        for (int q = 0; q < 4; ++q) {
            int L16 = q * 256 + tid;
            int r = L16 >> 3;
            int csw = ((L16 & 7) << 4) ^ ((r & 7) << 4);
            const char* ga = (const char*)(A  + (size_t)(i0 + r) * LD + k0) + csw;
            const char* gb = (const char*)(BT + (size_t)(j0 + r) * LD + k0) + csw;
            gload16(ga, As + (size_t)L16 * 8);
            gload16(gb, Bs + (size_t)L16 * 8);
        }
        __syncthreads();
        #pragma unroll
        for (int ks = 0; ks < 2; ++ks) {
            bf16x8 af[4], bf[4];
            #pragma unroll
            for (int m = 0; m < 4; ++m) {
                int r = wr * 64 + m * 16 + lr;
                int cb = (ks * 64 + g * 16) ^ ((r & 7) << 4);
                af[m] = __builtin_bit_cast(bf16x8, *(const u16x8*)((const char*)As + r * 128 + cb));
            }
            #pragma unroll
            for (int n = 0; n < 4; ++n) {
                int r = wc * 64 + n * 16 + lr;
                int cb = (ks * 64 + g * 16) ^ ((r & 7) << 4);
                bf[n] = __builtin_bit_cast(bf16x8, *(const u16x8*)((const char*)Bs + r * 128 + cb));
            }
            #pragma unroll
            for (int m = 0; m < 4; ++m)
                #pragma unroll
                for (int n = 0; n < 4; ++n)
                    acc[m][n] = __builtin_amdgcn_mfma_f32_16x16x32_bf16(af[m], bf[n], acc[m][n], 0, 0, 0);
        }
    }
}

// ---------------- reduction helpers ----------------
__device__ __forceinline__ float blockReduceSum(float v, float* sbuf) {
    #pragma unroll
    for (int off = 32; off; off >>= 1) v += __shfl_down(v, off, 64);
    __syncthreads();
    if ((threadIdx.x & 63) == 0) sbuf[threadIdx.x >> 6] = v;
    __syncthreads();
    return sbuf[0] + sbuf[1] + sbuf[2] + sbuf[3];
}
__device__ __forceinline__ float blockReduceMax(float v, float* sbuf) {
    #pragma unroll
    for (int off = 32; off; off >>= 1) v = fmaxf(v, __shfl_down(v, off, 64));
    __syncthreads();
    if ((threadIdx.x & 63) == 0) sbuf[threadIdx.x >> 6] = v;
    __syncthreads();
    return fmaxf(fmaxf(sbuf[0], sbuf[1]), fmaxf(sbuf[2], sbuf[3]));
}

// ---------------- K1a: pack feats -> bf16 A[(b,t,n), c] ----------------
__global__ __launch_bounds__(256) void k_pack(const float* __restrict__ feats,
                                              unsigned int* __restrict__ Abf32)
{
    __shared__ float lds[Cc * 9];
    int bid = blockIdx.x;
    int b = bid / Nc, n = bid % Nc;
    const float* src = feats + (size_t)(b * Nc + n) * Cc * Tc;
    int tid = threadIdx.x;
    for (int i = tid; i < Cc * Tc; i += 256) lds[(i >> 3) * 9 + (i & 7)] = src[i];
    __syncthreads();
    #pragma unroll
    for (int t = 0; t < Tc; ++t) {
        size_t row = (size_t)(b * Tc + t) * Nc + n;
        float v0 = lds[(2 * tid) * 9 + t];
        float v1 = lds[(2 * tid + 1) * 9 + t];
        unsigned int pk = (unsigned int)f2bf(v0) | ((unsigned int)f2bf(v1) << 16);
        Abf32[row * (Cc / 2) + tid] = pk;
    }
}

// ---------------- K1b: pack W -> bf16 WT[which][d][c] ----------------
__global__ __launch_bounds__(256) void k_packw(const float* __restrict__ Wself,
                                               const float* __restrict__ Wdust,
                                               unsigned short* __restrict__ WTb)
{
    __shared__ float tile[64][65];
    int which = blockIdx.z;
    const float* W = which ? Wdust : Wself;
    unsigned short* O = WTb + (size_t)which * Dc * Cc;
    int d0 = blockIdx.x * 64, c0 = blockIdx.y * 64;
    int tx = threadIdx.x & 63, ty = threadIdx.x >> 6;
    #pragma unroll
    for (int y = 0; y < 64; y += 4) tile[y + ty][tx] = W[(size_t)(c0 + y + ty) * Dc + d0 + tx];
    __syncthreads();
    #pragma unroll
    for (int y = 0; y < 64; y += 4) O[(size_t)(d0 + y + ty) * Cc + c0 + tx] = f2bf(tile[tx][y + ty]);
}

// ---------------- K1c: projection GEMM fbuf = Abf @ WT^T + bias (MFMA) ----------------
__global__ __launch_bounds__(256, 3) void k_gemm_proj(const unsigned short* __restrict__ A,
                                                      const unsigned short* __restrict__ BT,
                                                      const float* __restrict__ bias,
                                                      float* __restrict__ Cf)
{
    __shared__ __align__(16) unsigned short As[128 * 64];
    __shared__ __align__(16) unsigned short Bs[128 * 64];
    const int i0 = blockIdx.y * 128;
    const int tid = threadIdx.x, lane = tid & 63, w = tid >> 6;
    const int wr = w >> 1, wc = w & 1;
    const int g = lane >> 4, lr = lane & 15;

    f32x4 acc[4][4] = {};
    mfma_tile_loop<Cc>(A, BT, As, Bs, i0, 0, tid, acc);

    #pragma unroll
    for (int n = 0; n < 4; ++n) {
        int col = wc * 64 + n * 16 + lr;
        float bv = bias[col];
        #pragma unroll
        for (int m = 0; m < 4; ++m)
            #pragma unroll
            for (int j = 0; j < 4; ++j) {
                int row = i0 + wr * 64 + m * 16 + g * 4 + j;
                Cf[(size_t)row * Dc + col] = acc[m][n][j] + bv;
            }
    }
}

// ---------------- K1d: dust projection + l2norm (fp32 exact) ----------------
__global__ __launch_bounds__(128) void k_dustproj(const float* __restrict__ dust,
                                                  const float* __restrict__ Wdust,
                                                  const float* __restrict__ bdust,
                                                  unsigned short* __restrict__ qTb,
                                                  float* __restrict__ qout)
{
    __shared__ float sdust[Cc];
    __shared__ float red[2];
    int bt = blockIdx.x;
    int b = bt >> 3, t = bt & 7;
    int tid = threadIdx.x;
    for (int i = tid; i < Cc; i += 128) sdust[i] = dust[((size_t)b * Cc + i) * Tc + t];
    __syncthreads();
    float acc = 0.f;
    for (int c = 0; c < Cc; ++c) acc += sdust[c] * Wdust[(size_t)c * Dc + tid];
    acc += bdust[tid];
    float s = acc * acc;
    #pragma unroll
    for (int off = 32; off; off >>= 1) s += __shfl_down(s, off, 64);
    if ((tid & 63) == 0) red[tid >> 6] = s;
    __syncthreads();
    float inv = 1.f / fmaxf(sqrtf(red[0] + red[1]), 1e-12f);
    float qv = acc * inv;
    qTb[((size_t)bt * Qrows + Nc) * Dc + tid] = f2bf(qv);
    qout[(((size_t)b * Dc + tid) * Tc + t) * Mc + Nc] = qv;
}

// ---------------- K1e: l2norm rows of fbuf -> bf16 qTb + fp32 qout ----------------
__global__ __launch_bounds__(256) void k_norm(const float* __restrict__ fbuf,
                                              unsigned short* __restrict__ qTb,
                                              float* __restrict__ qout)
{
    __shared__ float lds[64][129];
    __shared__ float nrm[64][4];
    __shared__ float inv[64];
    int bt = blockIdx.y;
    int b = bt >> 3, t = bt & 7;
    int n0 = blockIdx.x * 64;
    int tid = threadIdx.x;
    #pragma unroll
    for (int q = 0; q < 8; ++q) {
        int i = q * 256 + tid;
        int nl = i >> 5, d4 = i & 31;
        f32x4 v = {};
        if (n0 + nl < Nc) v = *(const f32x4*)(fbuf + ((size_t)bt * Nc + n0 + nl) * Dc + d4 * 4);
        *(f32x4*)(&lds[nl][d4 * 4]) = v;
    }
    __syncthreads();
    {
        int r = tid & 63, p = tid >> 6;
        float s = 0.f;
        #pragma unroll
        for (int j = 0; j < 32; ++j) { float v = lds[r][p * 32 + j]; s += v * v; }
        nrm[r][p] = s;
    }
    __syncthreads();
    if (tid < 64) inv[tid] = 1.f / fmaxf(sqrtf(nrm[tid][0] + nrm[tid][1] + nrm[tid][2] + nrm[tid][3]), 1e-12f);
    __syncthreads();
    unsigned int* qT32 = (unsigned int*)(qTb + (size_t)bt * Qrows * Dc);
    #pragma unroll
    for (int q = 0; q < 16; ++q) {
        int i = q * 256 + tid;
        int nl = i >> 6, dp = i & 63;
        if (n0 + nl < Nc) {
            float iv = inv[nl];
            unsigned int pk = (unsigned int)f2bf(lds[nl][2 * dp] * iv)
                            | ((unsigned int)f2bf(lds[nl][2 * dp + 1] * iv) << 16);
            qT32[((size_t)(n0 + nl) * Dc >> 1) + dp] = pk;
        }
    }
    int nl = tid & 63;
    if (n0 + nl < Nc) {
        float iv = inv[nl];
        #pragma unroll
        for (int dd = 0; dd < Dc; dd += 4) {
            int d = dd + (tid >> 6);
            qout[(((size_t)b * Dc + d) * Tc + t) * Mc + n0 + nl] = lds[nl][d] * iv;
        }
    }
}

// ---------------- K2: fused affinity, XCD-pinned, no atomics, LDS-staged output ----------------
// 1-D grid 2744 = 8 XCDs * 343. xcd = f&7, slot = f>>3; grp = xcd + 8*(slot/49).
// colsum trick: colsum_j(core[side,bt]) = rowsum_j(core[other side, b,6-t]) — each
// block plain-stores its 16 rowsums into the OTHER side's cs buffer (no atomics).
__global__ __launch_bounds__(256) void k_affinity(const unsigned short* __restrict__ qTb,
                                                  unsigned short* __restrict__ P12h,
                                                  unsigned short* __restrict__ P21h,
                                                  float* __restrict__ cs12,
                                                  float* __restrict__ cs21,
                                                  float wconst)
{
    constexpr float INVT = 1.0f / TEMP;
    const size_t MMp = (size_t)Pp * Pp;
    __shared__ unsigned short otile[16][840];   // padded: 840*2B=1680B rows -> 4-bank row offset
    __shared__ float sred[16][4][2];
    __shared__ float rowsum[16], invZ[16], entP[16];

    int f = blockIdx.x;
    int xcd = f & 7, slot = f >> 3;
    int grp = xcd + 8 * (slot / 49);
    int strip = slot % 49;
    int side = grp >= 28 ? 1 : 0;
    int bt = grp - side * 28;
    int b = bt / TM1, t = bt % TM1;
    const unsigned short *Aq, *Bq;
    unsigned short* OUT;
    if (side == 0) {
        Aq = qTb + (size_t)(b * Tc + t)     * Qrows * Dc;
        Bq = qTb + (size_t)(b * Tc + t + 1) * Qrows * Dc;
        OUT = P12h + (size_t)bt * MMp;
    } else {
        Aq = qTb + (size_t)(b * Tc + 7 - t) * Qrows * Dc;
        Bq = qTb + (size_t)(b * Tc + 6 - t) * Qrows * Dc;
        OUT = P21h + (size_t)bt * MMp;
    }
    // flip-side colsum target
    float* csFlip = (side == 0 ? cs21 : cs12) + (size_t)(b * TM1 + (6 - t)) * Pp;

    const int r0 = strip * 16;
    const int tid = threadIdx.x, lane = tid & 63, w = tid >> 6;
    const int g = lane >> 4, lr = lane & 15;

    // MFMA: wave w owns col-tiles w*13 .. w*13+12; B loads batched in chunks of 7
    f32x4 acc[13] = {};
    #pragma unroll
    for (int ks = 0; ks < 4; ++ks) {
        bf16x8 af = __builtin_bit_cast(bf16x8,
            *(const u16x8*)(Aq + (size_t)(r0 + lr) * Dc + ks * 32 + g * 8));
        bf16x8 bfr[7];
        #pragma unroll
        for (int tt = 0; tt < 7; ++tt)
            if (w * 13 + tt < 49)
                bfr[tt] = __builtin_bit_cast(bf16x8,
                    *(const u16x8*)(Bq + (size_t)((w * 13 + tt) * 16 + lr) * Dc + ks * 32 + g * 8));
        #pragma unroll
        for (int tt = 0; tt < 7; ++tt)
            if (w * 13 + tt < 49)
                acc[tt] = __builtin_amdgcn_mfma_f32_16x16x32_bf16(af, bfr[tt], acc[tt], 0, 0, 0);
        #pragma unroll
        for (int tt = 7; tt < 13; ++tt)
            if (w * 13 + tt < 49)
                bfr[tt - 7] = __builtin_bit_cast(bf16x8,
                    *(const u16x8*)(Bq + (size_t)((w * 13 + tt) * 16 + lr) * Dc + ks * 32 + g * 8));
        #pragma unroll
        for (int tt = 7; tt < 13; ++tt)
            if (w * 13 + tt < 49)
                acc[tt] = __builtin_amdgcn_mfma_f32_16x16x32_bf16(af, bfr[tt - 7], acc[tt], 0, 0, 0);
    }
    // lane holds rows r0+g*4+j (j=0..3), cols (w*13+tt)*16+lr

    // sweep 1: rowsums only
    float rs[4] = {0.f, 0.f, 0.f, 0.f};
    #pragma unroll
    for (int tt = 0; tt < 13; ++tt) {
        if (w * 13 + tt < 49) {
            #pragma unroll
            for (int j = 0; j < 4; ++j) rs[j] += acc[tt][j];
        }
    }
    #pragma unroll
    for (int off = 1; off <= 8; off <<= 1) {
        #pragma unroll
        for (int j = 0; j < 4; ++j) rs[j] += __shfl_xor(rs[j], off, 64);
    }
    if (lr == 0) {
        #pragma unroll
        for (int j = 0; j < 4; ++j) sred[g * 4 + j][w][0] = rs[j];
    }
    __syncthreads();
    if (tid < 16) {
        float r = sred[tid][0][0] + sred[tid][1][0] + sred[tid][2][0] + sred[tid][3][0];
        rowsum[tid] = r;
        csFlip[r0 + tid] = r;      // plain store: this IS the flip-side colsum
    }
    __syncthreads();

    // sweep 2: exp-sum + entropy; cache exp into acc
    float invr[4];
    #pragma unroll
    for (int j = 0; j < 4; ++j) invr[j] = 1.0f / rowsum[g * 4 + j];
    float en[4] = {0.f, 0.f, 0.f, 0.f}, es[4] = {0.f, 0.f, 0.f, 0.f};
    #pragma unroll
    for (int tt = 0; tt < 13; ++tt) {
        if (w * 13 + tt < 49) {
            #pragma unroll
            for (int j = 0; j < 4; ++j) {
                float a = acc[tt][j];
                float e = __expf(a * INVT);
                es[j] += e;
                float p = a * invr[j];
                en[j] -= p * __logf(fmaxf(p, 1e-20f));
                acc[tt][j] = e;
            }
        }
    }
    #pragma unroll
    for (int off = 1; off <= 8; off <<= 1) {
        #pragma unroll
        for (int j = 0; j < 4; ++j) {
            es[j] += __shfl_xor(es[j], off, 64);
            en[j] += __shfl_xor(en[j], off, 64);
        }
    }
    if (lr == 0) {
        #pragma unroll
        for (int j = 0; j < 4; ++j) { sred[g * 4 + j][w][0] = es[j]; sred[g * 4 + j][w][1] = en[j]; }
    }
    __syncthreads();
    if (tid < 16) {
        float esum = sred[tid][0][0] + sred[tid][1][0] + sred[tid][2][0] + sred[tid][3][0];
        float ent  = sred[tid][0][1] + sred[tid][1][1] + sred[tid][2][1] + sred[tid][3][1];
        float ez  = __expf(ent * wconst * INVT);
        float Z   = esum + ez;
        float iz  = 1.0f / Z;
        invZ[tid] = iz;
        entP[tid] = ez * iz;
    }
    __syncthreads();

    // sweep 3: normalized probs -> LDS tile (bf16)
    float izl[4];
    #pragma unroll
    for (int j = 0; j < 4; ++j) izl[j] = invZ[g * 4 + j];
    #pragma unroll
    for (int tt = 0; tt < 13; ++tt) {
        int gt = w * 13 + tt;
        if (gt < 49) {
            int col = gt * 16 + lr;
            #pragma unroll
            for (int j = 0; j < 4; ++j)
                otile[g * 4 + j][col] = f2bf(acc[tt][j] * izl[j]);
        }
    }
    if (tid < 16) otile[tid][784] = f2bf(entP[tid]);
    for (int i = tid; i < 16 * 47; i += 256) otile[i / 47][785 + i % 47] = 0;
    __syncthreads();

    // coalesced wide store: 16 rows x 104 u16x8
    for (int v = tid; v < 16 * 104; v += 256) {
        int row = v / 104, cv = v % 104;
        *(u16x8*)(OUT + (size_t)(r0 + row) * Pp + cv * 8) = *(const u16x8*)(&otile[row][cv * 8]);
    }
}

// ---------------- K3: dust rows (row 784) + zero pad rows ----------------
__global__ __launch_bounds__(256) void k_dustrow(const float* __restrict__ cs12,
                                                 const float* __restrict__ cs21,
                                                 unsigned short* __restrict__ P12h,
                                                 unsigned short* __restrict__ P21h)
{
    constexpr float INVT = 1.0f / TEMP;
    const size_t MMp = (size_t)Pp * Pp;
    int bt = blockIdx.x, side = blockIdx.y;
    const float* cs = (side ? cs21 : cs12) + (size_t)bt * Pp;
    unsigned short* OUT = (side ? P21h : P12h) + (size_t)bt * MMp;
    __shared__ float sbuf[4];
    int tid = threadIdx.x;
    float v[4];
    #pragma unroll
    for (int k = 0; k < 4; ++k) {
        int j = tid + k * 256;
        float val = -INFINITY;
        if (j < Nc)       val = -cs[j] * INVT;
        else if (j == Nc) val = 0.f;
        v[k] = val;
    }
    float mx = fmaxf(fmaxf(v[0], v[1]), fmaxf(v[2], v[3]));
    mx = blockReduceMax(mx, sbuf);
    float e[4]; float s = 0.f;
    #pragma unroll
    for (int k = 0; k < 4; ++k) {
        int j = tid + k * 256;
        e[k] = (j < Mc) ? __expf(v[k] - mx) : 0.f;
        s += e[k];
    }
    s = blockReduceSum(s, sbuf);
    float invs = 1.f / s;
    #pragma unroll
    for (int k = 0; k < 4; ++k) {
        int j = tid + k * 256;
        if (j < Mc)      OUT[(size_t)Nc * Pp + j] = f2bf(e[k] * invs);
        else if (j < Pp) OUT[(size_t)Nc * Pp + j] = 0;
    }
    u16x8 z = {};
    u16x8* dst = (u16x8*)(OUT + (size_t)785 * Pp);
    for (int i = tid; i < (Pp - 785) * Pp / 8; i += 256) dst[i] = z;
}

// ---------------- K6: merged bf16 transposes (grid z = 0..27) ----------------
__global__ __launch_bounds__(256) void k_transpose_bf16(const unsigned short* __restrict__ P12h,
                                                        const unsigned short* __restrict__ P21h,
                                                        unsigned short* __restrict__ Db)
{
    const size_t MMp = (size_t)Pp * Pp;
    __shared__ unsigned short tile[64][65];
    int z = blockIdx.z;
    const unsigned short* S;
    if (z < 24) { int b = z / 6, tm = z % 6; S = P12h + ((size_t)b * 7 + tm + 1) * MMp; }
    else        { S = P21h + ((size_t)(z - 24) * 7 + 6) * MMp; }
    unsigned short* D = Db + (size_t)z * MMp;
    int x0 = blockIdx.x * 64, y0 = blockIdx.y * 64;
    int tx = threadIdx.x & 63, ty = threadIdx.x >> 6;
    #pragma unroll
    for (int y = 0; y < 64; y += 4) tile[y + ty][tx] = S[(size_t)(y0 + y + ty) * Pp + x0 + tx];
    __syncthreads();
    #pragma unroll
    for (int y = 0; y < 64; y += 4) D[(size_t)(x0 + y + ty) * Pp + y0 + tx] = tile[tx][y + ty];
}

// ---------------- K7: fused chain GEMM + loss ----------------
struct GJobs {
    const unsigned short* A[2];
    const unsigned short* BT[2];
    unsigned short* Cb[2];
    float* cs[2];
    long long sA[2], sB[2], sC[2];
    const unsigned short* Lr;
    const unsigned short* Rr;
    const float* csL;
    float* loss;
    float scale;
};

__global__ __launch_bounds__(256, 3) void k_gemm_loss(GJobs J)
{
    const size_t MMp = (size_t)Pp * Pp;
    if (blockIdx.x >= 392) {
        // ---- loss role ----
        int q = blockIdx.x - 392;
        int w = threadIdx.x >> 6, lane = threadIdx.x & 63;
        int r = q * 4 + w;
        int b = r / Mc, i = r % Mc;
        const u16x8* lrow = (const u16x8*)(J.Lr + (size_t)b * MMp + (size_t)i * Pp);
        const u16x8* rrow = (const u16x8*)(J.Rr + (size_t)b * MMp + (size_t)i * Pp);
        const f32x4* cs4  = (const f32x4*)(J.csL + (size_t)b * Pp);
        float sR = 0.f, sD = 0.f;
        for (int c = lane; c < Pp / 8; c += 64) {
            u16x8 lv = lrow[c];
            u16x8 rv = rrow[c];
            f32x4 c0 = cs4[2 * c], c1 = cs4[2 * c + 1];
            #pragma unroll
            for (int k = 0; k < 4; ++k) {
                float fl = bf2f(lv[k]);
                sR += fl * c0[k];
                sD += fl * bf2f(rv[k]);
            }
            #pragma unroll
            for (int k = 0; k < 4; ++k) {
                float fl = bf2f(lv[4 + k]);
                sR += fl * c1[k];
                sD += fl * bf2f(rv[4 + k]);
            }
        }
        #pragma unroll
        for (int off = 1; off <= 32; off <<= 1) {
            sR += __shfl_xor(sR, off, 64);
            sD += __shfl_xor(sD, off, 64);
        }
        if (lane == 0)
            atomicAdd(J.loss, (logf(sR + Mc * 1e-20f) - logf(sD + 1e-20f)) * J.scale);
        return;
    }

    // ---- GEMM role ----
    __shared__ __align__(16) unsigned short As[128 * 64];
    __shared__ __align__(16) unsigned short Bs[128 * 64];

    int f = blockIdx.x;
    int zz = f & 7, slot = f >> 3;
    int job = zz >> 2, b = zz & 3;
    const unsigned short* A  = J.A[job]  + (size_t)b * J.sA[job];
    const unsigned short* BT = J.BT[job] + (size_t)b * J.sB[job];

    const int i0 = (slot / 7) * 128, j0 = (slot % 7) * 128;
    const int tid = threadIdx.x, lane = tid & 63, w = tid >> 6;
    const int wr = w >> 1, wc = w & 1;
    const int g = lane >> 4, lr = lane & 15;

    f32x4 acc[4][4] = {};
    mfma_tile_loop<Pp>(A, BT, As, Bs, i0, j0, tid, acc);

    unsigned short* Co = J.Cb[job] + (size_t)b * J.sC[job];
    float* csp = J.cs[job];
    float csacc[4] = {0.f, 0.f, 0.f, 0.f};
    #pragma unroll
    for (int m = 0; m < 4; ++m)
        #pragma unroll
        for (int n = 0; n < 4; ++n)
            #pragma unroll
            for (int j = 0; j < 4; ++j) {
                int row = i0 + wr * 64 + m * 16 + g * 4 + j;
                int col = j0 + wc * 64 + n * 16 + lr;
                if (row < Pp && col < Pp) {
                    unsigned short h = f2bf(acc[m][n][j]);
                    Co[(size_t)row * Pp + col] = h;
                    csacc[n] += bf2f(h);
                }
            }
    if (csp) {
        csp += (size_t)b * Pp;
        #pragma unroll
        for (int n = 0; n < 4; ++n) {
            float p = csacc[n];
            p += __shfl_xor(p, 16, 64);
            p += __shfl_xor(p, 32, 64);
            int col = j0 + wc * 64 + n * 16 + lr;
            if (g == 0 && col < Pp) atomicAdd(&csp[col], p);
        }
    }
}

// ---------------- K8: standalone loss rows (final step) ----------------
__global__ __launch_bounds__(64) void k_lossrow(const unsigned short* __restrict__ L,
                                                const unsigned short* __restrict__ R,
                                                const float* __restrict__ csR,
                                                float* __restrict__ loss, float scale)
{
    const size_t MMp = (size_t)Pp * Pp;
    int r = blockIdx.x;
    int b = r / Mc, i = r % Mc;
    const u16x8* lrow = (const u16x8*)(L + (size_t)b * MMp + (size_t)i * Pp);
    const u16x8* rrow = (const u16x8*)(R + (size_t)b * MMp + (size_t)i * Pp);
    const f32x4* cs4  = (const f32x4*)(csR + (size_t)b * Pp);
    int lane = threadIdx.x;
    float sR = 0.f, sD = 0.f;
    for (int c = lane; c < Pp / 8; c += 64) {
        u16x8 lv = lrow[c];
        u16x8 rv = rrow[c];
        f32x4 c0 = cs4[2 * c], c1 = cs4[2 * c + 1];
        #pragma unroll
        for (int k = 0; k < 4; ++k) {
            float fl = bf2f(lv[k]);
            sR += fl * c0[k];
            sD += fl * bf2f(rv[k]);
        }
        #pragma unroll
        for (int k = 0; k < 4; ++k) {
            float fl = bf2f(lv[4 + k]);
            sR += fl * c1[k];
            sD += fl * bf2f(rv[4 + k]);
        }
    }
    #pragma unroll
    for (int off = 1; off <= 32; off <<= 1) {
        sR += __shfl_xor(sR, off, 64);
        sD += __shfl_xor(sD, off, 64);
    }
    if (lane == 0)
        atomicAdd(loss, (logf(sR + Mc * 1e-20f) - logf(sD + 1e-20f)) * scale);
}

// ---------------- host orchestration ----------------
extern "C" void kernel_launch(void* const* d_in, const int* in_sizes, int n_in,
                              void* d_out, int out_size, void* d_ws, size_t ws_size,
                              hipStream_t stream)
{
    const float* feats = (const float*)d_in[0];
    const float* dust  = (const float*)d_in[1];
    const float* Wself = (const float*)d_in[2];
    const float* bself = (const float*)d_in[3];
    const float* Wdust = (const float*)d_in[4];
    const float* bdust = (const float*)d_in[5];

    float* out  = (float*)d_out;
    float* qout = out;
    float* loss = out + (size_t)Bc * Dc * Tc * Mc;

    const size_t MMp = (size_t)Pp * Pp;       // 692,224

    // ---- workspace ----
    float* ws = (float*)d_ws;
    float* csR = ws;                                                // 6 slots * Bc * Pp fp32
    unsigned short* P12h = (unsigned short*)(ws + 4 * MMp);         // 28*MMp bf16
    unsigned short* P21h = P12h + (size_t)28 * MMp;                 // 28*MMp bf16
    unsigned short* chainT = P21h + (size_t)28 * MMp;               // 44*MMp bf16 region
    unsigned short* P12T  = chainT;
    unsigned short* P21T6 = P12T + (size_t)24 * MMp;
    unsigned short* l0    = P21T6 + (size_t)4 * MMp;
    unsigned short* l1    = l0 + (size_t)4 * MMp;
    unsigned short* R0    = l1 + (size_t)4 * MMp;
    unsigned short* R1    = R0 + (size_t)4 * MMp;
    unsigned short* qTb   = R1 + (size_t)4 * MMp;                   // 32*Qrows*Dc bf16
    float* cs12 = (float*)(qTb + (size_t)32 * Qrows * Dc);          // 28*Pp fp32
    float* cs21 = cs12 + (size_t)28 * Pp;                           // 28*Pp fp32

    // phase-1 overlays in chainT region:
    unsigned short* Abf   = chainT;
    unsigned int*   Abf32 = (unsigned int*)Abf;
    unsigned short* WTb   = Abf + (size_t)Bc * Tc * Nc * Cc;
    float*          fbuf  = (float*)(WTb + 2 * (size_t)Dc * Cc);

    // 1. pack inputs to bf16
    k_pack<<<Bc * Nc, 256, 0, stream>>>(feats, Abf32);
    k_packw<<<dim3(2, 8, 2), 256, 0, stream>>>(Wself, Wdust, WTb);
    hipMemsetAsync(csR, 0, (size_t)6 * Bc * Pp * sizeof(float), stream);
    hipMemsetAsync(loss, 0, sizeof(float), stream);
    // 2. projection GEMM + bias
    k_gemm_proj<<<dim3(1, 196), 256, 0, stream>>>(Abf, WTb, bself, fbuf);
    // 3. dust projection (fp32) + norms
    k_dustproj<<<32, 128, 0, stream>>>(dust, Wdust, bdust, qTb, qout);
    k_norm<<<dim3(13, 32), 256, 0, stream>>>(fbuf, qTb, qout);
    // 4. fused affinity (XCD-pinned, atomic-free), then dust rows
    float wconst = (float)(1.0 / log(784.0));
    k_affinity<<<2744, 256, 0, stream>>>(qTb, P12h, P21h, cs12, cs21, wconst);
    k_dustrow<<<dim3(28, 2), 256, 0, stream>>>(cs12, cs21, P12h, P21h);
    // 5. merged bf16 transposes
    k_transpose_bf16<<<dim3(13, 13, 28), 256, 0, stream>>>(P12h, P21h, P12T);

    // 6. chain
    const float scale = 1.0f / (6.0f * Bc * Mc);

    // prologue: L1 = P12[0] @ P12[1]^T-form;  R1 = P21T6 @ P21[5]^T (colsum slot 0)
    {
        GJobs J = {};
        J.A[0] = P12h;  J.sA[0] = (long long)7 * MMp;
        J.BT[0] = P12T; J.sB[0] = (long long)6 * MMp;
        J.Cb[0] = l0;   J.sC[0] = (long long)MMp; J.cs[0] = nullptr;
        J.A[1] = P21T6;                   J.sA[1] = (long long)MMp;
        J.BT[1] = P21h + (size_t)5 * MMp; J.sB[1] = (long long)7 * MMp;
        J.Cb[1] = R0;   J.sC[1] = (long long)MMp; J.cs[1] = csR;   // slot 0
        k_gemm_loss<<<392, 256, 0, stream>>>(J);
    }

    unsigned short *lcur = l0, *lnxt = l1, *rcur = R0, *rnxt = R1;
    for (int i = 1; i <= 5; ++i) {
        GJobs J = {};
        J.A[0] = lcur; J.sA[0] = (long long)MMp;
        J.BT[0] = P12T + (size_t)i * MMp; J.sB[0] = (long long)6 * MMp;
        J.Cb[0] = lnxt; J.sC[0] = (long long)MMp; J.cs[0] = nullptr;
        J.A[1] = rcur; J.sA[1] = (long long)MMp;
        J.BT[1] = P21h + (size_t)(5 - i) * MMp; J.sB[1] = (long long)7 * MMp;
        J.Cb[1] = rnxt; J.sC[1] = (long long)MMp; J.cs[1] = csR + (size_t)i * Bc * Pp;
        J.Lr = lcur; J.Rr = rcur; J.csL = csR + (size_t)(i - 1) * Bc * Pp;
        J.loss = loss; J.scale = scale;
        k_gemm_loss<<<392 + 785, 256, 0, stream>>>(J);
        unsigned short* t;
        t = lcur; lcur = lnxt; lnxt = t;
        t = rcur; rcur = rnxt; rnxt = t;
    }
    // final loss (state 6)
    k_lossrow<<<Bc * Mc, 64, 0, stream>>>(lcur, rcur, csR + (size_t)5 * Bc * Pp, loss, scale);
}

// Round 11
// 481.641 us; speedup vs baseline: 8.1708x; 1.0328x over previous
//
#include <hip/hip_runtime.h>
#include <hip/hip_bf16.h>
#include <math.h>

// Problem constants
constexpr int Bc = 4;      // batch
constexpr int Nc = 784;    // tokens
constexpr int Cc = 512;    // enc channels
constexpr int Tc = 8;      // time
constexpr int Dc = 128;    // proj dim
constexpr int Mc = 785;    // N+1
constexpr int TM1 = 7;     // T-1
constexpr int Pp = 832;    // padded chain dim (13*64)
constexpr int Qrows = 896; // padded q rows
constexpr float TEMP = 0.07f;

typedef __attribute__((ext_vector_type(4))) float f32x4;
typedef __attribute__((ext_vector_type(8))) unsigned short u16x8;
typedef __attribute__((ext_vector_type(8))) __bf16 bf16x8;

__device__ __forceinline__ unsigned short f2bf(float v) {
    __hip_bfloat16 h = __float2bfloat16(v);
    return __builtin_bit_cast(unsigned short, h);
}
__device__ __forceinline__ float bf2f(unsigned short u) {
    return __builtin_bit_cast(float, (unsigned int)u << 16);
}

// ---------------- async 16B global->LDS ----------------
__device__ __forceinline__ void gload16(const void* g, void* l) {
    __builtin_amdgcn_global_load_lds(
        (const __attribute__((address_space(1))) unsigned int*)g,
        (__attribute__((address_space(3))) unsigned int*)l, 16, 0, 0);
}

// Shared MFMA K-loop: 128x128 C-tile, BK=64, 4 waves, global_load_lds staging
// with XOR-16B involution swizzle. (used by k_gemm_proj)
template<int LD>
__device__ __forceinline__ void mfma_tile_loop(const unsigned short* __restrict__ A,
                                               const unsigned short* __restrict__ BT,
                                               unsigned short* __restrict__ As,
                                               unsigned short* __restrict__ Bs,
                                               int i0, int j0, int tid,
                                               f32x4 (&acc)[4][4])
{
    const int lane = tid & 63, w = tid >> 6;
    const int wr = w >> 1, wc = w & 1;
    const int g = lane >> 4, lr = lane & 15;

    for (int k0 = 0; k0 < LD; k0 += 64) {
        __syncthreads();
        #pragma unroll
        for (int q = 0; q < 4; ++q) {
            int L16 = q * 256 + tid;
            int r = L16 >> 3;
            int csw = ((L16 & 7) << 4) ^ ((r & 7) << 4);
            const char* ga = (const char*)(A  + (size_t)(i0 + r) * LD + k0) + csw;
            const char* gb = (const char*)(BT + (size_t)(j0 + r) * LD + k0) + csw;
            gload16(ga, As + (size_t)L16 * 8);
            gload16(gb, Bs + (size_t)L16 * 8);
        }
        __syncthreads();
        #pragma unroll
        for (int ks = 0; ks < 2; ++ks) {
            bf16x8 af[4], bf[4];
            #pragma unroll
            for (int m = 0; m < 4; ++m) {
                int r = wr * 64 + m * 16 + lr;
                int cb = (ks * 64 + g * 16) ^ ((r & 7) << 4);
                af[m] = __builtin_bit_cast(bf16x8, *(const u16x8*)((const char*)As + r * 128 + cb));
            }
            #pragma unroll
            for (int n = 0; n < 4; ++n) {
                int r = wc * 64 + n * 16 + lr;
                int cb = (ks * 64 + g * 16) ^ ((r & 7) << 4);
                bf[n] = __builtin_bit_cast(bf16x8, *(const u16x8*)((const char*)Bs + r * 128 + cb));
            }
            #pragma unroll
            for (int m = 0; m < 4; ++m)
                #pragma unroll
                for (int n = 0; n < 4; ++n)
                    acc[m][n] = __builtin_amdgcn_mfma_f32_16x16x32_bf16(af[m], bf[n], acc[m][n], 0, 0, 0);
        }
    }
}

// ---------------- reduction helpers ----------------
__device__ __forceinline__ float blockReduceSum(float v, float* sbuf) {
    #pragma unroll
    for (int off = 32; off; off >>= 1) v += __shfl_down(v, off, 64);
    __syncthreads();
    if ((threadIdx.x & 63) == 0) sbuf[threadIdx.x >> 6] = v;
    __syncthreads();
    return sbuf[0] + sbuf[1] + sbuf[2] + sbuf[3];
}
__device__ __forceinline__ float blockReduceMax(float v, float* sbuf) {
    #pragma unroll
    for (int off = 32; off; off >>= 1) v = fmaxf(v, __shfl_down(v, off, 64));
    __syncthreads();
    if ((threadIdx.x & 63) == 0) sbuf[threadIdx.x >> 6] = v;
    __syncthreads();
    return fmaxf(fmaxf(sbuf[0], sbuf[1]), fmaxf(sbuf[2], sbuf[3]));
}

// ---------------- K1a: pack feats -> bf16 A[(b,t,n), c] ----------------
__global__ __launch_bounds__(256) void k_pack(const float* __restrict__ feats,
                                              unsigned int* __restrict__ Abf32)
{
    __shared__ float lds[Cc * 9];
    int bid = blockIdx.x;
    int b = bid / Nc, n = bid % Nc;
    const float* src = feats + (size_t)(b * Nc + n) * Cc * Tc;
    int tid = threadIdx.x;
    for (int i = tid; i < Cc * Tc; i += 256) lds[(i >> 3) * 9 + (i & 7)] = src[i];
    __syncthreads();
    #pragma unroll
    for (int t = 0; t < Tc; ++t) {
        size_t row = (size_t)(b * Tc + t) * Nc + n;
        float v0 = lds[(2 * tid) * 9 + t];
        float v1 = lds[(2 * tid + 1) * 9 + t];
        unsigned int pk = (unsigned int)f2bf(v0) | ((unsigned int)f2bf(v1) << 16);
        Abf32[row * (Cc / 2) + tid] = pk;
    }
}

// ---------------- K1b: pack W -> bf16 WT[which][d][c] ----------------
__global__ __launch_bounds__(256) void k_packw(const float* __restrict__ Wself,
                                               const float* __restrict__ Wdust,
                                               unsigned short* __restrict__ WTb)
{
    __shared__ float tile[64][65];
    int which = blockIdx.z;
    const float* W = which ? Wdust : Wself;
    unsigned short* O = WTb + (size_t)which * Dc * Cc;
    int d0 = blockIdx.x * 64, c0 = blockIdx.y * 64;
    int tx = threadIdx.x & 63, ty = threadIdx.x >> 6;
    #pragma unroll
    for (int y = 0; y < 64; y += 4) tile[y + ty][tx] = W[(size_t)(c0 + y + ty) * Dc + d0 + tx];
    __syncthreads();
    #pragma unroll
    for (int y = 0; y < 64; y += 4) O[(size_t)(d0 + y + ty) * Cc + c0 + tx] = f2bf(tile[tx][y + ty]);
}

// ---------------- K1c: projection GEMM fbuf = Abf @ WT^T + bias (MFMA) ----------------
__global__ __launch_bounds__(256, 3) void k_gemm_proj(const unsigned short* __restrict__ A,
                                                      const unsigned short* __restrict__ BT,
                                                      const float* __restrict__ bias,
                                                      float* __restrict__ Cf)
{
    __shared__ __align__(16) unsigned short As[128 * 64];
    __shared__ __align__(16) unsigned short Bs[128 * 64];
    const int i0 = blockIdx.y * 128;
    const int tid = threadIdx.x, lane = tid & 63, w = tid >> 6;
    const int wr = w >> 1, wc = w & 1;
    const int g = lane >> 4, lr = lane & 15;

    f32x4 acc[4][4] = {};
    mfma_tile_loop<Cc>(A, BT, As, Bs, i0, 0, tid, acc);

    #pragma unroll
    for (int n = 0; n < 4; ++n) {
        int col = wc * 64 + n * 16 + lr;
        float bv = bias[col];
        #pragma unroll
        for (int m = 0; m < 4; ++m)
            #pragma unroll
            for (int j = 0; j < 4; ++j) {
                int row = i0 + wr * 64 + m * 16 + g * 4 + j;
                Cf[(size_t)row * Dc + col] = acc[m][n][j] + bv;
            }
    }
}

// ---------------- K1d: dust projection + l2norm (fp32 exact) ----------------
__global__ __launch_bounds__(128) void k_dustproj(const float* __restrict__ dust,
                                                  const float* __restrict__ Wdust,
                                                  const float* __restrict__ bdust,
                                                  unsigned short* __restrict__ qTb,
                                                  float* __restrict__ qout)
{
    __shared__ float sdust[Cc];
    __shared__ float red[2];
    int bt = blockIdx.x;
    int b = bt >> 3, t = bt & 7;
    int tid = threadIdx.x;
    for (int i = tid; i < Cc; i += 128) sdust[i] = dust[((size_t)b * Cc + i) * Tc + t];
    __syncthreads();
    float acc = 0.f;
    for (int c = 0; c < Cc; ++c) acc += sdust[c] * Wdust[(size_t)c * Dc + tid];
    acc += bdust[tid];
    float s = acc * acc;
    #pragma unroll
    for (int off = 32; off; off >>= 1) s += __shfl_down(s, off, 64);
    if ((tid & 63) == 0) red[tid >> 6] = s;
    __syncthreads();
    float inv = 1.f / fmaxf(sqrtf(red[0] + red[1]), 1e-12f);
    float qv = acc * inv;
    qTb[((size_t)bt * Qrows + Nc) * Dc + tid] = f2bf(qv);
    qout[(((size_t)b * Dc + tid) * Tc + t) * Mc + Nc] = qv;
}

// ---------------- K1e: l2norm rows of fbuf -> bf16 qTb + fp32 qout ----------------
__global__ __launch_bounds__(256) void k_norm(const float* __restrict__ fbuf,
                                              unsigned short* __restrict__ qTb,
                                              float* __restrict__ qout)
{
    __shared__ float lds[64][129];
    __shared__ float nrm[64][4];
    __shared__ float inv[64];
    int bt = blockIdx.y;
    int b = bt >> 3, t = bt & 7;
    int n0 = blockIdx.x * 64;
    int tid = threadIdx.x;
    #pragma unroll
    for (int q = 0; q < 8; ++q) {
        int i = q * 256 + tid;
        int nl = i >> 5, d4 = i & 31;
        f32x4 v = {};
        if (n0 + nl < Nc) v = *(const f32x4*)(fbuf + ((size_t)bt * Nc + n0 + nl) * Dc + d4 * 4);
        *(f32x4*)(&lds[nl][d4 * 4]) = v;
    }
    __syncthreads();
    {
        int r = tid & 63, p = tid >> 6;
        float s = 0.f;
        #pragma unroll
        for (int j = 0; j < 32; ++j) { float v = lds[r][p * 32 + j]; s += v * v; }
        nrm[r][p] = s;
    }
    __syncthreads();
    if (tid < 64) inv[tid] = 1.f / fmaxf(sqrtf(nrm[tid][0] + nrm[tid][1] + nrm[tid][2] + nrm[tid][3]), 1e-12f);
    __syncthreads();
    unsigned int* qT32 = (unsigned int*)(qTb + (size_t)bt * Qrows * Dc);
    #pragma unroll
    for (int q = 0; q < 16; ++q) {
        int i = q * 256 + tid;
        int nl = i >> 6, dp = i & 63;
        if (n0 + nl < Nc) {
            float iv = inv[nl];
            unsigned int pk = (unsigned int)f2bf(lds[nl][2 * dp] * iv)
                            | ((unsigned int)f2bf(lds[nl][2 * dp + 1] * iv) << 16);
            qT32[((size_t)(n0 + nl) * Dc >> 1) + dp] = pk;
        }
    }
    int nl = tid & 63;
    if (n0 + nl < Nc) {
        float iv = inv[nl];
        #pragma unroll
        for (int dd = 0; dd < Dc; dd += 4) {
            int d = dd + (tid >> 6);
            qout[(((size_t)b * Dc + d) * Tc + t) * Mc + n0 + nl] = lds[nl][d] * iv;
        }
    }
}

// ---------------- K2: fused affinity, XCD-pinned, no atomics, LDS-staged output ----------------
__global__ __launch_bounds__(256) void k_affinity(const unsigned short* __restrict__ qTb,
                                                  unsigned short* __restrict__ P12h,
                                                  unsigned short* __restrict__ P21h,
                                                  float* __restrict__ cs12,
                                                  float* __restrict__ cs21,
                                                  float wconst)
{
    constexpr float INVT = 1.0f / TEMP;
    const size_t MMp = (size_t)Pp * Pp;
    __shared__ unsigned short otile[16][840];
    __shared__ float sred[16][4][2];
    __shared__ float rowsum[16], invZ[16], entP[16];

    int f = blockIdx.x;
    int xcd = f & 7, slot = f >> 3;
    int grp = xcd + 8 * (slot / 49);
    int strip = slot % 49;
    int side = grp >= 28 ? 1 : 0;
    int bt = grp - side * 28;
    int b = bt / TM1, t = bt % TM1;
    const unsigned short *Aq, *Bq;
    unsigned short* OUT;
    if (side == 0) {
        Aq = qTb + (size_t)(b * Tc + t)     * Qrows * Dc;
        Bq = qTb + (size_t)(b * Tc + t + 1) * Qrows * Dc;
        OUT = P12h + (size_t)bt * MMp;
    } else {
        Aq = qTb + (size_t)(b * Tc + 7 - t) * Qrows * Dc;
        Bq = qTb + (size_t)(b * Tc + 6 - t) * Qrows * Dc;
        OUT = P21h + (size_t)bt * MMp;
    }
    float* csFlip = (side == 0 ? cs21 : cs12) + (size_t)(b * TM1 + (6 - t)) * Pp;

    const int r0 = strip * 16;
    const int tid = threadIdx.x, lane = tid & 63, w = tid >> 6;
    const int g = lane >> 4, lr = lane & 15;

    f32x4 acc[13] = {};
    #pragma unroll
    for (int ks = 0; ks < 4; ++ks) {
        bf16x8 af = __builtin_bit_cast(bf16x8,
            *(const u16x8*)(Aq + (size_t)(r0 + lr) * Dc + ks * 32 + g * 8));
        bf16x8 bfr[7];
        #pragma unroll
        for (int tt = 0; tt < 7; ++tt)
            if (w * 13 + tt < 49)
                bfr[tt] = __builtin_bit_cast(bf16x8,
                    *(const u16x8*)(Bq + (size_t)((w * 13 + tt) * 16 + lr) * Dc + ks * 32 + g * 8));
        #pragma unroll
        for (int tt = 0; tt < 7; ++tt)
            if (w * 13 + tt < 49)
                acc[tt] = __builtin_amdgcn_mfma_f32_16x16x32_bf16(af, bfr[tt], acc[tt], 0, 0, 0);
        #pragma unroll
        for (int tt = 7; tt < 13; ++tt)
            if (w * 13 + tt < 49)
                bfr[tt - 7] = __builtin_bit_cast(bf16x8,
                    *(const u16x8*)(Bq + (size_t)((w * 13 + tt) * 16 + lr) * Dc + ks * 32 + g * 8));
        #pragma unroll
        for (int tt = 7; tt < 13; ++tt)
            if (w * 13 + tt < 49)
                acc[tt] = __builtin_amdgcn_mfma_f32_16x16x32_bf16(af, bfr[tt - 7], acc[tt], 0, 0, 0);
    }

    // sweep 1: rowsums only
    float rs[4] = {0.f, 0.f, 0.f, 0.f};
    #pragma unroll
    for (int tt = 0; tt < 13; ++tt) {
        if (w * 13 + tt < 49) {
            #pragma unroll
            for (int j = 0; j < 4; ++j) rs[j] += acc[tt][j];
        }
    }
    #pragma unroll
    for (int off = 1; off <= 8; off <<= 1) {
        #pragma unroll
        for (int j = 0; j < 4; ++j) rs[j] += __shfl_xor(rs[j], off, 64);
    }
    if (lr == 0) {
        #pragma unroll
        for (int j = 0; j < 4; ++j) sred[g * 4 + j][w][0] = rs[j];
    }
    __syncthreads();
    if (tid < 16) {
        float r = sred[tid][0][0] + sred[tid][1][0] + sred[tid][2][0] + sred[tid][3][0];
        rowsum[tid] = r;
        csFlip[r0 + tid] = r;
    }
    __syncthreads();

    // sweep 2: exp-sum + entropy; cache exp into acc
    float invr[4];
    #pragma unroll
    for (int j = 0; j < 4; ++j) invr[j] = 1.0f / rowsum[g * 4 + j];
    float en[4] = {0.f, 0.f, 0.f, 0.f}, es[4] = {0.f, 0.f, 0.f, 0.f};
    #pragma unroll
    for (int tt = 0; tt < 13; ++tt) {
        if (w * 13 + tt < 49) {
            #pragma unroll
            for (int j = 0; j < 4; ++j) {
                float a = acc[tt][j];
                float e = __expf(a * INVT);
                es[j] += e;
                float p = a * invr[j];
                en[j] -= p * __logf(fmaxf(p, 1e-20f));
                acc[tt][j] = e;
            }
        }
    }
    #pragma unroll
    for (int off = 1; off <= 8; off <<= 1) {
        #pragma unroll
        for (int j = 0; j < 4; ++j) {
            es[j] += __shfl_xor(es[j], off, 64);
            en[j] += __shfl_xor(en[j], off, 64);
        }
    }
    if (lr == 0) {
        #pragma unroll
        for (int j = 0; j < 4; ++j) { sred[g * 4 + j][w][0] = es[j]; sred[g * 4 + j][w][1] = en[j]; }
    }
    __syncthreads();
    if (tid < 16) {
        float esum = sred[tid][0][0] + sred[tid][1][0] + sred[tid][2][0] + sred[tid][3][0];
        float ent  = sred[tid][0][1] + sred[tid][1][1] + sred[tid][2][1] + sred[tid][3][1];
        float ez  = __expf(ent * wconst * INVT);
        float Z   = esum + ez;
        float iz  = 1.0f / Z;
        invZ[tid] = iz;
        entP[tid] = ez * iz;
    }
    __syncthreads();

    // sweep 3: normalized probs -> LDS tile (bf16)
    float izl[4];
    #pragma unroll
    for (int j = 0; j < 4; ++j) izl[j] = invZ[g * 4 + j];
    #pragma unroll
    for (int tt = 0; tt < 13; ++tt) {
        int gt = w * 13 + tt;
        if (gt < 49) {
            int col = gt * 16 + lr;
            #pragma unroll
            for (int j = 0; j < 4; ++j)
                otile[g * 4 + j][col] = f2bf(acc[tt][j] * izl[j]);
        }
    }
    if (tid < 16) otile[tid][784] = f2bf(entP[tid]);
    for (int i = tid; i < 16 * 47; i += 256) otile[i / 47][785 + i % 47] = 0;
    __syncthreads();

    for (int v = tid; v < 16 * 104; v += 256) {
        int row = v / 104, cv = v % 104;
        *(u16x8*)(OUT + (size_t)(r0 + row) * Pp + cv * 8) = *(const u16x8*)(&otile[row][cv * 8]);
    }
}

// ---------------- K3: dust rows (row 784) + zero pad rows ----------------
__global__ __launch_bounds__(256) void k_dustrow(const float* __restrict__ cs12,
                                                 const float* __restrict__ cs21,
                                                 unsigned short* __restrict__ P12h,
                                                 unsigned short* __restrict__ P21h)
{
    constexpr float INVT = 1.0f / TEMP;
    const size_t MMp = (size_t)Pp * Pp;
    int bt = blockIdx.x, side = blockIdx.y;
    const float* cs = (side ? cs21 : cs12) + (size_t)bt * Pp;
    unsigned short* OUT = (side ? P21h : P12h) + (size_t)bt * MMp;
    __shared__ float sbuf[4];
    int tid = threadIdx.x;
    float v[4];
    #pragma unroll
    for (int k = 0; k < 4; ++k) {
        int j = tid + k * 256;
        float val = -INFINITY;
        if (j < Nc)       val = -cs[j] * INVT;
        else if (j == Nc) val = 0.f;
        v[k] = val;
    }
    float mx = fmaxf(fmaxf(v[0], v[1]), fmaxf(v[2], v[3]));
    mx = blockReduceMax(mx, sbuf);
    float e[4]; float s = 0.f;
    #pragma unroll
    for (int k = 0; k < 4; ++k) {
        int j = tid + k * 256;
        e[k] = (j < Mc) ? __expf(v[k] - mx) : 0.f;
        s += e[k];
    }
    s = blockReduceSum(s, sbuf);
    float invs = 1.f / s;
    #pragma unroll
    for (int k = 0; k < 4; ++k) {
        int j = tid + k * 256;
        if (j < Mc)      OUT[(size_t)Nc * Pp + j] = f2bf(e[k] * invs);
        else if (j < Pp) OUT[(size_t)Nc * Pp + j] = 0;
    }
    u16x8 z = {};
    u16x8* dst = (u16x8*)(OUT + (size_t)785 * Pp);
    for (int i = tid; i < (Pp - 785) * Pp / 8; i += 256) dst[i] = z;
}

// ---------------- K6: merged bf16 transposes (grid z = 0..27) ----------------
__global__ __launch_bounds__(256) void k_transpose_bf16(const unsigned short* __restrict__ P12h,
                                                        const unsigned short* __restrict__ P21h,
                                                        unsigned short* __restrict__ Db)
{
    const size_t MMp = (size_t)Pp * Pp;
    __shared__ unsigned short tile[64][65];
    int z = blockIdx.z;
    const unsigned short* S;
    if (z < 24) { int b = z / 6, tm = z % 6; S = P12h + ((size_t)b * 7 + tm + 1) * MMp; }
    else        { S = P21h + ((size_t)(z - 24) * 7 + 6) * MMp; }
    unsigned short* D = Db + (size_t)z * MMp;
    int x0 = blockIdx.x * 64, y0 = blockIdx.y * 64;
    int tx = threadIdx.x & 63, ty = threadIdx.x >> 6;
    #pragma unroll
    for (int y = 0; y < 64; y += 4) tile[y + ty][tx] = S[(size_t)(y0 + y + ty) * Pp + x0 + tx];
    __syncthreads();
    #pragma unroll
    for (int y = 0; y < 64; y += 4) D[(size_t)(x0 + y + ty) * Pp + y0 + tx] = tile[tx][y + ty];
}

// ---------------- K7: fused chain GEMM (64x128 tiles) + loss ----------------
// Blocks [0,728): GEMM. zz = f&7 -> (job,batch) pinned per XCD; slot = f>>3 (0..90):
//   i0 = (slot/7)*64 (rows, exact 13x64=832); j0 = (slot%7)*128 (cols, guarded).
// Blocks [728, 728+785): loss role (wave per row).
struct GJobs {
    const unsigned short* A[2];
    const unsigned short* BT[2];
    unsigned short* Cb[2];
    float* cs[2];
    long long sA[2], sB[2], sC[2];
    const unsigned short* Lr;
    const unsigned short* Rr;
    const float* csL;
    float* loss;
    float scale;
};

__global__ __launch_bounds__(256, 4) void k_gemm_loss(GJobs J)
{
    const size_t MMp = (size_t)Pp * Pp;
    if (blockIdx.x >= 728) {
        // ---- loss role ----
        int q = blockIdx.x - 728;
        int w = threadIdx.x >> 6, lane = threadIdx.x & 63;
        int r = q * 4 + w;
        int b = r / Mc, i = r % Mc;
        const u16x8* lrow = (const u16x8*)(J.Lr + (size_t)b * MMp + (size_t)i * Pp);
        const u16x8* rrow = (const u16x8*)(J.Rr + (size_t)b * MMp + (size_t)i * Pp);
        const f32x4* cs4  = (const f32x4*)(J.csL + (size_t)b * Pp);
        float sR = 0.f, sD = 0.f;
        for (int c = lane; c < Pp / 8; c += 64) {
            u16x8 lv = lrow[c];
            u16x8 rv = rrow[c];
            f32x4 c0 = cs4[2 * c], c1 = cs4[2 * c + 1];
            #pragma unroll
            for (int k = 0; k < 4; ++k) {
                float fl = bf2f(lv[k]);
                sR += fl * c0[k];
                sD += fl * bf2f(rv[k]);
            }
            #pragma unroll
            for (int k = 0; k < 4; ++k) {
                float fl = bf2f(lv[4 + k]);
                sR += fl * c1[k];
                sD += fl * bf2f(rv[4 + k]);
            }
        }
        #pragma unroll
        for (int off = 1; off <= 32; off <<= 1) {
            sR += __shfl_xor(sR, off, 64);
            sD += __shfl_xor(sD, off, 64);
        }
        if (lane == 0)
            atomicAdd(J.loss, (logf(sR + Mc * 1e-20f) - logf(sD + 1e-20f)) * J.scale);
        return;
    }

    // ---- GEMM role: 64x128 tile, BK=64 ----
    __shared__ __align__(16) unsigned short As[64 * 64];     // 8 KB
    __shared__ __align__(16) unsigned short Bs[128 * 64];    // 16 KB

    int f = blockIdx.x;
    int zz = f & 7, slot = f >> 3;
    int job = zz >> 2, b = zz & 3;
    const unsigned short* A  = J.A[job]  + (size_t)b * J.sA[job];
    const unsigned short* BT = J.BT[job] + (size_t)b * J.sB[job];

    const int i0 = (slot / 7) * 64, j0 = (slot % 7) * 128;
    const int tid = threadIdx.x, lane = tid & 63, wv = tid >> 6;
    const int g = lane >> 4, lr = lane & 15;

    f32x4 acc[4][2] = {};

    for (int k0 = 0; k0 < Pp; k0 += 64) {
        __syncthreads();
        #pragma unroll
        for (int q = 0; q < 2; ++q) {          // A: 512 slots
            int s = q * 256 + tid;
            int r = s >> 3;
            int csw = ((s & 7) << 4) ^ ((r & 7) << 4);
            gload16((const char*)(A + (size_t)(i0 + r) * Pp + k0) + csw, As + (size_t)s * 8);
        }
        #pragma unroll
        for (int q = 0; q < 4; ++q) {          // B: 1024 slots
            int s = q * 256 + tid;
            int r = s >> 3;
            int csw = ((s & 7) << 4) ^ ((r & 7) << 4);
            gload16((const char*)(BT + (size_t)(j0 + r) * Pp + k0) + csw, Bs + (size_t)s * 8);
        }
        __syncthreads();
        #pragma unroll
        for (int ks = 0; ks < 2; ++ks) {
            bf16x8 af[4], bf[2];
            #pragma unroll
            for (int m = 0; m < 4; ++m) {
                int r = m * 16 + lr;
                int cb = (ks * 64 + g * 16) ^ ((r & 7) << 4);
                af[m] = __builtin_bit_cast(bf16x8, *(const u16x8*)((const char*)As + r * 128 + cb));
            }
            #pragma unroll
            for (int n = 0; n < 2; ++n) {
                int r = wv * 32 + n * 16 + lr;
                int cb = (ks * 64 + g * 16) ^ ((r & 7) << 4);
                bf[n] = __builtin_bit_cast(bf16x8, *(const u16x8*)((const char*)Bs + r * 128 + cb));
            }
            #pragma unroll
            for (int m = 0; m < 4; ++m)
                #pragma unroll
                for (int n = 0; n < 2; ++n)
                    acc[m][n] = __builtin_amdgcn_mfma_f32_16x16x32_bf16(af[m], bf[n], acc[m][n], 0, 0, 0);
        }
    }

    unsigned short* Co = J.Cb[job] + (size_t)b * J.sC[job];
    float* csp = J.cs[job];
    float csacc[2] = {0.f, 0.f};
    #pragma unroll
    for (int m = 0; m < 4; ++m)
        #pragma unroll
        for (int n = 0; n < 2; ++n)
            #pragma unroll
            for (int j = 0; j < 4; ++j) {
                int row = i0 + m * 16 + g * 4 + j;           // always < 832
                int col = j0 + wv * 32 + n * 16 + lr;
                if (col < Pp) {
                    unsigned short h = f2bf(acc[m][n][j]);
                    Co[(size_t)row * Pp + col] = h;
                    csacc[n] += bf2f(h);
                }
            }
    if (csp) {
        csp += (size_t)b * Pp;
        #pragma unroll
        for (int n = 0; n < 2; ++n) {
            float p = csacc[n];
            p += __shfl_xor(p, 16, 64);
            p += __shfl_xor(p, 32, 64);
            int col = j0 + wv * 32 + n * 16 + lr;
            if (g == 0 && col < Pp) atomicAdd(&csp[col], p);
        }
    }
}

// ---------------- K8: standalone loss rows (final step) ----------------
__global__ __launch_bounds__(64) void k_lossrow(const unsigned short* __restrict__ L,
                                                const unsigned short* __restrict__ R,
                                                const float* __restrict__ csR,
                                                float* __restrict__ loss, float scale)
{
    const size_t MMp = (size_t)Pp * Pp;
    int r = blockIdx.x;
    int b = r / Mc, i = r % Mc;
    const u16x8* lrow = (const u16x8*)(L + (size_t)b * MMp + (size_t)i * Pp);
    const u16x8* rrow = (const u16x8*)(R + (size_t)b * MMp + (size_t)i * Pp);
    const f32x4* cs4  = (const f32x4*)(csR + (size_t)b * Pp);
    int lane = threadIdx.x;
    float sR = 0.f, sD = 0.f;
    for (int c = lane; c < Pp / 8; c += 64) {
        u16x8 lv = lrow[c];
        u16x8 rv = rrow[c];
        f32x4 c0 = cs4[2 * c], c1 = cs4[2 * c + 1];
        #pragma unroll
        for (int k = 0; k < 4; ++k) {
            float fl = bf2f(lv[k]);
            sR += fl * c0[k];
            sD += fl * bf2f(rv[k]);
        }
        #pragma unroll
        for (int k = 0; k < 4; ++k) {
            float fl = bf2f(lv[4 + k]);
            sR += fl * c1[k];
            sD += fl * bf2f(rv[4 + k]);
        }
    }
    #pragma unroll
    for (int off = 1; off <= 32; off <<= 1) {
        sR += __shfl_xor(sR, off, 64);
        sD += __shfl_xor(sD, off, 64);
    }
    if (lane == 0)
        atomicAdd(loss, (logf(sR + Mc * 1e-20f) - logf(sD + 1e-20f)) * scale);
}

// ---------------- host orchestration ----------------
extern "C" void kernel_launch(void* const* d_in, const int* in_sizes, int n_in,
                              void* d_out, int out_size, void* d_ws, size_t ws_size,
                              hipStream_t stream)
{
    const float* feats = (const float*)d_in[0];
    const float* dust  = (const float*)d_in[1];
    const float* Wself = (const float*)d_in[2];
    const float* bself = (const float*)d_in[3];
    const float* Wdust = (const float*)d_in[4];
    const float* bdust = (const float*)d_in[5];

    float* out  = (float*)d_out;
    float* qout = out;
    float* loss = out + (size_t)Bc * Dc * Tc * Mc;

    const size_t MMp = (size_t)Pp * Pp;       // 692,224

    // ---- workspace ----
    float* ws = (float*)d_ws;
    float* csR = ws;                                                // 6 slots * Bc * Pp fp32
    unsigned short* P12h = (unsigned short*)(ws + 4 * MMp);         // 28*MMp bf16
    unsigned short* P21h = P12h + (size_t)28 * MMp;                 // 28*MMp bf16
    unsigned short* chainT = P21h + (size_t)28 * MMp;               // 44*MMp bf16 region
    unsigned short* P12T  = chainT;
    unsigned short* P21T6 = P12T + (size_t)24 * MMp;
    unsigned short* l0    = P21T6 + (size_t)4 * MMp;
    unsigned short* l1    = l0 + (size_t)4 * MMp;
    unsigned short* R0    = l1 + (size_t)4 * MMp;
    unsigned short* R1    = R0 + (size_t)4 * MMp;
    unsigned short* qTb   = R1 + (size_t)4 * MMp;                   // 32*Qrows*Dc bf16
    float* cs12 = (float*)(qTb + (size_t)32 * Qrows * Dc);          // 28*Pp fp32
    float* cs21 = cs12 + (size_t)28 * Pp;                           // 28*Pp fp32

    // phase-1 overlays in chainT region:
    unsigned short* Abf   = chainT;
    unsigned int*   Abf32 = (unsigned int*)Abf;
    unsigned short* WTb   = Abf + (size_t)Bc * Tc * Nc * Cc;
    float*          fbuf  = (float*)(WTb + 2 * (size_t)Dc * Cc);

    // 1. pack inputs to bf16
    k_pack<<<Bc * Nc, 256, 0, stream>>>(feats, Abf32);
    k_packw<<<dim3(2, 8, 2), 256, 0, stream>>>(Wself, Wdust, WTb);
    hipMemsetAsync(csR, 0, (size_t)6 * Bc * Pp * sizeof(float), stream);
    hipMemsetAsync(loss, 0, sizeof(float), stream);
    // 2. projection GEMM + bias
    k_gemm_proj<<<dim3(1, 196), 256, 0, stream>>>(Abf, WTb, bself, fbuf);
    // 3. dust projection (fp32) + norms
    k_dustproj<<<32, 128, 0, stream>>>(dust, Wdust, bdust, qTb, qout);
    k_norm<<<dim3(13, 32), 256, 0, stream>>>(fbuf, qTb, qout);
    // 4. fused affinity (XCD-pinned, atomic-free), then dust rows
    float wconst = (float)(1.0 / log(784.0));
    k_affinity<<<2744, 256, 0, stream>>>(qTb, P12h, P21h, cs12, cs21, wconst);
    k_dustrow<<<dim3(28, 2), 256, 0, stream>>>(cs12, cs21, P12h, P21h);
    // 5. merged bf16 transposes
    k_transpose_bf16<<<dim3(13, 13, 28), 256, 0, stream>>>(P12h, P21h, P12T);

    // 6. chain
    const float scale = 1.0f / (6.0f * Bc * Mc);

    // prologue: L1 = P12[0] @ P12[1]^T-form;  R1 = P21T6 @ P21[5]^T (colsum slot 0)
    {
        GJobs J = {};
        J.A[0] = P12h;  J.sA[0] = (long long)7 * MMp;
        J.BT[0] = P12T; J.sB[0] = (long long)6 * MMp;
        J.Cb[0] = l0;   J.sC[0] = (long long)MMp; J.cs[0] = nullptr;
        J.A[1] = P21T6;                   J.sA[1] = (long long)MMp;
        J.BT[1] = P21h + (size_t)5 * MMp; J.sB[1] = (long long)7 * MMp;
        J.Cb[1] = R0;   J.sC[1] = (long long)MMp; J.cs[1] = csR;   // slot 0
        k_gemm_loss<<<728, 256, 0, stream>>>(J);
    }

    unsigned short *lcur = l0, *lnxt = l1, *rcur = R0, *rnxt = R1;
    for (int i = 1; i <= 5; ++i) {
        GJobs J = {};
        J.A[0] = lcur; J.sA[0] = (long long)MMp;
        J.BT[0] = P12T + (size_t)i * MMp; J.sB[0] = (long long)6 * MMp;
        J.Cb[0] = lnxt; J.sC[0] = (long long)MMp; J.cs[0] = nullptr;
        J.A[1] = rcur; J.sA[1] = (long long)MMp;
        J.BT[1] = P21h + (size_t)(5 - i) * MMp; J.sB[1] = (long long)7 * MMp;
        J.Cb[1] = rnxt; J.sC[1] = (long long)MMp; J.cs[1] = csR + (size_t)i * Bc * Pp;
        J.Lr = lcur; J.Rr = rcur; J.csL = csR + (size_t)(i - 1) * Bc * Pp;
        J.loss = loss; J.scale = scale;
        k_gemm_loss<<<728 + 785, 256, 0, stream>>>(J);
        unsigned short* t;
        t = lcur; lcur = lnxt; lnxt = t;
        t = rcur; rcur = rnxt; rnxt = t;
    }
    // final loss (state 6)
    k_lossrow<<<Bc * Mc, 64, 0, stream>>>(lcur, rcur, csR + (size_t)5 * Bc * Pp, loss, scale);
}

// Round 12
// 470.628 us; speedup vs baseline: 8.3620x; 1.0234x over previous
//
#include <hip/hip_runtime.h>
#include <hip/hip_bf16.h>
#include <math.h>

// Problem constants
constexpr int Bc = 4;      // batch
constexpr int Nc = 784;    // tokens
constexpr int Cc = 512;    // enc channels
constexpr int Tc = 8;      // time
constexpr int Dc = 128;    // proj dim
constexpr int Mc = 785;    // N+1
constexpr int TM1 = 7;     // T-1
constexpr int Pp = 832;    // padded chain dim (13*64)
constexpr int Qrows = 896; // padded q rows
constexpr float TEMP = 0.07f;

typedef __attribute__((ext_vector_type(4))) float f32x4;
typedef __attribute__((ext_vector_type(8))) unsigned short u16x8;
typedef __attribute__((ext_vector_type(8))) __bf16 bf16x8;

__device__ __forceinline__ unsigned short f2bf(float v) {
    __hip_bfloat16 h = __float2bfloat16(v);
    return __builtin_bit_cast(unsigned short, h);
}
__device__ __forceinline__ float bf2f(unsigned short u) {
    return __builtin_bit_cast(float, (unsigned int)u << 16);
}

// ---------------- async 16B global->LDS ----------------
__device__ __forceinline__ void gload16(const void* g, void* l) {
    __builtin_amdgcn_global_load_lds(
        (const __attribute__((address_space(1))) unsigned int*)g,
        (__attribute__((address_space(3))) unsigned int*)l, 16, 0, 0);
}

// Shared MFMA K-loop: 128x128 C-tile, BK=64, 4 waves, global_load_lds staging
// with XOR-16B involution swizzle. (used by k_gemm_proj)
template<int LD>
__device__ __forceinline__ void mfma_tile_loop(const unsigned short* __restrict__ A,
                                               const unsigned short* __restrict__ BT,
                                               unsigned short* __restrict__ As,
                                               unsigned short* __restrict__ Bs,
                                               int i0, int j0, int tid,
                                               f32x4 (&acc)[4][4])
{
    const int lane = tid & 63, w = tid >> 6;
    const int wr = w >> 1, wc = w & 1;
    const int g = lane >> 4, lr = lane & 15;

    for (int k0 = 0; k0 < LD; k0 += 64) {
        __syncthreads();
        #pragma unroll
        for (int q = 0; q < 4; ++q) {
            int L16 = q * 256 + tid;
            int r = L16 >> 3;
            int csw = ((L16 & 7) << 4) ^ ((r & 7) << 4);
            const char* ga = (const char*)(A  + (size_t)(i0 + r) * LD + k0) + csw;
            const char* gb = (const char*)(BT + (size_t)(j0 + r) * LD + k0) + csw;
            gload16(ga, As + (size_t)L16 * 8);
            gload16(gb, Bs + (size_t)L16 * 8);
        }
        __syncthreads();
        #pragma unroll
        for (int ks = 0; ks < 2; ++ks) {
            bf16x8 af[4], bf[4];
            #pragma unroll
            for (int m = 0; m < 4; ++m) {
                int r = wr * 64 + m * 16 + lr;
                int cb = (ks * 64 + g * 16) ^ ((r & 7) << 4);
                af[m] = __builtin_bit_cast(bf16x8, *(const u16x8*)((const char*)As + r * 128 + cb));
            }
            #pragma unroll
            for (int n = 0; n < 4; ++n) {
                int r = wc * 64 + n * 16 + lr;
                int cb = (ks * 64 + g * 16) ^ ((r & 7) << 4);
                bf[n] = __builtin_bit_cast(bf16x8, *(const u16x8*)((const char*)Bs + r * 128 + cb));
            }
            #pragma unroll
            for (int m = 0; m < 4; ++m)
                #pragma unroll
                for (int n = 0; n < 4; ++n)
                    acc[m][n] = __builtin_amdgcn_mfma_f32_16x16x32_bf16(af[m], bf[n], acc[m][n], 0, 0, 0);
        }
    }
}

// ---------------- reduction helpers ----------------
__device__ __forceinline__ float blockReduceSum(float v, float* sbuf) {
    #pragma unroll
    for (int off = 32; off; off >>= 1) v += __shfl_down(v, off, 64);
    __syncthreads();
    if ((threadIdx.x & 63) == 0) sbuf[threadIdx.x >> 6] = v;
    __syncthreads();
    return sbuf[0] + sbuf[1] + sbuf[2] + sbuf[3];
}
__device__ __forceinline__ float blockReduceMax(float v, float* sbuf) {
    #pragma unroll
    for (int off = 32; off; off >>= 1) v = fmaxf(v, __shfl_down(v, off, 64));
    __syncthreads();
    if ((threadIdx.x & 63) == 0) sbuf[threadIdx.x >> 6] = v;
    __syncthreads();
    return fmaxf(fmaxf(sbuf[0], sbuf[1]), fmaxf(sbuf[2], sbuf[3]));
}

// ---------------- K1a: pack feats -> bf16 A[(b,t,n), c] ----------------
__global__ __launch_bounds__(256) void k_pack(const float* __restrict__ feats,
                                              unsigned int* __restrict__ Abf32)
{
    __shared__ float lds[Cc * 9];
    int bid = blockIdx.x;
    int b = bid / Nc, n = bid % Nc;
    const float* src = feats + (size_t)(b * Nc + n) * Cc * Tc;
    int tid = threadIdx.x;
    for (int i = tid; i < Cc * Tc; i += 256) lds[(i >> 3) * 9 + (i & 7)] = src[i];
    __syncthreads();
    #pragma unroll
    for (int t = 0; t < Tc; ++t) {
        size_t row = (size_t)(b * Tc + t) * Nc + n;
        float v0 = lds[(2 * tid) * 9 + t];
        float v1 = lds[(2 * tid + 1) * 9 + t];
        unsigned int pk = (unsigned int)f2bf(v0) | ((unsigned int)f2bf(v1) << 16);
        Abf32[row * (Cc / 2) + tid] = pk;
    }
}

// ---------------- K1b: pack W -> bf16 WT[which][d][c] ----------------
__global__ __launch_bounds__(256) void k_packw(const float* __restrict__ Wself,
                                               const float* __restrict__ Wdust,
                                               unsigned short* __restrict__ WTb)
{
    __shared__ float tile[64][65];
    int which = blockIdx.z;
    const float* W = which ? Wdust : Wself;
    unsigned short* O = WTb + (size_t)which * Dc * Cc;
    int d0 = blockIdx.x * 64, c0 = blockIdx.y * 64;
    int tx = threadIdx.x & 63, ty = threadIdx.x >> 6;
    #pragma unroll
    for (int y = 0; y < 64; y += 4) tile[y + ty][tx] = W[(size_t)(c0 + y + ty) * Dc + d0 + tx];
    __syncthreads();
    #pragma unroll
    for (int y = 0; y < 64; y += 4) O[(size_t)(d0 + y + ty) * Cc + c0 + tx] = f2bf(tile[tx][y + ty]);
}

// ---------------- K1c: projection GEMM fbuf = Abf @ WT^T + bias (MFMA) ----------------
__global__ __launch_bounds__(256, 3) void k_gemm_proj(const unsigned short* __restrict__ A,
                                                      const unsigned short* __restrict__ BT,
                                                      const float* __restrict__ bias,
                                                      float* __restrict__ Cf)
{
    __shared__ __align__(16) unsigned short As[128 * 64];
    __shared__ __align__(16) unsigned short Bs[128 * 64];
    const int i0 = blockIdx.y * 128;
    const int tid = threadIdx.x, lane = tid & 63, w = tid >> 6;
    const int wr = w >> 1, wc = w & 1;
    const int g = lane >> 4, lr = lane & 15;

    f32x4 acc[4][4] = {};
    mfma_tile_loop<Cc>(A, BT, As, Bs, i0, 0, tid, acc);

    #pragma unroll
    for (int n = 0; n < 4; ++n) {
        int col = wc * 64 + n * 16 + lr;
        float bv = bias[col];
        #pragma unroll
        for (int m = 0; m < 4; ++m)
            #pragma unroll
            for (int j = 0; j < 4; ++j) {
                int row = i0 + wr * 64 + m * 16 + g * 4 + j;
                Cf[(size_t)row * Dc + col] = acc[m][n][j] + bv;
            }
    }
}

// ---------------- K1d: dust projection + l2norm (fp32 exact) ----------------
__global__ __launch_bounds__(128) void k_dustproj(const float* __restrict__ dust,
                                                  const float* __restrict__ Wdust,
                                                  const float* __restrict__ bdust,
                                                  unsigned short* __restrict__ qTb,
                                                  float* __restrict__ qout)
{
    __shared__ float sdust[Cc];
    __shared__ float red[2];
    int bt = blockIdx.x;
    int b = bt >> 3, t = bt & 7;
    int tid = threadIdx.x;
    for (int i = tid; i < Cc; i += 128) sdust[i] = dust[((size_t)b * Cc + i) * Tc + t];
    __syncthreads();
    float acc = 0.f;
    for (int c = 0; c < Cc; ++c) acc += sdust[c] * Wdust[(size_t)c * Dc + tid];
    acc += bdust[tid];
    float s = acc * acc;
    #pragma unroll
    for (int off = 32; off; off >>= 1) s += __shfl_down(s, off, 64);
    if ((tid & 63) == 0) red[tid >> 6] = s;
    __syncthreads();
    float inv = 1.f / fmaxf(sqrtf(red[0] + red[1]), 1e-12f);
    float qv = acc * inv;
    qTb[((size_t)bt * Qrows + Nc) * Dc + tid] = f2bf(qv);
    qout[(((size_t)b * Dc + tid) * Tc + t) * Mc + Nc] = qv;
}

// ---------------- K1e: l2norm rows of fbuf -> bf16 qTb + fp32 qout ----------------
__global__ __launch_bounds__(256) void k_norm(const float* __restrict__ fbuf,
                                              unsigned short* __restrict__ qTb,
                                              float* __restrict__ qout)
{
    __shared__ float lds[64][129];
    __shared__ float nrm[64][4];
    __shared__ float inv[64];
    int bt = blockIdx.y;
    int b = bt >> 3, t = bt & 7;
    int n0 = blockIdx.x * 64;
    int tid = threadIdx.x;
    #pragma unroll
    for (int q = 0; q < 8; ++q) {
        int i = q * 256 + tid;
        int nl = i >> 5, d4 = i & 31;
        f32x4 v = {};
        if (n0 + nl < Nc) v = *(const f32x4*)(fbuf + ((size_t)bt * Nc + n0 + nl) * Dc + d4 * 4);
        *(f32x4*)(&lds[nl][d4 * 4]) = v;
    }
    __syncthreads();
    {
        int r = tid & 63, p = tid >> 6;
        float s = 0.f;
        #pragma unroll
        for (int j = 0; j < 32; ++j) { float v = lds[r][p * 32 + j]; s += v * v; }
        nrm[r][p] = s;
    }
    __syncthreads();
    if (tid < 64) inv[tid] = 1.f / fmaxf(sqrtf(nrm[tid][0] + nrm[tid][1] + nrm[tid][2] + nrm[tid][3]), 1e-12f);
    __syncthreads();
    unsigned int* qT32 = (unsigned int*)(qTb + (size_t)bt * Qrows * Dc);
    #pragma unroll
    for (int q = 0; q < 16; ++q) {
        int i = q * 256 + tid;
        int nl = i >> 6, dp = i & 63;
        if (n0 + nl < Nc) {
            float iv = inv[nl];
            unsigned int pk = (unsigned int)f2bf(lds[nl][2 * dp] * iv)
                            | ((unsigned int)f2bf(lds[nl][2 * dp + 1] * iv) << 16);
            qT32[((size_t)(n0 + nl) * Dc >> 1) + dp] = pk;
        }
    }
    int nl = tid & 63;
    if (n0 + nl < Nc) {
        float iv = inv[nl];
        #pragma unroll
        for (int dd = 0; dd < Dc; dd += 4) {
            int d = dd + (tid >> 6);
            qout[(((size_t)b * Dc + d) * Tc + t) * Mc + n0 + nl] = lds[nl][d] * iv;
        }
    }
}

// ---------------- K2: fused affinity, XCD-pinned, no atomics, LDS-staged output ----------------
// __launch_bounds__(256,2): lift VGPR cap so acc[13]+bfr[7]+af fit with NO spills.
__global__ __launch_bounds__(256, 2) void k_affinity(const unsigned short* __restrict__ qTb,
                                                     unsigned short* __restrict__ P12h,
                                                     unsigned short* __restrict__ P21h,
                                                     float* __restrict__ cs12,
                                                     float* __restrict__ cs21,
                                                     float wconst)
{
    constexpr float INVT = 1.0f / TEMP;
    const size_t MMp = (size_t)Pp * Pp;
    __shared__ unsigned short otile[16][840];
    __shared__ float sred[16][4][2];
    __shared__ float rowsum[16], invZ[16], entP[16];

    int f = blockIdx.x;
    int xcd = f & 7, slot = f >> 3;
    int grp = xcd + 8 * (slot / 49);
    int strip = slot % 49;
    int side = grp >= 28 ? 1 : 0;
    int bt = grp - side * 28;
    int b = bt / TM1, t = bt % TM1;
    const unsigned short *Aq, *Bq;
    unsigned short* OUT;
    if (side == 0) {
        Aq = qTb + (size_t)(b * Tc + t)     * Qrows * Dc;
        Bq = qTb + (size_t)(b * Tc + t + 1) * Qrows * Dc;
        OUT = P12h + (size_t)bt * MMp;
    } else {
        Aq = qTb + (size_t)(b * Tc + 7 - t) * Qrows * Dc;
        Bq = qTb + (size_t)(b * Tc + 6 - t) * Qrows * Dc;
        OUT = P21h + (size_t)bt * MMp;
    }
    float* csFlip = (side == 0 ? cs21 : cs12) + (size_t)(b * TM1 + (6 - t)) * Pp;

    const int r0 = strip * 16;
    const int tid = threadIdx.x, lane = tid & 63, w = tid >> 6;
    const int g = lane >> 4, lr = lane & 15;

    f32x4 acc[13] = {};
    #pragma unroll
    for (int ks = 0; ks < 4; ++ks) {
        bf16x8 af = __builtin_bit_cast(bf16x8,
            *(const u16x8*)(Aq + (size_t)(r0 + lr) * Dc + ks * 32 + g * 8));
        bf16x8 bfr[7];
        #pragma unroll
        for (int tt = 0; tt < 7; ++tt)
            if (w * 13 + tt < 49)
                bfr[tt] = __builtin_bit_cast(bf16x8,
                    *(const u16x8*)(Bq + (size_t)((w * 13 + tt) * 16 + lr) * Dc + ks * 32 + g * 8));
        #pragma unroll
        for (int tt = 0; tt < 7; ++tt)
            if (w * 13 + tt < 49)
                acc[tt] = __builtin_amdgcn_mfma_f32_16x16x32_bf16(af, bfr[tt], acc[tt], 0, 0, 0);
        #pragma unroll
        for (int tt = 7; tt < 13; ++tt)
            if (w * 13 + tt < 49)
                bfr[tt - 7] = __builtin_bit_cast(bf16x8,
                    *(const u16x8*)(Bq + (size_t)((w * 13 + tt) * 16 + lr) * Dc + ks * 32 + g * 8));
        #pragma unroll
        for (int tt = 7; tt < 13; ++tt)
            if (w * 13 + tt < 49)
                acc[tt] = __builtin_amdgcn_mfma_f32_16x16x32_bf16(af, bfr[tt - 7], acc[tt], 0, 0, 0);
    }

    // sweep 1: rowsums only
    float rs[4] = {0.f, 0.f, 0.f, 0.f};
    #pragma unroll
    for (int tt = 0; tt < 13; ++tt) {
        if (w * 13 + tt < 49) {
            #pragma unroll
            for (int j = 0; j < 4; ++j) rs[j] += acc[tt][j];
        }
    }
    #pragma unroll
    for (int off = 1; off <= 8; off <<= 1) {
        #pragma unroll
        for (int j = 0; j < 4; ++j) rs[j] += __shfl_xor(rs[j], off, 64);
    }
    if (lr == 0) {
        #pragma unroll
        for (int j = 0; j < 4; ++j) sred[g * 4 + j][w][0] = rs[j];
    }
    __syncthreads();
    if (tid < 16) {
        float r = sred[tid][0][0] + sred[tid][1][0] + sred[tid][2][0] + sred[tid][3][0];
        rowsum[tid] = r;
        csFlip[r0 + tid] = r;
    }
    __syncthreads();

    // sweep 2: exp-sum + entropy; cache exp into acc
    float invr[4];
    #pragma unroll
    for (int j = 0; j < 4; ++j) invr[j] = 1.0f / rowsum[g * 4 + j];
    float en[4] = {0.f, 0.f, 0.f, 0.f}, es[4] = {0.f, 0.f, 0.f, 0.f};
    #pragma unroll
    for (int tt = 0; tt < 13; ++tt) {
        if (w * 13 + tt < 49) {
            #pragma unroll
            for (int j = 0; j < 4; ++j) {
                float a = acc[tt][j];
                float e = __expf(a * INVT);
                es[j] += e;
                float p = a * invr[j];
                en[j] -= p * __logf(fmaxf(p, 1e-20f));
                acc[tt][j] = e;
            }
        }
    }
    #pragma unroll
    for (int off = 1; off <= 8; off <<= 1) {
        #pragma unroll
        for (int j = 0; j < 4; ++j) {
            es[j] += __shfl_xor(es[j], off, 64);
            en[j] += __shfl_xor(en[j], off, 64);
        }
    }
    if (lr == 0) {
        #pragma unroll
        for (int j = 0; j < 4; ++j) { sred[g * 4 + j][w][0] = es[j]; sred[g * 4 + j][w][1] = en[j]; }
    }
    __syncthreads();
    if (tid < 16) {
        float esum = sred[tid][0][0] + sred[tid][1][0] + sred[tid][2][0] + sred[tid][3][0];
        float ent  = sred[tid][0][1] + sred[tid][1][1] + sred[tid][2][1] + sred[tid][3][1];
        float ez  = __expf(ent * wconst * INVT);
        float Z   = esum + ez;
        float iz  = 1.0f / Z;
        invZ[tid] = iz;
        entP[tid] = ez * iz;
    }
    __syncthreads();

    // sweep 3: normalized probs -> LDS tile (bf16)
    float izl[4];
    #pragma unroll
    for (int j = 0; j < 4; ++j) izl[j] = invZ[g * 4 + j];
    #pragma unroll
    for (int tt = 0; tt < 13; ++tt) {
        int gt = w * 13 + tt;
        if (gt < 49) {
            int col = gt * 16 + lr;
            #pragma unroll
            for (int j = 0; j < 4; ++j)
                otile[g * 4 + j][col] = f2bf(acc[tt][j] * izl[j]);
        }
    }
    if (tid < 16) otile[tid][784] = f2bf(entP[tid]);
    for (int i = tid; i < 16 * 47; i += 256) otile[i / 47][785 + i % 47] = 0;
    __syncthreads();

    for (int v = tid; v < 16 * 104; v += 256) {
        int row = v / 104, cv = v % 104;
        *(u16x8*)(OUT + (size_t)(r0 + row) * Pp + cv * 8) = *(const u16x8*)(&otile[row][cv * 8]);
    }
}

// ---------------- K3: dust rows (row 784) + zero pad rows ----------------
__global__ __launch_bounds__(256) void k_dustrow(const float* __restrict__ cs12,
                                                 const float* __restrict__ cs21,
                                                 unsigned short* __restrict__ P12h,
                                                 unsigned short* __restrict__ P21h)
{
    constexpr float INVT = 1.0f / TEMP;
    const size_t MMp = (size_t)Pp * Pp;
    int bt = blockIdx.x, side = blockIdx.y;
    const float* cs = (side ? cs21 : cs12) + (size_t)bt * Pp;
    unsigned short* OUT = (side ? P21h : P12h) + (size_t)bt * MMp;
    __shared__ float sbuf[4];
    int tid = threadIdx.x;
    float v[4];
    #pragma unroll
    for (int k = 0; k < 4; ++k) {
        int j = tid + k * 256;
        float val = -INFINITY;
        if (j < Nc)       val = -cs[j] * INVT;
        else if (j == Nc) val = 0.f;
        v[k] = val;
    }
    float mx = fmaxf(fmaxf(v[0], v[1]), fmaxf(v[2], v[3]));
    mx = blockReduceMax(mx, sbuf);
    float e[4]; float s = 0.f;
    #pragma unroll
    for (int k = 0; k < 4; ++k) {
        int j = tid + k * 256;
        e[k] = (j < Mc) ? __expf(v[k] - mx) : 0.f;
        s += e[k];
    }
    s = blockReduceSum(s, sbuf);
    float invs = 1.f / s;
    #pragma unroll
    for (int k = 0; k < 4; ++k) {
        int j = tid + k * 256;
        if (j < Mc)      OUT[(size_t)Nc * Pp + j] = f2bf(e[k] * invs);
        else if (j < Pp) OUT[(size_t)Nc * Pp + j] = 0;
    }
    u16x8 z = {};
    u16x8* dst = (u16x8*)(OUT + (size_t)785 * Pp);
    for (int i = tid; i < (Pp - 785) * Pp / 8; i += 256) dst[i] = z;
}

// ---------------- K6: merged bf16 transposes (grid z = 0..27) ----------------
__global__ __launch_bounds__(256) void k_transpose_bf16(const unsigned short* __restrict__ P12h,
                                                        const unsigned short* __restrict__ P21h,
                                                        unsigned short* __restrict__ Db)
{
    const size_t MMp = (size_t)Pp * Pp;
    __shared__ unsigned short tile[64][65];
    int z = blockIdx.z;
    const unsigned short* S;
    if (z < 24) { int b = z / 6, tm = z % 6; S = P12h + ((size_t)b * 7 + tm + 1) * MMp; }
    else        { S = P21h + ((size_t)(z - 24) * 7 + 6) * MMp; }
    unsigned short* D = Db + (size_t)z * MMp;
    int x0 = blockIdx.x * 64, y0 = blockIdx.y * 64;
    int tx = threadIdx.x & 63, ty = threadIdx.x >> 6;
    #pragma unroll
    for (int y = 0; y < 64; y += 4) tile[y + ty][tx] = S[(size_t)(y0 + y + ty) * Pp + x0 + tx];
    __syncthreads();
    #pragma unroll
    for (int y = 0; y < 64; y += 4) D[(size_t)(x0 + y + ty) * Pp + y0 + tx] = tile[tx][y + ty];
}

// ---------------- K7: fused chain GEMM (64x128 tiles, reg-prefetch pipeline) + loss ----------------
struct GJobs {
    const unsigned short* A[2];
    const unsigned short* BT[2];
    unsigned short* Cb[2];
    float* cs[2];
    long long sA[2], sB[2], sC[2];
    const unsigned short* Lr;
    const unsigned short* Rr;
    const float* csL;
    float* loss;
    float scale;
};

__global__ __launch_bounds__(256, 4) void k_gemm_loss(GJobs J)
{
    const size_t MMp = (size_t)Pp * Pp;
    if (blockIdx.x >= 728) {
        // ---- loss role ----
        int q = blockIdx.x - 728;
        int w = threadIdx.x >> 6, lane = threadIdx.x & 63;
        int r = q * 4 + w;
        int b = r / Mc, i = r % Mc;
        const u16x8* lrow = (const u16x8*)(J.Lr + (size_t)b * MMp + (size_t)i * Pp);
        const u16x8* rrow = (const u16x8*)(J.Rr + (size_t)b * MMp + (size_t)i * Pp);
        const f32x4* cs4  = (const f32x4*)(J.csL + (size_t)b * Pp);
        float sR = 0.f, sD = 0.f;
        for (int c = lane; c < Pp / 8; c += 64) {
            u16x8 lv = lrow[c];
            u16x8 rv = rrow[c];
            f32x4 c0 = cs4[2 * c], c1 = cs4[2 * c + 1];
            #pragma unroll
            for (int k = 0; k < 4; ++k) {
                float fl = bf2f(lv[k]);
                sR += fl * c0[k];
                sD += fl * bf2f(rv[k]);
            }
            #pragma unroll
            for (int k = 0; k < 4; ++k) {
                float fl = bf2f(lv[4 + k]);
                sR += fl * c1[k];
                sD += fl * bf2f(rv[4 + k]);
            }
        }
        #pragma unroll
        for (int off = 1; off <= 32; off <<= 1) {
            sR += __shfl_xor(sR, off, 64);
            sD += __shfl_xor(sD, off, 64);
        }
        if (lane == 0)
            atomicAdd(J.loss, (logf(sR + Mc * 1e-20f) - logf(sD + 1e-20f)) * J.scale);
        return;
    }

    // ---- GEMM role: 64x128 tile, BK=64, register-prefetch pipeline ----
    __shared__ __align__(16) unsigned short As[64 * 64];     // 8 KB
    __shared__ __align__(16) unsigned short Bs[128 * 64];    // 16 KB

    int f = blockIdx.x;
    int zz = f & 7, slot = f >> 3;
    int job = zz >> 2, b = zz & 3;
    const unsigned short* A  = J.A[job]  + (size_t)b * J.sA[job];
    const unsigned short* BT = J.BT[job] + (size_t)b * J.sB[job];

    const int i0 = (slot / 7) * 64, j0 = (slot % 7) * 128;
    const int tid = threadIdx.x, lane = tid & 63, wv = tid >> 6;
    const int g = lane >> 4, lr = lane & 15;

    f32x4 acc[4][2] = {};

    // stage tile 0
    #pragma unroll
    for (int q = 0; q < 2; ++q) {
        int s = q * 256 + tid;
        int r = s >> 3;
        int csw = ((s & 7) << 4) ^ ((r & 7) << 4);
        gload16((const char*)(A + (size_t)(i0 + r) * Pp) + csw, As + (size_t)s * 8);
    }
    #pragma unroll
    for (int q = 0; q < 4; ++q) {
        int s = q * 256 + tid;
        int r = s >> 3;
        int csw = ((s & 7) << 4) ^ ((r & 7) << 4);
        gload16((const char*)(BT + (size_t)(j0 + r) * Pp) + csw, Bs + (size_t)s * 8);
    }
    __syncthreads();   // drains vmcnt: tile 0 resident

    for (int t = 0; t < 13; ++t) {
        // 1. read all fragments of current tile into registers
        bf16x8 af[2][4], bf[2][2];
        #pragma unroll
        for (int ks = 0; ks < 2; ++ks) {
            #pragma unroll
            for (int m = 0; m < 4; ++m) {
                int r = m * 16 + lr;
                int cb = (ks * 64 + g * 16) ^ ((r & 7) << 4);
                af[ks][m] = __builtin_bit_cast(bf16x8, *(const u16x8*)((const char*)As + r * 128 + cb));
            }
            #pragma unroll
            for (int n = 0; n < 2; ++n) {
                int r = wv * 32 + n * 16 + lr;
                int cb = (ks * 64 + g * 16) ^ ((r & 7) << 4);
                bf[ks][n] = __builtin_bit_cast(bf16x8, *(const u16x8*)((const char*)Bs + r * 128 + cb));
            }
        }
        __syncthreads();   // all waves done reading LDS (lgkm drained)
        // 2. issue next tile's loads (async, overlap with MFMA below)
        if (t < 12) {
            int k0 = (t + 1) * 64;
            #pragma unroll
            for (int q = 0; q < 2; ++q) {
                int s = q * 256 + tid;
                int r = s >> 3;
                int csw = ((s & 7) << 4) ^ ((r & 7) << 4);
                gload16((const char*)(A + (size_t)(i0 + r) * Pp + k0) + csw, As + (size_t)s * 8);
            }
            #pragma unroll
            for (int q = 0; q < 4; ++q) {
                int s = q * 256 + tid;
                int r = s >> 3;
                int csw = ((s & 7) << 4) ^ ((r & 7) << 4);
                gload16((const char*)(BT + (size_t)(j0 + r) * Pp + k0) + csw, Bs + (size_t)s * 8);
            }
        }
        // 3. MFMA from registers (no LDS dependency)
        #pragma unroll
        for (int ks = 0; ks < 2; ++ks)
            #pragma unroll
            for (int m = 0; m < 4; ++m)
                #pragma unroll
                for (int n = 0; n < 2; ++n)
                    acc[m][n] = __builtin_amdgcn_mfma_f32_16x16x32_bf16(af[ks][m], bf[ks][n], acc[m][n], 0, 0, 0);
        __syncthreads();   // drains vmcnt: next tile resident
    }

    unsigned short* Co = J.Cb[job] + (size_t)b * J.sC[job];
    float* csp = J.cs[job];
    float csacc[2] = {0.f, 0.f};
    #pragma unroll
    for (int m = 0; m < 4; ++m)
        #pragma unroll
        for (int n = 0; n < 2; ++n)
            #pragma unroll
            for (int j = 0; j < 4; ++j) {
                int row = i0 + m * 16 + g * 4 + j;
                int col = j0 + wv * 32 + n * 16 + lr;
                if (col < Pp) {
                    unsigned short h = f2bf(acc[m][n][j]);
                    Co[(size_t)row * Pp + col] = h;
                    csacc[n] += bf2f(h);
                }
            }
    if (csp) {
        csp += (size_t)b * Pp;
        #pragma unroll
        for (int n = 0; n < 2; ++n) {
            float p = csacc[n];
            p += __shfl_xor(p, 16, 64);
            p += __shfl_xor(p, 32, 64);
            int col = j0 + wv * 32 + n * 16 + lr;
            if (g == 0 && col < Pp) atomicAdd(&csp[col], p);
        }
    }
}

// ---------------- K8: standalone loss rows (final step) ----------------
__global__ __launch_bounds__(64) void k_lossrow(const unsigned short* __restrict__ L,
                                                const unsigned short* __restrict__ R,
                                                const float* __restrict__ csR,
                                                float* __restrict__ loss, float scale)
{
    const size_t MMp = (size_t)Pp * Pp;
    int r = blockIdx.x;
    int b = r / Mc, i = r % Mc;
    const u16x8* lrow = (const u16x8*)(L + (size_t)b * MMp + (size_t)i * Pp);
    const u16x8* rrow = (const u16x8*)(R + (size_t)b * MMp + (size_t)i * Pp);
    const f32x4* cs4  = (const f32x4*)(csR + (size_t)b * Pp);
    int lane = threadIdx.x;
    float sR = 0.f, sD = 0.f;
    for (int c = lane; c < Pp / 8; c += 64) {
        u16x8 lv = lrow[c];
        u16x8 rv = rrow[c];
        f32x4 c0 = cs4[2 * c], c1 = cs4[2 * c + 1];
        #pragma unroll
        for (int k = 0; k < 4; ++k) {
            float fl = bf2f(lv[k]);
            sR += fl * c0[k];
            sD += fl * bf2f(rv[k]);
        }
        #pragma unroll
        for (int k = 0; k < 4; ++k) {
            float fl = bf2f(lv[4 + k]);
            sR += fl * c1[k];
            sD += fl * bf2f(rv[4 + k]);
        }
    }
    #pragma unroll
    for (int off = 1; off <= 32; off <<= 1) {
        sR += __shfl_xor(sR, off, 64);
        sD += __shfl_xor(sD, off, 64);
    }
    if (lane == 0)
        atomicAdd(loss, (logf(sR + Mc * 1e-20f) - logf(sD + 1e-20f)) * scale);
}

// ---------------- host orchestration ----------------
extern "C" void kernel_launch(void* const* d_in, const int* in_sizes, int n_in,
                              void* d_out, int out_size, void* d_ws, size_t ws_size,
                              hipStream_t stream)
{
    const float* feats = (const float*)d_in[0];
    const float* dust  = (const float*)d_in[1];
    const float* Wself = (const float*)d_in[2];
    const float* bself = (const float*)d_in[3];
    const float* Wdust = (const float*)d_in[4];
    const float* bdust = (const float*)d_in[5];

    float* out  = (float*)d_out;
    float* qout = out;
    float* loss = out + (size_t)Bc * Dc * Tc * Mc;

    const size_t MMp = (size_t)Pp * Pp;       // 692,224

    // ---- workspace ----
    float* ws = (float*)d_ws;
    float* csR = ws;                                                // 6 slots * Bc * Pp fp32
    unsigned short* P12h = (unsigned short*)(ws + 4 * MMp);         // 28*MMp bf16
    unsigned short* P21h = P12h + (size_t)28 * MMp;                 // 28*MMp bf16
    unsigned short* chainT = P21h + (size_t)28 * MMp;               // 44*MMp bf16 region
    unsigned short* P12T  = chainT;
    unsigned short* P21T6 = P12T + (size_t)24 * MMp;
    unsigned short* l0    = P21T6 + (size_t)4 * MMp;
    unsigned short* l1    = l0 + (size_t)4 * MMp;
    unsigned short* R0    = l1 + (size_t)4 * MMp;
    unsigned short* R1    = R0 + (size_t)4 * MMp;
    unsigned short* qTb   = R1 + (size_t)4 * MMp;                   // 32*Qrows*Dc bf16
    float* cs12 = (float*)(qTb + (size_t)32 * Qrows * Dc);          // 28*Pp fp32
    float* cs21 = cs12 + (size_t)28 * Pp;                           // 28*Pp fp32

    // phase-1 overlays in chainT region:
    unsigned short* Abf   = chainT;
    unsigned int*   Abf32 = (unsigned int*)Abf;
    unsigned short* WTb   = Abf + (size_t)Bc * Tc * Nc * Cc;
    float*          fbuf  = (float*)(WTb + 2 * (size_t)Dc * Cc);

    // 1. pack inputs to bf16
    k_pack<<<Bc * Nc, 256, 0, stream>>>(feats, Abf32);
    k_packw<<<dim3(2, 8, 2), 256, 0, stream>>>(Wself, Wdust, WTb);
    hipMemsetAsync(csR, 0, (size_t)6 * Bc * Pp * sizeof(float), stream);
    hipMemsetAsync(loss, 0, sizeof(float), stream);
    // 2. projection GEMM + bias
    k_gemm_proj<<<dim3(1, 196), 256, 0, stream>>>(Abf, WTb, bself, fbuf);
    // 3. dust projection (fp32) + norms
    k_dustproj<<<32, 128, 0, stream>>>(dust, Wdust, bdust, qTb, qout);
    k_norm<<<dim3(13, 32), 256, 0, stream>>>(fbuf, qTb, qout);
    // 4. fused affinity (XCD-pinned, atomic-free), then dust rows
    float wconst = (float)(1.0 / log(784.0));
    k_affinity<<<2744, 256, 0, stream>>>(qTb, P12h, P21h, cs12, cs21, wconst);
    k_dustrow<<<dim3(28, 2), 256, 0, stream>>>(cs12, cs21, P12h, P21h);
    // 5. merged bf16 transposes
    k_transpose_bf16<<<dim3(13, 13, 28), 256, 0, stream>>>(P12h, P21h, P12T);

    // 6. chain
    const float scale = 1.0f / (6.0f * Bc * Mc);

    // prologue: L1 = P12[0] @ P12[1]^T-form;  R1 = P21T6 @ P21[5]^T (colsum slot 0)
    {
        GJobs J = {};
        J.A[0] = P12h;  J.sA[0] = (long long)7 * MMp;
        J.BT[0] = P12T; J.sB[0] = (long long)6 * MMp;
        J.Cb[0] = l0;   J.sC[0] = (long long)MMp; J.cs[0] = nullptr;
        J.A[1] = P21T6;                   J.sA[1] = (long long)MMp;
        J.BT[1] = P21h + (size_t)5 * MMp; J.sB[1] = (long long)7 * MMp;
        J.Cb[1] = R0;   J.sC[1] = (long long)MMp; J.cs[1] = csR;   // slot 0
        k_gemm_loss<<<728, 256, 0, stream>>>(J);
    }

    unsigned short *lcur = l0, *lnxt = l1, *rcur = R0, *rnxt = R1;
    for (int i = 1; i <= 5; ++i) {
        GJobs J = {};
        J.A[0] = lcur; J.sA[0] = (long long)MMp;
        J.BT[0] = P12T + (size_t)i * MMp; J.sB[0] = (long long)6 * MMp;
        J.Cb[0] = lnxt; J.sC[0] = (long long)MMp; J.cs[0] = nullptr;
        J.A[1] = rcur; J.sA[1] = (long long)MMp;
        J.BT[1] = P21h + (size_t)(5 - i) * MMp; J.sB[1] = (long long)7 * MMp;
        J.Cb[1] = rnxt; J.sC[1] = (long long)MMp; J.cs[1] = csR + (size_t)i * Bc * Pp;
        J.Lr = lcur; J.Rr = rcur; J.csL = csR + (size_t)(i - 1) * Bc * Pp;
        J.loss = loss; J.scale = scale;
        k_gemm_loss<<<728 + 785, 256, 0, stream>>>(J);
        unsigned short* t;
        t = lcur; lcur = lnxt; lnxt = t;
        t = rcur; rcur = rnxt; rnxt = t;
    }
    // final loss (state 6)
    k_lossrow<<<Bc * Mc, 64, 0, stream>>>(lcur, rcur, csR + (size_t)5 * Bc * Pp, loss, scale);
}

// Round 13
// 445.504 us; speedup vs baseline: 8.8335x; 1.0564x over previous
//
#include <hip/hip_runtime.h>
#include <hip/hip_bf16.h>
#include <math.h>

// Problem constants
constexpr int Bc = 4;      // batch
constexpr int Nc = 784;    // tokens
constexpr int Cc = 512;    // enc channels
constexpr int Tc = 8;      // time
constexpr int Dc = 128;    // proj dim
constexpr int Mc = 785;    // N+1
constexpr int TM1 = 7;     // T-1
constexpr int Pp = 832;    // padded chain dim (13*64)
constexpr int Qrows = 896; // padded q rows
constexpr float TEMP = 0.07f;

typedef __attribute__((ext_vector_type(4))) float f32x4;
typedef __attribute__((ext_vector_type(8))) unsigned short u16x8;
typedef __attribute__((ext_vector_type(8))) __bf16 bf16x8;

__device__ __forceinline__ unsigned short f2bf(float v) {
    __hip_bfloat16 h = __float2bfloat16(v);
    return __builtin_bit_cast(unsigned short, h);
}
__device__ __forceinline__ float bf2f(unsigned short u) {
    return __builtin_bit_cast(float, (unsigned int)u << 16);
}

// ---------------- async 16B global->LDS ----------------
__device__ __forceinline__ void gload16(const void* g, void* l) {
    __builtin_amdgcn_global_load_lds(
        (const __attribute__((address_space(1))) unsigned int*)g,
        (__attribute__((address_space(3))) unsigned int*)l, 16, 0, 0);
}

// ---------------- shared 64x128 double-buffered MFMA K-loop ----------------
// A: 64 rows (i0..), BT: 128 rows (j0..), stride LD, XOR-16B involution swizzle.
// Loads for tile t+1 issued at top of iter t into alternate buffer -> overlap
// with ds_read + MFMA; single barrier per iter.
template<int LD>
__device__ __forceinline__ void gemm64x128_db(const unsigned short* __restrict__ A,
                                              const unsigned short* __restrict__ BT,
                                              unsigned short* As0, unsigned short* As1,
                                              unsigned short* Bs0, unsigned short* Bs1,
                                              int i0, int j0, int tid, f32x4 (&acc)[4][2])
{
    const int lane = tid & 63, wv = tid >> 6;
    const int g = lane >> 4, lr = lane & 15;
    constexpr int NT = LD / 64;

    // prologue: stage tile 0 -> buf0
    #pragma unroll
    for (int q = 0; q < 2; ++q) {
        int s = q * 256 + tid; int r = s >> 3;
        int csw = ((s & 7) << 4) ^ ((r & 7) << 4);
        gload16((const char*)(A + (size_t)(i0 + r) * LD) + csw, As0 + (size_t)s * 8);
    }
    #pragma unroll
    for (int q = 0; q < 4; ++q) {
        int s = q * 256 + tid; int r = s >> 3;
        int csw = ((s & 7) << 4) ^ ((r & 7) << 4);
        gload16((const char*)(BT + (size_t)(j0 + r) * LD) + csw, Bs0 + (size_t)s * 8);
    }
    __syncthreads();

    for (int t = 0; t < NT; ++t) {
        unsigned short* Asc = (t & 1) ? As1 : As0;
        unsigned short* Bsc = (t & 1) ? Bs1 : Bs0;
        if (t + 1 < NT) {
            int k0 = (t + 1) * 64;
            unsigned short* Asn = (t & 1) ? As0 : As1;
            unsigned short* Bsn = (t & 1) ? Bs0 : Bs1;
            #pragma unroll
            for (int q = 0; q < 2; ++q) {
                int s = q * 256 + tid; int r = s >> 3;
                int csw = ((s & 7) << 4) ^ ((r & 7) << 4);
                gload16((const char*)(A + (size_t)(i0 + r) * LD + k0) + csw, Asn + (size_t)s * 8);
            }
            #pragma unroll
            for (int q = 0; q < 4; ++q) {
                int s = q * 256 + tid; int r = s >> 3;
                int csw = ((s & 7) << 4) ^ ((r & 7) << 4);
                gload16((const char*)(BT + (size_t)(j0 + r) * LD + k0) + csw, Bsn + (size_t)s * 8);
            }
        }
        bf16x8 af[2][4], bf[2][2];
        #pragma unroll
        for (int ks = 0; ks < 2; ++ks) {
            #pragma unroll
            for (int m = 0; m < 4; ++m) {
                int r = m * 16 + lr;
                int cb = (ks * 64 + g * 16) ^ ((r & 7) << 4);
                af[ks][m] = __builtin_bit_cast(bf16x8, *(const u16x8*)((const char*)Asc + r * 128 + cb));
            }
            #pragma unroll
            for (int n = 0; n < 2; ++n) {
                int r = wv * 32 + n * 16 + lr;
                int cb = (ks * 64 + g * 16) ^ ((r & 7) << 4);
                bf[ks][n] = __builtin_bit_cast(bf16x8, *(const u16x8*)((const char*)Bsc + r * 128 + cb));
            }
        }
        #pragma unroll
        for (int ks = 0; ks < 2; ++ks)
            #pragma unroll
            for (int m = 0; m < 4; ++m)
                #pragma unroll
                for (int n = 0; n < 2; ++n)
                    acc[m][n] = __builtin_amdgcn_mfma_f32_16x16x32_bf16(af[ks][m], bf[ks][n], acc[m][n], 0, 0, 0);
        __syncthreads();   // drains vmcnt (next tile resident) + buffer reuse safety
    }
}

// ---------------- reduction helpers ----------------
__device__ __forceinline__ float blockReduceSum(float v, float* sbuf) {
    #pragma unroll
    for (int off = 32; off; off >>= 1) v += __shfl_down(v, off, 64);
    __syncthreads();
    if ((threadIdx.x & 63) == 0) sbuf[threadIdx.x >> 6] = v;
    __syncthreads();
    return sbuf[0] + sbuf[1] + sbuf[2] + sbuf[3];
}
__device__ __forceinline__ float blockReduceMax(float v, float* sbuf) {
    #pragma unroll
    for (int off = 32; off; off >>= 1) v = fmaxf(v, __shfl_down(v, off, 64));
    __syncthreads();
    if ((threadIdx.x & 63) == 0) sbuf[threadIdx.x >> 6] = v;
    __syncthreads();
    return fmaxf(fmaxf(sbuf[0], sbuf[1]), fmaxf(sbuf[2], sbuf[3]));
}

// ---------------- K1a: pack feats -> bf16 A + pack W -> WT + zero-init (merged roles) ----------------
// bid < 3136: feats pack; 3136 <= bid < 3168: W pack; bid == 3168: zero csR+loss.
__global__ __launch_bounds__(256) void k_pack(const float* __restrict__ feats,
                                              const float* __restrict__ Wself,
                                              const float* __restrict__ Wdust,
                                              unsigned int* __restrict__ Abf32,
                                              unsigned short* __restrict__ WTb,
                                              float* __restrict__ csR,
                                              float* __restrict__ loss)
{
    __shared__ float lds[Cc * 9];   // 18.4 KB; packw uses first 64*65 floats
    int bid = blockIdx.x;
    int tid = threadIdx.x;
    if (bid == Bc * Nc + 32) {
        // zero role
        int n = 6 * Bc * Pp;
        for (int i = tid; i < n; i += 256) csR[i] = 0.f;
        if (tid == 0) *loss = 0.f;
        return;
    }
    if (bid >= Bc * Nc) {
        // packw role
        int pidx = bid - Bc * Nc;          // 0..31
        int which = pidx >> 4;
        int rem = pidx & 15;
        int d0 = (rem >> 3) * 64, c0 = (rem & 7) * 64;
        const float* W = which ? Wdust : Wself;
        unsigned short* O = WTb + (size_t)which * Dc * Cc;
        int tx = tid & 63, ty = tid >> 6;
        #pragma unroll
        for (int y = 0; y < 64; y += 4) lds[(y + ty) * 65 + tx] = W[(size_t)(c0 + y + ty) * Dc + d0 + tx];
        __syncthreads();
        #pragma unroll
        for (int y = 0; y < 64; y += 4) O[(size_t)(d0 + y + ty) * Cc + c0 + tx] = f2bf(lds[tx * 65 + y + ty]);
        return;
    }
    // feats pack role
    int b = bid / Nc, n = bid % Nc;
    const float* src = feats + (size_t)(b * Nc + n) * Cc * Tc;
    for (int i = tid; i < Cc * Tc; i += 256) lds[(i >> 3) * 9 + (i & 7)] = src[i];
    __syncthreads();
    #pragma unroll
    for (int t = 0; t < Tc; ++t) {
        size_t row = (size_t)(b * Tc + t) * Nc + n;
        float v0 = lds[(2 * tid) * 9 + t];
        float v1 = lds[(2 * tid + 1) * 9 + t];
        unsigned int pk = (unsigned int)f2bf(v0) | ((unsigned int)f2bf(v1) << 16);
        Abf32[row * (Cc / 2) + tid] = pk;
    }
}

// ---------------- K1c: projection GEMM fbuf = Abf @ WT^T + bias (64x128 db tiles) ----------------
__global__ __launch_bounds__(256, 3) void k_gemm_proj(const unsigned short* __restrict__ A,
                                                      const unsigned short* __restrict__ BT,
                                                      const float* __restrict__ bias,
                                                      float* __restrict__ Cf)
{
    __shared__ __align__(16) unsigned short As0[64 * 64], As1[64 * 64];
    __shared__ __align__(16) unsigned short Bs0[128 * 64], Bs1[128 * 64];
    const int i0 = blockIdx.x * 64;
    const int tid = threadIdx.x, lane = tid & 63, wv = tid >> 6;
    const int g = lane >> 4, lr = lane & 15;

    f32x4 acc[4][2] = {};
    gemm64x128_db<Cc>(A, BT, As0, As1, Bs0, Bs1, i0, 0, tid, acc);

    #pragma unroll
    for (int n = 0; n < 2; ++n) {
        int col = wv * 32 + n * 16 + lr;
        float bv = bias[col];
        #pragma unroll
        for (int m = 0; m < 4; ++m)
            #pragma unroll
            for (int j = 0; j < 4; ++j) {
                int row = i0 + m * 16 + g * 4 + j;
                Cf[(size_t)row * Dc + col] = acc[m][n][j] + bv;
            }
    }
}

// ---------------- K1e: l2norm rows of fbuf -> bf16 qTb + fp32 qout (+dust role) ----------------
// grid (14, 32): x<13 = norm chunk; x==13 = dust projection role.
__global__ __launch_bounds__(256) void k_norm(const float* __restrict__ fbuf,
                                              const float* __restrict__ dust,
                                              const float* __restrict__ Wdust,
                                              const float* __restrict__ bdust,
                                              unsigned short* __restrict__ qTb,
                                              float* __restrict__ qout)
{
    __shared__ float lds[64][129];
    __shared__ float nrm[64][4];
    __shared__ float inv[64];
    __shared__ float red2[2];
    int bt = blockIdx.y;
    int b = bt >> 3, t = bt & 7;
    int tid = threadIdx.x;

    if (blockIdx.x == 13) {
        // ---- dust projection role (fp32 exact) ----
        float* sdust = &lds[0][0];
        for (int i = tid; i < Cc; i += 256) sdust[i] = dust[((size_t)b * Cc + i) * Tc + t];
        __syncthreads();
        float acc = 0.f;
        if (tid < 128) {
            for (int c = 0; c < Cc; ++c) acc += sdust[c] * Wdust[(size_t)c * Dc + tid];
            acc += bdust[tid];
            float s = acc * acc;
            #pragma unroll
            for (int off = 32; off; off >>= 1) s += __shfl_down(s, off, 64);
            if ((tid & 63) == 0) red2[tid >> 6] = s;
        }
        __syncthreads();
        if (tid < 128) {
            float inv0 = 1.f / fmaxf(sqrtf(red2[0] + red2[1]), 1e-12f);
            float qv = acc * inv0;
            qTb[((size_t)bt * Qrows + Nc) * Dc + tid] = f2bf(qv);
            qout[(((size_t)b * Dc + tid) * Tc + t) * Mc + Nc] = qv;
        }
        return;
    }

    int n0 = blockIdx.x * 64;
    #pragma unroll
    for (int q = 0; q < 8; ++q) {
        int i = q * 256 + tid;
        int nl = i >> 5, d4 = i & 31;
        f32x4 v = {};
        if (n0 + nl < Nc) v = *(const f32x4*)(fbuf + ((size_t)bt * Nc + n0 + nl) * Dc + d4 * 4);
        *(f32x4*)(&lds[nl][d4 * 4]) = v;
    }
    __syncthreads();
    {
        int r = tid & 63, p = tid >> 6;
        float s = 0.f;
        #pragma unroll
        for (int j = 0; j < 32; ++j) { float v = lds[r][p * 32 + j]; s += v * v; }
        nrm[r][p] = s;
    }
    __syncthreads();
    if (tid < 64) inv[tid] = 1.f / fmaxf(sqrtf(nrm[tid][0] + nrm[tid][1] + nrm[tid][2] + nrm[tid][3]), 1e-12f);
    __syncthreads();
    unsigned int* qT32 = (unsigned int*)(qTb + (size_t)bt * Qrows * Dc);
    #pragma unroll
    for (int q = 0; q < 16; ++q) {
        int i = q * 256 + tid;
        int nl = i >> 6, dp = i & 63;
        if (n0 + nl < Nc) {
            float iv = inv[nl];
            unsigned int pk = (unsigned int)f2bf(lds[nl][2 * dp] * iv)
                            | ((unsigned int)f2bf(lds[nl][2 * dp + 1] * iv) << 16);
            qT32[((size_t)(n0 + nl) * Dc >> 1) + dp] = pk;
        }
    }
    int nl = tid & 63;
    if (n0 + nl < Nc) {
        float iv = inv[nl];
        #pragma unroll
        for (int dd = 0; dd < Dc; dd += 4) {
            int d = dd + (tid >> 6);
            qout[(((size_t)b * Dc + d) * Tc + t) * Mc + n0 + nl] = lds[nl][d] * iv;
        }
    }
}

// ---------------- K2: fused affinity, XCD-pinned, no atomics, LDS-staged output ----------------
__global__ __launch_bounds__(256, 2) void k_affinity(const unsigned short* __restrict__ qTb,
                                                     unsigned short* __restrict__ P12h,
                                                     unsigned short* __restrict__ P21h,
                                                     float* __restrict__ cs12,
                                                     float* __restrict__ cs21,
                                                     float wconst)
{
    constexpr float INVT = 1.0f / TEMP;
    const size_t MMp = (size_t)Pp * Pp;
    __shared__ unsigned short otile[16][840];
    __shared__ float sred[16][4][2];
    __shared__ float rowsum[16], invZ[16], entP[16];

    int f = blockIdx.x;
    int xcd = f & 7, slot = f >> 3;
    int grp = xcd + 8 * (slot / 49);
    int strip = slot % 49;
    int side = grp >= 28 ? 1 : 0;
    int bt = grp - side * 28;
    int b = bt / TM1, t = bt % TM1;
    const unsigned short *Aq, *Bq;
    unsigned short* OUT;
    if (side == 0) {
        Aq = qTb + (size_t)(b * Tc + t)     * Qrows * Dc;
        Bq = qTb + (size_t)(b * Tc + t + 1) * Qrows * Dc;
        OUT = P12h + (size_t)bt * MMp;
    } else {
        Aq = qTb + (size_t)(b * Tc + 7 - t) * Qrows * Dc;
        Bq = qTb + (size_t)(b * Tc + 6 - t) * Qrows * Dc;
        OUT = P21h + (size_t)bt * MMp;
    }
    float* csFlip = (side == 0 ? cs21 : cs12) + (size_t)(b * TM1 + (6 - t)) * Pp;

    const int r0 = strip * 16;
    const int tid = threadIdx.x, lane = tid & 63, w = tid >> 6;
    const int g = lane >> 4, lr = lane & 15;

    f32x4 acc[13] = {};
    #pragma unroll
    for (int ks = 0; ks < 4; ++ks) {
        bf16x8 af = __builtin_bit_cast(bf16x8,
            *(const u16x8*)(Aq + (size_t)(r0 + lr) * Dc + ks * 32 + g * 8));
        bf16x8 bfr[7];
        #pragma unroll
        for (int tt = 0; tt < 7; ++tt)
            if (w * 13 + tt < 49)
                bfr[tt] = __builtin_bit_cast(bf16x8,
                    *(const u16x8*)(Bq + (size_t)((w * 13 + tt) * 16 + lr) * Dc + ks * 32 + g * 8));
        #pragma unroll
        for (int tt = 0; tt < 7; ++tt)
            if (w * 13 + tt < 49)
                acc[tt] = __builtin_amdgcn_mfma_f32_16x16x32_bf16(af, bfr[tt], acc[tt], 0, 0, 0);
        #pragma unroll
        for (int tt = 7; tt < 13; ++tt)
            if (w * 13 + tt < 49)
                bfr[tt - 7] = __builtin_bit_cast(bf16x8,
                    *(const u16x8*)(Bq + (size_t)((w * 13 + tt) * 16 + lr) * Dc + ks * 32 + g * 8));
        #pragma unroll
        for (int tt = 7; tt < 13; ++tt)
            if (w * 13 + tt < 49)
                acc[tt] = __builtin_amdgcn_mfma_f32_16x16x32_bf16(af, bfr[tt - 7], acc[tt], 0, 0, 0);
    }

    // sweep 1: rowsums only
    float rs[4] = {0.f, 0.f, 0.f, 0.f};
    #pragma unroll
    for (int tt = 0; tt < 13; ++tt) {
        if (w * 13 + tt < 49) {
            #pragma unroll
            for (int j = 0; j < 4; ++j) rs[j] += acc[tt][j];
        }
    }
    #pragma unroll
    for (int off = 1; off <= 8; off <<= 1) {
        #pragma unroll
        for (int j = 0; j < 4; ++j) rs[j] += __shfl_xor(rs[j], off, 64);
    }
    if (lr == 0) {
        #pragma unroll
        for (int j = 0; j < 4; ++j) sred[g * 4 + j][w][0] = rs[j];
    }
    __syncthreads();
    if (tid < 16) {
        float r = sred[tid][0][0] + sred[tid][1][0] + sred[tid][2][0] + sred[tid][3][0];
        rowsum[tid] = r;
        csFlip[r0 + tid] = r;
    }
    __syncthreads();

    // sweep 2: exp-sum + entropy; cache exp into acc
    float invr[4];
    #pragma unroll
    for (int j = 0; j < 4; ++j) invr[j] = 1.0f / rowsum[g * 4 + j];
    float en[4] = {0.f, 0.f, 0.f, 0.f}, es[4] = {0.f, 0.f, 0.f, 0.f};
    #pragma unroll
    for (int tt = 0; tt < 13; ++tt) {
        if (w * 13 + tt < 49) {
            #pragma unroll
            for (int j = 0; j < 4; ++j) {
                float a = acc[tt][j];
                float e = __expf(a * INVT);
                es[j] += e;
                float p = a * invr[j];
                en[j] -= p * __logf(fmaxf(p, 1e-20f));
                acc[tt][j] = e;
            }
        }
    }
    #pragma unroll
    for (int off = 1; off <= 8; off <<= 1) {
        #pragma unroll
        for (int j = 0; j < 4; ++j) {
            es[j] += __shfl_xor(es[j], off, 64);
            en[j] += __shfl_xor(en[j], off, 64);
        }
    }
    if (lr == 0) {
        #pragma unroll
        for (int j = 0; j < 4; ++j) { sred[g * 4 + j][w][0] = es[j]; sred[g * 4 + j][w][1] = en[j]; }
    }
    __syncthreads();
    if (tid < 16) {
        float esum = sred[tid][0][0] + sred[tid][1][0] + sred[tid][2][0] + sred[tid][3][0];
        float ent  = sred[tid][0][1] + sred[tid][1][1] + sred[tid][2][1] + sred[tid][3][1];
        float ez  = __expf(ent * wconst * INVT);
        float Z   = esum + ez;
        float iz  = 1.0f / Z;
        invZ[tid] = iz;
        entP[tid] = ez * iz;
    }
    __syncthreads();

    // sweep 3: normalized probs -> LDS tile (bf16)
    float izl[4];
    #pragma unroll
    for (int j = 0; j < 4; ++j) izl[j] = invZ[g * 4 + j];
    #pragma unroll
    for (int tt = 0; tt < 13; ++tt) {
        int gt = w * 13 + tt;
        if (gt < 49) {
            int col = gt * 16 + lr;
            #pragma unroll
            for (int j = 0; j < 4; ++j)
                otile[g * 4 + j][col] = f2bf(acc[tt][j] * izl[j]);
        }
    }
    if (tid < 16) otile[tid][784] = f2bf(entP[tid]);
    for (int i = tid; i < 16 * 47; i += 256) otile[i / 47][785 + i % 47] = 0;
    __syncthreads();

    for (int v = tid; v < 16 * 104; v += 256) {
        int row = v / 104, cv = v % 104;
        *(u16x8*)(OUT + (size_t)(r0 + row) * Pp + cv * 8) = *(const u16x8*)(&otile[row][cv * 8]);
    }
}

// ---------------- K3: dust rows (row 784) + zero pad rows ----------------
__global__ __launch_bounds__(256) void k_dustrow(const float* __restrict__ cs12,
                                                 const float* __restrict__ cs21,
                                                 unsigned short* __restrict__ P12h,
                                                 unsigned short* __restrict__ P21h)
{
    constexpr float INVT = 1.0f / TEMP;
    const size_t MMp = (size_t)Pp * Pp;
    int bt = blockIdx.x, side = blockIdx.y;
    const float* cs = (side ? cs21 : cs12) + (size_t)bt * Pp;
    unsigned short* OUT = (side ? P21h : P12h) + (size_t)bt * MMp;
    __shared__ float sbuf[4];
    int tid = threadIdx.x;
    float v[4];
    #pragma unroll
    for (int k = 0; k < 4; ++k) {
        int j = tid + k * 256;
        float val = -INFINITY;
        if (j < Nc)       val = -cs[j] * INVT;
        else if (j == Nc) val = 0.f;
        v[k] = val;
    }
    float mx = fmaxf(fmaxf(v[0], v[1]), fmaxf(v[2], v[3]));
    mx = blockReduceMax(mx, sbuf);
    float e[4]; float s = 0.f;
    #pragma unroll
    for (int k = 0; k < 4; ++k) {
        int j = tid + k * 256;
        e[k] = (j < Mc) ? __expf(v[k] - mx) : 0.f;
        s += e[k];
    }
    s = blockReduceSum(s, sbuf);
    float invs = 1.f / s;
    #pragma unroll
    for (int k = 0; k < 4; ++k) {
        int j = tid + k * 256;
        if (j < Mc)      OUT[(size_t)Nc * Pp + j] = f2bf(e[k] * invs);
        else if (j < Pp) OUT[(size_t)Nc * Pp + j] = 0;
    }
    u16x8 z = {};
    u16x8* dst = (u16x8*)(OUT + (size_t)785 * Pp);
    for (int i = tid; i < (Pp - 785) * Pp / 8; i += 256) dst[i] = z;
}

// ---------------- K6: merged bf16 transposes (grid z = 0..27) ----------------
__global__ __launch_bounds__(256) void k_transpose_bf16(const unsigned short* __restrict__ P12h,
                                                        const unsigned short* __restrict__ P21h,
                                                        unsigned short* __restrict__ Db)
{
    const size_t MMp = (size_t)Pp * Pp;
    __shared__ unsigned short tile[64][65];
    int z = blockIdx.z;
    const unsigned short* S;
    if (z < 24) { int b = z / 6, tm = z % 6; S = P12h + ((size_t)b * 7 + tm + 1) * MMp; }
    else        { S = P21h + ((size_t)(z - 24) * 7 + 6) * MMp; }
    unsigned short* D = Db + (size_t)z * MMp;
    int x0 = blockIdx.x * 64, y0 = blockIdx.y * 64;
    int tx = threadIdx.x & 63, ty = threadIdx.x >> 6;
    #pragma unroll
    for (int y = 0; y < 64; y += 4) tile[y + ty][tx] = S[(size_t)(y0 + y + ty) * Pp + x0 + tx];
    __syncthreads();
    #pragma unroll
    for (int y = 0; y < 64; y += 4) D[(size_t)(x0 + y + ty) * Pp + y0 + tx] = tile[tx][y + ty];
}

// ---------------- K7: fused chain GEMM (64x128 db tiles) + loss ----------------
struct GJobs {
    const unsigned short* A[2];
    const unsigned short* BT[2];
    unsigned short* Cb[2];
    float* cs[2];
    long long sA[2], sB[2], sC[2];
    const unsigned short* Lr;
    const unsigned short* Rr;
    const float* csL;
    float* loss;
    float scale;
};

__global__ __launch_bounds__(256, 3) void k_gemm_loss(GJobs J)
{
    const size_t MMp = (size_t)Pp * Pp;
    if (blockIdx.x >= 728) {
        // ---- loss role ----
        int q = blockIdx.x - 728;
        int w = threadIdx.x >> 6, lane = threadIdx.x & 63;
        int r = q * 4 + w;
        int b = r / Mc, i = r % Mc;
        const u16x8* lrow = (const u16x8*)(J.Lr + (size_t)b * MMp + (size_t)i * Pp);
        const u16x8* rrow = (const u16x8*)(J.Rr + (size_t)b * MMp + (size_t)i * Pp);
        const f32x4* cs4  = (const f32x4*)(J.csL + (size_t)b * Pp);
        float sR = 0.f, sD = 0.f;
        for (int c = lane; c < Pp / 8; c += 64) {
            u16x8 lv = lrow[c];
            u16x8 rv = rrow[c];
            f32x4 c0 = cs4[2 * c], c1 = cs4[2 * c + 1];
            #pragma unroll
            for (int k = 0; k < 4; ++k) {
                float fl = bf2f(lv[k]);
                sR += fl * c0[k];
                sD += fl * bf2f(rv[k]);
            }
            #pragma unroll
            for (int k = 0; k < 4; ++k) {
                float fl = bf2f(lv[4 + k]);
                sR += fl * c1[k];
                sD += fl * bf2f(rv[4 + k]);
            }
        }
        #pragma unroll
        for (int off = 1; off <= 32; off <<= 1) {
            sR += __shfl_xor(sR, off, 64);
            sD += __shfl_xor(sD, off, 64);
        }
        if (lane == 0)
            atomicAdd(J.loss, (logf(sR + Mc * 1e-20f) - logf(sD + 1e-20f)) * J.scale);
        return;
    }

    // ---- GEMM role: 64x128 tile, double-buffered ----
    __shared__ __align__(16) unsigned short As0[64 * 64], As1[64 * 64];
    __shared__ __align__(16) unsigned short Bs0[128 * 64], Bs1[128 * 64];

    int f = blockIdx.x;
    int zz = f & 7, slot = f >> 3;
    int job = zz >> 2, b = zz & 3;
    const unsigned short* A  = J.A[job]  + (size_t)b * J.sA[job];
    const unsigned short* BT = J.BT[job] + (size_t)b * J.sB[job];

    const int i0 = (slot / 7) * 64, j0 = (slot % 7) * 128;
    const int tid = threadIdx.x, lane = tid & 63, wv = tid >> 6;
    const int g = lane >> 4, lr = lane & 15;

    f32x4 acc[4][2] = {};
    gemm64x128_db<Pp>(A, BT, As0, As1, Bs0, Bs1, i0, j0, tid, acc);

    unsigned short* Co = J.Cb[job] + (size_t)b * J.sC[job];
    float* csp = J.cs[job];
    float csacc[2] = {0.f, 0.f};
    #pragma unroll
    for (int m = 0; m < 4; ++m)
        #pragma unroll
        for (int n = 0; n < 2; ++n)
            #pragma unroll
            for (int j = 0; j < 4; ++j) {
                int row = i0 + m * 16 + g * 4 + j;
                int col = j0 + wv * 32 + n * 16 + lr;
                if (col < Pp) {
                    unsigned short h = f2bf(acc[m][n][j]);
                    Co[(size_t)row * Pp + col] = h;
                    csacc[n] += bf2f(h);
                }
            }
    if (csp) {
        csp += (size_t)b * Pp;
        #pragma unroll
        for (int n = 0; n < 2; ++n) {
            float p = csacc[n];
            p += __shfl_xor(p, 16, 64);
            p += __shfl_xor(p, 32, 64);
            int col = j0 + wv * 32 + n * 16 + lr;
            if (g == 0 && col < Pp) atomicAdd(&csp[col], p);
        }
    }
}

// ---------------- K8: standalone loss rows (final step) ----------------
__global__ __launch_bounds__(64) void k_lossrow(const unsigned short* __restrict__ L,
                                                const unsigned short* __restrict__ R,
                                                const float* __restrict__ csR,
                                                float* __restrict__ loss, float scale)
{
    const size_t MMp = (size_t)Pp * Pp;
    int r = blockIdx.x;
    int b = r / Mc, i = r % Mc;
    const u16x8* lrow = (const u16x8*)(L + (size_t)b * MMp + (size_t)i * Pp);
    const u16x8* rrow = (const u16x8*)(R + (size_t)b * MMp + (size_t)i * Pp);
    const f32x4* cs4  = (const f32x4*)(csR + (size_t)b * Pp);
    int lane = threadIdx.x;
    float sR = 0.f, sD = 0.f;
    for (int c = lane; c < Pp / 8; c += 64) {
        u16x8 lv = lrow[c];
        u16x8 rv = rrow[c];
        f32x4 c0 = cs4[2 * c], c1 = cs4[2 * c + 1];
        #pragma unroll
        for (int k = 0; k < 4; ++k) {
            float fl = bf2f(lv[k]);
            sR += fl * c0[k];
            sD += fl * bf2f(rv[k]);
        }
        #pragma unroll
        for (int k = 0; k < 4; ++k) {
            float fl = bf2f(lv[4 + k]);
            sR += fl * c1[k];
            sD += fl * bf2f(rv[4 + k]);
        }
    }
    #pragma unroll
    for (int off = 1; off <= 32; off <<= 1) {
        sR += __shfl_xor(sR, off, 64);
        sD += __shfl_xor(sD, off, 64);
    }
    if (lane == 0)
        atomicAdd(loss, (logf(sR + Mc * 1e-20f) - logf(sD + 1e-20f)) * scale);
}

// ---------------- host orchestration ----------------
extern "C" void kernel_launch(void* const* d_in, const int* in_sizes, int n_in,
                              void* d_out, int out_size, void* d_ws, size_t ws_size,
                              hipStream_t stream)
{
    const float* feats = (const float*)d_in[0];
    const float* dust  = (const float*)d_in[1];
    const float* Wself = (const float*)d_in[2];
    const float* bself = (const float*)d_in[3];
    const float* Wdust = (const float*)d_in[4];
    const float* bdust = (const float*)d_in[5];

    float* out  = (float*)d_out;
    float* qout = out;
    float* loss = out + (size_t)Bc * Dc * Tc * Mc;

    const size_t MMp = (size_t)Pp * Pp;       // 692,224

    // ---- workspace ----
    float* ws = (float*)d_ws;
    float* csR = ws;                                                // 6 slots * Bc * Pp fp32
    unsigned short* P12h = (unsigned short*)(ws + 4 * MMp);         // 28*MMp bf16
    unsigned short* P21h = P12h + (size_t)28 * MMp;                 // 28*MMp bf16
    unsigned short* chainT = P21h + (size_t)28 * MMp;               // 44*MMp bf16 region
    unsigned short* P12T  = chainT;
    unsigned short* P21T6 = P12T + (size_t)24 * MMp;
    unsigned short* l0    = P21T6 + (size_t)4 * MMp;
    unsigned short* l1    = l0 + (size_t)4 * MMp;
    unsigned short* R0    = l1 + (size_t)4 * MMp;
    unsigned short* R1    = R0 + (size_t)4 * MMp;
    unsigned short* qTb   = R1 + (size_t)4 * MMp;                   // 32*Qrows*Dc bf16
    float* cs12 = (float*)(qTb + (size_t)32 * Qrows * Dc);          // 28*Pp fp32
    float* cs21 = cs12 + (size_t)28 * Pp;                           // 28*Pp fp32

    // phase-1 overlays in chainT region:
    unsigned short* Abf   = chainT;
    unsigned int*   Abf32 = (unsigned int*)Abf;
    unsigned short* WTb   = Abf + (size_t)Bc * Tc * Nc * Cc;
    float*          fbuf  = (float*)(WTb + 2 * (size_t)Dc * Cc);

    // 1. pack inputs to bf16 (+W pack +zero-init roles)
    k_pack<<<Bc * Nc + 32 + 1, 256, 0, stream>>>(feats, Wself, Wdust, Abf32, WTb, csR, loss);
    // 2. projection GEMM + bias (64x128 tiles)
    k_gemm_proj<<<392, 256, 0, stream>>>(Abf, WTb, bself, fbuf);
    // 3. norms (+dust projection role)
    k_norm<<<dim3(14, 32), 256, 0, stream>>>(fbuf, dust, Wdust, bdust, qTb, qout);
    // 4. fused affinity (XCD-pinned, atomic-free), then dust rows
    float wconst = (float)(1.0 / log(784.0));
    k_affinity<<<2744, 256, 0, stream>>>(qTb, P12h, P21h, cs12, cs21, wconst);
    k_dustrow<<<dim3(28, 2), 256, 0, stream>>>(cs12, cs21, P12h, P21h);
    // 5. merged bf16 transposes
    k_transpose_bf16<<<dim3(13, 13, 28), 256, 0, stream>>>(P12h, P21h, P12T);

    // 6. chain
    const float scale = 1.0f / (6.0f * Bc * Mc);

    // prologue: L1 = P12[0] @ P12[1]^T-form;  R1 = P21T6 @ P21[5]^T (colsum slot 0)
    {
        GJobs J = {};
        J.A[0] = P12h;  J.sA[0] = (long long)7 * MMp;
        J.BT[0] = P12T; J.sB[0] = (long long)6 * MMp;
        J.Cb[0] = l0;   J.sC[0] = (long long)MMp; J.cs[0] = nullptr;
        J.A[1] = P21T6;                   J.sA[1] = (long long)MMp;
        J.BT[1] = P21h + (size_t)5 * MMp; J.sB[1] = (long long)7 * MMp;
        J.Cb[1] = R0;   J.sC[1] = (long long)MMp; J.cs[1] = csR;   // slot 0
        k_gemm_loss<<<728, 256, 0, stream>>>(J);
    }

    unsigned short *lcur = l0, *lnxt = l1, *rcur = R0, *rnxt = R1;
    for (int i = 1; i <= 5; ++i) {
        GJobs J = {};
        J.A[0] = lcur; J.sA[0] = (long long)MMp;
        J.BT[0] = P12T + (size_t)i * MMp; J.sB[0] = (long long)6 * MMp;
        J.Cb[0] = lnxt; J.sC[0] = (long long)MMp; J.cs[0] = nullptr;
        J.A[1] = rcur; J.sA[1] = (long long)MMp;
        J.BT[1] = P21h + (size_t)(5 - i) * MMp; J.sB[1] = (long long)7 * MMp;
        J.Cb[1] = rnxt; J.sC[1] = (long long)MMp; J.cs[1] = csR + (size_t)i * Bc * Pp;
        J.Lr = lcur; J.Rr = rcur; J.csL = csR + (size_t)(i - 1) * Bc * Pp;
        J.loss = loss; J.scale = scale;
        k_gemm_loss<<<728 + 785, 256, 0, stream>>>(J);
        unsigned short* t;
        t = lcur; lcur = lnxt; lnxt = t;
        t = rcur; rcur = rnxt; rnxt = t;
    }
    // final loss (state 6)
    k_lossrow<<<Bc * Mc, 64, 0, stream>>>(lcur, rcur, csR + (size_t)5 * Bc * Pp, loss, scale);
}

// Round 14
// 435.196 us; speedup vs baseline: 9.0428x; 1.0237x over previous
//
#include <hip/hip_runtime.h>
#include <hip/hip_bf16.h>
#include <math.h>

// Problem constants
constexpr int Bc = 4;      // batch
constexpr int Nc = 784;    // tokens
constexpr int Cc = 512;    // enc channels
constexpr int Tc = 8;      // time
constexpr int Dc = 128;    // proj dim
constexpr int Mc = 785;    // N+1
constexpr int TM1 = 7;     // T-1
constexpr int Pp = 832;    // padded chain dim (13*64)
constexpr int Qrows = 896; // padded q rows
constexpr float TEMP = 0.07f;

typedef __attribute__((ext_vector_type(4))) float f32x4;
typedef __attribute__((ext_vector_type(8))) unsigned short u16x8;
typedef __attribute__((ext_vector_type(8))) __bf16 bf16x8;

__device__ __forceinline__ unsigned short f2bf(float v) {
    __hip_bfloat16 h = __float2bfloat16(v);
    return __builtin_bit_cast(unsigned short, h);
}
__device__ __forceinline__ float bf2f(unsigned short u) {
    return __builtin_bit_cast(float, (unsigned int)u << 16);
}

// ---------------- async 16B global->LDS ----------------
__device__ __forceinline__ void gload16(const void* g, void* l) {
    __builtin_amdgcn_global_load_lds(
        (const __attribute__((address_space(1))) unsigned int*)g,
        (__attribute__((address_space(3))) unsigned int*)l, 16, 0, 0);
}

// ---------------- shared 64x128 double-buffered MFMA K-loop ----------------
template<int LD>
__device__ __forceinline__ void gemm64x128_db(const unsigned short* __restrict__ A,
                                              const unsigned short* __restrict__ BT,
                                              unsigned short* As0, unsigned short* As1,
                                              unsigned short* Bs0, unsigned short* Bs1,
                                              int i0, int j0, int tid, f32x4 (&acc)[4][2])
{
    const int lane = tid & 63, wv = tid >> 6;
    const int g = lane >> 4, lr = lane & 15;
    constexpr int NT = LD / 64;

    #pragma unroll
    for (int q = 0; q < 2; ++q) {
        int s = q * 256 + tid; int r = s >> 3;
        int csw = ((s & 7) << 4) ^ ((r & 7) << 4);
        gload16((const char*)(A + (size_t)(i0 + r) * LD) + csw, As0 + (size_t)s * 8);
    }
    #pragma unroll
    for (int q = 0; q < 4; ++q) {
        int s = q * 256 + tid; int r = s >> 3;
        int csw = ((s & 7) << 4) ^ ((r & 7) << 4);
        gload16((const char*)(BT + (size_t)(j0 + r) * LD) + csw, Bs0 + (size_t)s * 8);
    }
    __syncthreads();

    for (int t = 0; t < NT; ++t) {
        unsigned short* Asc = (t & 1) ? As1 : As0;
        unsigned short* Bsc = (t & 1) ? Bs1 : Bs0;
        if (t + 1 < NT) {
            int k0 = (t + 1) * 64;
            unsigned short* Asn = (t & 1) ? As0 : As1;
            unsigned short* Bsn = (t & 1) ? Bs0 : Bs1;
            #pragma unroll
            for (int q = 0; q < 2; ++q) {
                int s = q * 256 + tid; int r = s >> 3;
                int csw = ((s & 7) << 4) ^ ((r & 7) << 4);
                gload16((const char*)(A + (size_t)(i0 + r) * LD + k0) + csw, Asn + (size_t)s * 8);
            }
            #pragma unroll
            for (int q = 0; q < 4; ++q) {
                int s = q * 256 + tid; int r = s >> 3;
                int csw = ((s & 7) << 4) ^ ((r & 7) << 4);
                gload16((const char*)(BT + (size_t)(j0 + r) * LD + k0) + csw, Bsn + (size_t)s * 8);
            }
        }
        bf16x8 af[2][4], bf[2][2];
        #pragma unroll
        for (int ks = 0; ks < 2; ++ks) {
            #pragma unroll
            for (int m = 0; m < 4; ++m) {
                int r = m * 16 + lr;
                int cb = (ks * 64 + g * 16) ^ ((r & 7) << 4);
                af[ks][m] = __builtin_bit_cast(bf16x8, *(const u16x8*)((const char*)Asc + r * 128 + cb));
            }
            #pragma unroll
            for (int n = 0; n < 2; ++n) {
                int r = wv * 32 + n * 16 + lr;
                int cb = (ks * 64 + g * 16) ^ ((r & 7) << 4);
                bf[ks][n] = __builtin_bit_cast(bf16x8, *(const u16x8*)((const char*)Bsc + r * 128 + cb));
            }
        }
        #pragma unroll
        for (int ks = 0; ks < 2; ++ks)
            #pragma unroll
            for (int m = 0; m < 4; ++m)
                #pragma unroll
                for (int n = 0; n < 2; ++n)
                    acc[m][n] = __builtin_amdgcn_mfma_f32_16x16x32_bf16(af[ks][m], bf[ks][n], acc[m][n], 0, 0, 0);
        __syncthreads();
    }
}

// ---------------- reduction helpers ----------------
__device__ __forceinline__ float blockReduceSum(float v, float* sbuf) {
    #pragma unroll
    for (int off = 32; off; off >>= 1) v += __shfl_down(v, off, 64);
    __syncthreads();
    if ((threadIdx.x & 63) == 0) sbuf[threadIdx.x >> 6] = v;
    __syncthreads();
    return sbuf[0] + sbuf[1] + sbuf[2] + sbuf[3];
}
__device__ __forceinline__ float blockReduceMax(float v, float* sbuf) {
    #pragma unroll
    for (int off = 32; off; off >>= 1) v = fmaxf(v, __shfl_down(v, off, 64));
    __syncthreads();
    if ((threadIdx.x & 63) == 0) sbuf[threadIdx.x >> 6] = v;
    __syncthreads();
    return fmaxf(fmaxf(sbuf[0], sbuf[1]), fmaxf(sbuf[2], sbuf[3]));
}

// ---------------- K1a: pack feats + pack W + zero-init roles ----------------
// bid < 3136: feats pack; [3136,3168): W pack; [3168,3176): zero roles
// (csR+loss on first; qTb pad rows 784..895 split across all 8).
__global__ __launch_bounds__(256) void k_pack(const float* __restrict__ feats,
                                              const float* __restrict__ Wself,
                                              const float* __restrict__ Wdust,
                                              unsigned int* __restrict__ Abf32,
                                              unsigned short* __restrict__ WTb,
                                              unsigned short* __restrict__ qTb,
                                              float* __restrict__ csR,
                                              float* __restrict__ loss)
{
    __shared__ float lds[Cc * 9];
    int bid = blockIdx.x;
    int tid = threadIdx.x;
    if (bid >= Bc * Nc + 32) {
        // zero role
        int zb = bid - (Bc * Nc + 32);     // 0..7
        if (zb == 0) {
            int n = 6 * Bc * Pp;
            for (int i = tid; i < n; i += 256) csR[i] = 0.f;
            if (tid == 0) *loss = 0.f;
        }
        u16x8 z = {};
        for (int bt = zb * 4; bt < zb * 4 + 4; ++bt) {
            u16x8* dst = (u16x8*)(qTb + ((size_t)bt * Qrows + Nc) * Dc);
            for (int i = tid; i < (Qrows - Nc) * Dc / 8; i += 256) dst[i] = z;
        }
        return;
    }
    if (bid >= Bc * Nc) {
        // packw role
        int pidx = bid - Bc * Nc;
        int which = pidx >> 4;
        int rem = pidx & 15;
        int d0 = (rem >> 3) * 64, c0 = (rem & 7) * 64;
        const float* W = which ? Wdust : Wself;
        unsigned short* O = WTb + (size_t)which * Dc * Cc;
        int tx = tid & 63, ty = tid >> 6;
        #pragma unroll
        for (int y = 0; y < 64; y += 4) lds[(y + ty) * 65 + tx] = W[(size_t)(c0 + y + ty) * Dc + d0 + tx];
        __syncthreads();
        #pragma unroll
        for (int y = 0; y < 64; y += 4) O[(size_t)(d0 + y + ty) * Cc + c0 + tx] = f2bf(lds[tx * 65 + y + ty]);
        return;
    }
    // feats pack role
    int b = bid / Nc, n = bid % Nc;
    const float* src = feats + (size_t)(b * Nc + n) * Cc * Tc;
    for (int i = tid; i < Cc * Tc; i += 256) lds[(i >> 3) * 9 + (i & 7)] = src[i];
    __syncthreads();
    #pragma unroll
    for (int t = 0; t < Tc; ++t) {
        size_t row = (size_t)(b * Tc + t) * Nc + n;
        float v0 = lds[(2 * tid) * 9 + t];
        float v1 = lds[(2 * tid + 1) * 9 + t];
        unsigned int pk = (unsigned int)f2bf(v0) | ((unsigned int)f2bf(v1) << 16);
        Abf32[row * (Cc / 2) + tid] = pk;
    }
}

// ---------------- K1c: projection GEMM fbuf = Abf @ WT^T + bias ----------------
__global__ __launch_bounds__(256, 3) void k_gemm_proj(const unsigned short* __restrict__ A,
                                                      const unsigned short* __restrict__ BT,
                                                      const float* __restrict__ bias,
                                                      float* __restrict__ Cf)
{
    __shared__ __align__(16) unsigned short As0[64 * 64], As1[64 * 64];
    __shared__ __align__(16) unsigned short Bs0[128 * 64], Bs1[128 * 64];
    const int i0 = blockIdx.x * 64;
    const int tid = threadIdx.x, lane = tid & 63, wv = tid >> 6;
    const int g = lane >> 4, lr = lane & 15;

    f32x4 acc[4][2] = {};
    gemm64x128_db<Cc>(A, BT, As0, As1, Bs0, Bs1, i0, 0, tid, acc);

    #pragma unroll
    for (int n = 0; n < 2; ++n) {
        int col = wv * 32 + n * 16 + lr;
        float bv = bias[col];
        #pragma unroll
        for (int m = 0; m < 4; ++m)
            #pragma unroll
            for (int j = 0; j < 4; ++j) {
                int row = i0 + m * 16 + g * 4 + j;
                Cf[(size_t)row * Dc + col] = acc[m][n][j] + bv;
            }
    }
}

// ---------------- K1e: l2norm rows -> bf16 qTb + fp32 qout (+dust role) ----------------
// Dust role writes qout ONLY (qTb row 784 must stay ZERO for the padded affinity).
__global__ __launch_bounds__(256) void k_norm(const float* __restrict__ fbuf,
                                              const float* __restrict__ dust,
                                              const float* __restrict__ Wdust,
                                              const float* __restrict__ bdust,
                                              unsigned short* __restrict__ qTb,
                                              float* __restrict__ qout)
{
    __shared__ float lds[64][129];
    __shared__ float nrm[64][4];
    __shared__ float inv[64];
    __shared__ float red2[2];
    int bt = blockIdx.y;
    int b = bt >> 3, t = bt & 7;
    int tid = threadIdx.x;

    if (blockIdx.x == 13) {
        float* sdust = &lds[0][0];
        for (int i = tid; i < Cc; i += 256) sdust[i] = dust[((size_t)b * Cc + i) * Tc + t];
        __syncthreads();
        float acc = 0.f;
        if (tid < 128) {
            for (int c = 0; c < Cc; ++c) acc += sdust[c] * Wdust[(size_t)c * Dc + tid];
            acc += bdust[tid];
            float s = acc * acc;
            #pragma unroll
            for (int off = 32; off; off >>= 1) s += __shfl_down(s, off, 64);
            if ((tid & 63) == 0) red2[tid >> 6] = s;
        }
        __syncthreads();
        if (tid < 128) {
            float inv0 = 1.f / fmaxf(sqrtf(red2[0] + red2[1]), 1e-12f);
            float qv = acc * inv0;
            qout[(((size_t)b * Dc + tid) * Tc + t) * Mc + Nc] = qv;
        }
        return;
    }

    int n0 = blockIdx.x * 64;
    #pragma unroll
    for (int q = 0; q < 8; ++q) {
        int i = q * 256 + tid;
        int nl = i >> 5, d4 = i & 31;
        f32x4 v = {};
        if (n0 + nl < Nc) v = *(const f32x4*)(fbuf + ((size_t)bt * Nc + n0 + nl) * Dc + d4 * 4);
        *(f32x4*)(&lds[nl][d4 * 4]) = v;
    }
    __syncthreads();
    {
        int r = tid & 63, p = tid >> 6;
        float s = 0.f;
        #pragma unroll
        for (int j = 0; j < 32; ++j) { float v = lds[r][p * 32 + j]; s += v * v; }
        nrm[r][p] = s;
    }
    __syncthreads();
    if (tid < 64) inv[tid] = 1.f / fmaxf(sqrtf(nrm[tid][0] + nrm[tid][1] + nrm[tid][2] + nrm[tid][3]), 1e-12f);
    __syncthreads();
    unsigned int* qT32 = (unsigned int*)(qTb + (size_t)bt * Qrows * Dc);
    #pragma unroll
    for (int q = 0; q < 16; ++q) {
        int i = q * 256 + tid;
        int nl = i >> 6, dp = i & 63;
        if (n0 + nl < Nc) {
            float iv = inv[nl];
            unsigned int pk = (unsigned int)f2bf(lds[nl][2 * dp] * iv)
                            | ((unsigned int)f2bf(lds[nl][2 * dp + 1] * iv) << 16);
            qT32[((size_t)(n0 + nl) * Dc >> 1) + dp] = pk;
        }
    }
    int nl = tid & 63;
    if (n0 + nl < Nc) {
        float iv = inv[nl];
        #pragma unroll
        for (int dd = 0; dd < Dc; dd += 4) {
            int d = dd + (tid >> 6);
            qout[(((size_t)b * Dc + d) * Tc + t) * Mc + n0 + nl] = lds[nl][d] * iv;
        }
    }
}

// ---------------- K2: fused affinity — GUARD-FREE hot path ----------------
// Tiles padded to 52 (rows 784..831 of qTb are ZERO): pad tiles give acc==0
// exactly, so rowsum/colsum/entropy need no guards; esum corrected by the
// exact exp(0)=1 count (wave 3 has 3 pad tiles); sweep-3 selects 0 for pad.
__global__ __launch_bounds__(256, 2) void k_affinity(const unsigned short* __restrict__ qTb,
                                                     unsigned short* __restrict__ P12h,
                                                     unsigned short* __restrict__ P21h,
                                                     float* __restrict__ cs12,
                                                     float* __restrict__ cs21,
                                                     float wconst)
{
    constexpr float INVT = 1.0f / TEMP;
    const size_t MMp = (size_t)Pp * Pp;
    __shared__ unsigned short otile[16][840];
    __shared__ float sred[16][4][2];
    __shared__ float rowsum[16], invZ[16], entP[16];

    int f = blockIdx.x;
    int xcd = f & 7, slot = f >> 3;
    int grp = xcd + 8 * (slot / 49);
    int strip = slot % 49;
    int side = grp >= 28 ? 1 : 0;
    int bt = grp - side * 28;
    int b = bt / TM1, t = bt % TM1;
    const unsigned short *Aq, *Bq;
    unsigned short* OUT;
    if (side == 0) {
        Aq = qTb + (size_t)(b * Tc + t)     * Qrows * Dc;
        Bq = qTb + (size_t)(b * Tc + t + 1) * Qrows * Dc;
        OUT = P12h + (size_t)bt * MMp;
    } else {
        Aq = qTb + (size_t)(b * Tc + 7 - t) * Qrows * Dc;
        Bq = qTb + (size_t)(b * Tc + 6 - t) * Qrows * Dc;
        OUT = P21h + (size_t)bt * MMp;
    }
    float* csFlip = (side == 0 ? cs21 : cs12) + (size_t)(b * TM1 + (6 - t)) * Pp;

    const int r0 = strip * 16;
    const int tid = threadIdx.x, lane = tid & 63, w = tid >> 6;
    const int g = lane >> 4, lr = lane & 15;

    // straight-line MFMA: 13 tiles per wave, no guards (pad tiles hit zero rows)
    f32x4 acc[13] = {};
    #pragma unroll
    for (int ks = 0; ks < 4; ++ks) {
        bf16x8 af = __builtin_bit_cast(bf16x8,
            *(const u16x8*)(Aq + (size_t)(r0 + lr) * Dc + ks * 32 + g * 8));
        bf16x8 bfr[13];
        #pragma unroll
        for (int tt = 0; tt < 13; ++tt)
            bfr[tt] = __builtin_bit_cast(bf16x8,
                *(const u16x8*)(Bq + (size_t)((w * 13 + tt) * 16 + lr) * Dc + ks * 32 + g * 8));
        #pragma unroll
        for (int tt = 0; tt < 13; ++tt)
            acc[tt] = __builtin_amdgcn_mfma_f32_16x16x32_bf16(af, bfr[tt], acc[tt], 0, 0, 0);
    }

    // sweep 1: rowsums (pad tiles contribute exactly 0)
    float rs[4] = {0.f, 0.f, 0.f, 0.f};
    #pragma unroll
    for (int tt = 0; tt < 13; ++tt) {
        #pragma unroll
        for (int j = 0; j < 4; ++j) rs[j] += acc[tt][j];
    }
    #pragma unroll
    for (int off = 1; off <= 8; off <<= 1) {
        #pragma unroll
        for (int j = 0; j < 4; ++j) rs[j] += __shfl_xor(rs[j], off, 64);
    }
    if (lr == 0) {
        #pragma unroll
        for (int j = 0; j < 4; ++j) sred[g * 4 + j][w][0] = rs[j];
    }
    __syncthreads();
    if (tid < 16) {
        float r = sred[tid][0][0] + sred[tid][1][0] + sred[tid][2][0] + sred[tid][3][0];
        rowsum[tid] = r;
        csFlip[r0 + tid] = r;
    }
    __syncthreads();

    // sweep 2: exp-sum + entropy (pad: exp(0)=1 -> exact scalar correction; en adds 0)
    float invr[4];
    #pragma unroll
    for (int j = 0; j < 4; ++j) invr[j] = 1.0f / rowsum[g * 4 + j];
    const float padc = (w == 3) ? 3.0f : 0.0f;
    float en[4] = {0.f, 0.f, 0.f, 0.f}, es[4] = {0.f, 0.f, 0.f, 0.f};
    #pragma unroll
    for (int tt = 0; tt < 13; ++tt) {
        #pragma unroll
        for (int j = 0; j < 4; ++j) {
            float a = acc[tt][j];
            float e = __expf(a * INVT);
            es[j] += e;
            float p = a * invr[j];
            en[j] -= p * __logf(fmaxf(p, 1e-20f));
            acc[tt][j] = e;
        }
    }
    #pragma unroll
    for (int j = 0; j < 4; ++j) es[j] -= padc;
    #pragma unroll
    for (int off = 1; off <= 8; off <<= 1) {
        #pragma unroll
        for (int j = 0; j < 4; ++j) {
            es[j] += __shfl_xor(es[j], off, 64);
            en[j] += __shfl_xor(en[j], off, 64);
        }
    }
    if (lr == 0) {
        #pragma unroll
        for (int j = 0; j < 4; ++j) { sred[g * 4 + j][w][0] = es[j]; sred[g * 4 + j][w][1] = en[j]; }
    }
    __syncthreads();
    if (tid < 16) {
        float esum = sred[tid][0][0] + sred[tid][1][0] + sred[tid][2][0] + sred[tid][3][0];
        float ent  = sred[tid][0][1] + sred[tid][1][1] + sred[tid][2][1] + sred[tid][3][1];
        float ez  = __expf(ent * wconst * INVT);
        float Z   = esum + ez;
        float iz  = 1.0f / Z;
        invZ[tid] = iz;
        entP[tid] = ez * iz;
    }
    __syncthreads();

    // sweep 3: normalized probs -> LDS (pad cols select 0; covers cols 784..831)
    float izl[4];
    #pragma unroll
    for (int j = 0; j < 4; ++j) izl[j] = invZ[g * 4 + j];
    #pragma unroll
    for (int tt = 0; tt < 13; ++tt) {
        int gt = w * 13 + tt;
        int col = gt * 16 + lr;
        #pragma unroll
        for (int j = 0; j < 4; ++j) {
            float v = acc[tt][j] * izl[j];
            if (gt >= 49) v = 0.f;
            otile[g * 4 + j][col] = f2bf(v);
        }
    }
    __syncthreads();
    if (tid < 16) otile[tid][784] = f2bf(entP[tid]);
    __syncthreads();

    for (int v = tid; v < 16 * 104; v += 256) {
        int row = v / 104, cv = v % 104;
        *(u16x8*)(OUT + (size_t)(r0 + row) * Pp + cv * 8) = *(const u16x8*)(&otile[row][cv * 8]);
    }
}

// ---------------- K3: dust rows (row 784) + zero pad rows ----------------
__global__ __launch_bounds__(256) void k_dustrow(const float* __restrict__ cs12,
                                                 const float* __restrict__ cs21,
                                                 unsigned short* __restrict__ P12h,
                                                 unsigned short* __restrict__ P21h)
{
    constexpr float INVT = 1.0f / TEMP;
    const size_t MMp = (size_t)Pp * Pp;
    int bt = blockIdx.x, side = blockIdx.y;
    const float* cs = (side ? cs21 : cs12) + (size_t)bt * Pp;
    unsigned short* OUT = (side ? P21h : P12h) + (size_t)bt * MMp;
    __shared__ float sbuf[4];
    int tid = threadIdx.x;
    float v[4];
    #pragma unroll
    for (int k = 0; k < 4; ++k) {
        int j = tid + k * 256;
        float val = -INFINITY;
        if (j < Nc)       val = -cs[j] * INVT;
        else if (j == Nc) val = 0.f;
        v[k] = val;
    }
    float mx = fmaxf(fmaxf(v[0], v[1]), fmaxf(v[2], v[3]));
    mx = blockReduceMax(mx, sbuf);
    float e[4]; float s = 0.f;
    #pragma unroll
    for (int k = 0; k < 4; ++k) {
        int j = tid + k * 256;
        e[k] = (j < Mc) ? __expf(v[k] - mx) : 0.f;
        s += e[k];
    }
    s = blockReduceSum(s, sbuf);
    float invs = 1.f / s;
    #pragma unroll
    for (int k = 0; k < 4; ++k) {
        int j = tid + k * 256;
        if (j < Mc)      OUT[(size_t)Nc * Pp + j] = f2bf(e[k] * invs);
        else if (j < Pp) OUT[(size_t)Nc * Pp + j] = 0;
    }
    u16x8 z = {};
    u16x8* dst = (u16x8*)(OUT + (size_t)785 * Pp);
    for (int i = tid; i < (Pp - 785) * Pp / 8; i += 256) dst[i] = z;
}

// ---------------- K6: merged bf16 transposes (grid z = 0..27) ----------------
__global__ __launch_bounds__(256) void k_transpose_bf16(const unsigned short* __restrict__ P12h,
                                                        const unsigned short* __restrict__ P21h,
                                                        unsigned short* __restrict__ Db)
{
    const size_t MMp = (size_t)Pp * Pp;
    __shared__ unsigned short tile[64][65];
    int z = blockIdx.z;
    const unsigned short* S;
    if (z < 24) { int b = z / 6, tm = z % 6; S = P12h + ((size_t)b * 7 + tm + 1) * MMp; }
    else        { S = P21h + ((size_t)(z - 24) * 7 + 6) * MMp; }
    unsigned short* D = Db + (size_t)z * MMp;
    int x0 = blockIdx.x * 64, y0 = blockIdx.y * 64;
    int tx = threadIdx.x & 63, ty = threadIdx.x >> 6;
    #pragma unroll
    for (int y = 0; y < 64; y += 4) tile[y + ty][tx] = S[(size_t)(y0 + y + ty) * Pp + x0 + tx];
    __syncthreads();
    #pragma unroll
    for (int y = 0; y < 64; y += 4) D[(size_t)(x0 + y + ty) * Pp + y0 + tx] = tile[tx][y + ty];
}

// ---------------- K7: fused chain GEMM (64x128 db tiles) + loss ----------------
struct GJobs {
    const unsigned short* A[2];
    const unsigned short* BT[2];
    unsigned short* Cb[2];
    float* cs[2];
    long long sA[2], sB[2], sC[2];
    const unsigned short* Lr;
    const unsigned short* Rr;
    const float* csL;
    float* loss;
    float scale;
};

__global__ __launch_bounds__(256, 3) void k_gemm_loss(GJobs J)
{
    const size_t MMp = (size_t)Pp * Pp;
    if (blockIdx.x >= 728) {
        int q = blockIdx.x - 728;
        int w = threadIdx.x >> 6, lane = threadIdx.x & 63;
        int r = q * 4 + w;
        int b = r / Mc, i = r % Mc;
        const u16x8* lrow = (const u16x8*)(J.Lr + (size_t)b * MMp + (size_t)i * Pp);
        const u16x8* rrow = (const u16x8*)(J.Rr + (size_t)b * MMp + (size_t)i * Pp);
        const f32x4* cs4  = (const f32x4*)(J.csL + (size_t)b * Pp);
        float sR = 0.f, sD = 0.f;
        for (int c = lane; c < Pp / 8; c += 64) {
            u16x8 lv = lrow[c];
            u16x8 rv = rrow[c];
            f32x4 c0 = cs4[2 * c], c1 = cs4[2 * c + 1];
            #pragma unroll
            for (int k = 0; k < 4; ++k) {
                float fl = bf2f(lv[k]);
                sR += fl * c0[k];
                sD += fl * bf2f(rv[k]);
            }
            #pragma unroll
            for (int k = 0; k < 4; ++k) {
                float fl = bf2f(lv[4 + k]);
                sR += fl * c1[k];
                sD += fl * bf2f(rv[4 + k]);
            }
        }
        #pragma unroll
        for (int off = 1; off <= 32; off <<= 1) {
            sR += __shfl_xor(sR, off, 64);
            sD += __shfl_xor(sD, off, 64);
        }
        if (lane == 0)
            atomicAdd(J.loss, (logf(sR + Mc * 1e-20f) - logf(sD + 1e-20f)) * J.scale);
        return;
    }

    __shared__ __align__(16) unsigned short As0[64 * 64], As1[64 * 64];
    __shared__ __align__(16) unsigned short Bs0[128 * 64], Bs1[128 * 64];

    int f = blockIdx.x;
    int zz = f & 7, slot = f >> 3;
    int job = zz >> 2, b = zz & 3;
    const unsigned short* A  = J.A[job]  + (size_t)b * J.sA[job];
    const unsigned short* BT = J.BT[job] + (size_t)b * J.sB[job];

    const int i0 = (slot / 7) * 64, j0 = (slot % 7) * 128;
    const int tid = threadIdx.x, lane = tid & 63, wv = tid >> 6;
    const int g = lane >> 4, lr = lane & 15;

    f32x4 acc[4][2] = {};
    gemm64x128_db<Pp>(A, BT, As0, As1, Bs0, Bs1, i0, j0, tid, acc);

    unsigned short* Co = J.Cb[job] + (size_t)b * J.sC[job];
    float* csp = J.cs[job];
    float csacc[2] = {0.f, 0.f};
    #pragma unroll
    for (int m = 0; m < 4; ++m)
        #pragma unroll
        for (int n = 0; n < 2; ++n)
            #pragma unroll
            for (int j = 0; j < 4; ++j) {
                int row = i0 + m * 16 + g * 4 + j;
                int col = j0 + wv * 32 + n * 16 + lr;
                if (col < Pp) {
                    unsigned short h = f2bf(acc[m][n][j]);
                    Co[(size_t)row * Pp + col] = h;
                    csacc[n] += bf2f(h);
                }
            }
    if (csp) {
        csp += (size_t)b * Pp;
        #pragma unroll
        for (int n = 0; n < 2; ++n) {
            float p = csacc[n];
            p += __shfl_xor(p, 16, 64);
            p += __shfl_xor(p, 32, 64);
            int col = j0 + wv * 32 + n * 16 + lr;
            if (g == 0 && col < Pp) atomicAdd(&csp[col], p);
        }
    }
}

// ---------------- K8: standalone loss rows (final step) ----------------
__global__ __launch_bounds__(64) void k_lossrow(const unsigned short* __restrict__ L,
                                                const unsigned short* __restrict__ R,
                                                const float* __restrict__ csR,
                                                float* __restrict__ loss, float scale)
{
    const size_t MMp = (size_t)Pp * Pp;
    int r = blockIdx.x;
    int b = r / Mc, i = r % Mc;
    const u16x8* lrow = (const u16x8*)(L + (size_t)b * MMp + (size_t)i * Pp);
    const u16x8* rrow = (const u16x8*)(R + (size_t)b * MMp + (size_t)i * Pp);
    const f32x4* cs4  = (const f32x4*)(csR + (size_t)b * Pp);
    int lane = threadIdx.x;
    float sR = 0.f, sD = 0.f;
    for (int c = lane; c < Pp / 8; c += 64) {
        u16x8 lv = lrow[c];
        u16x8 rv = rrow[c];
        f32x4 c0 = cs4[2 * c], c1 = cs4[2 * c + 1];
        #pragma unroll
        for (int k = 0; k < 4; ++k) {
            float fl = bf2f(lv[k]);
            sR += fl * c0[k];
            sD += fl * bf2f(rv[k]);
        }
        #pragma unroll
        for (int k = 0; k < 4; ++k) {
            float fl = bf2f(lv[4 + k]);
            sR += fl * c1[k];
            sD += fl * bf2f(rv[4 + k]);
        }
    }
    #pragma unroll
    for (int off = 1; off <= 32; off <<= 1) {
        sR += __shfl_xor(sR, off, 64);
        sD += __shfl_xor(sD, off, 64);
    }
    if (lane == 0)
        atomicAdd(loss, (logf(sR + Mc * 1e-20f) - logf(sD + 1e-20f)) * scale);
}

// ---------------- host orchestration ----------------
extern "C" void kernel_launch(void* const* d_in, const int* in_sizes, int n_in,
                              void* d_out, int out_size, void* d_ws, size_t ws_size,
                              hipStream_t stream)
{
    const float* feats = (const float*)d_in[0];
    const float* dust  = (const float*)d_in[1];
    const float* Wself = (const float*)d_in[2];
    const float* bself = (const float*)d_in[3];
    const float* Wdust = (const float*)d_in[4];
    const float* bdust = (const float*)d_in[5];

    float* out  = (float*)d_out;
    float* qout = out;
    float* loss = out + (size_t)Bc * Dc * Tc * Mc;

    const size_t MMp = (size_t)Pp * Pp;       // 692,224

    // ---- workspace ----
    float* ws = (float*)d_ws;
    float* csR = ws;                                                // 6 slots * Bc * Pp fp32
    unsigned short* P12h = (unsigned short*)(ws + 4 * MMp);         // 28*MMp bf16
    unsigned short* P21h = P12h + (size_t)28 * MMp;                 // 28*MMp bf16
    unsigned short* chainT = P21h + (size_t)28 * MMp;               // 44*MMp bf16 region
    unsigned short* P12T  = chainT;
    unsigned short* P21T6 = P12T + (size_t)24 * MMp;
    unsigned short* l0    = P21T6 + (size_t)4 * MMp;
    unsigned short* l1    = l0 + (size_t)4 * MMp;
    unsigned short* R0    = l1 + (size_t)4 * MMp;
    unsigned short* R1    = R0 + (size_t)4 * MMp;
    unsigned short* qTb   = R1 + (size_t)4 * MMp;                   // 32*Qrows*Dc bf16
    float* cs12 = (float*)(qTb + (size_t)32 * Qrows * Dc);          // 28*Pp fp32
    float* cs21 = cs12 + (size_t)28 * Pp;                           // 28*Pp fp32

    // phase-1 overlays in chainT region:
    unsigned short* Abf   = chainT;
    unsigned int*   Abf32 = (unsigned int*)Abf;
    unsigned short* WTb   = Abf + (size_t)Bc * Tc * Nc * Cc;
    float*          fbuf  = (float*)(WTb + 2 * (size_t)Dc * Cc);

    // 1. pack inputs (+W pack +zero roles incl. qTb pad rows)
    k_pack<<<Bc * Nc + 32 + 8, 256, 0, stream>>>(feats, Wself, Wdust, Abf32, WTb, qTb, csR, loss);
    // 2. projection GEMM + bias (64x128 tiles)
    k_gemm_proj<<<392, 256, 0, stream>>>(Abf, WTb, bself, fbuf);
    // 3. norms (+dust projection role; qTb row 784 stays zero)
    k_norm<<<dim3(14, 32), 256, 0, stream>>>(fbuf, dust, Wdust, bdust, qTb, qout);
    // 4. fused affinity (guard-free), then dust rows
    float wconst = (float)(1.0 / log(784.0));
    k_affinity<<<2744, 256, 0, stream>>>(qTb, P12h, P21h, cs12, cs21, wconst);
    k_dustrow<<<dim3(28, 2), 256, 0, stream>>>(cs12, cs21, P12h, P21h);
    // 5. merged bf16 transposes
    k_transpose_bf16<<<dim3(13, 13, 28), 256, 0, stream>>>(P12h, P21h, P12T);

    // 6. chain
    const float scale = 1.0f / (6.0f * Bc * Mc);

    {
        GJobs J = {};
        J.A[0] = P12h;  J.sA[0] = (long long)7 * MMp;
        J.BT[0] = P12T; J.sB[0] = (long long)6 * MMp;
        J.Cb[0] = l0;   J.sC[0] = (long long)MMp; J.cs[0] = nullptr;
        J.A[1] = P21T6;                   J.sA[1] = (long long)MMp;
        J.BT[1] = P21h + (size_t)5 * MMp; J.sB[1] = (long long)7 * MMp;
        J.Cb[1] = R0;   J.sC[1] = (long long)MMp; J.cs[1] = csR;   // slot 0
        k_gemm_loss<<<728, 256, 0, stream>>>(J);
    }

    unsigned short *lcur = l0, *lnxt = l1, *rcur = R0, *rnxt = R1;
    for (int i = 1; i <= 5; ++i) {
        GJobs J = {};
        J.A[0] = lcur; J.sA[0] = (long long)MMp;
        J.BT[0] = P12T + (size_t)i * MMp; J.sB[0] = (long long)6 * MMp;
        J.Cb[0] = lnxt; J.sC[0] = (long long)MMp; J.cs[0] = nullptr;
        J.A[1] = rcur; J.sA[1] = (long long)MMp;
        J.BT[1] = P21h + (size_t)(5 - i) * MMp; J.sB[1] = (long long)7 * MMp;
        J.Cb[1] = rnxt; J.sC[1] = (long long)MMp; J.cs[1] = csR + (size_t)i * Bc * Pp;
        J.Lr = lcur; J.Rr = rcur; J.csL = csR + (size_t)(i - 1) * Bc * Pp;
        J.loss = loss; J.scale = scale;
        k_gemm_loss<<<728 + 785, 256, 0, stream>>>(J);
        unsigned short* t;
        t = lcur; lcur = lnxt; lnxt = t;
        t = rcur; rcur = rnxt; rnxt = t;
    }
    // final loss (state 6)
    k_lossrow<<<Bc * Mc, 64, 0, stream>>>(lcur, rcur, csR + (size_t)5 * Bc * Pp, loss, scale);
}